// Round 7
// baseline (1714.419 us; speedup 1.0000x reference)
//
#include <hip/hip_runtime.h>
#include <math.h>

#define HH 200
#define WW 200
#define HWP 40000
#define NP4 10000
#define BB 4

#define LKS 40   // lkconv LDS row stride
#define DPS 24   // dwproj/conv3 LDS row stride
#define PARTSZ 2560000   // one (B,16,H,W) partial buffer

__device__ __forceinline__ float gelu_f(float x) {
    return 0.5f * x * (1.0f + erff(x * 0.7071067811865475f));
}

// ---------------- weight prep (transposes for scalar weight loads) ----------------
// wt layout offsets (floats):
//  0      wtP   (64,128)   proj_p
//  8192   wtAO  (64,64)    attn_out
//  12288  wtFP0 (64,80)    ffn_p[0]
//  17408  wtFP1 (64,80)    ffn_p[1]
//  22528  wtPA  (128,64)   proj_a
//  30720  wtFA0 (80,64)    ffn_a[0]
//  35840  wtFA1 (80,64)    ffn_a[1]
//  40960  wtPC0 (64,64)    pconv[0]
//  45056  wtPC1 (64,64)    pconv[1]
//  49152  wt3   (64,9,64)  conv_out  [ci][tap][co]
//  86016  wtQKV (64,192)   qkv
__device__ __forceinline__ void tr_w(const float* __restrict__ w, float* __restrict__ wt,
                                     int Co, int Ci, int idx) {
    int o = idx / Ci, c = idx - o * Ci;
    wt[c * Co + o] = w[idx];
}

__global__ __launch_bounds__(256) void prep_kernel(
    const float* __restrict__ pp, const float* __restrict__ ao,
    const float* __restrict__ fp, const float* __restrict__ pa,
    const float* __restrict__ fa, const float* __restrict__ pc,
    const float* __restrict__ co3, const float* __restrict__ qkvw,
    float* __restrict__ wt)
{
    int i = blockIdx.x * 256 + threadIdx.x;
    if (i < 8192) { tr_w(pp, wt + 0, 128, 64, i); return; } i -= 8192;
    if (i < 4096) { tr_w(ao, wt + 8192, 64, 64, i); return; } i -= 4096;
    if (i < 5120) { tr_w(fp, wt + 12288, 80, 64, i); return; } i -= 5120;
    if (i < 5120) { tr_w(fp + 5120, wt + 17408, 80, 64, i); return; } i -= 5120;
    if (i < 8192) { tr_w(pa, wt + 22528, 64, 128, i); return; } i -= 8192;
    if (i < 5120) { tr_w(fa, wt + 30720, 64, 80, i); return; } i -= 5120;
    if (i < 5120) { tr_w(fa + 5120, wt + 35840, 64, 80, i); return; } i -= 5120;
    if (i < 4096) { tr_w(pc, wt + 40960, 64, 64, i); return; } i -= 4096;
    if (i < 4096) { tr_w(pc + 4096, wt + 45056, 64, 64, i); return; } i -= 4096;
    if (i < 36864) {
        int o = i / 576; int r = i - o * 576; int c = r / 9; int t = r - c * 9;
        wt[49152 + (c * 9 + t) * 64 + o] = co3[i];
        return;
    } i -= 36864;
    if (i < 12288) { tr_w(qkvw, wt + 86016, 192, 64, i); return; }
}

// ---------------- LayerNorm over 64 channels ----------------
__global__ __launch_bounds__(256, 2) void ln_kernel(
    const float* __restrict__ in, const float* __restrict__ w,
    const float* __restrict__ b, float* __restrict__ out)
{
    int p = blockIdx.x * 256 + threadIdx.x;
    int bb = blockIdx.y;
    if (p >= HWP) return;
    const float* ib = in + (size_t)bb * 64 * HWP + p;
    float v[64];
    float mu = 0.f;
#pragma unroll
    for (int c = 0; c < 64; ++c) { v[c] = ib[(size_t)c * HWP]; mu += v[c]; }
    mu *= (1.f / 64.f);
    float var = 0.f;
#pragma unroll
    for (int c = 0; c < 64; ++c) { float d = v[c] - mu; var += d * d; }
    var *= (1.f / 64.f);
    float r = rsqrtf(var + 1e-6f);
    float* ob = out + (size_t)bb * 64 * HWP + p;
#pragma unroll
    for (int c = 0; c < 64; ++c) ob[(size_t)c * HWP] = (v[c] - mu) * r * w[c] + b[c];
}

// ---------------- 1x1 conv: float4 pixels, 16 outputs/thread, scalar weights ----------------
__global__ __launch_bounds__(256, 2) void conv1x1_kernel(
    const float* __restrict__ in, const float* __restrict__ wt,  // (Ci,Co)
    const float* __restrict__ bias, float* __restrict__ out,
    int Ci, int Co, int do_gelu, int do_add)
{
    int p4 = blockIdx.x * 256 + threadIdx.x;
    int o0 = blockIdx.y * 16;
    int bb = blockIdx.z;
    if (p4 >= NP4) return;
    float4 acc[16];
#pragma unroll
    for (int j = 0; j < 16; ++j) {
        float bv = bias[o0 + j];
        acc[j] = make_float4(bv, bv, bv, bv);
    }
    const float4* ib = (const float4*)(in + (size_t)bb * Ci * HWP) + p4;
    for (int c = 0; c < Ci; ++c) {
        float4 xv = ib[(size_t)c * NP4];
        const float* wr = wt + c * Co + o0;
#pragma unroll
        for (int j = 0; j < 16; ++j) {
            float w = wr[j];
            acc[j].x += xv.x * w; acc[j].y += xv.y * w;
            acc[j].z += xv.z * w; acc[j].w += xv.w * w;
        }
    }
    float4* ob = (float4*)(out + ((size_t)bb * Co + o0) * HWP) + p4;
#pragma unroll
    for (int j = 0; j < 16; ++j) {
        float4 r = acc[j];
        if (do_gelu) {
            r.x = gelu_f(r.x); r.y = gelu_f(r.y); r.z = gelu_f(r.z); r.w = gelu_f(r.w);
        }
        if (do_add) {
            float4 old = ob[(size_t)j * NP4];
            r.x += old.x; r.y += old.y; r.z += old.z; r.w += old.w;
        }
        ob[(size_t)j * NP4] = r;
    }
}

// ------- fused: gelu(dwconv3x3(in)) + in, then 1x1 proj (Ci -> 32 of 64), co-split -------
// grid (13,13,B*2); z -> bb = z>>1, half = z&1 (output channels half*32 .. half*32+31)
__global__ __launch_bounds__(256, 4) void dwproj_kernel(
    const float* __restrict__ in,   // (B,Ci,H,W)
    const float* __restrict__ dw,   // (Ci,9)
    const float* __restrict__ db,   // (Ci)
    const float* __restrict__ awt,  // (Ci,64) transposed
    const float* __restrict__ ab,   // (64)
    float* __restrict__ out,        // (B,64,H,W)
    int Ci)
{
    __shared__ float s_p[16][18 * DPS];
    int tid = threadIdx.x;
    int tx = tid & 15, ty = tid >> 4;
    int x0 = blockIdx.x * 16, y0 = blockIdx.y * 16;
    int bb = blockIdx.z >> 1, half = blockIdx.z & 1;
    int oo = half * 32;
    int x = x0 + tx, y = y0 + ty;

    float acc[32];
#pragma unroll
    for (int o = 0; o < 32; ++o) acc[o] = ab[oo + o];

    const float* ibase = in + (size_t)bb * Ci * HWP;
    for (int c0 = 0; c0 < Ci; c0 += 16) {
        __syncthreads();
        for (int i = tid; i < 16 * 324; i += 256) {
            int ci = i / 324; int r = i - ci * 324;
            int py = r / 18, px = r - py * 18;
            int yy = y0 + py - 1, xx = x0 + px - 1;
            float v = 0.f;
            if ((unsigned)yy < HH && (unsigned)xx < WW)
                v = ibase[(size_t)(c0 + ci) * HWP + yy * WW + xx];
            s_p[ci][py * DPS + px] = v;
        }
        __syncthreads();
        for (int ci = 0; ci < 16; ++ci) {
            int c = c0 + ci;
            float s = db[c];
            const float* dwr = dw + c * 9;
#pragma unroll
            for (int ky = 0; ky < 3; ++ky)
#pragma unroll
                for (int kx = 0; kx < 3; ++kx)
                    s += s_p[ci][(ty + ky) * DPS + tx + kx] * dwr[ky * 3 + kx];
            float v = gelu_f(s) + s_p[ci][(ty + 1) * DPS + tx + 1];
            const float* wr = awt + c * 64 + oo;
#pragma unroll
            for (int o = 0; o < 32; ++o) acc[o] += v * wr[o];
        }
    }

    if (x < WW && y < HH) {
        int p = y * WW + x;
        float* ob = out + ((size_t)bb * 64 + oo) * HWP + p;
#pragma unroll
        for (int o = 0; o < 32; ++o) ob[(size_t)o * HWP] = acc[o];
    }
}

// ---------------- attention v2: qkv precomputed; one block = (window, head) ----------------
__global__ __launch_bounds__(128) void winattn2_kernel(
    const float* __restrict__ qkv,  // (B,192,H,W)
    const float* __restrict__ rpb,  // (8,361)
    float* __restrict__ out)        // (B,64,H,W)
{
    __shared__ __align__(16) float s_k[100][8];
    __shared__ __align__(16) float s_v[100][8];
    __shared__ float s_b[361];

    int head = blockIdx.y, bb = blockIdx.z;
    int wy = blockIdx.x / 20, wx = blockIdx.x - wy * 20;
    int tid = threadIdx.x;

    for (int i = tid; i < 361; i += 128) s_b[i] = rpb[head * 361 + i];

    int ty = tid / 10, tx = tid - ty * 10;
    float q[8];
    if (tid < 100) {
        int y = wy * 10 + ty, x = wx * 10 + tx;
        int gp = y * WW + x;
        const float* qb = qkv + ((size_t)bb * 192 + head * 8) * HWP + gp;
        const float* kb = qb + (size_t)64 * HWP;
        const float* vb = qb + (size_t)128 * HWP;
#pragma unroll
        for (int cc = 0; cc < 8; ++cc) q[cc] = qb[(size_t)cc * HWP];
        float4 t0, t1;
        t0.x = kb[0];               t0.y = kb[(size_t)1 * HWP];
        t0.z = kb[(size_t)2 * HWP]; t0.w = kb[(size_t)3 * HWP];
        t1.x = kb[(size_t)4 * HWP]; t1.y = kb[(size_t)5 * HWP];
        t1.z = kb[(size_t)6 * HWP]; t1.w = kb[(size_t)7 * HWP];
        *(float4*)(&s_k[tid][0]) = t0;
        *(float4*)(&s_k[tid][4]) = t1;
        t0.x = vb[0];               t0.y = vb[(size_t)1 * HWP];
        t0.z = vb[(size_t)2 * HWP]; t0.w = vb[(size_t)3 * HWP];
        t1.x = vb[(size_t)4 * HWP]; t1.y = vb[(size_t)5 * HWP];
        t1.z = vb[(size_t)6 * HWP]; t1.w = vb[(size_t)7 * HWP];
        *(float4*)(&s_v[tid][0]) = t0;
        *(float4*)(&s_v[tid][4]) = t1;
    }
    __syncthreads();

    if (tid < 100) {
        const float scale = 0.3535533905932738f; // 1/sqrt(8)
        const float4* k4 = (const float4*)s_k;
        const float4* v4 = (const float4*)s_v;
        float m = -1e30f;
        {
            int ky = 0, kx = 0;
            for (int kk = 0; kk < 100; ++kk) {
                float4 ka = k4[kk * 2], kb = k4[kk * 2 + 1];
                float s = q[0] * ka.x + q[1] * ka.y + q[2] * ka.z + q[3] * ka.w
                        + q[4] * kb.x + q[5] * kb.y + q[6] * kb.z + q[7] * kb.w;
                s = s * scale + s_b[(ky - ty + 9) * 19 + (kx - tx + 9)];
                m = fmaxf(m, s);
                if (++kx == 10) { kx = 0; ++ky; }
            }
        }
        float l = 0.f;
        float o[8];
#pragma unroll
        for (int cc = 0; cc < 8; ++cc) o[cc] = 0.f;
        {
            int ky = 0, kx = 0;
            for (int kk = 0; kk < 100; ++kk) {
                float4 ka = k4[kk * 2], kb = k4[kk * 2 + 1];
                float s = q[0] * ka.x + q[1] * ka.y + q[2] * ka.z + q[3] * ka.w
                        + q[4] * kb.x + q[5] * kb.y + q[6] * kb.z + q[7] * kb.w;
                s = s * scale + s_b[(ky - ty + 9) * 19 + (kx - tx + 9)];
                float e = __expf(s - m);
                l += e;
                float4 va = v4[kk * 2], vb = v4[kk * 2 + 1];
                o[0] += e * va.x; o[1] += e * va.y; o[2] += e * va.z; o[3] += e * va.w;
                o[4] += e * vb.x; o[5] += e * vb.y; o[6] += e * vb.z; o[7] += e * vb.w;
                if (++kx == 10) { kx = 0; ++ky; }
            }
        }
        float rl = 1.f / l;
        int y = wy * 10 + ty, x = wx * 10 + tx;
        float* ob = out + ((size_t)bb * 64 + head * 8) * HWP + y * WW + x;
#pragma unroll
        for (int cc = 0; cc < 8; ++cc) ob[(size_t)cc * HWP] = o[cc] * rl;
    }
}

// ---------------- attention v1 (fallback, fused qkv) ----------------
__global__ __launch_bounds__(128) void winattn_kernel(
    const float* __restrict__ xin, const float* __restrict__ qkvw,
    const float* __restrict__ qkvb, const float* __restrict__ rpb,
    float* __restrict__ out)
{
    __shared__ __align__(16) float s_wq[8][64];
    __shared__ __align__(16) float s_wk[8][64];
    __shared__ __align__(16) float s_wv[8][64];
    __shared__ __align__(16) float s_k[100][8];
    __shared__ __align__(16) float s_v[100][8];
    __shared__ float s_b[361];

    int head = blockIdx.y, bb = blockIdx.z;
    int wy = blockIdx.x / 20, wx = blockIdx.x - wy * 20;
    int tid = threadIdx.x;

    for (int i = tid; i < 8 * 64; i += 128) {
        (&s_wq[0][0])[i] = qkvw[(head * 8) * 64 + i];
        (&s_wk[0][0])[i] = qkvw[(64 + head * 8) * 64 + i];
        (&s_wv[0][0])[i] = qkvw[(128 + head * 8) * 64 + i];
    }
    for (int i = tid; i < 361; i += 128) s_b[i] = rpb[head * 361 + i];
    __syncthreads();

    float q[8];
    int ty = tid / 10, tx = tid - ty * 10;
    if (tid < 100) {
        int y = wy * 10 + ty, x = wx * 10 + tx;
        const float* xb = xin + (size_t)bb * 64 * HWP + y * WW + x;
        float xr[64];
#pragma unroll
        for (int c = 0; c < 64; ++c) xr[c] = xb[(size_t)c * HWP];
#pragma unroll
        for (int cc = 0; cc < 8; ++cc) {
            float aq = qkvb[head * 8 + cc];
            float ak = qkvb[64 + head * 8 + cc];
            float av = qkvb[128 + head * 8 + cc];
#pragma unroll
            for (int c = 0; c < 64; ++c) {
                float xv = xr[c];
                aq += xv * s_wq[cc][c];
                ak += xv * s_wk[cc][c];
                av += xv * s_wv[cc][c];
            }
            q[cc] = aq;
            s_k[tid][cc] = ak;
            s_v[tid][cc] = av;
        }
    }
    __syncthreads();

    if (tid < 100) {
        const float scale = 0.3535533905932738f;
        const float4* k4 = (const float4*)s_k;
        const float4* v4 = (const float4*)s_v;
        float m = -1e30f;
        {
            int ky = 0, kx = 0;
            for (int kk = 0; kk < 100; ++kk) {
                float4 ka = k4[kk * 2], kb = k4[kk * 2 + 1];
                float s = q[0] * ka.x + q[1] * ka.y + q[2] * ka.z + q[3] * ka.w
                        + q[4] * kb.x + q[5] * kb.y + q[6] * kb.z + q[7] * kb.w;
                s = s * scale + s_b[(ky - ty + 9) * 19 + (kx - tx + 9)];
                m = fmaxf(m, s);
                if (++kx == 10) { kx = 0; ++ky; }
            }
        }
        float l = 0.f;
        float o[8];
#pragma unroll
        for (int cc = 0; cc < 8; ++cc) o[cc] = 0.f;
        {
            int ky = 0, kx = 0;
            for (int kk = 0; kk < 100; ++kk) {
                float4 ka = k4[kk * 2], kb = k4[kk * 2 + 1];
                float s = q[0] * ka.x + q[1] * ka.y + q[2] * ka.z + q[3] * ka.w
                        + q[4] * kb.x + q[5] * kb.y + q[6] * kb.z + q[7] * kb.w;
                s = s * scale + s_b[(ky - ty + 9) * 19 + (kx - tx + 9)];
                float e = __expf(s - m);
                l += e;
                float4 va = v4[kk * 2], vb = v4[kk * 2 + 1];
                o[0] += e * va.x; o[1] += e * va.y; o[2] += e * va.z; o[3] += e * va.w;
                o[4] += e * vb.x; o[5] += e * vb.y; o[6] += e * vb.z; o[7] += e * vb.w;
                if (++kx == 10) { kx = 0; ++ky; }
            }
        }
        float rl = 1.f / l;
        int y = wy * 10 + ty, x = wx * 10 + tx;
        float* ob = out + ((size_t)bb * 64 + head * 8) * HWP + y * WW + x;
#pragma unroll
        for (int cc = 0; cc < 8; ++cc) ob[(size_t)cc * HWP] = o[cc] * rl;
    }
}

// ------- geometric ensemble -> D4-orbit weight table (ci, rep, co) -------
__global__ __launch_bounds__(256) void geo_kernel(
    const float* __restrict__ k, float* __restrict__ out)
{
    int i = blockIdx.x * 256 + threadIdx.x;
    if (i >= 256 * 28) return;
    int oc = i / 28, rep = i - oc * 28;   // oc = co*16 + ci
    int co = oc >> 4, ci = oc & 15;
    int a = 0, r = rep;
    while (r >= 7 - a) { r -= 7 - a; ++a; }
    int b2 = a + r;
    int y = 6 + a, x = 6 + b2;
    const float* kb = k + oc * 169;
    float s = kb[y * 13 + x] + kb[y * 13 + (12 - x)] + kb[(12 - y) * 13 + x] + kb[(12 - y) * 13 + (12 - x)]
            + kb[(12 - x) * 13 + y] + kb[x * 13 + y] + kb[(12 - x) * 13 + (12 - y)] + kb[x * 13 + (12 - y)];
    out[(ci * 28 + rep) * 16 + co] = s * 0.125f;
}

// ---------------- global mean over H,W of first-16 channels ----------------
__global__ __launch_bounds__(256) void gmean_kernel(
    const float* __restrict__ in, float* __restrict__ g)
{
    int bc = blockIdx.x;            // b*16 + c
    int bb = bc >> 4, c = bc & 15;
    const float* p = in + ((size_t)bb * 64 + c) * HWP;
    float s = 0.f;
    for (int i = threadIdx.x; i < HWP; i += 256) s += p[i];
#pragma unroll
    for (int off = 32; off > 0; off >>= 1) s += __shfl_down(s, off);
    __shared__ float red[4];
    int wave = threadIdx.x >> 6;
    if ((threadIdx.x & 63) == 0) red[wave] = s;
    __syncthreads();
    if (threadIdx.x == 0)
        g[bc] = (red[0] + red[1] + red[2] + red[3]) * (1.f / 40000.f);
}

// ---------------- tiny MLP -> dynamic 3x3 kernels ----------------
__global__ __launch_bounds__(192) void dynk_kernel(
    const float* __restrict__ g, const float* __restrict__ w1, const float* __restrict__ b1,
    const float* __restrict__ w2, const float* __restrict__ b2, float* __restrict__ dk)
{
    int bb = blockIdx.x;
    __shared__ float s_g2[8];
    int tid = threadIdx.x;
    if (tid < 8) {
        float a = b1[tid];
        for (int c = 0; c < 16; ++c) a += w1[tid * 16 + c] * g[bb * 16 + c];
        s_g2[tid] = gelu_f(a);
    }
    __syncthreads();
    if (tid < 144) {
        float a = b2[tid];
#pragma unroll
        for (int i = 0; i < 8; ++i) a += w2[tid * 8 + i] * s_g2[i];
        dk[bb * 144 + tid] = a;
    }
}

// ------- 13x13 D4-symmetric conv via 28 orbit sums + dynamic depthwise 3x3 -------
// 4-way ci-split: grid (13,13,B*4); z -> bb = z>>2, q = z&3; ci range [q*4, q*4+4).
// Each quarter writes its partial (B,16,H,W) to out + q*PARTSZ; pconv sums the 4.
__global__ __launch_bounds__(256, 4) void lkconv_kernel(
    const float* __restrict__ in,   // (B,64,H,W) — channels 0..15 used
    const float* __restrict__ lkO,  // (16,28,16)  [ci][rep][co]
    const float* __restrict__ dk,   // (B,144)
    float* __restrict__ out)        // 4 partial buffers, stride PARTSZ
{
    __shared__ float s_p[4][28 * LKS];  // 17.9 KB
    int z = blockIdx.z;
    int bb = z >> 2, q = z & 3;
    int tid = threadIdx.x;
    int tx = tid & 15, ty = tid >> 4;
    int x0 = blockIdx.x * 16, y0 = blockIdx.y * 16;
    int x = x0 + tx, y = y0 + ty;

    const float* ibase = in + ((size_t)bb * 64 + q * 4) * HWP;
    for (int i = tid; i < 4 * 784; i += 256) {
        int ci = i / 784; int r = i - ci * 784;
        int py = r / 28, px = r - py * 28;
        int yy = y0 + py - 6, xx = x0 + px - 6;
        float v = 0.f;
        if ((unsigned)yy < HH && (unsigned)xx < WW)
            v = ibase[(size_t)ci * HWP + yy * WW + xx];
        s_p[ci][py * LKS + px] = v;
    }
    __syncthreads();

    float acc[16];
#pragma unroll
    for (int co = 0; co < 16; ++co) acc[co] = 0.f;

#pragma unroll
    for (int ci4 = 0; ci4 < 4; ++ci4) {
        int ci = q * 4 + ci4;
        // D4 orbit sums: 28 buckets, static indexing via full unroll
        float orb[28];
#pragma unroll
        for (int o = 0; o < 28; ++o) orb[o] = 0.f;
#pragma unroll
        for (int ky = 0; ky < 13; ++ky) {
#pragma unroll
            for (int kx = 0; kx < 13; ++kx) {
                const int a = (ky < 6) ? (6 - ky) : (ky - 6);
                const int b = (kx < 6) ? (6 - kx) : (kx - 6);
                const int lo = (a < b) ? a : b;
                const int hi = (a < b) ? b : a;
                const int idx = lo * 7 - (lo * (lo - 1)) / 2 + (hi - lo);
                orb[idx] += s_p[ci4][(ty + ky) * LKS + tx + kx];
            }
        }
        const float* wci = lkO + ci * 28 * 16;
#pragma unroll
        for (int o = 0; o < 28; ++o) {
            float ov = orb[o];
            const float* wr = wci + o * 16;
#pragma unroll
            for (int co = 0; co < 16; ++co) acc[co] += ov * wr[co];
        }
        // dynamic depthwise 3x3 contributes to output channel == ci
        float d = 0.f;
        const float* dkr = dk + bb * 144 + ci * 9;
#pragma unroll
        for (int dy = 0; dy < 3; ++dy)
#pragma unroll
            for (int dx = 0; dx < 3; ++dx)
                d += s_p[ci4][(ty + 5 + dy) * LKS + tx + 5 + dx] * dkr[dy * 3 + dx];
#pragma unroll
        for (int co = 0; co < 16; ++co) acc[co] += (co == ci) ? d : 0.f;
    }

    if (x < WW && y < HH) {
        int p = y * WW + x;
        float* ob = out + (size_t)q * PARTSZ + (size_t)bb * 16 * HWP + p;
#pragma unroll
        for (int co = 0; co < 16; ++co) ob[(size_t)co * HWP] = acc[co];
    }
}

// ------- 1x1 conv over concat(sum of 4 x1 partials, y[16..63]) and add into xout -------
__global__ __launch_bounds__(256, 2) void pconv_add_kernel(
    const float* __restrict__ x1q,  // 4 partial buffers, stride PARTSZ
    const float* __restrict__ yy,
    const float* __restrict__ wt, const float* __restrict__ bias,
    float* __restrict__ xout)
{
    int p4 = blockIdx.x * 256 + threadIdx.x;
    int o0 = blockIdx.y * 16;
    int bb = blockIdx.z;
    if (p4 >= NP4) return;
    float4 acc[16];
#pragma unroll
    for (int j = 0; j < 16; ++j) {
        float bv = bias[o0 + j];
        acc[j] = make_float4(bv, bv, bv, bv);
    }
    const float4* xb0 = (const float4*)(x1q + (size_t)bb * 16 * HWP) + p4;
    const float4* xb1 = (const float4*)(x1q + PARTSZ + (size_t)bb * 16 * HWP) + p4;
    const float4* xb2 = (const float4*)(x1q + 2 * PARTSZ + (size_t)bb * 16 * HWP) + p4;
    const float4* xb3 = (const float4*)(x1q + 3 * PARTSZ + (size_t)bb * 16 * HWP) + p4;
    for (int c = 0; c < 16; ++c) {
        float4 a0 = xb0[(size_t)c * NP4], a1 = xb1[(size_t)c * NP4];
        float4 a2 = xb2[(size_t)c * NP4], a3 = xb3[(size_t)c * NP4];
        float4 xv;
        xv.x = (a0.x + a1.x) + (a2.x + a3.x);
        xv.y = (a0.y + a1.y) + (a2.y + a3.y);
        xv.z = (a0.z + a1.z) + (a2.z + a3.z);
        xv.w = (a0.w + a1.w) + (a2.w + a3.w);
        const float* wr = wt + c * 64 + o0;
#pragma unroll
        for (int j = 0; j < 16; ++j) {
            float w = wr[j];
            acc[j].x += xv.x * w; acc[j].y += xv.y * w;
            acc[j].z += xv.z * w; acc[j].w += xv.w * w;
        }
    }
    const float4* yb = (const float4*)(yy + ((size_t)bb * 64 + 16) * HWP) + p4;
    for (int c = 0; c < 48; ++c) {
        float4 xv = yb[(size_t)c * NP4];
        const float* wr = wt + (16 + c) * 64 + o0;
#pragma unroll
        for (int j = 0; j < 16; ++j) {
            float w = wr[j];
            acc[j].x += xv.x * w; acc[j].y += xv.y * w;
            acc[j].z += xv.z * w; acc[j].w += xv.w * w;
        }
    }
    float4* ob = (float4*)(xout + ((size_t)bb * 64 + o0) * HWP) + p4;
#pragma unroll
    for (int j = 0; j < 16; ++j) {
        float4 old = ob[(size_t)j * NP4];
        old.x += acc[j].x; old.y += acc[j].y; old.z += acc[j].z; old.w += acc[j].w;
        ob[(size_t)j * NP4] = old;
    }
}

// ---------------- final 3x3 conv (64->64) + bias + skip, co-split ----------------
// grid (13,13,B*2); z -> bb = z>>1, half = z&1 (output channels half*32 ..)
__global__ __launch_bounds__(256, 4) void conv3_skip_kernel(
    const float* __restrict__ in, const float* __restrict__ wt3,  // (ci,tap,64)
    const float* __restrict__ bias, const float* __restrict__ skip,
    float* __restrict__ out)
{
    __shared__ float s_p[16][18 * DPS];
    int tid = threadIdx.x;
    int tx = tid & 15, ty = tid >> 4;
    int x0 = blockIdx.x * 16, y0 = blockIdx.y * 16;
    int bb = blockIdx.z >> 1, half = blockIdx.z & 1;
    int oo = half * 32;
    int x = x0 + tx, y = y0 + ty;

    float acc[32];
#pragma unroll
    for (int o = 0; o < 32; ++o) acc[o] = bias[oo + o];

    const float* ibase = in + (size_t)bb * 64 * HWP;
    for (int c0 = 0; c0 < 64; c0 += 16) {
        __syncthreads();
        for (int i = tid; i < 16 * 324; i += 256) {
            int ci = i / 324; int r = i - ci * 324;
            int py = r / 18, px = r - py * 18;
            int yy = y0 + py - 1, xx = x0 + px - 1;
            float v = 0.f;
            if ((unsigned)yy < HH && (unsigned)xx < WW)
                v = ibase[(size_t)(c0 + ci) * HWP + yy * WW + xx];
            s_p[ci][py * DPS + px] = v;
        }
        __syncthreads();
#pragma unroll 2
        for (int ci = 0; ci < 16; ++ci) {
            const float* wr0 = wt3 + (size_t)(c0 + ci) * 9 * 64 + oo;
#pragma unroll
            for (int ky = 0; ky < 3; ++ky) {
#pragma unroll
                for (int kx = 0; kx < 3; ++kx) {
                    float xv = s_p[ci][(ty + ky) * DPS + tx + kx];
                    const float* wr = wr0 + (ky * 3 + kx) * 64;
#pragma unroll
                    for (int o = 0; o < 32; ++o) acc[o] += xv * wr[o];
                }
            }
        }
    }

    if (x < WW && y < HH) {
        int p = y * WW + x;
        const float* sb = skip + ((size_t)bb * 64 + oo) * HWP + p;
        float* ob = out + ((size_t)bb * 64 + oo) * HWP + p;
#pragma unroll
        for (int o = 0; o < 32; ++o) ob[(size_t)o * HWP] = acc[o] + sb[(size_t)o * HWP];
    }
}

extern "C" void kernel_launch(void* const* d_in, const int* in_sizes, int n_in,
                              void* d_out, int out_size, void* d_ws, size_t ws_size,
                              hipStream_t stream)
{
    const float* x_in      = (const float*)d_in[0];
    const float* ln_proj_w = (const float*)d_in[1];
    const float* ln_proj_b = (const float*)d_in[2];
    const float* proj_p_w  = (const float*)d_in[3];
    const float* proj_p_b  = (const float*)d_in[4];
    const float* proj_d_w  = (const float*)d_in[5];
    const float* proj_d_b  = (const float*)d_in[6];
    const float* proj_a_w  = (const float*)d_in[7];
    const float* proj_a_b  = (const float*)d_in[8];
    const float* ln_attn_w = (const float*)d_in[9];
    const float* ln_attn_b = (const float*)d_in[10];
    const float* qkv_w     = (const float*)d_in[11];
    const float* qkv_b     = (const float*)d_in[12];
    const float* attn_o_w  = (const float*)d_in[13];
    const float* attn_o_b  = (const float*)d_in[14];
    const float* rpb       = (const float*)d_in[15];
    const float* dwcp1_w   = (const float*)d_in[16];
    const float* dwcp1_b   = (const float*)d_in[17];
    const float* dwcp2_w   = (const float*)d_in[18];
    const float* dwcp2_b   = (const float*)d_in[19];
    const float* pconv_w   = (const float*)d_in[20];
    const float* pconv_b   = (const float*)d_in[21];
    const float* ffn_p_w   = (const float*)d_in[22];
    const float* ffn_p_b   = (const float*)d_in[23];
    const float* ffn_d_w   = (const float*)d_in[24];
    const float* ffn_d_b   = (const float*)d_in[25];
    const float* ffn_a_w   = (const float*)d_in[26];
    const float* ffn_a_b   = (const float*)d_in[27];
    const float* ln_out_w  = (const float*)d_in[28];
    const float* ln_out_b  = (const float*)d_in[29];
    const float* conv_o_w  = (const float*)d_in[30];
    const float* conv_o_b  = (const float*)d_in[31];
    const float* plk       = (const float*)d_in[32];

    float* X  = (float*)d_out;
    float* ws = (float*)d_ws;

    // big path needs A(10.24M) + QKV(30.72M) + R2(2.56M) + tables ≈ 43.67M floats
    bool big = ws_size >= (size_t)43700000 * 4;

    float* A   = ws;                                  // 10.24M floats
    float* QKV = ws + 10240000;                       // 30.72M floats (big path; overlaps R1)
    float* R1  = ws + 10240000;                       // R1 live part: 12.8M floats (80ch)
    float* R2Q = ws + 23040000;                       // 4 x 2.56M partials (dead QKV/R1 tail)
    float* R2  = big ? ws + 40960000 : ws + 30720000; // legacy base for table placement
    float* LKT = R2 + 2560000;                        // 7168 (orbit table)
    float* GM  = LKT + 43264;                         // 64
    float* DK  = GM + 64;                             // 576
    float* WT  = DK + 576;                            // 98304

    dim3 b256(256);
    dim3 gLN(157, 4);
    dim3 gT8(13, 13, 8);

    prep_kernel<<<dim3(384), b256, 0, stream>>>(proj_p_w, attn_o_w, ffn_p_w, proj_a_w,
                                                ffn_a_w, pconv_w, conv_o_w, qkv_w, WT);
    geo_kernel<<<dim3(28), b256, 0, stream>>>(plk, LKT);

    // x = LN(x); x = conv_ffn(x) [proj]
    ln_kernel<<<gLN, b256, 0, stream>>>(x_in, ln_proj_w, ln_proj_b, A);
    conv1x1_kernel<<<dim3(40, 8, 4), b256, 0, stream>>>(A, WT + 0, proj_p_b, R1, 64, 128, 1, 0);
    dwproj_kernel<<<gT8, b256, 0, stream>>>(R1, proj_d_w, proj_d_b, WT + 22528, proj_a_b, X, 128);

    // x = x + window_attention(LN(x))
    ln_kernel<<<gLN, b256, 0, stream>>>(X, ln_attn_w, ln_attn_b, A);
    if (big) {
        conv1x1_kernel<<<dim3(40, 12, 4), b256, 0, stream>>>(A, WT + 86016, qkv_b, QKV, 64, 192, 0, 0);
        winattn2_kernel<<<dim3(400, 8, 4), dim3(128), 0, stream>>>(QKV, rpb, A);
        conv1x1_kernel<<<dim3(40, 4, 4), b256, 0, stream>>>(A, WT + 8192, attn_o_b, X, 64, 64, 0, 1);
    } else {
        winattn_kernel<<<dim3(400, 8, 4), dim3(128), 0, stream>>>(A, qkv_w, qkv_b, rpb, R1);
        conv1x1_kernel<<<dim3(40, 4, 4), b256, 0, stream>>>(R1, WT + 8192, attn_o_b, X, 64, 64, 0, 1);
    }

    for (int i = 0; i < 2; ++i) {
        conv1x1_kernel<<<dim3(40, 5, 4), b256, 0, stream>>>(X, WT + 12288 + i * 5120, ffn_p_b + i * 80, R1, 64, 80, 1, 0);
        dwproj_kernel<<<gT8, b256, 0, stream>>>(R1, ffn_d_w + i * 720, ffn_d_b + i * 80,
                                                WT + 30720 + i * 5120, ffn_a_b + i * 64, A, 80);
        gmean_kernel<<<dim3(64), b256, 0, stream>>>(A, GM);
        dynk_kernel<<<dim3(4), dim3(192), 0, stream>>>(GM, dwcp1_w + i * 128, dwcp1_b + i * 8,
                                                       dwcp2_w + i * 1152, dwcp2_b + i * 144, DK);
        lkconv_kernel<<<dim3(13, 13, 16), b256, 0, stream>>>(A, LKT, DK, R2Q);
        pconv_add_kernel<<<dim3(40, 4, 4), b256, 0, stream>>>(R2Q, A, WT + 40960 + i * 4096, pconv_b + i * 64, X);
    }

    ln_kernel<<<gLN, b256, 0, stream>>>(X, ln_out_w, ln_out_b, A);
    conv3_skip_kernel<<<gT8, b256, 0, stream>>>(A, WT + 49152, conv_o_b, x_in, X);
}

// Round 8
// 1506.097 us; speedup vs baseline: 1.1383x; 1.1383x over previous
//
#include <hip/hip_runtime.h>
#include <math.h>

#define HH 200
#define WW 200
#define HWP 40000
#define NP4 10000
#define BB 4

#define LKS 40   // lkconv LDS row stride
#define DPS 24   // dwproj/conv3 LDS row stride
#define PARTSZ 2560000    // one (B,16,H,W) partial buffer (lkconv)
#define PART64 10240000   // one (B,64,H,W) partial buffer (conv3)

__device__ __forceinline__ float gelu_f(float x) {
    return 0.5f * x * (1.0f + erff(x * 0.7071067811865475f));
}

// ---------------- weight prep (transposes for scalar weight loads) ----------------
// wt layout offsets (floats):
//  0      wtP   (64,128)   proj_p
//  8192   wtAO  (64,64)    attn_out
//  12288  wtFP0 (64,80)    ffn_p[0]
//  17408  wtFP1 (64,80)    ffn_p[1]
//  22528  wtPA  (128,64)   proj_a
//  30720  wtFA0 (80,64)    ffn_a[0]
//  35840  wtFA1 (80,64)    ffn_a[1]
//  40960  wtPC0 (64,64)    pconv[0]
//  45056  wtPC1 (64,64)    pconv[1]
//  49152  wt3   (64,9,64)  conv_out  [ci][tap][co]
//  86016  wtQKV (64,192)   qkv
__device__ __forceinline__ void tr_w(const float* __restrict__ w, float* __restrict__ wt,
                                     int Co, int Ci, int idx) {
    int o = idx / Ci, c = idx - o * Ci;
    wt[c * Co + o] = w[idx];
}

__global__ __launch_bounds__(256) void prep_kernel(
    const float* __restrict__ pp, const float* __restrict__ ao,
    const float* __restrict__ fp, const float* __restrict__ pa,
    const float* __restrict__ fa, const float* __restrict__ pc,
    const float* __restrict__ co3, const float* __restrict__ qkvw,
    float* __restrict__ wt)
{
    int i = blockIdx.x * 256 + threadIdx.x;
    if (i < 8192) { tr_w(pp, wt + 0, 128, 64, i); return; } i -= 8192;
    if (i < 4096) { tr_w(ao, wt + 8192, 64, 64, i); return; } i -= 4096;
    if (i < 5120) { tr_w(fp, wt + 12288, 80, 64, i); return; } i -= 5120;
    if (i < 5120) { tr_w(fp + 5120, wt + 17408, 80, 64, i); return; } i -= 5120;
    if (i < 8192) { tr_w(pa, wt + 22528, 64, 128, i); return; } i -= 8192;
    if (i < 5120) { tr_w(fa, wt + 30720, 64, 80, i); return; } i -= 5120;
    if (i < 5120) { tr_w(fa + 5120, wt + 35840, 64, 80, i); return; } i -= 5120;
    if (i < 4096) { tr_w(pc, wt + 40960, 64, 64, i); return; } i -= 4096;
    if (i < 4096) { tr_w(pc + 4096, wt + 45056, 64, 64, i); return; } i -= 4096;
    if (i < 36864) {
        int o = i / 576; int r = i - o * 576; int c = r / 9; int t = r - c * 9;
        wt[49152 + (c * 9 + t) * 64 + o] = co3[i];
        return;
    } i -= 36864;
    if (i < 12288) { tr_w(qkvw, wt + 86016, 192, 64, i); return; }
}

// ---------------- LayerNorm over 64 channels ----------------
__global__ __launch_bounds__(256, 2) void ln_kernel(
    const float* __restrict__ in, const float* __restrict__ w,
    const float* __restrict__ b, float* __restrict__ out)
{
    int p = blockIdx.x * 256 + threadIdx.x;
    int bb = blockIdx.y;
    if (p >= HWP) return;
    const float* ib = in + (size_t)bb * 64 * HWP + p;
    float v[64];
    float mu = 0.f;
#pragma unroll
    for (int c = 0; c < 64; ++c) { v[c] = ib[(size_t)c * HWP]; mu += v[c]; }
    mu *= (1.f / 64.f);
    float var = 0.f;
#pragma unroll
    for (int c = 0; c < 64; ++c) { float d = v[c] - mu; var += d * d; }
    var *= (1.f / 64.f);
    float r = rsqrtf(var + 1e-6f);
    float* ob = out + (size_t)bb * 64 * HWP + p;
#pragma unroll
    for (int c = 0; c < 64; ++c) ob[(size_t)c * HWP] = (v[c] - mu) * r * w[c] + b[c];
}

// ---------------- 1x1 conv: float4 pixels, 16 outputs/thread, scalar weights ----------------
__global__ __launch_bounds__(256, 2) void conv1x1_kernel(
    const float* __restrict__ in, const float* __restrict__ wt,  // (Ci,Co)
    const float* __restrict__ bias, float* __restrict__ out,
    int Ci, int Co, int do_gelu, int do_add)
{
    int p4 = blockIdx.x * 256 + threadIdx.x;
    int o0 = blockIdx.y * 16;
    int bb = blockIdx.z;
    if (p4 >= NP4) return;
    float4 acc[16];
#pragma unroll
    for (int j = 0; j < 16; ++j) {
        float bv = bias[o0 + j];
        acc[j] = make_float4(bv, bv, bv, bv);
    }
    const float4* ib = (const float4*)(in + (size_t)bb * Ci * HWP) + p4;
    for (int c = 0; c < Ci; ++c) {
        float4 xv = ib[(size_t)c * NP4];
        const float* wr = wt + c * Co + o0;
#pragma unroll
        for (int j = 0; j < 16; ++j) {
            float w = wr[j];
            acc[j].x += xv.x * w; acc[j].y += xv.y * w;
            acc[j].z += xv.z * w; acc[j].w += xv.w * w;
        }
    }
    float4* ob = (float4*)(out + ((size_t)bb * Co + o0) * HWP) + p4;
#pragma unroll
    for (int j = 0; j < 16; ++j) {
        float4 r = acc[j];
        if (do_gelu) {
            r.x = gelu_f(r.x); r.y = gelu_f(r.y); r.z = gelu_f(r.z); r.w = gelu_f(r.w);
        }
        if (do_add) {
            float4 old = ob[(size_t)j * NP4];
            r.x += old.x; r.y += old.y; r.z += old.z; r.w += old.w;
        }
        ob[(size_t)j * NP4] = r;
    }
}

// ------- fused: gelu(dwconv3x3(in)) + in, then 1x1 proj (Ci -> 64), 16-ci chunked LDS -------
__global__ __launch_bounds__(256, 3) void dwproj_kernel(
    const float* __restrict__ in,   // (B,Ci,H,W)
    const float* __restrict__ dw,   // (Ci,9)
    const float* __restrict__ db,   // (Ci)
    const float* __restrict__ awt,  // (Ci,64) transposed
    const float* __restrict__ ab,   // (64)
    float* __restrict__ out,        // (B,64,H,W)
    int Ci)
{
    __shared__ float s_p[16][18 * DPS];
    int tid = threadIdx.x;
    int tx = tid & 15, ty = tid >> 4;
    int x0 = blockIdx.x * 16, y0 = blockIdx.y * 16;
    int bb = blockIdx.z;
    int x = x0 + tx, y = y0 + ty;

    float acc[64];
#pragma unroll
    for (int o = 0; o < 64; ++o) acc[o] = ab[o];

    const float* ibase = in + (size_t)bb * Ci * HWP;
    for (int c0 = 0; c0 < Ci; c0 += 16) {
        __syncthreads();
        for (int i = tid; i < 16 * 324; i += 256) {
            int ci = i / 324; int r = i - ci * 324;
            int py = r / 18, px = r - py * 18;
            int yy = y0 + py - 1, xx = x0 + px - 1;
            float v = 0.f;
            if ((unsigned)yy < HH && (unsigned)xx < WW)
                v = ibase[(size_t)(c0 + ci) * HWP + yy * WW + xx];
            s_p[ci][py * DPS + px] = v;
        }
        __syncthreads();
        for (int ci = 0; ci < 16; ++ci) {
            int c = c0 + ci;
            float s = db[c];
            const float* dwr = dw + c * 9;
#pragma unroll
            for (int ky = 0; ky < 3; ++ky)
#pragma unroll
                for (int kx = 0; kx < 3; ++kx)
                    s += s_p[ci][(ty + ky) * DPS + tx + kx] * dwr[ky * 3 + kx];
            float v = gelu_f(s) + s_p[ci][(ty + 1) * DPS + tx + 1];
            const float* wr = awt + c * 64;
#pragma unroll
            for (int o = 0; o < 64; ++o) acc[o] += v * wr[o];
        }
    }

    if (x < WW && y < HH) {
        int p = y * WW + x;
        float* ob = out + (size_t)bb * 64 * HWP + p;
#pragma unroll
        for (int o = 0; o < 64; ++o) ob[(size_t)o * HWP] = acc[o];
    }
}

// ---------------- attention v2: qkv precomputed; one block = (window, head) ----------------
__global__ __launch_bounds__(128) void winattn2_kernel(
    const float* __restrict__ qkv,  // (B,192,H,W)
    const float* __restrict__ rpb,  // (8,361)
    float* __restrict__ out)        // (B,64,H,W)
{
    __shared__ __align__(16) float s_k[100][8];
    __shared__ __align__(16) float s_v[100][8];
    __shared__ float s_b[361];

    int head = blockIdx.y, bb = blockIdx.z;
    int wy = blockIdx.x / 20, wx = blockIdx.x - wy * 20;
    int tid = threadIdx.x;

    for (int i = tid; i < 361; i += 128) s_b[i] = rpb[head * 361 + i];

    int ty = tid / 10, tx = tid - ty * 10;
    float q[8];
    if (tid < 100) {
        int y = wy * 10 + ty, x = wx * 10 + tx;
        int gp = y * WW + x;
        const float* qb = qkv + ((size_t)bb * 192 + head * 8) * HWP + gp;
        const float* kb = qb + (size_t)64 * HWP;
        const float* vb = qb + (size_t)128 * HWP;
#pragma unroll
        for (int cc = 0; cc < 8; ++cc) q[cc] = qb[(size_t)cc * HWP];
        float4 t0, t1;
        t0.x = kb[0];               t0.y = kb[(size_t)1 * HWP];
        t0.z = kb[(size_t)2 * HWP]; t0.w = kb[(size_t)3 * HWP];
        t1.x = kb[(size_t)4 * HWP]; t1.y = kb[(size_t)5 * HWP];
        t1.z = kb[(size_t)6 * HWP]; t1.w = kb[(size_t)7 * HWP];
        *(float4*)(&s_k[tid][0]) = t0;
        *(float4*)(&s_k[tid][4]) = t1;
        t0.x = vb[0];               t0.y = vb[(size_t)1 * HWP];
        t0.z = vb[(size_t)2 * HWP]; t0.w = vb[(size_t)3 * HWP];
        t1.x = vb[(size_t)4 * HWP]; t1.y = vb[(size_t)5 * HWP];
        t1.z = vb[(size_t)6 * HWP]; t1.w = vb[(size_t)7 * HWP];
        *(float4*)(&s_v[tid][0]) = t0;
        *(float4*)(&s_v[tid][4]) = t1;
    }
    __syncthreads();

    if (tid < 100) {
        const float scale = 0.3535533905932738f; // 1/sqrt(8)
        const float4* k4 = (const float4*)s_k;
        const float4* v4 = (const float4*)s_v;
        float m = -1e30f;
        {
            int ky = 0, kx = 0;
            for (int kk = 0; kk < 100; ++kk) {
                float4 ka = k4[kk * 2], kb = k4[kk * 2 + 1];
                float s = q[0] * ka.x + q[1] * ka.y + q[2] * ka.z + q[3] * ka.w
                        + q[4] * kb.x + q[5] * kb.y + q[6] * kb.z + q[7] * kb.w;
                s = s * scale + s_b[(ky - ty + 9) * 19 + (kx - tx + 9)];
                m = fmaxf(m, s);
                if (++kx == 10) { kx = 0; ++ky; }
            }
        }
        float l = 0.f;
        float o[8];
#pragma unroll
        for (int cc = 0; cc < 8; ++cc) o[cc] = 0.f;
        {
            int ky = 0, kx = 0;
            for (int kk = 0; kk < 100; ++kk) {
                float4 ka = k4[kk * 2], kb = k4[kk * 2 + 1];
                float s = q[0] * ka.x + q[1] * ka.y + q[2] * ka.z + q[3] * ka.w
                        + q[4] * kb.x + q[5] * kb.y + q[6] * kb.z + q[7] * kb.w;
                s = s * scale + s_b[(ky - ty + 9) * 19 + (kx - tx + 9)];
                float e = __expf(s - m);
                l += e;
                float4 va = v4[kk * 2], vb = v4[kk * 2 + 1];
                o[0] += e * va.x; o[1] += e * va.y; o[2] += e * va.z; o[3] += e * va.w;
                o[4] += e * vb.x; o[5] += e * vb.y; o[6] += e * vb.z; o[7] += e * vb.w;
                if (++kx == 10) { kx = 0; ++ky; }
            }
        }
        float rl = 1.f / l;
        int y = wy * 10 + ty, x = wx * 10 + tx;
        float* ob = out + ((size_t)bb * 64 + head * 8) * HWP + y * WW + x;
#pragma unroll
        for (int cc = 0; cc < 8; ++cc) ob[(size_t)cc * HWP] = o[cc] * rl;
    }
}

// ---------------- attention v1 (fallback, fused qkv) ----------------
__global__ __launch_bounds__(128) void winattn_kernel(
    const float* __restrict__ xin, const float* __restrict__ qkvw,
    const float* __restrict__ qkvb, const float* __restrict__ rpb,
    float* __restrict__ out)
{
    __shared__ __align__(16) float s_wq[8][64];
    __shared__ __align__(16) float s_wk[8][64];
    __shared__ __align__(16) float s_wv[8][64];
    __shared__ __align__(16) float s_k[100][8];
    __shared__ __align__(16) float s_v[100][8];
    __shared__ float s_b[361];

    int head = blockIdx.y, bb = blockIdx.z;
    int wy = blockIdx.x / 20, wx = blockIdx.x - wy * 20;
    int tid = threadIdx.x;

    for (int i = tid; i < 8 * 64; i += 128) {
        (&s_wq[0][0])[i] = qkvw[(head * 8) * 64 + i];
        (&s_wk[0][0])[i] = qkvw[(64 + head * 8) * 64 + i];
        (&s_wv[0][0])[i] = qkvw[(128 + head * 8) * 64 + i];
    }
    for (int i = tid; i < 361; i += 128) s_b[i] = rpb[head * 361 + i];
    __syncthreads();

    float q[8];
    int ty = tid / 10, tx = tid - ty * 10;
    if (tid < 100) {
        int y = wy * 10 + ty, x = wx * 10 + tx;
        const float* xb = xin + (size_t)bb * 64 * HWP + y * WW + x;
        float xr[64];
#pragma unroll
        for (int c = 0; c < 64; ++c) xr[c] = xb[(size_t)c * HWP];
#pragma unroll
        for (int cc = 0; cc < 8; ++cc) {
            float aq = qkvb[head * 8 + cc];
            float ak = qkvb[64 + head * 8 + cc];
            float av = qkvb[128 + head * 8 + cc];
#pragma unroll
            for (int c = 0; c < 64; ++c) {
                float xv = xr[c];
                aq += xv * s_wq[cc][c];
                ak += xv * s_wk[cc][c];
                av += xv * s_wv[cc][c];
            }
            q[cc] = aq;
            s_k[tid][cc] = ak;
            s_v[tid][cc] = av;
        }
    }
    __syncthreads();

    if (tid < 100) {
        const float scale = 0.3535533905932738f;
        const float4* k4 = (const float4*)s_k;
        const float4* v4 = (const float4*)s_v;
        float m = -1e30f;
        {
            int ky = 0, kx = 0;
            for (int kk = 0; kk < 100; ++kk) {
                float4 ka = k4[kk * 2], kb = k4[kk * 2 + 1];
                float s = q[0] * ka.x + q[1] * ka.y + q[2] * ka.z + q[3] * ka.w
                        + q[4] * kb.x + q[5] * kb.y + q[6] * kb.z + q[7] * kb.w;
                s = s * scale + s_b[(ky - ty + 9) * 19 + (kx - tx + 9)];
                m = fmaxf(m, s);
                if (++kx == 10) { kx = 0; ++ky; }
            }
        }
        float l = 0.f;
        float o[8];
#pragma unroll
        for (int cc = 0; cc < 8; ++cc) o[cc] = 0.f;
        {
            int ky = 0, kx = 0;
            for (int kk = 0; kk < 100; ++kk) {
                float4 ka = k4[kk * 2], kb = k4[kk * 2 + 1];
                float s = q[0] * ka.x + q[1] * ka.y + q[2] * ka.z + q[3] * ka.w
                        + q[4] * kb.x + q[5] * kb.y + q[6] * kb.z + q[7] * kb.w;
                s = s * scale + s_b[(ky - ty + 9) * 19 + (kx - tx + 9)];
                float e = __expf(s - m);
                l += e;
                float4 va = v4[kk * 2], vb = v4[kk * 2 + 1];
                o[0] += e * va.x; o[1] += e * va.y; o[2] += e * va.z; o[3] += e * va.w;
                o[4] += e * vb.x; o[5] += e * vb.y; o[6] += e * vb.z; o[7] += e * vb.w;
                if (++kx == 10) { kx = 0; ++ky; }
            }
        }
        float rl = 1.f / l;
        int y = wy * 10 + ty, x = wx * 10 + tx;
        float* ob = out + ((size_t)bb * 64 + head * 8) * HWP + y * WW + x;
#pragma unroll
        for (int cc = 0; cc < 8; ++cc) ob[(size_t)cc * HWP] = o[cc] * rl;
    }
}

// ------- geometric ensemble -> D4-orbit weight table (ci, rep, co) -------
__global__ __launch_bounds__(256) void geo_kernel(
    const float* __restrict__ k, float* __restrict__ out)
{
    int i = blockIdx.x * 256 + threadIdx.x;
    if (i >= 256 * 28) return;
    int oc = i / 28, rep = i - oc * 28;   // oc = co*16 + ci
    int co = oc >> 4, ci = oc & 15;
    int a = 0, r = rep;
    while (r >= 7 - a) { r -= 7 - a; ++a; }
    int b2 = a + r;
    int y = 6 + a, x = 6 + b2;
    const float* kb = k + oc * 169;
    float s = kb[y * 13 + x] + kb[y * 13 + (12 - x)] + kb[(12 - y) * 13 + x] + kb[(12 - y) * 13 + (12 - x)]
            + kb[(12 - x) * 13 + y] + kb[x * 13 + y] + kb[(12 - x) * 13 + (12 - y)] + kb[x * 13 + (12 - y)];
    out[(ci * 28 + rep) * 16 + co] = s * 0.125f;
}

// ---------------- global mean over H,W of first-16 channels ----------------
__global__ __launch_bounds__(256) void gmean_kernel(
    const float* __restrict__ in, float* __restrict__ g)
{
    int bc = blockIdx.x;            // b*16 + c
    int bb = bc >> 4, c = bc & 15;
    const float* p = in + ((size_t)bb * 64 + c) * HWP;
    float s = 0.f;
    for (int i = threadIdx.x; i < HWP; i += 256) s += p[i];
#pragma unroll
    for (int off = 32; off > 0; off >>= 1) s += __shfl_down(s, off);
    __shared__ float red[4];
    int wave = threadIdx.x >> 6;
    if ((threadIdx.x & 63) == 0) red[wave] = s;
    __syncthreads();
    if (threadIdx.x == 0)
        g[bc] = (red[0] + red[1] + red[2] + red[3]) * (1.f / 40000.f);
}

// ---------------- tiny MLP -> dynamic 3x3 kernels ----------------
__global__ __launch_bounds__(192) void dynk_kernel(
    const float* __restrict__ g, const float* __restrict__ w1, const float* __restrict__ b1,
    const float* __restrict__ w2, const float* __restrict__ b2, float* __restrict__ dk)
{
    int bb = blockIdx.x;
    __shared__ float s_g2[8];
    int tid = threadIdx.x;
    if (tid < 8) {
        float a = b1[tid];
        for (int c = 0; c < 16; ++c) a += w1[tid * 16 + c] * g[bb * 16 + c];
        s_g2[tid] = gelu_f(a);
    }
    __syncthreads();
    if (tid < 144) {
        float a = b2[tid];
#pragma unroll
        for (int i = 0; i < 8; ++i) a += w2[tid * 8 + i] * s_g2[i];
        dk[bb * 144 + tid] = a;
    }
}

// ------- 13x13 D4-symmetric conv via 28 orbit sums + dynamic depthwise 3x3 -------
// 4-way ci-split: grid (13,13,B*4); z -> bb = z>>2, q = z&3; ci range [q*4, q*4+4).
__global__ __launch_bounds__(256, 4) void lkconv_kernel(
    const float* __restrict__ in,   // (B,64,H,W) — channels 0..15 used
    const float* __restrict__ lkO,  // (16,28,16)  [ci][rep][co]
    const float* __restrict__ dk,   // (B,144)
    float* __restrict__ out)        // 4 partial buffers, stride PARTSZ
{
    __shared__ float s_p[4][28 * LKS];  // 17.9 KB
    int z = blockIdx.z;
    int bb = z >> 2, q = z & 3;
    int tid = threadIdx.x;
    int tx = tid & 15, ty = tid >> 4;
    int x0 = blockIdx.x * 16, y0 = blockIdx.y * 16;
    int x = x0 + tx, y = y0 + ty;

    const float* ibase = in + ((size_t)bb * 64 + q * 4) * HWP;
    for (int i = tid; i < 4 * 784; i += 256) {
        int ci = i / 784; int r = i - ci * 784;
        int py = r / 28, px = r - py * 28;
        int yy = y0 + py - 6, xx = x0 + px - 6;
        float v = 0.f;
        if ((unsigned)yy < HH && (unsigned)xx < WW)
            v = ibase[(size_t)ci * HWP + yy * WW + xx];
        s_p[ci][py * LKS + px] = v;
    }
    __syncthreads();

    float acc[16];
#pragma unroll
    for (int co = 0; co < 16; ++co) acc[co] = 0.f;

#pragma unroll
    for (int ci4 = 0; ci4 < 4; ++ci4) {
        int ci = q * 4 + ci4;
        float orb[28];
#pragma unroll
        for (int o = 0; o < 28; ++o) orb[o] = 0.f;
#pragma unroll
        for (int ky = 0; ky < 13; ++ky) {
#pragma unroll
            for (int kx = 0; kx < 13; ++kx) {
                const int a = (ky < 6) ? (6 - ky) : (ky - 6);
                const int b = (kx < 6) ? (6 - kx) : (kx - 6);
                const int lo = (a < b) ? a : b;
                const int hi = (a < b) ? b : a;
                const int idx = lo * 7 - (lo * (lo - 1)) / 2 + (hi - lo);
                orb[idx] += s_p[ci4][(ty + ky) * LKS + tx + kx];
            }
        }
        const float* wci = lkO + ci * 28 * 16;
#pragma unroll
        for (int o = 0; o < 28; ++o) {
            float ov = orb[o];
            const float* wr = wci + o * 16;
#pragma unroll
            for (int co = 0; co < 16; ++co) acc[co] += ov * wr[co];
        }
        float d = 0.f;
        const float* dkr = dk + bb * 144 + ci * 9;
#pragma unroll
        for (int dy = 0; dy < 3; ++dy)
#pragma unroll
            for (int dx = 0; dx < 3; ++dx)
                d += s_p[ci4][(ty + 5 + dy) * LKS + tx + 5 + dx] * dkr[dy * 3 + dx];
#pragma unroll
        for (int co = 0; co < 16; ++co) acc[co] += (co == ci) ? d : 0.f;
    }

    if (x < WW && y < HH) {
        int p = y * WW + x;
        float* ob = out + (size_t)q * PARTSZ + (size_t)bb * 16 * HWP + p;
#pragma unroll
        for (int co = 0; co < 16; ++co) ob[(size_t)co * HWP] = acc[co];
    }
}

// ------- 1x1 conv over concat(sum of 4 x1 partials, y[16..63]) and add into xout -------
__global__ __launch_bounds__(256, 2) void pconv_add_kernel(
    const float* __restrict__ x1q,  // 4 partial buffers, stride PARTSZ
    const float* __restrict__ yy,
    const float* __restrict__ wt, const float* __restrict__ bias,
    float* __restrict__ xout)
{
    int p4 = blockIdx.x * 256 + threadIdx.x;
    int o0 = blockIdx.y * 16;
    int bb = blockIdx.z;
    if (p4 >= NP4) return;
    float4 acc[16];
#pragma unroll
    for (int j = 0; j < 16; ++j) {
        float bv = bias[o0 + j];
        acc[j] = make_float4(bv, bv, bv, bv);
    }
    const float4* xb0 = (const float4*)(x1q + (size_t)bb * 16 * HWP) + p4;
    const float4* xb1 = (const float4*)(x1q + PARTSZ + (size_t)bb * 16 * HWP) + p4;
    const float4* xb2 = (const float4*)(x1q + 2 * PARTSZ + (size_t)bb * 16 * HWP) + p4;
    const float4* xb3 = (const float4*)(x1q + 3 * PARTSZ + (size_t)bb * 16 * HWP) + p4;
    for (int c = 0; c < 16; ++c) {
        float4 a0 = xb0[(size_t)c * NP4], a1 = xb1[(size_t)c * NP4];
        float4 a2 = xb2[(size_t)c * NP4], a3 = xb3[(size_t)c * NP4];
        float4 xv;
        xv.x = (a0.x + a1.x) + (a2.x + a3.x);
        xv.y = (a0.y + a1.y) + (a2.y + a3.y);
        xv.z = (a0.z + a1.z) + (a2.z + a3.z);
        xv.w = (a0.w + a1.w) + (a2.w + a3.w);
        const float* wr = wt + c * 64 + o0;
#pragma unroll
        for (int j = 0; j < 16; ++j) {
            float w = wr[j];
            acc[j].x += xv.x * w; acc[j].y += xv.y * w;
            acc[j].z += xv.z * w; acc[j].w += xv.w * w;
        }
    }
    const float4* yb = (const float4*)(yy + ((size_t)bb * 64 + 16) * HWP) + p4;
    for (int c = 0; c < 48; ++c) {
        float4 xv = yb[(size_t)c * NP4];
        const float* wr = wt + (16 + c) * 64 + o0;
#pragma unroll
        for (int j = 0; j < 16; ++j) {
            float w = wr[j];
            acc[j].x += xv.x * w; acc[j].y += xv.y * w;
            acc[j].z += xv.z * w; acc[j].w += xv.w * w;
        }
    }
    float4* ob = (float4*)(xout + ((size_t)bb * 64 + o0) * HWP) + p4;
#pragma unroll
    for (int j = 0; j < 16; ++j) {
        float4 old = ob[(size_t)j * NP4];
        old.x += acc[j].x; old.y += acc[j].y; old.z += acc[j].z; old.w += acc[j].w;
        ob[(size_t)j * NP4] = old;
    }
}

// ---------------- final 3x3 conv, ci-split 2-way: partials, no bias/skip ----------------
// grid (13,13,B*2); z -> bb = z>>1, half = z&1 (input channels half*32 .. half*32+31)
__global__ __launch_bounds__(256, 4) void conv3_part_kernel(
    const float* __restrict__ in, const float* __restrict__ wt3,  // (ci,tap,64)
    float* __restrict__ pout)   // 2 partial buffers, stride PART64
{
    __shared__ float s_p[16][18 * DPS];
    int tid = threadIdx.x;
    int tx = tid & 15, ty = tid >> 4;
    int x0 = blockIdx.x * 16, y0 = blockIdx.y * 16;
    int bb = blockIdx.z >> 1, half = blockIdx.z & 1;
    int cbase = half * 32;
    int x = x0 + tx, y = y0 + ty;

    float acc[64];
#pragma unroll
    for (int o = 0; o < 64; ++o) acc[o] = 0.f;

    const float* ibase = in + ((size_t)bb * 64 + cbase) * HWP;
    for (int c0 = 0; c0 < 32; c0 += 16) {
        __syncthreads();
        for (int i = tid; i < 16 * 324; i += 256) {
            int ci = i / 324; int r = i - ci * 324;
            int py = r / 18, px = r - py * 18;
            int yy = y0 + py - 1, xx = x0 + px - 1;
            float v = 0.f;
            if ((unsigned)yy < HH && (unsigned)xx < WW)
                v = ibase[(size_t)(c0 + ci) * HWP + yy * WW + xx];
            s_p[ci][py * DPS + px] = v;
        }
        __syncthreads();
#pragma unroll 2
        for (int ci = 0; ci < 16; ++ci) {
            const float* wr0 = wt3 + (size_t)(cbase + c0 + ci) * 9 * 64;
#pragma unroll
            for (int ky = 0; ky < 3; ++ky) {
#pragma unroll
                for (int kx = 0; kx < 3; ++kx) {
                    float xv = s_p[ci][(ty + ky) * DPS + tx + kx];
                    const float* wr = wr0 + (ky * 3 + kx) * 64;
#pragma unroll
                    for (int o = 0; o < 64; ++o) acc[o] += xv * wr[o];
                }
            }
        }
    }

    if (x < WW && y < HH) {
        int p = y * WW + x;
        float* ob = pout + (size_t)half * PART64 + (size_t)bb * 64 * HWP + p;
#pragma unroll
        for (int o = 0; o < 64; ++o) ob[(size_t)o * HWP] = acc[o];
    }
}

// ---------------- combine conv3 partials: out = p0 + p1 + bias[c] + skip ----------------
__global__ __launch_bounds__(256) void combine3_kernel(
    const float* __restrict__ p0, const float* __restrict__ p1,
    const float* __restrict__ bias, const float* __restrict__ skip,
    float* __restrict__ out)
{
    int idx = blockIdx.x * 256 + threadIdx.x;   // float4 index over B*64*NP4
    if (idx >= BB * 64 * NP4) return;
    int c = (idx / NP4) & 63;
    float4 a = ((const float4*)p0)[idx];
    float4 b = ((const float4*)p1)[idx];
    float4 s = ((const float4*)skip)[idx];
    float bv = bias[c];
    float4 r;
    r.x = a.x + b.x + s.x + bv;
    r.y = a.y + b.y + s.y + bv;
    r.z = a.z + b.z + s.z + bv;
    r.w = a.w + b.w + s.w + bv;
    ((float4*)out)[idx] = r;
}

extern "C" void kernel_launch(void* const* d_in, const int* in_sizes, int n_in,
                              void* d_out, int out_size, void* d_ws, size_t ws_size,
                              hipStream_t stream)
{
    const float* x_in      = (const float*)d_in[0];
    const float* ln_proj_w = (const float*)d_in[1];
    const float* ln_proj_b = (const float*)d_in[2];
    const float* proj_p_w  = (const float*)d_in[3];
    const float* proj_p_b  = (const float*)d_in[4];
    const float* proj_d_w  = (const float*)d_in[5];
    const float* proj_d_b  = (const float*)d_in[6];
    const float* proj_a_w  = (const float*)d_in[7];
    const float* proj_a_b  = (const float*)d_in[8];
    const float* ln_attn_w = (const float*)d_in[9];
    const float* ln_attn_b = (const float*)d_in[10];
    const float* qkv_w     = (const float*)d_in[11];
    const float* qkv_b     = (const float*)d_in[12];
    const float* attn_o_w  = (const float*)d_in[13];
    const float* attn_o_b  = (const float*)d_in[14];
    const float* rpb       = (const float*)d_in[15];
    const float* dwcp1_w   = (const float*)d_in[16];
    const float* dwcp1_b   = (const float*)d_in[17];
    const float* dwcp2_w   = (const float*)d_in[18];
    const float* dwcp2_b   = (const float*)d_in[19];
    const float* pconv_w   = (const float*)d_in[20];
    const float* pconv_b   = (const float*)d_in[21];
    const float* ffn_p_w   = (const float*)d_in[22];
    const float* ffn_p_b   = (const float*)d_in[23];
    const float* ffn_d_w   = (const float*)d_in[24];
    const float* ffn_d_b   = (const float*)d_in[25];
    const float* ffn_a_w   = (const float*)d_in[26];
    const float* ffn_a_b   = (const float*)d_in[27];
    const float* ln_out_w  = (const float*)d_in[28];
    const float* ln_out_b  = (const float*)d_in[29];
    const float* conv_o_w  = (const float*)d_in[30];
    const float* conv_o_b  = (const float*)d_in[31];
    const float* plk       = (const float*)d_in[32];

    float* X  = (float*)d_out;
    float* ws = (float*)d_ws;

    bool big = ws_size >= (size_t)43700000 * 4;

    float* A   = ws;                                  // 10.24M floats (live conv3 input)
    float* QKV = ws + 10240000;                       // 30.72M floats (dead after attention)
    float* R1  = ws + 10240000;                       // R1 live part: 12.8M floats (80ch)
    float* R2Q = ws + 23040000;                       // 4 x 2.56M lkconv partials
    float* P0  = ws + 10240000;                       // conv3 partial 0 (dead QKV region)
    float* P1  = ws + 20480000;                       // conv3 partial 1
    float* R2  = big ? ws + 40960000 : ws + 30720000; // legacy base for table placement
    float* LKT = R2 + 2560000;                        // 7168 (orbit table)
    float* GM  = LKT + 43264;                         // 64
    float* DK  = GM + 64;                             // 576
    float* WT  = DK + 576;                            // 98304

    dim3 b256(256);
    dim3 gLN(157, 4);
    dim3 gT(13, 13, 4);
    dim3 gT8(13, 13, 8);

    prep_kernel<<<dim3(384), b256, 0, stream>>>(proj_p_w, attn_o_w, ffn_p_w, proj_a_w,
                                                ffn_a_w, pconv_w, conv_o_w, qkv_w, WT);
    geo_kernel<<<dim3(28), b256, 0, stream>>>(plk, LKT);

    // x = LN(x); x = conv_ffn(x) [proj]
    ln_kernel<<<gLN, b256, 0, stream>>>(x_in, ln_proj_w, ln_proj_b, A);
    conv1x1_kernel<<<dim3(40, 8, 4), b256, 0, stream>>>(A, WT + 0, proj_p_b, R1, 64, 128, 1, 0);
    dwproj_kernel<<<gT, b256, 0, stream>>>(R1, proj_d_w, proj_d_b, WT + 22528, proj_a_b, X, 128);

    // x = x + window_attention(LN(x))
    ln_kernel<<<gLN, b256, 0, stream>>>(X, ln_attn_w, ln_attn_b, A);
    if (big) {
        conv1x1_kernel<<<dim3(40, 12, 4), b256, 0, stream>>>(A, WT + 86016, qkv_b, QKV, 64, 192, 0, 0);
        winattn2_kernel<<<dim3(400, 8, 4), dim3(128), 0, stream>>>(QKV, rpb, A);
        conv1x1_kernel<<<dim3(40, 4, 4), b256, 0, stream>>>(A, WT + 8192, attn_o_b, X, 64, 64, 0, 1);
    } else {
        winattn_kernel<<<dim3(400, 8, 4), dim3(128), 0, stream>>>(A, qkv_w, qkv_b, rpb, R1);
        conv1x1_kernel<<<dim3(40, 4, 4), b256, 0, stream>>>(R1, WT + 8192, attn_o_b, X, 64, 64, 0, 1);
    }

    for (int i = 0; i < 2; ++i) {
        conv1x1_kernel<<<dim3(40, 5, 4), b256, 0, stream>>>(X, WT + 12288 + i * 5120, ffn_p_b + i * 80, R1, 64, 80, 1, 0);
        dwproj_kernel<<<gT, b256, 0, stream>>>(R1, ffn_d_w + i * 720, ffn_d_b + i * 80,
                                               WT + 30720 + i * 5120, ffn_a_b + i * 64, A, 80);
        gmean_kernel<<<dim3(64), b256, 0, stream>>>(A, GM);
        dynk_kernel<<<dim3(4), dim3(192), 0, stream>>>(GM, dwcp1_w + i * 128, dwcp1_b + i * 8,
                                                       dwcp2_w + i * 1152, dwcp2_b + i * 144, DK);
        lkconv_kernel<<<dim3(13, 13, 16), b256, 0, stream>>>(A, LKT, DK, R2Q);
        pconv_add_kernel<<<dim3(40, 4, 4), b256, 0, stream>>>(R2Q, A, WT + 40960 + i * 4096, pconv_b + i * 64, X);
    }

    // x = conv3x3(LN(x)) + skip  — ci-split into 2 partials, then combine
    ln_kernel<<<gLN, b256, 0, stream>>>(X, ln_out_w, ln_out_b, A);
    conv3_part_kernel<<<gT8, b256, 0, stream>>>(A, WT + 49152, P0);
    combine3_kernel<<<dim3(10000), b256, 0, stream>>>(P0, P1, conv_o_b, x_in, X);
}

// Round 9
// 1481.219 us; speedup vs baseline: 1.1574x; 1.0168x over previous
//
#include <hip/hip_runtime.h>
#include <math.h>

#define HH 200
#define WW 200
#define HWP 40000
#define NP4 10000
#define BB 4

#define LKS 40   // lkconv LDS row stride
#define DPS 24   // dwproj/conv3 LDS row stride
#define PARTSZ 2560000    // one (B,16,H,W) partial buffer (lkconv)
#define PART64 10240000   // one (B,64,H,W) partial buffer

__device__ __forceinline__ float gelu_f(float x) {
    return 0.5f * x * (1.0f + erff(x * 0.7071067811865475f));
}

// ---------------- weight prep (transposes for scalar weight loads) ----------------
// wt layout offsets (floats):
//  0      wtP   (64,128)   proj_p
//  8192   wtAO  (64,64)    attn_out
//  12288  wtFP0 (64,80)    ffn_p[0]
//  17408  wtFP1 (64,80)    ffn_p[1]
//  22528  wtPA  (128,64)   proj_a
//  30720  wtFA0 (80,64)    ffn_a[0]
//  35840  wtFA1 (80,64)    ffn_a[1]
//  40960  wtPC0 (64,64)    pconv[0]
//  45056  wtPC1 (64,64)    pconv[1]
//  49152  wt3   (64,9,64)  conv_out  [ci][tap][co]
//  86016  wtQKV (64,192)   qkv
__device__ __forceinline__ void tr_w(const float* __restrict__ w, float* __restrict__ wt,
                                     int Co, int Ci, int idx) {
    int o = idx / Ci, c = idx - o * Ci;
    wt[c * Co + o] = w[idx];
}

__global__ __launch_bounds__(256) void prep_kernel(
    const float* __restrict__ pp, const float* __restrict__ ao,
    const float* __restrict__ fp, const float* __restrict__ pa,
    const float* __restrict__ fa, const float* __restrict__ pc,
    const float* __restrict__ co3, const float* __restrict__ qkvw,
    float* __restrict__ wt)
{
    int i = blockIdx.x * 256 + threadIdx.x;
    if (i < 8192) { tr_w(pp, wt + 0, 128, 64, i); return; } i -= 8192;
    if (i < 4096) { tr_w(ao, wt + 8192, 64, 64, i); return; } i -= 4096;
    if (i < 5120) { tr_w(fp, wt + 12288, 80, 64, i); return; } i -= 5120;
    if (i < 5120) { tr_w(fp + 5120, wt + 17408, 80, 64, i); return; } i -= 5120;
    if (i < 8192) { tr_w(pa, wt + 22528, 64, 128, i); return; } i -= 8192;
    if (i < 5120) { tr_w(fa, wt + 30720, 64, 80, i); return; } i -= 5120;
    if (i < 5120) { tr_w(fa + 5120, wt + 35840, 64, 80, i); return; } i -= 5120;
    if (i < 4096) { tr_w(pc, wt + 40960, 64, 64, i); return; } i -= 4096;
    if (i < 4096) { tr_w(pc + 4096, wt + 45056, 64, 64, i); return; } i -= 4096;
    if (i < 36864) {
        int o = i / 576; int r = i - o * 576; int c = r / 9; int t = r - c * 9;
        wt[49152 + (c * 9 + t) * 64 + o] = co3[i];
        return;
    } i -= 36864;
    if (i < 12288) { tr_w(qkvw, wt + 86016, 192, 64, i); return; }
}

// ---------------- LayerNorm over 64 channels ----------------
__global__ __launch_bounds__(256, 2) void ln_kernel(
    const float* __restrict__ in, const float* __restrict__ w,
    const float* __restrict__ b, float* __restrict__ out)
{
    int p = blockIdx.x * 256 + threadIdx.x;
    int bb = blockIdx.y;
    if (p >= HWP) return;
    const float* ib = in + (size_t)bb * 64 * HWP + p;
    float v[64];
    float mu = 0.f;
#pragma unroll
    for (int c = 0; c < 64; ++c) { v[c] = ib[(size_t)c * HWP]; mu += v[c]; }
    mu *= (1.f / 64.f);
    float var = 0.f;
#pragma unroll
    for (int c = 0; c < 64; ++c) { float d = v[c] - mu; var += d * d; }
    var *= (1.f / 64.f);
    float r = rsqrtf(var + 1e-6f);
    float* ob = out + (size_t)bb * 64 * HWP + p;
#pragma unroll
    for (int c = 0; c < 64; ++c) ob[(size_t)c * HWP] = (v[c] - mu) * r * w[c] + b[c];
}

// ---------------- 1x1 conv: float4 pixels, 16 outputs/thread, scalar weights ----------------
__global__ __launch_bounds__(256, 2) void conv1x1_kernel(
    const float* __restrict__ in, const float* __restrict__ wt,  // (Ci,Co)
    const float* __restrict__ bias, float* __restrict__ out,
    int Ci, int Co, int do_gelu, int do_add)
{
    int p4 = blockIdx.x * 256 + threadIdx.x;
    int o0 = blockIdx.y * 16;
    int bb = blockIdx.z;
    if (p4 >= NP4) return;
    float4 acc[16];
#pragma unroll
    for (int j = 0; j < 16; ++j) {
        float bv = bias[o0 + j];
        acc[j] = make_float4(bv, bv, bv, bv);
    }
    const float4* ib = (const float4*)(in + (size_t)bb * Ci * HWP) + p4;
    for (int c = 0; c < Ci; ++c) {
        float4 xv = ib[(size_t)c * NP4];
        const float* wr = wt + c * Co + o0;
#pragma unroll
        for (int j = 0; j < 16; ++j) {
            float w = wr[j];
            acc[j].x += xv.x * w; acc[j].y += xv.y * w;
            acc[j].z += xv.z * w; acc[j].w += xv.w * w;
        }
    }
    float4* ob = (float4*)(out + ((size_t)bb * Co + o0) * HWP) + p4;
#pragma unroll
    for (int j = 0; j < 16; ++j) {
        float4 r = acc[j];
        if (do_gelu) {
            r.x = gelu_f(r.x); r.y = gelu_f(r.y); r.z = gelu_f(r.z); r.w = gelu_f(r.w);
        }
        if (do_add) {
            float4 old = ob[(size_t)j * NP4];
            r.x += old.x; r.y += old.y; r.z += old.z; r.w += old.w;
        }
        ob[(size_t)j * NP4] = r;
    }
}

// ------- fused: gelu(dwconv3x3(in)) + in, then 1x1 proj partial (ci-split) -------
// grid (13,13,B<<splitlog); z -> part = z & ((1<<splitlog)-1), bb = z >> splitlog
// part handles ci in [part*Ci/nsplit, ...); writes full-64co partial to out0/out1.
__global__ __launch_bounds__(256, 4) void dwproj_kernel(
    const float* __restrict__ in,   // (B,Ci,H,W)
    const float* __restrict__ dw,   // (Ci,9)
    const float* __restrict__ db,   // (Ci)
    const float* __restrict__ awt,  // (Ci,64) transposed
    const float* __restrict__ ab,   // (64)
    float* __restrict__ out0, float* __restrict__ out1,
    int Ci, int splitlog)
{
    __shared__ float s_p[16][18 * DPS];
    int tid = threadIdx.x;
    int tx = tid & 15, ty = tid >> 4;
    int x0 = blockIdx.x * 16, y0 = blockIdx.y * 16;
    int part = blockIdx.z & ((1 << splitlog) - 1);
    int bb = blockIdx.z >> splitlog;
    int cic = Ci >> splitlog;
    int cbase = part * cic;
    float* dst = (part == 0) ? out0 : out1;
    int x = x0 + tx, y = y0 + ty;

    float acc[64];
    if (part == 0) {
#pragma unroll
        for (int o = 0; o < 64; ++o) acc[o] = ab[o];
    } else {
#pragma unroll
        for (int o = 0; o < 64; ++o) acc[o] = 0.f;
    }

    const float* ibase = in + (size_t)bb * Ci * HWP;
    for (int c0 = cbase; c0 < cbase + cic; c0 += 16) {
        int chunk = cbase + cic - c0; if (chunk > 16) chunk = 16;
        __syncthreads();
        for (int i = tid; i < chunk * 324; i += 256) {
            int ci = i / 324; int r = i - ci * 324;
            int py = r / 18, px = r - py * 18;
            int yy = y0 + py - 1, xx = x0 + px - 1;
            float v = 0.f;
            if ((unsigned)yy < HH && (unsigned)xx < WW)
                v = ibase[(size_t)(c0 + ci) * HWP + yy * WW + xx];
            s_p[ci][py * DPS + px] = v;
        }
        __syncthreads();
        for (int ci = 0; ci < chunk; ++ci) {
            int c = c0 + ci;
            float s = db[c];
            const float* dwr = dw + c * 9;
#pragma unroll
            for (int ky = 0; ky < 3; ++ky)
#pragma unroll
                for (int kx = 0; kx < 3; ++kx)
                    s += s_p[ci][(ty + ky) * DPS + tx + kx] * dwr[ky * 3 + kx];
            float v = gelu_f(s) + s_p[ci][(ty + 1) * DPS + tx + 1];
            const float* wr = awt + c * 64;
#pragma unroll
            for (int o = 0; o < 64; ++o) acc[o] += v * wr[o];
        }
    }

    if (x < WW && y < HH) {
        int p = y * WW + x;
        float* ob = dst + (size_t)bb * 64 * HWP + p;
#pragma unroll
        for (int o = 0; o < 64; ++o) ob[(size_t)o * HWP] = acc[o];
    }
}

// ---------------- attention v2: qkv precomputed; one block = (window, head) ----------------
__global__ __launch_bounds__(128) void winattn2_kernel(
    const float* __restrict__ qkv,  // (B,192,H,W)
    const float* __restrict__ rpb,  // (8,361)
    float* __restrict__ out)        // (B,64,H,W)
{
    __shared__ __align__(16) float s_k[100][8];
    __shared__ __align__(16) float s_v[100][8];
    __shared__ float s_b[361];

    int head = blockIdx.y, bb = blockIdx.z;
    int wy = blockIdx.x / 20, wx = blockIdx.x - wy * 20;
    int tid = threadIdx.x;

    for (int i = tid; i < 361; i += 128) s_b[i] = rpb[head * 361 + i];

    int ty = tid / 10, tx = tid - ty * 10;
    float q[8];
    if (tid < 100) {
        int y = wy * 10 + ty, x = wx * 10 + tx;
        int gp = y * WW + x;
        const float* qb = qkv + ((size_t)bb * 192 + head * 8) * HWP + gp;
        const float* kb = qb + (size_t)64 * HWP;
        const float* vb = qb + (size_t)128 * HWP;
#pragma unroll
        for (int cc = 0; cc < 8; ++cc) q[cc] = qb[(size_t)cc * HWP];
        float4 t0, t1;
        t0.x = kb[0];               t0.y = kb[(size_t)1 * HWP];
        t0.z = kb[(size_t)2 * HWP]; t0.w = kb[(size_t)3 * HWP];
        t1.x = kb[(size_t)4 * HWP]; t1.y = kb[(size_t)5 * HWP];
        t1.z = kb[(size_t)6 * HWP]; t1.w = kb[(size_t)7 * HWP];
        *(float4*)(&s_k[tid][0]) = t0;
        *(float4*)(&s_k[tid][4]) = t1;
        t0.x = vb[0];               t0.y = vb[(size_t)1 * HWP];
        t0.z = vb[(size_t)2 * HWP]; t0.w = vb[(size_t)3 * HWP];
        t1.x = vb[(size_t)4 * HWP]; t1.y = vb[(size_t)5 * HWP];
        t1.z = vb[(size_t)6 * HWP]; t1.w = vb[(size_t)7 * HWP];
        *(float4*)(&s_v[tid][0]) = t0;
        *(float4*)(&s_v[tid][4]) = t1;
    }
    __syncthreads();

    if (tid < 100) {
        const float scale = 0.3535533905932738f; // 1/sqrt(8)
        const float4* k4 = (const float4*)s_k;
        const float4* v4 = (const float4*)s_v;
        float m = -1e30f;
        {
            int ky = 0, kx = 0;
            for (int kk = 0; kk < 100; ++kk) {
                float4 ka = k4[kk * 2], kb = k4[kk * 2 + 1];
                float s = q[0] * ka.x + q[1] * ka.y + q[2] * ka.z + q[3] * ka.w
                        + q[4] * kb.x + q[5] * kb.y + q[6] * kb.z + q[7] * kb.w;
                s = s * scale + s_b[(ky - ty + 9) * 19 + (kx - tx + 9)];
                m = fmaxf(m, s);
                if (++kx == 10) { kx = 0; ++ky; }
            }
        }
        float l = 0.f;
        float o[8];
#pragma unroll
        for (int cc = 0; cc < 8; ++cc) o[cc] = 0.f;
        {
            int ky = 0, kx = 0;
            for (int kk = 0; kk < 100; ++kk) {
                float4 ka = k4[kk * 2], kb = k4[kk * 2 + 1];
                float s = q[0] * ka.x + q[1] * ka.y + q[2] * ka.z + q[3] * ka.w
                        + q[4] * kb.x + q[5] * kb.y + q[6] * kb.z + q[7] * kb.w;
                s = s * scale + s_b[(ky - ty + 9) * 19 + (kx - tx + 9)];
                float e = __expf(s - m);
                l += e;
                float4 va = v4[kk * 2], vb = v4[kk * 2 + 1];
                o[0] += e * va.x; o[1] += e * va.y; o[2] += e * va.z; o[3] += e * va.w;
                o[4] += e * vb.x; o[5] += e * vb.y; o[6] += e * vb.z; o[7] += e * vb.w;
                if (++kx == 10) { kx = 0; ++ky; }
            }
        }
        float rl = 1.f / l;
        int y = wy * 10 + ty, x = wx * 10 + tx;
        float* ob = out + ((size_t)bb * 64 + head * 8) * HWP + y * WW + x;
#pragma unroll
        for (int cc = 0; cc < 8; ++cc) ob[(size_t)cc * HWP] = o[cc] * rl;
    }
}

// ------- geometric ensemble -> D4-orbit weight table (ci, rep, co) -------
__global__ __launch_bounds__(256) void geo_kernel(
    const float* __restrict__ k, float* __restrict__ out)
{
    int i = blockIdx.x * 256 + threadIdx.x;
    if (i >= 256 * 28) return;
    int oc = i / 28, rep = i - oc * 28;   // oc = co*16 + ci
    int co = oc >> 4, ci = oc & 15;
    int a = 0, r = rep;
    while (r >= 7 - a) { r -= 7 - a; ++a; }
    int b2 = a + r;
    int y = 6 + a, x = 6 + b2;
    const float* kb = k + oc * 169;
    float s = kb[y * 13 + x] + kb[y * 13 + (12 - x)] + kb[(12 - y) * 13 + x] + kb[(12 - y) * 13 + (12 - x)]
            + kb[(12 - x) * 13 + y] + kb[x * 13 + y] + kb[(12 - x) * 13 + (12 - y)] + kb[x * 13 + (12 - y)];
    out[(ci * 28 + rep) * 16 + co] = s * 0.125f;
}

// ---------------- global mean over H,W of first-16 channels (sum of 2 partials) --------
__global__ __launch_bounds__(256) void gmean2_kernel(
    const float* __restrict__ in0, const float* __restrict__ in1, float* __restrict__ g)
{
    int bc = blockIdx.x;            // b*16 + c
    int bb = bc >> 4, c = bc & 15;
    const float* p0 = in0 + ((size_t)bb * 64 + c) * HWP;
    const float* p1 = in1 + ((size_t)bb * 64 + c) * HWP;
    float s = 0.f;
    for (int i = threadIdx.x; i < HWP; i += 256) s += p0[i] + p1[i];
#pragma unroll
    for (int off = 32; off > 0; off >>= 1) s += __shfl_down(s, off);
    __shared__ float red[4];
    int wave = threadIdx.x >> 6;
    if ((threadIdx.x & 63) == 0) red[wave] = s;
    __syncthreads();
    if (threadIdx.x == 0)
        g[bc] = (red[0] + red[1] + red[2] + red[3]) * (1.f / 40000.f);
}

// ---------------- tiny MLP -> dynamic 3x3 kernels ----------------
__global__ __launch_bounds__(192) void dynk_kernel(
    const float* __restrict__ g, const float* __restrict__ w1, const float* __restrict__ b1,
    const float* __restrict__ w2, const float* __restrict__ b2, float* __restrict__ dk)
{
    int bb = blockIdx.x;
    __shared__ float s_g2[8];
    int tid = threadIdx.x;
    if (tid < 8) {
        float a = b1[tid];
        for (int c = 0; c < 16; ++c) a += w1[tid * 16 + c] * g[bb * 16 + c];
        s_g2[tid] = gelu_f(a);
    }
    __syncthreads();
    if (tid < 144) {
        float a = b2[tid];
#pragma unroll
        for (int i = 0; i < 8; ++i) a += w2[tid * 8 + i] * s_g2[i];
        dk[bb * 144 + tid] = a;
    }
}

// ------- 13x13 D4-symmetric conv via 28 orbit sums + dynamic depthwise 3x3 -------
// input = in0 + in1 (dwproj partials). 4-way ci-split: grid (13,13,B*4).
__global__ __launch_bounds__(256, 4) void lkconv_kernel(
    const float* __restrict__ in0, const float* __restrict__ in1,
    const float* __restrict__ lkO,  // (16,28,16)  [ci][rep][co]
    const float* __restrict__ dk,   // (B,144)
    float* __restrict__ out)        // 4 partial buffers, stride PARTSZ
{
    __shared__ float s_p[4][28 * LKS];  // 17.9 KB
    int z = blockIdx.z;
    int bb = z >> 2, q = z & 3;
    int tid = threadIdx.x;
    int tx = tid & 15, ty = tid >> 4;
    int x0 = blockIdx.x * 16, y0 = blockIdx.y * 16;
    int x = x0 + tx, y = y0 + ty;

    const float* ib0 = in0 + ((size_t)bb * 64 + q * 4) * HWP;
    const float* ib1 = in1 + ((size_t)bb * 64 + q * 4) * HWP;
    for (int i = tid; i < 4 * 784; i += 256) {
        int ci = i / 784; int r = i - ci * 784;
        int py = r / 28, px = r - py * 28;
        int yy = y0 + py - 6, xx = x0 + px - 6;
        float v = 0.f;
        if ((unsigned)yy < HH && (unsigned)xx < WW) {
            int gp = (size_t)ci * HWP + yy * WW + xx;
            v = ib0[gp] + ib1[gp];
        }
        s_p[ci][py * LKS + px] = v;
    }
    __syncthreads();

    float acc[16];
#pragma unroll
    for (int co = 0; co < 16; ++co) acc[co] = 0.f;

#pragma unroll
    for (int ci4 = 0; ci4 < 4; ++ci4) {
        int ci = q * 4 + ci4;
        float orb[28];
#pragma unroll
        for (int o = 0; o < 28; ++o) orb[o] = 0.f;
#pragma unroll
        for (int ky = 0; ky < 13; ++ky) {
#pragma unroll
            for (int kx = 0; kx < 13; ++kx) {
                const int a = (ky < 6) ? (6 - ky) : (ky - 6);
                const int b = (kx < 6) ? (6 - kx) : (kx - 6);
                const int lo = (a < b) ? a : b;
                const int hi = (a < b) ? b : a;
                const int idx = lo * 7 - (lo * (lo - 1)) / 2 + (hi - lo);
                orb[idx] += s_p[ci4][(ty + ky) * LKS + tx + kx];
            }
        }
        const float* wci = lkO + ci * 28 * 16;
#pragma unroll
        for (int o = 0; o < 28; ++o) {
            float ov = orb[o];
            const float* wr = wci + o * 16;
#pragma unroll
            for (int co = 0; co < 16; ++co) acc[co] += ov * wr[co];
        }
        float d = 0.f;
        const float* dkr = dk + bb * 144 + ci * 9;
#pragma unroll
        for (int dy = 0; dy < 3; ++dy)
#pragma unroll
            for (int dx = 0; dx < 3; ++dx)
                d += s_p[ci4][(ty + 5 + dy) * LKS + tx + 5 + dx] * dkr[dy * 3 + dx];
#pragma unroll
        for (int co = 0; co < 16; ++co) acc[co] += (co == ci) ? d : 0.f;
    }

    if (x < WW && y < HH) {
        int p = y * WW + x;
        float* ob = out + (size_t)q * PARTSZ + (size_t)bb * 16 * HWP + p;
#pragma unroll
        for (int co = 0; co < 16; ++co) ob[(size_t)co * HWP] = acc[co];
    }
}

// ------- 1x1 conv over concat(sum of 4 x1 partials, (y0+y1)[16..63]) ; += into xout -----
__global__ __launch_bounds__(256, 2) void pconv_add_kernel(
    const float* __restrict__ x1q,  // 4 partial buffers, stride PARTSZ
    const float* __restrict__ y0, const float* __restrict__ y1,
    const float* __restrict__ wt, const float* __restrict__ bias,
    float* __restrict__ xout)
{
    int p4 = blockIdx.x * 256 + threadIdx.x;
    int o0 = blockIdx.y * 16;
    int bb = blockIdx.z;
    if (p4 >= NP4) return;
    float4 acc[16];
#pragma unroll
    for (int j = 0; j < 16; ++j) {
        float bv = bias[o0 + j];
        acc[j] = make_float4(bv, bv, bv, bv);
    }
    const float4* xb0 = (const float4*)(x1q + (size_t)bb * 16 * HWP) + p4;
    const float4* xb1 = (const float4*)(x1q + PARTSZ + (size_t)bb * 16 * HWP) + p4;
    const float4* xb2 = (const float4*)(x1q + 2 * PARTSZ + (size_t)bb * 16 * HWP) + p4;
    const float4* xb3 = (const float4*)(x1q + 3 * PARTSZ + (size_t)bb * 16 * HWP) + p4;
    for (int c = 0; c < 16; ++c) {
        float4 a0 = xb0[(size_t)c * NP4], a1 = xb1[(size_t)c * NP4];
        float4 a2 = xb2[(size_t)c * NP4], a3 = xb3[(size_t)c * NP4];
        float4 xv;
        xv.x = (a0.x + a1.x) + (a2.x + a3.x);
        xv.y = (a0.y + a1.y) + (a2.y + a3.y);
        xv.z = (a0.z + a1.z) + (a2.z + a3.z);
        xv.w = (a0.w + a1.w) + (a2.w + a3.w);
        const float* wr = wt + c * 64 + o0;
#pragma unroll
        for (int j = 0; j < 16; ++j) {
            float w = wr[j];
            acc[j].x += xv.x * w; acc[j].y += xv.y * w;
            acc[j].z += xv.z * w; acc[j].w += xv.w * w;
        }
    }
    const float4* yb0 = (const float4*)(y0 + ((size_t)bb * 64 + 16) * HWP) + p4;
    const float4* yb1 = (const float4*)(y1 + ((size_t)bb * 64 + 16) * HWP) + p4;
    for (int c = 0; c < 48; ++c) {
        float4 v0 = yb0[(size_t)c * NP4], v1 = yb1[(size_t)c * NP4];
        float4 xv;
        xv.x = v0.x + v1.x; xv.y = v0.y + v1.y;
        xv.z = v0.z + v1.z; xv.w = v0.w + v1.w;
        const float* wr = wt + (16 + c) * 64 + o0;
#pragma unroll
        for (int j = 0; j < 16; ++j) {
            float w = wr[j];
            acc[j].x += xv.x * w; acc[j].y += xv.y * w;
            acc[j].z += xv.z * w; acc[j].w += xv.w * w;
        }
    }
    float4* ob = (float4*)(xout + ((size_t)bb * 64 + o0) * HWP) + p4;
#pragma unroll
    for (int j = 0; j < 16; ++j) {
        float4 old = ob[(size_t)j * NP4];
        old.x += acc[j].x; old.y += acc[j].y; old.z += acc[j].z; old.w += acc[j].w;
        ob[(size_t)j * NP4] = old;
    }
}

// ---------------- final 3x3 conv, 4-way ci-split ----------------
// grid (13,13,B*4); z -> bb = z>>2, q = z&3 (input channels q*16 .. q*16+15)
// q<3 writes partial to pbase + q*PART64; q==3 writes (acc + bias + skip) into xout.
__global__ __launch_bounds__(256, 4) void conv3_part_kernel(
    const float* __restrict__ in, const float* __restrict__ wt3,  // (ci,tap,64)
    const float* __restrict__ bias, const float* __restrict__ skip,
    float* __restrict__ pbase, float* __restrict__ xout)
{
    __shared__ float s_p[16][18 * DPS];
    int tid = threadIdx.x;
    int tx = tid & 15, ty = tid >> 4;
    int x0 = blockIdx.x * 16, y0 = blockIdx.y * 16;
    int bb = blockIdx.z >> 2, q = blockIdx.z & 3;
    int cbase = q * 16;
    int x = x0 + tx, y = y0 + ty;

    float acc[64];
#pragma unroll
    for (int o = 0; o < 64; ++o) acc[o] = 0.f;

    const float* ibase = in + ((size_t)bb * 64 + cbase) * HWP;
    for (int i = tid; i < 16 * 324; i += 256) {
        int ci = i / 324; int r = i - ci * 324;
        int py = r / 18, px = r - py * 18;
        int yy = y0 + py - 1, xx = x0 + px - 1;
        float v = 0.f;
        if ((unsigned)yy < HH && (unsigned)xx < WW)
            v = ibase[(size_t)ci * HWP + yy * WW + xx];
        s_p[ci][py * DPS + px] = v;
    }
    __syncthreads();

#pragma unroll 2
    for (int ci = 0; ci < 16; ++ci) {
        const float* wr0 = wt3 + (size_t)(cbase + ci) * 9 * 64;
#pragma unroll
        for (int ky = 0; ky < 3; ++ky) {
#pragma unroll
            for (int kx = 0; kx < 3; ++kx) {
                float xv = s_p[ci][(ty + ky) * DPS + tx + kx];
                const float* wr = wr0 + (ky * 3 + kx) * 64;
#pragma unroll
                for (int o = 0; o < 64; ++o) acc[o] += xv * wr[o];
            }
        }
    }

    if (x < WW && y < HH) {
        int p = y * WW + x;
        if (q < 3) {
            float* ob = pbase + (size_t)q * PART64 + (size_t)bb * 64 * HWP + p;
#pragma unroll
            for (int o = 0; o < 64; ++o) ob[(size_t)o * HWP] = acc[o];
        } else {
            const float* sb = skip + (size_t)bb * 64 * HWP + p;
            float* ob = xout + (size_t)bb * 64 * HWP + p;
#pragma unroll
            for (int o = 0; o < 64; ++o)
                ob[(size_t)o * HWP] = acc[o] + bias[o] + sb[(size_t)o * HWP];
        }
    }
}

// ---------------- combine conv3 partials: x += p0 + p1 + p2 ----------------
__global__ __launch_bounds__(256) void combine4_kernel(
    const float* __restrict__ p, float* __restrict__ x)
{
    int idx = blockIdx.x * 256 + threadIdx.x;   // float4 index over B*64*NP4
    if (idx >= BB * 64 * NP4) return;
    const float4* pf = (const float4*)p;
    float4 a = pf[idx];
    float4 b = pf[idx + 2560000];
    float4 c = pf[idx + 5120000];
    float4 r = ((float4*)x)[idx];
    r.x += a.x + b.x + c.x;
    r.y += a.y + b.y + c.y;
    r.z += a.z + b.z + c.z;
    r.w += a.w + b.w + c.w;
    ((float4*)x)[idx] = r;
}

extern "C" void kernel_launch(void* const* d_in, const int* in_sizes, int n_in,
                              void* d_out, int out_size, void* d_ws, size_t ws_size,
                              hipStream_t stream)
{
    const float* x_in      = (const float*)d_in[0];
    const float* ln_proj_w = (const float*)d_in[1];
    const float* ln_proj_b = (const float*)d_in[2];
    const float* proj_p_w  = (const float*)d_in[3];
    const float* proj_p_b  = (const float*)d_in[4];
    const float* proj_d_w  = (const float*)d_in[5];
    const float* proj_d_b  = (const float*)d_in[6];
    const float* proj_a_w  = (const float*)d_in[7];
    const float* proj_a_b  = (const float*)d_in[8];
    const float* ln_attn_w = (const float*)d_in[9];
    const float* ln_attn_b = (const float*)d_in[10];
    const float* qkv_w     = (const float*)d_in[11];
    const float* qkv_b     = (const float*)d_in[12];
    const float* attn_o_w  = (const float*)d_in[13];
    const float* attn_o_b  = (const float*)d_in[14];
    const float* rpb       = (const float*)d_in[15];
    const float* dwcp1_w   = (const float*)d_in[16];
    const float* dwcp1_b   = (const float*)d_in[17];
    const float* dwcp2_w   = (const float*)d_in[18];
    const float* dwcp2_b   = (const float*)d_in[19];
    const float* pconv_w   = (const float*)d_in[20];
    const float* pconv_b   = (const float*)d_in[21];
    const float* ffn_p_w   = (const float*)d_in[22];
    const float* ffn_p_b   = (const float*)d_in[23];
    const float* ffn_d_w   = (const float*)d_in[24];
    const float* ffn_d_b   = (const float*)d_in[25];
    const float* ffn_a_w   = (const float*)d_in[26];
    const float* ffn_a_b   = (const float*)d_in[27];
    const float* ln_out_w  = (const float*)d_in[28];
    const float* ln_out_b  = (const float*)d_in[29];
    const float* conv_o_w  = (const float*)d_in[30];
    const float* conv_o_b  = (const float*)d_in[31];
    const float* plk       = (const float*)d_in[32];

    float* X  = (float*)d_out;
    float* ws = (float*)d_ws;

    // workspace map (floats):
    //  0        .. 10.24M : A (LN out) / AP0 (ffn dwproj partial 0)
    //  10.24M   .. 40.96M : QKV (attn) | R1 (10.24-23.04) | conv3 partials P0/P1/P2
    //  23.04M   .. 33.28M : AP1 (ffn dwproj partial 1)
    //  33.28M   .. 43.52M : R2Q (4 lkconv partials)
    //  43.52M   ..        : LKT, GM, DK, WT  (temporally always live)
    float* A   = ws;
    float* AP0 = ws;
    float* QKV = ws + 10240000;
    float* R1  = ws + 10240000;
    float* P3B = ws + 10240000;           // conv3 partials P0,P1,P2 (stride PART64)
    float* AP1 = ws + 23040000;
    float* R2Q = ws + 33280000;
    float* LKT = ws + 43520000;
    float* GM  = LKT + 43264;
    float* DK  = GM + 64;
    float* WT  = DK + 576;

    dim3 b256(256);
    dim3 gLN(157, 4);
    dim3 gT4(13, 13, 4);
    dim3 gT8(13, 13, 8);
    dim3 gT16(13, 13, 16);

    prep_kernel<<<dim3(384), b256, 0, stream>>>(proj_p_w, attn_o_w, ffn_p_w, proj_a_w,
                                                ffn_a_w, pconv_w, conv_o_w, qkv_w, WT);
    geo_kernel<<<dim3(28), b256, 0, stream>>>(plk, LKT);

    // x = LN(x); x = conv_ffn(x) [proj] — unsplit (output X must materialize)
    ln_kernel<<<gLN, b256, 0, stream>>>(x_in, ln_proj_w, ln_proj_b, A);
    conv1x1_kernel<<<dim3(40, 8, 4), b256, 0, stream>>>(A, WT + 0, proj_p_b, R1, 64, 128, 1, 0);
    dwproj_kernel<<<gT4, b256, 0, stream>>>(R1, proj_d_w, proj_d_b, WT + 22528, proj_a_b,
                                            X, X, 128, 0);

    // x = x + window_attention(LN(x))
    ln_kernel<<<gLN, b256, 0, stream>>>(X, ln_attn_w, ln_attn_b, A);
    conv1x1_kernel<<<dim3(40, 12, 4), b256, 0, stream>>>(A, WT + 86016, qkv_b, QKV, 64, 192, 0, 0);
    winattn2_kernel<<<dim3(400, 8, 4), dim3(128), 0, stream>>>(QKV, rpb, A);
    conv1x1_kernel<<<dim3(40, 4, 4), b256, 0, stream>>>(A, WT + 8192, attn_o_b, X, 64, 64, 0, 1);

    for (int i = 0; i < 2; ++i) {
        conv1x1_kernel<<<dim3(40, 5, 4), b256, 0, stream>>>(X, WT + 12288 + i * 5120, ffn_p_b + i * 80, R1, 64, 80, 1, 0);
        // y = dwproj(R1) as two ci-partials AP0 + AP1 (never materialized whole)
        dwproj_kernel<<<gT8, b256, 0, stream>>>(R1, ffn_d_w + i * 720, ffn_d_b + i * 80,
                                                WT + 30720 + i * 5120, ffn_a_b + i * 64,
                                                AP0, AP1, 80, 1);
        gmean2_kernel<<<dim3(64), b256, 0, stream>>>(AP0, AP1, GM);
        dynk_kernel<<<dim3(4), dim3(192), 0, stream>>>(GM, dwcp1_w + i * 128, dwcp1_b + i * 8,
                                                       dwcp2_w + i * 1152, dwcp2_b + i * 144, DK);
        lkconv_kernel<<<gT16, b256, 0, stream>>>(AP0, AP1, LKT, DK, R2Q);
        pconv_add_kernel<<<dim3(40, 4, 4), b256, 0, stream>>>(R2Q, AP0, AP1,
                                                              WT + 40960 + i * 4096, pconv_b + i * 64, X);
    }

    // x = conv3x3(LN(x)) + skip  — 4-way ci-split; q==3 folds bias+skip into X
    ln_kernel<<<gLN, b256, 0, stream>>>(X, ln_out_w, ln_out_b, A);
    conv3_part_kernel<<<gT16, b256, 0, stream>>>(A, WT + 49152, conv_o_b, x_in, P3B, X);
    combine4_kernel<<<dim3(10000), b256, 0, stream>>>(P3B, X);
}

// Round 11
// 1443.379 us; speedup vs baseline: 1.1878x; 1.0262x over previous
//
#include <hip/hip_runtime.h>
#include <math.h>

#define HH 200
#define WW 200
#define HWP 40000
#define NP4 10000
#define BB 4

#define LKS 40   // lkconv LDS row stride
#define DPS 24   // dwproj/conv3 LDS row stride
#define PARTSZ 2560000    // one (B,16,H,W) partial buffer (lkconv)
#define PART64 10240000   // one (B,64,H,W) partial buffer

typedef __fp16 f16x2 __attribute__((ext_vector_type(2)));

__device__ __forceinline__ float gelu_f(float x) {
    return 0.5f * x * (1.0f + erff(x * 0.7071067811865475f));
}

// ---------------- weight prep (transposes for scalar weight loads) ----------------
// wt layout offsets (floats):
//  0      wtP   (64,128)   proj_p
//  8192   wtAO  (64,64)    attn_out
//  12288  wtFP0 (64,80)    ffn_p[0]
//  17408  wtFP1 (64,80)    ffn_p[1]
//  22528  wtPA  (128,64)   proj_a
//  30720  wtFA0 (80,64)    ffn_a[0]
//  35840  wtFA1 (80,64)    ffn_a[1]
//  40960  wtPC0 (64,64)    pconv[0]
//  45056  wtPC1 (64,64)    pconv[1]
//  49152  wt3   (64,9,64)  conv_out  [ci][tap][co]
//  86016  wtQKV (64,192)   qkv
__device__ __forceinline__ void tr_w(const float* __restrict__ w, float* __restrict__ wt,
                                     int Co, int Ci, int idx) {
    int o = idx / Ci, c = idx - o * Ci;
    wt[c * Co + o] = w[idx];
}

__global__ __launch_bounds__(256) void prep_kernel(
    const float* __restrict__ pp, const float* __restrict__ ao,
    const float* __restrict__ fp, const float* __restrict__ pa,
    const float* __restrict__ fa, const float* __restrict__ pc,
    const float* __restrict__ co3, const float* __restrict__ qkvw,
    float* __restrict__ wt)
{
    int i = blockIdx.x * 256 + threadIdx.x;
    if (i < 8192) { tr_w(pp, wt + 0, 128, 64, i); return; } i -= 8192;
    if (i < 4096) { tr_w(ao, wt + 8192, 64, 64, i); return; } i -= 4096;
    if (i < 5120) { tr_w(fp, wt + 12288, 80, 64, i); return; } i -= 5120;
    if (i < 5120) { tr_w(fp + 5120, wt + 17408, 80, 64, i); return; } i -= 5120;
    if (i < 8192) { tr_w(pa, wt + 22528, 64, 128, i); return; } i -= 8192;
    if (i < 5120) { tr_w(fa, wt + 30720, 64, 80, i); return; } i -= 5120;
    if (i < 5120) { tr_w(fa + 5120, wt + 35840, 64, 80, i); return; } i -= 5120;
    if (i < 4096) { tr_w(pc, wt + 40960, 64, 64, i); return; } i -= 4096;
    if (i < 4096) { tr_w(pc + 4096, wt + 45056, 64, 64, i); return; } i -= 4096;
    if (i < 36864) {
        int o = i / 576; int r = i - o * 576; int c = r / 9; int t = r - c * 9;
        wt[49152 + (c * 9 + t) * 64 + o] = co3[i];
        return;
    } i -= 36864;
    if (i < 12288) { tr_w(qkvw, wt + 86016, 192, 64, i); return; }
}

// ---------------- LayerNorm over 64 channels ----------------
__global__ __launch_bounds__(256, 2) void ln_kernel(
    const float* __restrict__ in, const float* __restrict__ w,
    const float* __restrict__ b, float* __restrict__ out)
{
    int p = blockIdx.x * 256 + threadIdx.x;
    int bb = blockIdx.y;
    if (p >= HWP) return;
    const float* ib = in + (size_t)bb * 64 * HWP + p;
    float v[64];
    float mu = 0.f;
#pragma unroll
    for (int c = 0; c < 64; ++c) { v[c] = ib[(size_t)c * HWP]; mu += v[c]; }
    mu *= (1.f / 64.f);
    float var = 0.f;
#pragma unroll
    for (int c = 0; c < 64; ++c) { float d = v[c] - mu; var += d * d; }
    var *= (1.f / 64.f);
    float r = rsqrtf(var + 1e-6f);
    float* ob = out + (size_t)bb * 64 * HWP + p;
#pragma unroll
    for (int c = 0; c < 64; ++c) ob[(size_t)c * HWP] = (v[c] - mu) * r * w[c] + b[c];
}

// ------- LayerNorm over sum of two partials; writes xsum = in0+in1 AND lnout = LN ------
// lnout may alias in0 (per-pixel: all reads happen before writes in this thread).
__global__ __launch_bounds__(256, 2) void ln2_kernel(
    const float* in0, const float* in1,
    const float* __restrict__ w, const float* __restrict__ b,
    float* __restrict__ xsum, float* lnout)
{
    int p = blockIdx.x * 256 + threadIdx.x;
    int bb = blockIdx.y;
    if (p >= HWP) return;
    const float* i0 = in0 + (size_t)bb * 64 * HWP + p;
    const float* i1 = in1 + (size_t)bb * 64 * HWP + p;
    float v[64];
    float mu = 0.f;
#pragma unroll
    for (int c = 0; c < 64; ++c) { v[c] = i0[(size_t)c * HWP] + i1[(size_t)c * HWP]; mu += v[c]; }
    mu *= (1.f / 64.f);
    float var = 0.f;
#pragma unroll
    for (int c = 0; c < 64; ++c) { float d = v[c] - mu; var += d * d; }
    var *= (1.f / 64.f);
    float r = rsqrtf(var + 1e-6f);
    float* xb = xsum + (size_t)bb * 64 * HWP + p;
    float* ob = lnout + (size_t)bb * 64 * HWP + p;
#pragma unroll
    for (int c = 0; c < 64; ++c) {
        xb[(size_t)c * HWP] = v[c];
        ob[(size_t)c * HWP] = (v[c] - mu) * r * w[c] + b[c];
    }
}

// ---------------- 1x1 conv: float4 pixels, 16 outputs/thread, scalar weights ----------------
__global__ __launch_bounds__(256, 2) void conv1x1_kernel(
    const float* __restrict__ in, const float* __restrict__ wt,  // (Ci,Co)
    const float* __restrict__ bias, float* __restrict__ out,
    int Ci, int Co, int do_gelu, int do_add)
{
    int p4 = blockIdx.x * 256 + threadIdx.x;
    int o0 = blockIdx.y * 16;
    int bb = blockIdx.z;
    if (p4 >= NP4) return;
    float4 acc[16];
#pragma unroll
    for (int j = 0; j < 16; ++j) {
        float bv = bias[o0 + j];
        acc[j] = make_float4(bv, bv, bv, bv);
    }
    const float4* ib = (const float4*)(in + (size_t)bb * Ci * HWP) + p4;
    for (int c = 0; c < Ci; ++c) {
        float4 xv = ib[(size_t)c * NP4];
        const float* wr = wt + c * Co + o0;
#pragma unroll
        for (int j = 0; j < 16; ++j) {
            float w = wr[j];
            acc[j].x += xv.x * w; acc[j].y += xv.y * w;
            acc[j].z += xv.z * w; acc[j].w += xv.w * w;
        }
    }
    float4* ob = (float4*)(out + ((size_t)bb * Co + o0) * HWP) + p4;
#pragma unroll
    for (int j = 0; j < 16; ++j) {
        float4 r = acc[j];
        if (do_gelu) {
            r.x = gelu_f(r.x); r.y = gelu_f(r.y); r.z = gelu_f(r.z); r.w = gelu_f(r.w);
        }
        if (do_add) {
            float4 old = ob[(size_t)j * NP4];
            r.x += old.x; r.y += old.y; r.z += old.z; r.w += old.w;
        }
        ob[(size_t)j * NP4] = r;
    }
}

// ------- fused: gelu(dwconv3x3(in)) + in, then 1x1 proj partial (ci-split) -------
// grid (13,13,B<<splitlog); z -> part = z & ((1<<splitlog)-1), bb = z >> splitlog
__global__ __launch_bounds__(256, 4) void dwproj_kernel(
    const float* __restrict__ in,   // (B,Ci,H,W)
    const float* __restrict__ dw,   // (Ci,9)
    const float* __restrict__ db,   // (Ci)
    const float* __restrict__ awt,  // (Ci,64) transposed
    const float* __restrict__ ab,   // (64)
    float* __restrict__ out0, float* __restrict__ out1,
    int Ci, int splitlog)
{
    __shared__ float s_p[16][18 * DPS];
    int tid = threadIdx.x;
    int tx = tid & 15, ty = tid >> 4;
    int x0 = blockIdx.x * 16, y0 = blockIdx.y * 16;
    int part = blockIdx.z & ((1 << splitlog) - 1);
    int bb = blockIdx.z >> splitlog;
    int cic = Ci >> splitlog;
    int cbase = part * cic;
    float* dst = (part == 0) ? out0 : out1;
    int x = x0 + tx, y = y0 + ty;

    float acc[64];
    if (part == 0) {
#pragma unroll
        for (int o = 0; o < 64; ++o) acc[o] = ab[o];
    } else {
#pragma unroll
        for (int o = 0; o < 64; ++o) acc[o] = 0.f;
    }

    const float* ibase = in + (size_t)bb * Ci * HWP;
    for (int c0 = cbase; c0 < cbase + cic; c0 += 16) {
        int chunk = cbase + cic - c0; if (chunk > 16) chunk = 16;
        __syncthreads();
        for (int i = tid; i < chunk * 324; i += 256) {
            int ci = i / 324; int r = i - ci * 324;
            int py = r / 18, px = r - py * 18;
            int yy = y0 + py - 1, xx = x0 + px - 1;
            float v = 0.f;
            if ((unsigned)yy < HH && (unsigned)xx < WW)
                v = ibase[(size_t)(c0 + ci) * HWP + yy * WW + xx];
            s_p[ci][py * DPS + px] = v;
        }
        __syncthreads();
        for (int ci = 0; ci < chunk; ++ci) {
            int c = c0 + ci;
            float s = db[c];
            const float* dwr = dw + c * 9;
#pragma unroll
            for (int ky = 0; ky < 3; ++ky)
#pragma unroll
                for (int kx = 0; kx < 3; ++kx)
                    s += s_p[ci][(ty + ky) * DPS + tx + kx] * dwr[ky * 3 + kx];
            float v = gelu_f(s) + s_p[ci][(ty + 1) * DPS + tx + 1];
            const float* wr = awt + c * 64;
#pragma unroll
            for (int o = 0; o < 64; ++o) acc[o] += v * wr[o];
        }
    }

    if (x < WW && y < HH) {
        int p = y * WW + x;
        float* ob = dst + (size_t)bb * 64 * HWP + p;
#pragma unroll
        for (int o = 0; o < 64; ++o) ob[(size_t)o * HWP] = acc[o];
    }
}

// ---------------- attention v3: qkv precomputed; scores cached in f16-packed regs -------
__global__ __launch_bounds__(128, 4) void winattn2_kernel(
    const float* __restrict__ qkv,  // (B,192,H,W)
    const float* __restrict__ rpb,  // (8,361)
    float* __restrict__ out)        // (B,64,H,W)
{
    __shared__ __align__(16) float s_k[100][8];
    __shared__ __align__(16) float s_v[100][8];
    __shared__ float s_b[361];

    int head = blockIdx.y, bb = blockIdx.z;
    int wy = blockIdx.x / 20, wx = blockIdx.x - wy * 20;
    int tid = threadIdx.x;

    for (int i = tid; i < 361; i += 128) s_b[i] = rpb[head * 361 + i];

    int ty = tid / 10, tx = tid - ty * 10;
    float q[8];
    if (tid < 100) {
        int y = wy * 10 + ty, x = wx * 10 + tx;
        int gp = y * WW + x;
        const float* qb = qkv + ((size_t)bb * 192 + head * 8) * HWP + gp;
        const float* kb = qb + (size_t)64 * HWP;
        const float* vb = qb + (size_t)128 * HWP;
        const float scale = 0.3535533905932738f; // 1/sqrt(8)
#pragma unroll
        for (int cc = 0; cc < 8; ++cc) q[cc] = qb[(size_t)cc * HWP] * scale;
        float4 t0, t1;
        t0.x = kb[0];               t0.y = kb[(size_t)1 * HWP];
        t0.z = kb[(size_t)2 * HWP]; t0.w = kb[(size_t)3 * HWP];
        t1.x = kb[(size_t)4 * HWP]; t1.y = kb[(size_t)5 * HWP];
        t1.z = kb[(size_t)6 * HWP]; t1.w = kb[(size_t)7 * HWP];
        *(float4*)(&s_k[tid][0]) = t0;
        *(float4*)(&s_k[tid][4]) = t1;
        t0.x = vb[0];               t0.y = vb[(size_t)1 * HWP];
        t0.z = vb[(size_t)2 * HWP]; t0.w = vb[(size_t)3 * HWP];
        t1.x = vb[(size_t)4 * HWP]; t1.y = vb[(size_t)5 * HWP];
        t1.z = vb[(size_t)6 * HWP]; t1.w = vb[(size_t)7 * HWP];
        *(float4*)(&s_v[tid][0]) = t0;
        *(float4*)(&s_v[tid][4]) = t1;
    }
    __syncthreads();

    if (tid < 100) {
        const float4* k4 = (const float4*)s_k;
        const float4* v4 = (const float4*)s_v;
        const float* brow = s_b + (180 - ty * 19 - tx);

        f16x2 s16[50];
        float m = -1e30f;
        // pass 1: scores (stored packed) + max
#pragma unroll
        for (int i = 0; i < 50; ++i) {
            const int k0 = 2 * i, k1 = 2 * i + 1;
            const int c0 = (k0 / 10) * 19 + (k0 % 10);
            const int c1 = (k1 / 10) * 19 + (k1 % 10);
            float4 ka = k4[k0 * 2], kb2 = k4[k0 * 2 + 1];
            float s0 = brow[c0]
                     + q[0] * ka.x + q[1] * ka.y + q[2] * ka.z + q[3] * ka.w
                     + q[4] * kb2.x + q[5] * kb2.y + q[6] * kb2.z + q[7] * kb2.w;
            ka = k4[k1 * 2]; kb2 = k4[k1 * 2 + 1];
            float s1 = brow[c1]
                     + q[0] * ka.x + q[1] * ka.y + q[2] * ka.z + q[3] * ka.w
                     + q[4] * kb2.x + q[5] * kb2.y + q[6] * kb2.z + q[7] * kb2.w;
            m = fmaxf(m, fmaxf(s0, s1));
            s16[i] = __builtin_amdgcn_cvt_pkrtz(s0, s1);
        }
        // pass 2: exp + PV from stored scores
        float l = 0.f;
        float o[8];
#pragma unroll
        for (int cc = 0; cc < 8; ++cc) o[cc] = 0.f;
#pragma unroll
        for (int i = 0; i < 50; ++i) {
            float e0 = __expf((float)s16[i][0] - m);
            float e1 = __expf((float)s16[i][1] - m);
            l += e0 + e1;
            float4 va = v4[4 * i], vb2 = v4[4 * i + 1];
            o[0] += e0 * va.x; o[1] += e0 * va.y; o[2] += e0 * va.z; o[3] += e0 * va.w;
            o[4] += e0 * vb2.x; o[5] += e0 * vb2.y; o[6] += e0 * vb2.z; o[7] += e0 * vb2.w;
            va = v4[4 * i + 2]; vb2 = v4[4 * i + 3];
            o[0] += e1 * va.x; o[1] += e1 * va.y; o[2] += e1 * va.z; o[3] += e1 * va.w;
            o[4] += e1 * vb2.x; o[5] += e1 * vb2.y; o[6] += e1 * vb2.z; o[7] += e1 * vb2.w;
        }
        float rl = 1.f / l;
        int y = wy * 10 + ty, x = wx * 10 + tx;
        float* ob = out + ((size_t)bb * 64 + head * 8) * HWP + y * WW + x;
#pragma unroll
        for (int cc = 0; cc < 8; ++cc) ob[(size_t)cc * HWP] = o[cc] * rl;
    }
}

// ------- geometric ensemble -> D4-orbit weight table (ci, rep, co) -------
__global__ __launch_bounds__(256) void geo_kernel(
    const float* __restrict__ k, float* __restrict__ out)
{
    int i = blockIdx.x * 256 + threadIdx.x;
    if (i >= 256 * 28) return;
    int oc = i / 28, rep = i - oc * 28;   // oc = co*16 + ci
    int co = oc >> 4, ci = oc & 15;
    int a = 0, r = rep;
    while (r >= 7 - a) { r -= 7 - a; ++a; }
    int b2 = a + r;
    int y = 6 + a, x = 6 + b2;
    const float* kb = k + oc * 169;
    float s = kb[y * 13 + x] + kb[y * 13 + (12 - x)] + kb[(12 - y) * 13 + x] + kb[(12 - y) * 13 + (12 - x)]
            + kb[(12 - x) * 13 + y] + kb[x * 13 + y] + kb[(12 - x) * 13 + (12 - y)] + kb[x * 13 + (12 - y)];
    out[(ci * 28 + rep) * 16 + co] = s * 0.125f;
}

// ---------------- global mean over H,W of first-16 channels (sum of 2 partials) --------
__global__ __launch_bounds__(256) void gmean2_kernel(
    const float* __restrict__ in0, const float* __restrict__ in1, float* __restrict__ g)
{
    int bc = blockIdx.x;            // b*16 + c
    int bb = bc >> 4, c = bc & 15;
    const float* p0 = in0 + ((size_t)bb * 64 + c) * HWP;
    const float* p1 = in1 + ((size_t)bb * 64 + c) * HWP;
    float s = 0.f;
    for (int i = threadIdx.x; i < HWP; i += 256) s += p0[i] + p1[i];
#pragma unroll
    for (int off = 32; off > 0; off >>= 1) s += __shfl_down(s, off);
    __shared__ float red[4];
    int wave = threadIdx.x >> 6;
    if ((threadIdx.x & 63) == 0) red[wave] = s;
    __syncthreads();
    if (threadIdx.x == 0)
        g[bc] = (red[0] + red[1] + red[2] + red[3]) * (1.f / 40000.f);
}

// ---------------- tiny MLP -> dynamic 3x3 kernels ----------------
__global__ __launch_bounds__(192) void dynk_kernel(
    const float* __restrict__ g, const float* __restrict__ w1, const float* __restrict__ b1,
    const float* __restrict__ w2, const float* __restrict__ b2, float* __restrict__ dk)
{
    int bb = blockIdx.x;
    __shared__ float s_g2[8];
    int tid = threadIdx.x;
    if (tid < 8) {
        float a = b1[tid];
        for (int c = 0; c < 16; ++c) a += w1[tid * 16 + c] * g[bb * 16 + c];
        s_g2[tid] = gelu_f(a);
    }
    __syncthreads();
    if (tid < 144) {
        float a = b2[tid];
#pragma unroll
        for (int i = 0; i < 8; ++i) a += w2[tid * 8 + i] * s_g2[i];
        dk[bb * 144 + tid] = a;
    }
}

// ------- 13x13 D4-symmetric conv via 28 orbit sums + dynamic depthwise 3x3 -------
// input = in0 + in1 (dwproj partials). 4-way ci-split: grid (13,13,B*4).
__global__ __launch_bounds__(256, 4) void lkconv_kernel(
    const float* __restrict__ in0, const float* __restrict__ in1,
    const float* __restrict__ lkO,  // (16,28,16)  [ci][rep][co]
    const float* __restrict__ dk,   // (B,144)
    float* __restrict__ out)        // 4 partial buffers, stride PARTSZ
{
    __shared__ float s_p[4][28 * LKS];  // 17.9 KB
    int z = blockIdx.z;
    int bb = z >> 2, q = z & 3;
    int tid = threadIdx.x;
    int tx = tid & 15, ty = tid >> 4;
    int x0 = blockIdx.x * 16, y0 = blockIdx.y * 16;
    int x = x0 + tx, y = y0 + ty;

    const float* ib0 = in0 + ((size_t)bb * 64 + q * 4) * HWP;
    const float* ib1 = in1 + ((size_t)bb * 64 + q * 4) * HWP;
    for (int i = tid; i < 4 * 784; i += 256) {
        int ci = i / 784; int r = i - ci * 784;
        int py = r / 28, px = r - py * 28;
        int yy = y0 + py - 6, xx = x0 + px - 6;
        float v = 0.f;
        if ((unsigned)yy < HH && (unsigned)xx < WW) {
            int gp = (size_t)ci * HWP + yy * WW + xx;
            v = ib0[gp] + ib1[gp];
        }
        s_p[ci][py * LKS + px] = v;
    }
    __syncthreads();

    float acc[16];
#pragma unroll
    for (int co = 0; co < 16; ++co) acc[co] = 0.f;

#pragma unroll
    for (int ci4 = 0; ci4 < 4; ++ci4) {
        int ci = q * 4 + ci4;
        float orb[28];
#pragma unroll
        for (int o = 0; o < 28; ++o) orb[o] = 0.f;
#pragma unroll
        for (int ky = 0; ky < 13; ++ky) {
#pragma unroll
            for (int kx = 0; kx < 13; ++kx) {
                const int a = (ky < 6) ? (6 - ky) : (ky - 6);
                const int b = (kx < 6) ? (6 - kx) : (kx - 6);
                const int lo = (a < b) ? a : b;
                const int hi = (a < b) ? b : a;
                const int idx = lo * 7 - (lo * (lo - 1)) / 2 + (hi - lo);
                orb[idx] += s_p[ci4][(ty + ky) * LKS + tx + kx];
            }
        }
        const float* wci = lkO + ci * 28 * 16;
#pragma unroll
        for (int o = 0; o < 28; ++o) {
            float ov = orb[o];
            const float* wr = wci + o * 16;
#pragma unroll
            for (int co = 0; co < 16; ++co) acc[co] += ov * wr[co];
        }
        float d = 0.f;
        const float* dkr = dk + bb * 144 + ci * 9;
#pragma unroll
        for (int dy = 0; dy < 3; ++dy)
#pragma unroll
            for (int dx = 0; dx < 3; ++dx)
                d += s_p[ci4][(ty + 5 + dy) * LKS + tx + 5 + dx] * dkr[dy * 3 + dx];
#pragma unroll
        for (int co = 0; co < 16; ++co) acc[co] += (co == ci) ? d : 0.f;
    }

    if (x < WW && y < HH) {
        int p = y * WW + x;
        float* ob = out + (size_t)q * PARTSZ + (size_t)bb * 16 * HWP + p;
#pragma unroll
        for (int co = 0; co < 16; ++co) ob[(size_t)co * HWP] = acc[co];
    }
}

// ------- 1x1 conv over concat(sum of 4 x1 partials, (y0+y1)[16..63]) ; += into xout -----
__global__ __launch_bounds__(256, 2) void pconv_add_kernel(
    const float* __restrict__ x1q,  // 4 partial buffers, stride PARTSZ
    const float* __restrict__ y0, const float* __restrict__ y1,
    const float* __restrict__ wt, const float* __restrict__ bias,
    float* __restrict__ xout)
{
    int p4 = blockIdx.x * 256 + threadIdx.x;
    int o0 = blockIdx.y * 16;
    int bb = blockIdx.z;
    if (p4 >= NP4) return;
    float4 acc[16];
#pragma unroll
    for (int j = 0; j < 16; ++j) {
        float bv = bias[o0 + j];
        acc[j] = make_float4(bv, bv, bv, bv);
    }
    const float4* xb0 = (const float4*)(x1q + (size_t)bb * 16 * HWP) + p4;
    const float4* xb1 = (const float4*)(x1q + PARTSZ + (size_t)bb * 16 * HWP) + p4;
    const float4* xb2 = (const float4*)(x1q + 2 * PARTSZ + (size_t)bb * 16 * HWP) + p4;
    const float4* xb3 = (const float4*)(x1q + 3 * PARTSZ + (size_t)bb * 16 * HWP) + p4;
    for (int c = 0; c < 16; ++c) {
        float4 a0 = xb0[(size_t)c * NP4], a1 = xb1[(size_t)c * NP4];
        float4 a2 = xb2[(size_t)c * NP4], a3 = xb3[(size_t)c * NP4];
        float4 xv;
        xv.x = (a0.x + a1.x) + (a2.x + a3.x);
        xv.y = (a0.y + a1.y) + (a2.y + a3.y);
        xv.z = (a0.z + a1.z) + (a2.z + a3.z);
        xv.w = (a0.w + a1.w) + (a2.w + a3.w);
        const float* wr = wt + c * 64 + o0;
#pragma unroll
        for (int j = 0; j < 16; ++j) {
            float w = wr[j];
            acc[j].x += xv.x * w; acc[j].y += xv.y * w;
            acc[j].z += xv.z * w; acc[j].w += xv.w * w;
        }
    }
    const float4* yb0 = (const float4*)(y0 + ((size_t)bb * 64 + 16) * HWP) + p4;
    const float4* yb1 = (const float4*)(y1 + ((size_t)bb * 64 + 16) * HWP) + p4;
    for (int c = 0; c < 48; ++c) {
        float4 v0 = yb0[(size_t)c * NP4], v1 = yb1[(size_t)c * NP4];
        float4 xv;
        xv.x = v0.x + v1.x; xv.y = v0.y + v1.y;
        xv.z = v0.z + v1.z; xv.w = v0.w + v1.w;
        const float* wr = wt + (16 + c) * 64 + o0;
#pragma unroll
        for (int j = 0; j < 16; ++j) {
            float w = wr[j];
            acc[j].x += xv.x * w; acc[j].y += xv.y * w;
            acc[j].z += xv.z * w; acc[j].w += xv.w * w;
        }
    }
    float4* ob = (float4*)(xout + ((size_t)bb * 64 + o0) * HWP) + p4;
#pragma unroll
    for (int j = 0; j < 16; ++j) {
        float4 old = ob[(size_t)j * NP4];
        old.x += acc[j].x; old.y += acc[j].y; old.z += acc[j].z; old.w += acc[j].w;
        ob[(size_t)j * NP4] = old;
    }
}

// ---------------- final 3x3 conv, 4-way ci-split ----------------
// grid (13,13,B*4); z -> bb = z>>2, q = z&3 (input channels q*16 .. q*16+15)
// q<3 writes partial to pbase + q*PART64; q==3 writes (acc + bias + skip) into xout.
__global__ __launch_bounds__(256, 4) void conv3_part_kernel(
    const float* __restrict__ in, const float* __restrict__ wt3,  // (ci,tap,64)
    const float* __restrict__ bias, const float* __restrict__ skip,
    float* __restrict__ pbase, float* __restrict__ xout)
{
    __shared__ float s_p[16][18 * DPS];
    int tid = threadIdx.x;
    int tx = tid & 15, ty = tid >> 4;
    int x0 = blockIdx.x * 16, y0 = blockIdx.y * 16;
    int bb = blockIdx.z >> 2, q = blockIdx.z & 3;
    int cbase = q * 16;
    int x = x0 + tx, y = y0 + ty;

    float acc[64];
#pragma unroll
    for (int o = 0; o < 64; ++o) acc[o] = 0.f;

    const float* ibase = in + ((size_t)bb * 64 + cbase) * HWP;
    for (int i = tid; i < 16 * 324; i += 256) {
        int ci = i / 324; int r = i - ci * 324;
        int py = r / 18, px = r - py * 18;
        int yy = y0 + py - 1, xx = x0 + px - 1;
        float v = 0.f;
        if ((unsigned)yy < HH && (unsigned)xx < WW)
            v = ibase[(size_t)ci * HWP + yy * WW + xx];
        s_p[ci][py * DPS + px] = v;
    }
    __syncthreads();

#pragma unroll 2
    for (int ci = 0; ci < 16; ++ci) {
        const float* wr0 = wt3 + (size_t)(cbase + ci) * 9 * 64;
#pragma unroll
        for (int ky = 0; ky < 3; ++ky) {
#pragma unroll
            for (int kx = 0; kx < 3; ++kx) {
                float xv = s_p[ci][(ty + ky) * DPS + tx + kx];
                const float* wr = wr0 + (ky * 3 + kx) * 64;
#pragma unroll
                for (int o = 0; o < 64; ++o) acc[o] += xv * wr[o];
            }
        }
    }

    if (x < WW && y < HH) {
        int p = y * WW + x;
        if (q < 3) {
            float* ob = pbase + (size_t)q * PART64 + (size_t)bb * 64 * HWP + p;
#pragma unroll
            for (int o = 0; o < 64; ++o) ob[(size_t)o * HWP] = acc[o];
        } else {
            const float* sb = skip + (size_t)bb * 64 * HWP + p;
            float* ob = xout + (size_t)bb * 64 * HWP + p;
#pragma unroll
            for (int o = 0; o < 64; ++o)
                ob[(size_t)o * HWP] = acc[o] + bias[o] + sb[(size_t)o * HWP];
        }
    }
}

// ---------------- combine conv3 partials: x += p0 + p1 + p2 ----------------
__global__ __launch_bounds__(256) void combine4_kernel(
    const float* __restrict__ p, float* __restrict__ x)
{
    int idx = blockIdx.x * 256 + threadIdx.x;   // float4 index over B*64*NP4
    if (idx >= BB * 64 * NP4) return;
    const float4* pf = (const float4*)p;
    float4 a = pf[idx];
    float4 b = pf[idx + 2560000];
    float4 c = pf[idx + 5120000];
    float4 r = ((float4*)x)[idx];
    r.x += a.x + b.x + c.x;
    r.y += a.y + b.y + c.y;
    r.z += a.z + b.z + c.z;
    r.w += a.w + b.w + c.w;
    ((float4*)x)[idx] = r;
}

extern "C" void kernel_launch(void* const* d_in, const int* in_sizes, int n_in,
                              void* d_out, int out_size, void* d_ws, size_t ws_size,
                              hipStream_t stream)
{
    const float* x_in      = (const float*)d_in[0];
    const float* ln_proj_w = (const float*)d_in[1];
    const float* ln_proj_b = (const float*)d_in[2];
    const float* proj_p_w  = (const float*)d_in[3];
    const float* proj_p_b  = (const float*)d_in[4];
    const float* proj_d_w  = (const float*)d_in[5];
    const float* proj_d_b  = (const float*)d_in[6];
    const float* proj_a_w  = (const float*)d_in[7];
    const float* proj_a_b  = (const float*)d_in[8];
    const float* ln_attn_w = (const float*)d_in[9];
    const float* ln_attn_b = (const float*)d_in[10];
    const float* qkv_w     = (const float*)d_in[11];
    const float* qkv_b     = (const float*)d_in[12];
    const float* attn_o_w  = (const float*)d_in[13];
    const float* attn_o_b  = (const float*)d_in[14];
    const float* rpb       = (const float*)d_in[15];
    const float* dwcp1_w   = (const float*)d_in[16];
    const float* dwcp1_b   = (const float*)d_in[17];
    const float* dwcp2_w   = (const float*)d_in[18];
    const float* dwcp2_b   = (const float*)d_in[19];
    const float* pconv_w   = (const float*)d_in[20];
    const float* pconv_b   = (const float*)d_in[21];
    const float* ffn_p_w   = (const float*)d_in[22];
    const float* ffn_p_b   = (const float*)d_in[23];
    const float* ffn_d_w   = (const float*)d_in[24];
    const float* ffn_d_b   = (const float*)d_in[25];
    const float* ffn_a_w   = (const float*)d_in[26];
    const float* ffn_a_b   = (const float*)d_in[27];
    const float* ln_out_w  = (const float*)d_in[28];
    const float* ln_out_b  = (const float*)d_in[29];
    const float* conv_o_w  = (const float*)d_in[30];
    const float* conv_o_b  = (const float*)d_in[31];
    const float* plk       = (const float*)d_in[32];

    float* X  = (float*)d_out;
    float* ws = (float*)d_ws;

    // workspace map (floats):
    //  0        .. 10.24M : A / AP0 (dwproj partial 0) / winattn out
    //  10.24M   .. 40.96M : QKV | R1 | conv3 partials P0/P1/P2
    //  23.04M   .. 33.28M : AP1 (ffn dwproj partial 1)
    //  33.28M   .. 43.52M : R2Q (lkconv partials) / AP1p (proj dwproj partial 1)
    //  43.52M   ..        : LKT, GM, DK, WT  (always live)
    float* A    = ws;
    float* AP0  = ws;
    float* QKV  = ws + 10240000;
    float* R1   = ws + 10240000;
    float* P3B  = ws + 10240000;           // conv3 partials P0,P1,P2 (stride PART64)
    float* AP1  = ws + 23040000;
    float* R2Q  = ws + 33280000;
    float* AP1p = ws + 33280000;           // proj dwproj partial 1 (R2Q region, dead here)
    float* LKT  = ws + 43520000;
    float* GM   = LKT + 43264;
    float* DK   = GM + 64;
    float* WT   = DK + 576;

    dim3 b256(256);
    dim3 gLN(157, 4);
    dim3 gT8(13, 13, 8);
    dim3 gT16(13, 13, 16);

    prep_kernel<<<dim3(384), b256, 0, stream>>>(proj_p_w, attn_o_w, ffn_p_w, proj_a_w,
                                                ffn_a_w, pconv_w, conv_o_w, qkv_w, WT);
    geo_kernel<<<dim3(28), b256, 0, stream>>>(plk, LKT);

    // x = LN(x); x = conv_ffn(x) [proj] — dwproj 2-way split, combine fused into attn LN
    ln_kernel<<<gLN, b256, 0, stream>>>(x_in, ln_proj_w, ln_proj_b, A);
    conv1x1_kernel<<<dim3(40, 8, 4), b256, 0, stream>>>(A, WT + 0, proj_p_b, R1, 64, 128, 1, 0);
    dwproj_kernel<<<gT8, b256, 0, stream>>>(R1, proj_d_w, proj_d_b, WT + 22528, proj_a_b,
                                            AP0, AP1p, 128, 1);

    // X = AP0+AP1p ; AP0 = LN(X) in place; then attention
    ln2_kernel<<<gLN, b256, 0, stream>>>(AP0, AP1p, ln_attn_w, ln_attn_b, X, AP0);
    conv1x1_kernel<<<dim3(40, 12, 4), b256, 0, stream>>>(AP0, WT + 86016, qkv_b, QKV, 64, 192, 0, 0);
    winattn2_kernel<<<dim3(400, 8, 4), dim3(128), 0, stream>>>(QKV, rpb, A);
    conv1x1_kernel<<<dim3(40, 4, 4), b256, 0, stream>>>(A, WT + 8192, attn_o_b, X, 64, 64, 0, 1);

    for (int i = 0; i < 2; ++i) {
        conv1x1_kernel<<<dim3(40, 5, 4), b256, 0, stream>>>(X, WT + 12288 + i * 5120, ffn_p_b + i * 80, R1, 64, 80, 1, 0);
        // y = dwproj(R1) as two ci-partials AP0 + AP1 (never materialized whole)
        dwproj_kernel<<<gT8, b256, 0, stream>>>(R1, ffn_d_w + i * 720, ffn_d_b + i * 80,
                                                WT + 30720 + i * 5120, ffn_a_b + i * 64,
                                                AP0, AP1, 80, 1);
        gmean2_kernel<<<dim3(64), b256, 0, stream>>>(AP0, AP1, GM);
        dynk_kernel<<<dim3(4), dim3(192), 0, stream>>>(GM, dwcp1_w + i * 128, dwcp1_b + i * 8,
                                                       dwcp2_w + i * 1152, dwcp2_b + i * 144, DK);
        lkconv_kernel<<<gT16, b256, 0, stream>>>(AP0, AP1, LKT, DK, R2Q);
        pconv_add_kernel<<<dim3(40, 4, 4), b256, 0, stream>>>(R2Q, AP0, AP1,
                                                              WT + 40960 + i * 4096, pconv_b + i * 64, X);
    }

    // x = conv3x3(LN(x)) + skip  — 4-way ci-split; q==3 folds bias+skip into X
    ln_kernel<<<gLN, b256, 0, stream>>>(X, ln_out_w, ln_out_b, A);
    conv3_part_kernel<<<gT16, b256, 0, stream>>>(A, WT + 49152, conv_o_b, x_in, P3B, X);
    combine4_kernel<<<dim3(10000), b256, 0, stream>>>(P3B, X);
}

// Round 12
// 1276.644 us; speedup vs baseline: 1.3429x; 1.1306x over previous
//
#include <hip/hip_runtime.h>
#include <math.h>

#define HH 200
#define WW 200
#define HWP 40000
#define NP4 10000
#define BB 4

#define LKS 40   // lkconv LDS row stride
#define DPS 24   // dwproj/conv3 LDS row stride
#define PARTSZ 2560000    // one (B,16,H,W) partial buffer (lkconv)
#define PART64 10240000   // one (B,64,H,W) partial buffer

typedef __fp16 f16x2 __attribute__((ext_vector_type(2)));

#if __has_builtin(__builtin_amdgcn_fdot2)
__device__ __forceinline__ float fdot2f(f16x2 a, f16x2 b, float c) {
    return __builtin_amdgcn_fdot2(a, b, c, false);
}
#else
__device__ __forceinline__ float fdot2f(f16x2 a, f16x2 b, float c) {
    return c + (float)a[0] * (float)b[0] + (float)a[1] * (float)b[1];
}
#endif

__device__ __forceinline__ f16x2 pk2(float a, float b) {
    return __builtin_amdgcn_cvt_pkrtz(a, b);
}

__device__ __forceinline__ float gelu_f(float x) {
    return 0.5f * x * (1.0f + erff(x * 0.7071067811865475f));
}

// ---------------- weight prep: transpose + pack to f16x2 along reduction (ci) axis ------
// wth layout offsets (f16x2 slots):
//  0      wtP   (32,128)  proj_p
//  4096   wtAO  (32,64)   attn_out
//  6144   wtFP0 (32,80)   ffn_p[0]
//  8704   wtFP1 (32,80)   ffn_p[1]
//  11264  wtPA  (64,64)   proj_a
//  15360  wtFA0 (40,64)   ffn_a[0]
//  17920  wtFA1 (40,64)   ffn_a[1]
//  20480  wtPC0 (32,64)   pconv[0]
//  22528  wtPC1 (32,64)   pconv[1]
//  24576  wt3   (32,9,64) conv_out  [ci2][tap][co]
//  43008  wtQKV (32,192)  qkv      — total 49152 slots
__device__ __forceinline__ void pk_w(const float* __restrict__ w, f16x2* __restrict__ dst,
                                     int Co, int Ci, int idx) {
    int c2 = idx / Co, o = idx - c2 * Co;
    f16x2 r;
    r[0] = (__fp16)w[o * Ci + 2 * c2];
    r[1] = (__fp16)w[o * Ci + 2 * c2 + 1];
    dst[idx] = r;
}

__global__ __launch_bounds__(256) void prep_kernel(
    const float* __restrict__ pp, const float* __restrict__ ao,
    const float* __restrict__ fp, const float* __restrict__ pa,
    const float* __restrict__ fa, const float* __restrict__ pc,
    const float* __restrict__ co3, const float* __restrict__ qkvw,
    f16x2* __restrict__ wth)
{
    int i = blockIdx.x * 256 + threadIdx.x;
    if (i < 4096) { pk_w(pp, wth + 0, 128, 64, i); return; } i -= 4096;
    if (i < 2048) { pk_w(ao, wth + 4096, 64, 64, i); return; } i -= 2048;
    if (i < 2560) { pk_w(fp, wth + 6144, 80, 64, i); return; } i -= 2560;
    if (i < 2560) { pk_w(fp + 5120, wth + 8704, 80, 64, i); return; } i -= 2560;
    if (i < 4096) { pk_w(pa, wth + 11264, 64, 128, i); return; } i -= 4096;
    if (i < 2560) { pk_w(fa, wth + 15360, 64, 80, i); return; } i -= 2560;
    if (i < 2560) { pk_w(fa + 5120, wth + 17920, 64, 80, i); return; } i -= 2560;
    if (i < 2048) { pk_w(pc, wth + 20480, 64, 64, i); return; } i -= 2048;
    if (i < 2048) { pk_w(pc + 4096, wth + 22528, 64, 64, i); return; } i -= 2048;
    if (i < 18432) {
        int c2 = i / 576; int r = i - c2 * 576; int t = r / 64; int o = r - t * 64;
        f16x2 v;
        v[0] = (__fp16)co3[o * 576 + (2 * c2) * 9 + t];
        v[1] = (__fp16)co3[o * 576 + (2 * c2 + 1) * 9 + t];
        wth[24576 + (c2 * 9 + t) * 64 + o] = v;
        return;
    } i -= 18432;
    if (i < 6144) { pk_w(qkvw, wth + 43008, 192, 64, i); return; }
}

// ---------------- LayerNorm over 64 channels ----------------
__global__ __launch_bounds__(256, 2) void ln_kernel(
    const float* __restrict__ in, const float* __restrict__ w,
    const float* __restrict__ b, float* __restrict__ out)
{
    int p = blockIdx.x * 256 + threadIdx.x;
    int bb = blockIdx.y;
    if (p >= HWP) return;
    const float* ib = in + (size_t)bb * 64 * HWP + p;
    float v[64];
    float mu = 0.f;
#pragma unroll
    for (int c = 0; c < 64; ++c) { v[c] = ib[(size_t)c * HWP]; mu += v[c]; }
    mu *= (1.f / 64.f);
    float var = 0.f;
#pragma unroll
    for (int c = 0; c < 64; ++c) { float d = v[c] - mu; var += d * d; }
    var *= (1.f / 64.f);
    float r = rsqrtf(var + 1e-6f);
    float* ob = out + (size_t)bb * 64 * HWP + p;
#pragma unroll
    for (int c = 0; c < 64; ++c) ob[(size_t)c * HWP] = (v[c] - mu) * r * w[c] + b[c];
}

// ------- LayerNorm over sum of two partials; writes xsum = in0+in1 AND lnout = LN ------
__global__ __launch_bounds__(256, 2) void ln2_kernel(
    const float* in0, const float* in1,
    const float* __restrict__ w, const float* __restrict__ b,
    float* __restrict__ xsum, float* lnout)
{
    int p = blockIdx.x * 256 + threadIdx.x;
    int bb = blockIdx.y;
    if (p >= HWP) return;
    const float* i0 = in0 + (size_t)bb * 64 * HWP + p;
    const float* i1 = in1 + (size_t)bb * 64 * HWP + p;
    float v[64];
    float mu = 0.f;
#pragma unroll
    for (int c = 0; c < 64; ++c) { v[c] = i0[(size_t)c * HWP] + i1[(size_t)c * HWP]; mu += v[c]; }
    mu *= (1.f / 64.f);
    float var = 0.f;
#pragma unroll
    for (int c = 0; c < 64; ++c) { float d = v[c] - mu; var += d * d; }
    var *= (1.f / 64.f);
    float r = rsqrtf(var + 1e-6f);
    float* xb = xsum + (size_t)bb * 64 * HWP + p;
    float* ob = lnout + (size_t)bb * 64 * HWP + p;
#pragma unroll
    for (int c = 0; c < 64; ++c) {
        xb[(size_t)c * HWP] = v[c];
        ob[(size_t)c * HWP] = (v[c] - mu) * r * w[c] + b[c];
    }
}

// ---------------- 1x1 conv: float4 pixels, 16 outputs/thread, f16x2 dot2 ----------------
__global__ __launch_bounds__(256, 2) void conv1x1_kernel(
    const float* __restrict__ in, const f16x2* __restrict__ wt,  // (Ci/2, Co)
    const float* __restrict__ bias, float* __restrict__ out,
    int Ci, int Co, int do_gelu, int do_add)
{
    int p4 = blockIdx.x * 256 + threadIdx.x;
    int o0 = blockIdx.y * 16;
    int bb = blockIdx.z;
    if (p4 >= NP4) return;
    float4 acc[16];
#pragma unroll
    for (int j = 0; j < 16; ++j) {
        float bv = bias[o0 + j];
        acc[j] = make_float4(bv, bv, bv, bv);
    }
    const float4* ib = (const float4*)(in + (size_t)bb * Ci * HWP) + p4;
    int Ci2 = Ci >> 1;
    for (int c2 = 0; c2 < Ci2; ++c2) {
        float4 x0 = ib[(size_t)(2 * c2) * NP4];
        float4 x1 = ib[(size_t)(2 * c2 + 1) * NP4];
        f16x2 px = pk2(x0.x, x1.x), py = pk2(x0.y, x1.y);
        f16x2 pz = pk2(x0.z, x1.z), pw = pk2(x0.w, x1.w);
        const f16x2* wr = wt + c2 * Co + o0;
#pragma unroll
        for (int j = 0; j < 16; ++j) {
            f16x2 w = wr[j];
            acc[j].x = fdot2f(px, w, acc[j].x);
            acc[j].y = fdot2f(py, w, acc[j].y);
            acc[j].z = fdot2f(pz, w, acc[j].z);
            acc[j].w = fdot2f(pw, w, acc[j].w);
        }
    }
    float4* ob = (float4*)(out + ((size_t)bb * Co + o0) * HWP) + p4;
#pragma unroll
    for (int j = 0; j < 16; ++j) {
        float4 r = acc[j];
        if (do_gelu) {
            r.x = gelu_f(r.x); r.y = gelu_f(r.y); r.z = gelu_f(r.z); r.w = gelu_f(r.w);
        }
        if (do_add) {
            float4 old = ob[(size_t)j * NP4];
            r.x += old.x; r.y += old.y; r.z += old.z; r.w += old.w;
        }
        ob[(size_t)j * NP4] = r;
    }
}

// ------- fused: gelu(dwconv3x3(in)) + in, then 1x1 proj partial (ci-split), dot2 -------
__global__ __launch_bounds__(256, 4) void dwproj_kernel(
    const float* __restrict__ in,   // (B,Ci,H,W)
    const float* __restrict__ dw,   // (Ci,9)
    const float* __restrict__ db,   // (Ci)
    const f16x2* __restrict__ awt,  // (Ci/2, 64) packed
    const float* __restrict__ ab,   // (64)
    float* __restrict__ out0, float* __restrict__ out1,
    int Ci, int splitlog)
{
    __shared__ float s_p[16][18 * DPS];
    int tid = threadIdx.x;
    int tx = tid & 15, ty = tid >> 4;
    int x0 = blockIdx.x * 16, y0 = blockIdx.y * 16;
    int part = blockIdx.z & ((1 << splitlog) - 1);
    int bb = blockIdx.z >> splitlog;
    int cic = Ci >> splitlog;
    int cbase = part * cic;
    float* dst = (part == 0) ? out0 : out1;
    int x = x0 + tx, y = y0 + ty;

    float acc[64];
    if (part == 0) {
#pragma unroll
        for (int o = 0; o < 64; ++o) acc[o] = ab[o];
    } else {
#pragma unroll
        for (int o = 0; o < 64; ++o) acc[o] = 0.f;
    }

    const float* ibase = in + (size_t)bb * Ci * HWP;
    for (int c0 = cbase; c0 < cbase + cic; c0 += 16) {
        int chunk = cbase + cic - c0; if (chunk > 16) chunk = 16;
        __syncthreads();
        for (int i = tid; i < chunk * 324; i += 256) {
            int ci = i / 324; int r = i - ci * 324;
            int py = r / 18, px = r - py * 18;
            int yy = y0 + py - 1, xx = x0 + px - 1;
            float v = 0.f;
            if ((unsigned)yy < HH && (unsigned)xx < WW)
                v = ibase[(size_t)(c0 + ci) * HWP + yy * WW + xx];
            s_p[ci][py * DPS + px] = v;
        }
        __syncthreads();
        for (int ci = 0; ci < chunk; ci += 2) {
            int c = c0 + ci;
            float s0v = db[c], s1v = db[c + 1];
            const float* dwr0 = dw + c * 9;
            const float* dwr1 = dwr0 + 9;
#pragma unroll
            for (int ky = 0; ky < 3; ++ky)
#pragma unroll
                for (int kx = 0; kx < 3; ++kx) {
                    s0v += s_p[ci][(ty + ky) * DPS + tx + kx] * dwr0[ky * 3 + kx];
                    s1v += s_p[ci + 1][(ty + ky) * DPS + tx + kx] * dwr1[ky * 3 + kx];
                }
            float v0 = gelu_f(s0v) + s_p[ci][(ty + 1) * DPS + tx + 1];
            float v1 = gelu_f(s1v) + s_p[ci + 1][(ty + 1) * DPS + tx + 1];
            f16x2 vp = pk2(v0, v1);
            const f16x2* wr = awt + (size_t)((c >> 1)) * 64;
#pragma unroll
            for (int o = 0; o < 64; ++o) acc[o] = fdot2f(vp, wr[o], acc[o]);
        }
    }

    if (x < WW && y < HH) {
        int p = y * WW + x;
        float* ob = dst + (size_t)bb * 64 * HWP + p;
#pragma unroll
        for (int o = 0; o < 64; ++o) ob[(size_t)o * HWP] = acc[o];
    }
}

// ---------------- attention v3: qkv precomputed; scores cached in f16-packed regs -------
__global__ __launch_bounds__(128, 4) void winattn2_kernel(
    const float* __restrict__ qkv,  // (B,192,H,W)
    const float* __restrict__ rpb,  // (8,361)
    float* __restrict__ out)        // (B,64,H,W)
{
    __shared__ __align__(16) float s_k[100][8];
    __shared__ __align__(16) float s_v[100][8];
    __shared__ float s_b[361];

    int head = blockIdx.y, bb = blockIdx.z;
    int wy = blockIdx.x / 20, wx = blockIdx.x - wy * 20;
    int tid = threadIdx.x;

    for (int i = tid; i < 361; i += 128) s_b[i] = rpb[head * 361 + i];

    int ty = tid / 10, tx = tid - ty * 10;
    float q[8];
    if (tid < 100) {
        int y = wy * 10 + ty, x = wx * 10 + tx;
        int gp = y * WW + x;
        const float* qb = qkv + ((size_t)bb * 192 + head * 8) * HWP + gp;
        const float* kb = qb + (size_t)64 * HWP;
        const float* vb = qb + (size_t)128 * HWP;
        const float scale = 0.3535533905932738f; // 1/sqrt(8)
#pragma unroll
        for (int cc = 0; cc < 8; ++cc) q[cc] = qb[(size_t)cc * HWP] * scale;
        float4 t0, t1;
        t0.x = kb[0];               t0.y = kb[(size_t)1 * HWP];
        t0.z = kb[(size_t)2 * HWP]; t0.w = kb[(size_t)3 * HWP];
        t1.x = kb[(size_t)4 * HWP]; t1.y = kb[(size_t)5 * HWP];
        t1.z = kb[(size_t)6 * HWP]; t1.w = kb[(size_t)7 * HWP];
        *(float4*)(&s_k[tid][0]) = t0;
        *(float4*)(&s_k[tid][4]) = t1;
        t0.x = vb[0];               t0.y = vb[(size_t)1 * HWP];
        t0.z = vb[(size_t)2 * HWP]; t0.w = vb[(size_t)3 * HWP];
        t1.x = vb[(size_t)4 * HWP]; t1.y = vb[(size_t)5 * HWP];
        t1.z = vb[(size_t)6 * HWP]; t1.w = vb[(size_t)7 * HWP];
        *(float4*)(&s_v[tid][0]) = t0;
        *(float4*)(&s_v[tid][4]) = t1;
    }
    __syncthreads();

    if (tid < 100) {
        const float4* k4 = (const float4*)s_k;
        const float4* v4 = (const float4*)s_v;
        const float* brow = s_b + (180 - ty * 19 - tx);

        f16x2 s16[50];
        float m = -1e30f;
#pragma unroll
        for (int i = 0; i < 50; ++i) {
            const int k0 = 2 * i, k1 = 2 * i + 1;
            const int c0 = (k0 / 10) * 19 + (k0 % 10);
            const int c1 = (k1 / 10) * 19 + (k1 % 10);
            float4 ka = k4[k0 * 2], kb2 = k4[k0 * 2 + 1];
            float s0 = brow[c0]
                     + q[0] * ka.x + q[1] * ka.y + q[2] * ka.z + q[3] * ka.w
                     + q[4] * kb2.x + q[5] * kb2.y + q[6] * kb2.z + q[7] * kb2.w;
            ka = k4[k1 * 2]; kb2 = k4[k1 * 2 + 1];
            float s1 = brow[c1]
                     + q[0] * ka.x + q[1] * ka.y + q[2] * ka.z + q[3] * ka.w
                     + q[4] * kb2.x + q[5] * kb2.y + q[6] * kb2.z + q[7] * kb2.w;
            m = fmaxf(m, fmaxf(s0, s1));
            s16[i] = __builtin_amdgcn_cvt_pkrtz(s0, s1);
        }
        float l = 0.f;
        float o[8];
#pragma unroll
        for (int cc = 0; cc < 8; ++cc) o[cc] = 0.f;
#pragma unroll
        for (int i = 0; i < 50; ++i) {
            float e0 = __expf((float)s16[i][0] - m);
            float e1 = __expf((float)s16[i][1] - m);
            l += e0 + e1;
            float4 va = v4[4 * i], vb2 = v4[4 * i + 1];
            o[0] += e0 * va.x; o[1] += e0 * va.y; o[2] += e0 * va.z; o[3] += e0 * va.w;
            o[4] += e0 * vb2.x; o[5] += e0 * vb2.y; o[6] += e0 * vb2.z; o[7] += e0 * vb2.w;
            va = v4[4 * i + 2]; vb2 = v4[4 * i + 3];
            o[0] += e1 * va.x; o[1] += e1 * va.y; o[2] += e1 * va.z; o[3] += e1 * va.w;
            o[4] += e1 * vb2.x; o[5] += e1 * vb2.y; o[6] += e1 * vb2.z; o[7] += e1 * vb2.w;
        }
        float rl = 1.f / l;
        int y = wy * 10 + ty, x = wx * 10 + tx;
        float* ob = out + ((size_t)bb * 64 + head * 8) * HWP + y * WW + x;
#pragma unroll
        for (int cc = 0; cc < 8; ++cc) ob[(size_t)cc * HWP] = o[cc] * rl;
    }
}

// ------- geometric ensemble -> D4-orbit weight table packed f16x2 (ci, rep2, co) -------
__global__ __launch_bounds__(256) void geo_kernel(
    const float* __restrict__ k, f16x2* __restrict__ out)
{
    int i = blockIdx.x * 256 + threadIdx.x;
    if (i >= 256 * 14) return;
    int oc = i / 14, r2 = i - oc * 14;   // oc = co*16 + ci
    int co = oc >> 4, ci = oc & 15;
    const float* kb = k + oc * 169;
    float sv[2];
#pragma unroll
    for (int t = 0; t < 2; ++t) {
        int rep = 2 * r2 + t;
        int a = 0, r = rep;
        while (r >= 7 - a) { r -= 7 - a; ++a; }
        int b2 = a + r;
        int y = 6 + a, x = 6 + b2;
        float s = kb[y * 13 + x] + kb[y * 13 + (12 - x)] + kb[(12 - y) * 13 + x] + kb[(12 - y) * 13 + (12 - x)]
                + kb[(12 - x) * 13 + y] + kb[x * 13 + y] + kb[(12 - x) * 13 + (12 - y)] + kb[x * 13 + (12 - y)];
        sv[t] = s * 0.125f;
    }
    f16x2 v;
    v[0] = (__fp16)sv[0];
    v[1] = (__fp16)sv[1];
    out[(ci * 14 + r2) * 16 + co] = v;
}

// ---------------- global mean over H,W of first-16 channels (sum of 2 partials) --------
__global__ __launch_bounds__(256) void gmean2_kernel(
    const float* __restrict__ in0, const float* __restrict__ in1, float* __restrict__ g)
{
    int bc = blockIdx.x;            // b*16 + c
    int bb = bc >> 4, c = bc & 15;
    const float* p0 = in0 + ((size_t)bb * 64 + c) * HWP;
    const float* p1 = in1 + ((size_t)bb * 64 + c) * HWP;
    float s = 0.f;
    for (int i = threadIdx.x; i < HWP; i += 256) s += p0[i] + p1[i];
#pragma unroll
    for (int off = 32; off > 0; off >>= 1) s += __shfl_down(s, off);
    __shared__ float red[4];
    int wave = threadIdx.x >> 6;
    if ((threadIdx.x & 63) == 0) red[wave] = s;
    __syncthreads();
    if (threadIdx.x == 0)
        g[bc] = (red[0] + red[1] + red[2] + red[3]) * (1.f / 40000.f);
}

// ---------------- tiny MLP -> dynamic 3x3 kernels ----------------
__global__ __launch_bounds__(192) void dynk_kernel(
    const float* __restrict__ g, const float* __restrict__ w1, const float* __restrict__ b1,
    const float* __restrict__ w2, const float* __restrict__ b2, float* __restrict__ dk)
{
    int bb = blockIdx.x;
    __shared__ float s_g2[8];
    int tid = threadIdx.x;
    if (tid < 8) {
        float a = b1[tid];
        for (int c = 0; c < 16; ++c) a += w1[tid * 16 + c] * g[bb * 16 + c];
        s_g2[tid] = gelu_f(a);
    }
    __syncthreads();
    if (tid < 144) {
        float a = b2[tid];
#pragma unroll
        for (int i = 0; i < 8; ++i) a += w2[tid * 8 + i] * s_g2[i];
        dk[bb * 144 + tid] = a;
    }
}

// ------- 13x13 D4-symmetric conv via 28 orbit sums (dot2) + dynamic depthwise 3x3 -------
__global__ __launch_bounds__(256, 4) void lkconv_kernel(
    const float* __restrict__ in0, const float* __restrict__ in1,
    const f16x2* __restrict__ lkO,  // (16,14,16)  [ci][rep2][co] packed
    const float* __restrict__ dk,   // (B,144)
    float* __restrict__ out)        // 4 partial buffers, stride PARTSZ
{
    __shared__ float s_p[4][28 * LKS];  // 17.9 KB
    int z = blockIdx.z;
    int bb = z >> 2, q = z & 3;
    int tid = threadIdx.x;
    int tx = tid & 15, ty = tid >> 4;
    int x0 = blockIdx.x * 16, y0 = blockIdx.y * 16;
    int x = x0 + tx, y = y0 + ty;

    const float* ib0 = in0 + ((size_t)bb * 64 + q * 4) * HWP;
    const float* ib1 = in1 + ((size_t)bb * 64 + q * 4) * HWP;
    for (int i = tid; i < 4 * 784; i += 256) {
        int ci = i / 784; int r = i - ci * 784;
        int py = r / 28, px = r - py * 28;
        int yy = y0 + py - 6, xx = x0 + px - 6;
        float v = 0.f;
        if ((unsigned)yy < HH && (unsigned)xx < WW) {
            int gp = (size_t)ci * HWP + yy * WW + xx;
            v = ib0[gp] + ib1[gp];
        }
        s_p[ci][py * LKS + px] = v;
    }
    __syncthreads();

    float acc[16];
#pragma unroll
    for (int co = 0; co < 16; ++co) acc[co] = 0.f;

#pragma unroll
    for (int ci4 = 0; ci4 < 4; ++ci4) {
        int ci = q * 4 + ci4;
        float orb[28];
#pragma unroll
        for (int o = 0; o < 28; ++o) orb[o] = 0.f;
#pragma unroll
        for (int ky = 0; ky < 13; ++ky) {
#pragma unroll
            for (int kx = 0; kx < 13; ++kx) {
                const int a = (ky < 6) ? (6 - ky) : (ky - 6);
                const int b = (kx < 6) ? (6 - kx) : (kx - 6);
                const int lo = (a < b) ? a : b;
                const int hi = (a < b) ? b : a;
                const int idx = lo * 7 - (lo * (lo - 1)) / 2 + (hi - lo);
                orb[idx] += s_p[ci4][(ty + ky) * LKS + tx + kx];
            }
        }
        const f16x2* wci = lkO + ci * 14 * 16;
#pragma unroll
        for (int o2 = 0; o2 < 14; ++o2) {
            f16x2 ov = pk2(orb[2 * o2], orb[2 * o2 + 1]);
            const f16x2* wr = wci + o2 * 16;
#pragma unroll
            for (int co = 0; co < 16; ++co) acc[co] = fdot2f(ov, wr[co], acc[co]);
        }
        float d = 0.f;
        const float* dkr = dk + bb * 144 + ci * 9;
#pragma unroll
        for (int dy = 0; dy < 3; ++dy)
#pragma unroll
            for (int dx = 0; dx < 3; ++dx)
                d += s_p[ci4][(ty + 5 + dy) * LKS + tx + 5 + dx] * dkr[dy * 3 + dx];
#pragma unroll
        for (int co = 0; co < 16; ++co) acc[co] += (co == ci) ? d : 0.f;
    }

    if (x < WW && y < HH) {
        int p = y * WW + x;
        float* ob = out + (size_t)q * PARTSZ + (size_t)bb * 16 * HWP + p;
#pragma unroll
        for (int co = 0; co < 16; ++co) ob[(size_t)co * HWP] = acc[co];
    }
}

// ------- 1x1 conv over concat(sum of 4 x1 partials, (y0+y1)[16..63]), dot2; += xout -----
__global__ __launch_bounds__(256, 2) void pconv_add_kernel(
    const float* __restrict__ x1q,  // 4 partial buffers, stride PARTSZ
    const float* __restrict__ y0, const float* __restrict__ y1,
    const f16x2* __restrict__ wt,   // (32, 64) packed over concat axis
    const float* __restrict__ bias,
    float* __restrict__ xout)
{
    int p4 = blockIdx.x * 256 + threadIdx.x;
    int o0 = blockIdx.y * 16;
    int bb = blockIdx.z;
    if (p4 >= NP4) return;
    float4 acc[16];
#pragma unroll
    for (int j = 0; j < 16; ++j) {
        float bv = bias[o0 + j];
        acc[j] = make_float4(bv, bv, bv, bv);
    }
    const float4* xb0 = (const float4*)(x1q + (size_t)bb * 16 * HWP) + p4;
    const float4* xb1 = (const float4*)(x1q + PARTSZ + (size_t)bb * 16 * HWP) + p4;
    const float4* xb2 = (const float4*)(x1q + 2 * PARTSZ + (size_t)bb * 16 * HWP) + p4;
    const float4* xb3 = (const float4*)(x1q + 3 * PARTSZ + (size_t)bb * 16 * HWP) + p4;
    for (int c2 = 0; c2 < 8; ++c2) {
        int ca = 2 * c2, cb = 2 * c2 + 1;
        float4 a0 = xb0[(size_t)ca * NP4], a1 = xb1[(size_t)ca * NP4];
        float4 a2 = xb2[(size_t)ca * NP4], a3 = xb3[(size_t)ca * NP4];
        float4 s0;
        s0.x = (a0.x + a1.x) + (a2.x + a3.x);
        s0.y = (a0.y + a1.y) + (a2.y + a3.y);
        s0.z = (a0.z + a1.z) + (a2.z + a3.z);
        s0.w = (a0.w + a1.w) + (a2.w + a3.w);
        a0 = xb0[(size_t)cb * NP4]; a1 = xb1[(size_t)cb * NP4];
        a2 = xb2[(size_t)cb * NP4]; a3 = xb3[(size_t)cb * NP4];
        float4 s1;
        s1.x = (a0.x + a1.x) + (a2.x + a3.x);
        s1.y = (a0.y + a1.y) + (a2.y + a3.y);
        s1.z = (a0.z + a1.z) + (a2.z + a3.z);
        s1.w = (a0.w + a1.w) + (a2.w + a3.w);
        f16x2 px = pk2(s0.x, s1.x), py = pk2(s0.y, s1.y);
        f16x2 pz = pk2(s0.z, s1.z), pw = pk2(s0.w, s1.w);
        const f16x2* wr = wt + c2 * 64 + o0;
#pragma unroll
        for (int j = 0; j < 16; ++j) {
            f16x2 w = wr[j];
            acc[j].x = fdot2f(px, w, acc[j].x);
            acc[j].y = fdot2f(py, w, acc[j].y);
            acc[j].z = fdot2f(pz, w, acc[j].z);
            acc[j].w = fdot2f(pw, w, acc[j].w);
        }
    }
    const float4* yb0 = (const float4*)(y0 + ((size_t)bb * 64 + 16) * HWP) + p4;
    const float4* yb1 = (const float4*)(y1 + ((size_t)bb * 64 + 16) * HWP) + p4;
    for (int c2 = 8; c2 < 32; ++c2) {
        int cy = 2 * (c2 - 8);
        float4 v00 = yb0[(size_t)cy * NP4], v10 = yb1[(size_t)cy * NP4];
        float4 v01 = yb0[(size_t)(cy + 1) * NP4], v11 = yb1[(size_t)(cy + 1) * NP4];
        float4 s0, s1;
        s0.x = v00.x + v10.x; s0.y = v00.y + v10.y; s0.z = v00.z + v10.z; s0.w = v00.w + v10.w;
        s1.x = v01.x + v11.x; s1.y = v01.y + v11.y; s1.z = v01.z + v11.z; s1.w = v01.w + v11.w;
        f16x2 px = pk2(s0.x, s1.x), py = pk2(s0.y, s1.y);
        f16x2 pz = pk2(s0.z, s1.z), pw = pk2(s0.w, s1.w);
        const f16x2* wr = wt + c2 * 64 + o0;
#pragma unroll
        for (int j = 0; j < 16; ++j) {
            f16x2 w = wr[j];
            acc[j].x = fdot2f(px, w, acc[j].x);
            acc[j].y = fdot2f(py, w, acc[j].y);
            acc[j].z = fdot2f(pz, w, acc[j].z);
            acc[j].w = fdot2f(pw, w, acc[j].w);
        }
    }
    float4* ob = (float4*)(xout + ((size_t)bb * 64 + o0) * HWP) + p4;
#pragma unroll
    for (int j = 0; j < 16; ++j) {
        float4 old = ob[(size_t)j * NP4];
        old.x += acc[j].x; old.y += acc[j].y; old.z += acc[j].z; old.w += acc[j].w;
        ob[(size_t)j * NP4] = old;
    }
}

// ---------------- final 3x3 conv, 4-way ci-split, dot2 ----------------
__global__ __launch_bounds__(256, 4) void conv3_part_kernel(
    const float* __restrict__ in, const f16x2* __restrict__ wt3h,  // (ci2,tap,64)
    const float* __restrict__ bias, const float* __restrict__ skip,
    float* __restrict__ pbase, float* __restrict__ xout)
{
    __shared__ float s_p[16][18 * DPS];
    int tid = threadIdx.x;
    int tx = tid & 15, ty = tid >> 4;
    int x0 = blockIdx.x * 16, y0 = blockIdx.y * 16;
    int bb = blockIdx.z >> 2, q = blockIdx.z & 3;
    int cbase = q * 16;
    int x = x0 + tx, y = y0 + ty;

    float acc[64];
#pragma unroll
    for (int o = 0; o < 64; ++o) acc[o] = 0.f;

    const float* ibase = in + ((size_t)bb * 64 + cbase) * HWP;
    for (int i = tid; i < 16 * 324; i += 256) {
        int ci = i / 324; int r = i - ci * 324;
        int py = r / 18, px = r - py * 18;
        int yy = y0 + py - 1, xx = x0 + px - 1;
        float v = 0.f;
        if ((unsigned)yy < HH && (unsigned)xx < WW)
            v = ibase[(size_t)ci * HWP + yy * WW + xx];
        s_p[ci][py * DPS + px] = v;
    }
    __syncthreads();

    int cb2 = q * 8;
#pragma unroll 2
    for (int c2 = 0; c2 < 8; ++c2) {
        const f16x2* wr0 = wt3h + (size_t)(cb2 + c2) * 9 * 64;
#pragma unroll
        for (int ky = 0; ky < 3; ++ky) {
#pragma unroll
            for (int kx = 0; kx < 3; ++kx) {
                float xv0 = s_p[2 * c2][(ty + ky) * DPS + tx + kx];
                float xv1 = s_p[2 * c2 + 1][(ty + ky) * DPS + tx + kx];
                f16x2 xp = pk2(xv0, xv1);
                const f16x2* wr = wr0 + (ky * 3 + kx) * 64;
#pragma unroll
                for (int o = 0; o < 64; ++o) acc[o] = fdot2f(xp, wr[o], acc[o]);
            }
        }
    }

    if (x < WW && y < HH) {
        int p = y * WW + x;
        if (q < 3) {
            float* ob = pbase + (size_t)q * PART64 + (size_t)bb * 64 * HWP + p;
#pragma unroll
            for (int o = 0; o < 64; ++o) ob[(size_t)o * HWP] = acc[o];
        } else {
            const float* sb = skip + (size_t)bb * 64 * HWP + p;
            float* ob = xout + (size_t)bb * 64 * HWP + p;
#pragma unroll
            for (int o = 0; o < 64; ++o)
                ob[(size_t)o * HWP] = acc[o] + bias[o] + sb[(size_t)o * HWP];
        }
    }
}

// ---------------- combine conv3 partials: x += p0 + p1 + p2 ----------------
__global__ __launch_bounds__(256) void combine4_kernel(
    const float* __restrict__ p, float* __restrict__ x)
{
    int idx = blockIdx.x * 256 + threadIdx.x;   // float4 index over B*64*NP4
    if (idx >= BB * 64 * NP4) return;
    const float4* pf = (const float4*)p;
    float4 a = pf[idx];
    float4 b = pf[idx + 2560000];
    float4 c = pf[idx + 5120000];
    float4 r = ((float4*)x)[idx];
    r.x += a.x + b.x + c.x;
    r.y += a.y + b.y + c.y;
    r.z += a.z + b.z + c.z;
    r.w += a.w + b.w + c.w;
    ((float4*)x)[idx] = r;
}

extern "C" void kernel_launch(void* const* d_in, const int* in_sizes, int n_in,
                              void* d_out, int out_size, void* d_ws, size_t ws_size,
                              hipStream_t stream)
{
    const float* x_in      = (const float*)d_in[0];
    const float* ln_proj_w = (const float*)d_in[1];
    const float* ln_proj_b = (const float*)d_in[2];
    const float* proj_p_w  = (const float*)d_in[3];
    const float* proj_p_b  = (const float*)d_in[4];
    const float* proj_d_w  = (const float*)d_in[5];
    const float* proj_d_b  = (const float*)d_in[6];
    const float* proj_a_w  = (const float*)d_in[7];
    const float* proj_a_b  = (const float*)d_in[8];
    const float* ln_attn_w = (const float*)d_in[9];
    const float* ln_attn_b = (const float*)d_in[10];
    const float* qkv_w     = (const float*)d_in[11];
    const float* qkv_b     = (const float*)d_in[12];
    const float* attn_o_w  = (const float*)d_in[13];
    const float* attn_o_b  = (const float*)d_in[14];
    const float* rpb       = (const float*)d_in[15];
    const float* dwcp1_w   = (const float*)d_in[16];
    const float* dwcp1_b   = (const float*)d_in[17];
    const float* dwcp2_w   = (const float*)d_in[18];
    const float* dwcp2_b   = (const float*)d_in[19];
    const float* pconv_w   = (const float*)d_in[20];
    const float* pconv_b   = (const float*)d_in[21];
    const float* ffn_p_w   = (const float*)d_in[22];
    const float* ffn_p_b   = (const float*)d_in[23];
    const float* ffn_d_w   = (const float*)d_in[24];
    const float* ffn_d_b   = (const float*)d_in[25];
    const float* ffn_a_w   = (const float*)d_in[26];
    const float* ffn_a_b   = (const float*)d_in[27];
    const float* ln_out_w  = (const float*)d_in[28];
    const float* ln_out_b  = (const float*)d_in[29];
    const float* conv_o_w  = (const float*)d_in[30];
    const float* conv_o_b  = (const float*)d_in[31];
    const float* plk       = (const float*)d_in[32];

    float* X  = (float*)d_out;
    float* ws = (float*)d_ws;

    // workspace map (floats):
    //  0        .. 10.24M : A / AP0 (dwproj partial 0) / winattn out
    //  10.24M   .. 40.96M : QKV | R1 | conv3 partials P0/P1/P2
    //  23.04M   .. 33.28M : AP1 (ffn dwproj partial 1)
    //  33.28M   .. 43.52M : R2Q (lkconv partials) / AP1p (proj dwproj partial 1)
    //  43.52M   ..        : LKTH (f16x2), GM, DK, WTH (f16x2)  (always live)
    float* A    = ws;
    float* AP0  = ws;
    float* QKV  = ws + 10240000;
    float* R1   = ws + 10240000;
    float* P3B  = ws + 10240000;           // conv3 partials P0,P1,P2 (stride PART64)
    float* AP1  = ws + 23040000;
    float* R2Q  = ws + 33280000;
    float* AP1p = ws + 33280000;           // proj dwproj partial 1 (R2Q region, dead here)
    f16x2* LKTH = (f16x2*)(ws + 43520000); // 3584 slots
    float* GM   = ws + 43520000 + 4096;
    float* DK   = GM + 64;
    f16x2* WTH  = (f16x2*)(DK + 576);      // 49152 slots

    dim3 b256(256);
    dim3 gLN(157, 4);
    dim3 gT8(13, 13, 8);
    dim3 gT16(13, 13, 16);

    prep_kernel<<<dim3(192), b256, 0, stream>>>(proj_p_w, attn_o_w, ffn_p_w, proj_a_w,
                                                ffn_a_w, pconv_w, conv_o_w, qkv_w, WTH);
    geo_kernel<<<dim3(14), b256, 0, stream>>>(plk, LKTH);

    // x = LN(x); x = conv_ffn(x) [proj] — dwproj 2-way split, combine fused into attn LN
    ln_kernel<<<gLN, b256, 0, stream>>>(x_in, ln_proj_w, ln_proj_b, A);
    conv1x1_kernel<<<dim3(40, 8, 4), b256, 0, stream>>>(A, WTH + 0, proj_p_b, R1, 64, 128, 1, 0);
    dwproj_kernel<<<gT8, b256, 0, stream>>>(R1, proj_d_w, proj_d_b, WTH + 11264, proj_a_b,
                                            AP0, AP1p, 128, 1);

    // X = AP0+AP1p ; AP0 = LN(X) in place; then attention
    ln2_kernel<<<gLN, b256, 0, stream>>>(AP0, AP1p, ln_attn_w, ln_attn_b, X, AP0);
    conv1x1_kernel<<<dim3(40, 12, 4), b256, 0, stream>>>(AP0, WTH + 43008, qkv_b, QKV, 64, 192, 0, 0);
    winattn2_kernel<<<dim3(400, 8, 4), dim3(128), 0, stream>>>(QKV, rpb, A);
    conv1x1_kernel<<<dim3(40, 4, 4), b256, 0, stream>>>(A, WTH + 4096, attn_o_b, X, 64, 64, 0, 1);

    for (int i = 0; i < 2; ++i) {
        conv1x1_kernel<<<dim3(40, 5, 4), b256, 0, stream>>>(X, WTH + 6144 + i * 2560, ffn_p_b + i * 80, R1, 64, 80, 1, 0);
        dwproj_kernel<<<gT8, b256, 0, stream>>>(R1, ffn_d_w + i * 720, ffn_d_b + i * 80,
                                                WTH + 15360 + i * 2560, ffn_a_b + i * 64,
                                                AP0, AP1, 80, 1);
        gmean2_kernel<<<dim3(64), b256, 0, stream>>>(AP0, AP1, GM);
        dynk_kernel<<<dim3(4), dim3(192), 0, stream>>>(GM, dwcp1_w + i * 128, dwcp1_b + i * 8,
                                                       dwcp2_w + i * 1152, dwcp2_b + i * 144, DK);
        lkconv_kernel<<<gT16, b256, 0, stream>>>(AP0, AP1, LKTH, DK, R2Q);
        pconv_add_kernel<<<dim3(40, 4, 4), b256, 0, stream>>>(R2Q, AP0, AP1,
                                                              WTH + 20480 + i * 2048, pconv_b + i * 64, X);
    }

    // x = conv3x3(LN(x)) + skip  — 4-way ci-split; q==3 folds bias+skip into X
    ln_kernel<<<gLN, b256, 0, stream>>>(X, ln_out_w, ln_out_b, A);
    conv3_part_kernel<<<gT16, b256, 0, stream>>>(A, WTH + 24576, conv_o_b, x_in, P3B, X);
    combine4_kernel<<<dim3(10000), b256, 0, stream>>>(P3B, X);
}

// Round 13
// 1242.387 us; speedup vs baseline: 1.3799x; 1.0276x over previous
//
#include <hip/hip_runtime.h>
#include <math.h>

#define HH 200
#define WW 200
#define HWP 40000
#define NP4 10000
#define BB 4

#define LKS 40   // lkconv LDS row stride
#define DPS 24   // dwproj/conv3 LDS row stride
#define PARTSZ 2560000    // one (B,16,H,W) partial buffer (lkconv)
#define PART64 10240000   // one (B,64,H,W) partial buffer

typedef __fp16 f16x2 __attribute__((ext_vector_type(2)));
typedef __fp16 f16x8 __attribute__((ext_vector_type(8)));
typedef float fx4 __attribute__((ext_vector_type(4)));

#if __has_builtin(__builtin_amdgcn_fdot2)
__device__ __forceinline__ float fdot2f(f16x2 a, f16x2 b, float c) {
    return __builtin_amdgcn_fdot2(a, b, c, false);
}
#else
__device__ __forceinline__ float fdot2f(f16x2 a, f16x2 b, float c) {
    return c + (float)a[0] * (float)b[0] + (float)a[1] * (float)b[1];
}
#endif

__device__ __forceinline__ f16x2 pk2(float a, float b) {
    return __builtin_amdgcn_cvt_pkrtz(a, b);
}

__device__ __forceinline__ float gelu_f(float x) {
    return 0.5f * x * (1.0f + erff(x * 0.7071067811865475f));
}

// ---------------- weight prep: transpose + pack to f16x2 along reduction (ci) axis ------
// wth layout offsets (f16x2 slots): [unchanged; conv1x1 ranges now unused]
//  11264  wtPA  (64,64)   proj_a
//  15360  wtFA0 (40,64)   ffn_a[0]
//  17920  wtFA1 (40,64)   ffn_a[1]
//  20480  wtPC0 (32,64)   pconv[0]
//  22528  wtPC1 (32,64)   pconv[1]
//  24576  wt3   (32,9,64) conv_out  [ci2][tap][co]
__device__ __forceinline__ void pk_w(const float* __restrict__ w, f16x2* __restrict__ dst,
                                     int Co, int Ci, int idx) {
    int c2 = idx / Co, o = idx - c2 * Co;
    f16x2 r;
    r[0] = (__fp16)w[o * Ci + 2 * c2];
    r[1] = (__fp16)w[o * Ci + 2 * c2 + 1];
    dst[idx] = r;
}

__global__ __launch_bounds__(256) void prep_kernel(
    const float* __restrict__ pp, const float* __restrict__ ao,
    const float* __restrict__ fp, const float* __restrict__ pa,
    const float* __restrict__ fa, const float* __restrict__ pc,
    const float* __restrict__ co3, const float* __restrict__ qkvw,
    f16x2* __restrict__ wth)
{
    int i = blockIdx.x * 256 + threadIdx.x;
    if (i < 4096) { pk_w(pp, wth + 0, 128, 64, i); return; } i -= 4096;
    if (i < 2048) { pk_w(ao, wth + 4096, 64, 64, i); return; } i -= 2048;
    if (i < 2560) { pk_w(fp, wth + 6144, 80, 64, i); return; } i -= 2560;
    if (i < 2560) { pk_w(fp + 5120, wth + 8704, 80, 64, i); return; } i -= 2560;
    if (i < 4096) { pk_w(pa, wth + 11264, 64, 128, i); return; } i -= 4096;
    if (i < 2560) { pk_w(fa, wth + 15360, 64, 80, i); return; } i -= 2560;
    if (i < 2560) { pk_w(fa + 5120, wth + 17920, 64, 80, i); return; } i -= 2560;
    if (i < 2048) { pk_w(pc, wth + 20480, 64, 64, i); return; } i -= 2048;
    if (i < 2048) { pk_w(pc + 4096, wth + 22528, 64, 64, i); return; } i -= 2048;
    if (i < 18432) {
        int c2 = i / 576; int r = i - c2 * 576; int t = r / 64; int o = r - t * 64;
        f16x2 v;
        v[0] = (__fp16)co3[o * 576 + (2 * c2) * 9 + t];
        v[1] = (__fp16)co3[o * 576 + (2 * c2 + 1) * 9 + t];
        wth[24576 + (c2 * 9 + t) * 64 + o] = v;
        return;
    } i -= 18432;
    if (i < 6144) { pk_w(qkvw, wth + 43008, 192, 64, i); return; }
}

// ------- MFMA A-fragment prep for 1x1 convs (all Ci=64, ksteps=2) -------
// wA slot layout (f16x8 slots): qkv 0..1536, proj_p 1536..2560, attn_o 2560..3072,
// ffn_p0 3072..3712, ffn_p1 3712..4352.
// slot s (within weight): lane = s&63, t = s>>6, ks = t&1, cot = t>>1.
// elem j: W[cot*16 + (lane&15)][ks*32 + (lane>>4)*8 + j]
__global__ __launch_bounds__(256) void prepA_kernel(
    const float* __restrict__ qkvw, const float* __restrict__ pp,
    const float* __restrict__ ao, const float* __restrict__ fp,
    f16x8* __restrict__ wA)
{
    int s = blockIdx.x * 256 + threadIdx.x;
    if (s >= 4352) return;
    const float* src;
    int base;
    if (s < 1536)      { src = qkvw;      base = 0; }
    else if (s < 2560) { src = pp;        base = 1536; }
    else if (s < 3072) { src = ao;        base = 2560; }
    else if (s < 3712) { src = fp;        base = 3072; }
    else               { src = fp + 5120; base = 3712; }
    int r = s - base;
    int lane = r & 63;
    int t = r >> 6;
    int ks = t & 1;
    int cot = t >> 1;
    int co = cot * 16 + (lane & 15);
    int k0 = ks * 32 + ((lane >> 4) << 3);
    f16x8 v;
#pragma unroll
    for (int j = 0; j < 8; ++j) v[j] = (__fp16)src[co * 64 + k0 + j];
    wA[s] = v;
}

// ---------------- LayerNorm over 64 channels ----------------
__global__ __launch_bounds__(256, 2) void ln_kernel(
    const float* __restrict__ in, const float* __restrict__ w,
    const float* __restrict__ b, float* __restrict__ out)
{
    int p = blockIdx.x * 256 + threadIdx.x;
    int bb = blockIdx.y;
    if (p >= HWP) return;
    const float* ib = in + (size_t)bb * 64 * HWP + p;
    float v[64];
    float mu = 0.f;
#pragma unroll
    for (int c = 0; c < 64; ++c) { v[c] = ib[(size_t)c * HWP]; mu += v[c]; }
    mu *= (1.f / 64.f);
    float var = 0.f;
#pragma unroll
    for (int c = 0; c < 64; ++c) { float d = v[c] - mu; var += d * d; }
    var *= (1.f / 64.f);
    float r = rsqrtf(var + 1e-6f);
    float* ob = out + (size_t)bb * 64 * HWP + p;
#pragma unroll
    for (int c = 0; c < 64; ++c) ob[(size_t)c * HWP] = (v[c] - mu) * r * w[c] + b[c];
}

// ------- LayerNorm over sum of two partials; writes xsum = in0+in1 AND lnout = LN ------
__global__ __launch_bounds__(256, 2) void ln2_kernel(
    const float* in0, const float* in1,
    const float* __restrict__ w, const float* __restrict__ b,
    float* __restrict__ xsum, float* lnout)
{
    int p = blockIdx.x * 256 + threadIdx.x;
    int bb = blockIdx.y;
    if (p >= HWP) return;
    const float* i0 = in0 + (size_t)bb * 64 * HWP + p;
    const float* i1 = in1 + (size_t)bb * 64 * HWP + p;
    float v[64];
    float mu = 0.f;
#pragma unroll
    for (int c = 0; c < 64; ++c) { v[c] = i0[(size_t)c * HWP] + i1[(size_t)c * HWP]; mu += v[c]; }
    mu *= (1.f / 64.f);
    float var = 0.f;
#pragma unroll
    for (int c = 0; c < 64; ++c) { float d = v[c] - mu; var += d * d; }
    var *= (1.f / 64.f);
    float r = rsqrtf(var + 1e-6f);
    float* xb = xsum + (size_t)bb * 64 * HWP + p;
    float* ob = lnout + (size_t)bb * 64 * HWP + p;
#pragma unroll
    for (int c = 0; c < 64; ++c) {
        xb[(size_t)c * HWP] = v[c];
        ob[(size_t)c * HWP] = (v[c] - mu) * r * w[c] + b[c];
    }
}

// ---------------- 1x1 conv via MFMA f16 (Ci=64): wave = 64 px x up-to-4 co-tiles -------
__global__ __launch_bounds__(256, 2) void conv1x1_mfma_kernel(
    const float* __restrict__ in, const f16x8* __restrict__ wA,
    const float* __restrict__ bias, float* __restrict__ out,
    int Co, int do_gelu, int do_add)
{
    int lane = threadIdx.x & 63;
    int wv = threadIdx.x >> 6;
    int px0 = blockIdx.x * 256 + wv * 64;
    if (px0 >= HWP) return;
    int bb = blockIdx.z;
    int cot0 = blockIdx.y * 4;
    int nCot = (Co >> 4) - cot0; if (nCot > 4) nCot = 4;
    int row = lane >> 4;       // 0..3
    int colp = lane & 15;

    fx4 acc[4][4];   // [cot][nt]
#pragma unroll
    for (int c = 0; c < 4; ++c)
#pragma unroll
        for (int nt = 0; nt < 4; ++nt)
#pragma unroll
            for (int r = 0; r < 4; ++r) acc[c][nt][r] = 0.f;

    const float* ib = in + (size_t)bb * 64 * HWP;
#pragma unroll
    for (int ks = 0; ks < 2; ++ks) {
        f16x8 afr[4];
#pragma unroll
        for (int c = 0; c < 4; ++c)
            if (c < nCot) afr[c] = wA[(((cot0 + c) * 2 + ks) << 6) + lane];
#pragma unroll
        for (int nt = 0; nt < 4; ++nt) {
            int px = px0 + nt * 16 + colp;
            const float* bp = ib + (size_t)(ks * 32 + row * 8) * HWP + px;
            union { f16x8 v; f16x2 h[4]; } bu;
            bu.h[0] = pk2(bp[0],              bp[(size_t)1 * HWP]);
            bu.h[1] = pk2(bp[(size_t)2 * HWP], bp[(size_t)3 * HWP]);
            bu.h[2] = pk2(bp[(size_t)4 * HWP], bp[(size_t)5 * HWP]);
            bu.h[3] = pk2(bp[(size_t)6 * HWP], bp[(size_t)7 * HWP]);
#pragma unroll
            for (int c = 0; c < 4; ++c)
                if (c < nCot)
                    acc[c][nt] = __builtin_amdgcn_mfma_f32_16x16x32_f16(afr[c], bu.v, acc[c][nt], 0, 0, 0);
        }
    }

#pragma unroll
    for (int c = 0; c < 4; ++c) {
        if (c < nCot) {
#pragma unroll
            for (int r = 0; r < 4; ++r) {
                int co = (cot0 + c) * 16 + row * 4 + r;
                float bv = bias[co];
                float* op = out + ((size_t)bb * Co + co) * HWP;
#pragma unroll
                for (int nt = 0; nt < 4; ++nt) {
                    int px = px0 + nt * 16 + colp;
                    float v = acc[c][nt][r] + bv;
                    if (do_gelu) v = gelu_f(v);
                    if (do_add) v += op[px];
                    op[px] = v;
                }
            }
        }
    }
}

// ------- fused: gelu(dwconv3x3(in)) + in, then 1x1 proj partial (ci-split), dot2 -------
__global__ __launch_bounds__(256, 4) void dwproj_kernel(
    const float* __restrict__ in,   // (B,Ci,H,W)
    const float* __restrict__ dw,   // (Ci,9)
    const float* __restrict__ db,   // (Ci)
    const f16x2* __restrict__ awt,  // (Ci/2, 64) packed
    const float* __restrict__ ab,   // (64)
    float* __restrict__ out0, float* __restrict__ out1,
    int Ci, int splitlog)
{
    __shared__ float s_p[16][18 * DPS];
    int tid = threadIdx.x;
    int tx = tid & 15, ty = tid >> 4;
    int x0 = blockIdx.x * 16, y0 = blockIdx.y * 16;
    int part = blockIdx.z & ((1 << splitlog) - 1);
    int bb = blockIdx.z >> splitlog;
    int cic = Ci >> splitlog;
    int cbase = part * cic;
    float* dst = (part == 0) ? out0 : out1;
    int x = x0 + tx, y = y0 + ty;

    float acc[64];
    if (part == 0) {
#pragma unroll
        for (int o = 0; o < 64; ++o) acc[o] = ab[o];
    } else {
#pragma unroll
        for (int o = 0; o < 64; ++o) acc[o] = 0.f;
    }

    const float* ibase = in + (size_t)bb * Ci * HWP;
    for (int c0 = cbase; c0 < cbase + cic; c0 += 16) {
        int chunk = cbase + cic - c0; if (chunk > 16) chunk = 16;
        __syncthreads();
        for (int i = tid; i < chunk * 324; i += 256) {
            int ci = i / 324; int r = i - ci * 324;
            int py = r / 18, px = r - py * 18;
            int yy = y0 + py - 1, xx = x0 + px - 1;
            float v = 0.f;
            if ((unsigned)yy < HH && (unsigned)xx < WW)
                v = ibase[(size_t)(c0 + ci) * HWP + yy * WW + xx];
            s_p[ci][py * DPS + px] = v;
        }
        __syncthreads();
        for (int ci = 0; ci < chunk; ci += 2) {
            int c = c0 + ci;
            float s0v = db[c], s1v = db[c + 1];
            const float* dwr0 = dw + c * 9;
            const float* dwr1 = dwr0 + 9;
#pragma unroll
            for (int ky = 0; ky < 3; ++ky)
#pragma unroll
                for (int kx = 0; kx < 3; ++kx) {
                    s0v += s_p[ci][(ty + ky) * DPS + tx + kx] * dwr0[ky * 3 + kx];
                    s1v += s_p[ci + 1][(ty + ky) * DPS + tx + kx] * dwr1[ky * 3 + kx];
                }
            float v0 = gelu_f(s0v) + s_p[ci][(ty + 1) * DPS + tx + 1];
            float v1 = gelu_f(s1v) + s_p[ci + 1][(ty + 1) * DPS + tx + 1];
            f16x2 vp = pk2(v0, v1);
            const f16x2* wr = awt + (size_t)((c >> 1)) * 64;
#pragma unroll
            for (int o = 0; o < 64; ++o) acc[o] = fdot2f(vp, wr[o], acc[o]);
        }
    }

    if (x < WW && y < HH) {
        int p = y * WW + x;
        float* ob = dst + (size_t)bb * 64 * HWP + p;
#pragma unroll
        for (int o = 0; o < 64; ++o) ob[(size_t)o * HWP] = acc[o];
    }
}

// ---------------- attention v3: qkv precomputed; scores cached in f16-packed regs -------
__global__ __launch_bounds__(128, 4) void winattn2_kernel(
    const float* __restrict__ qkv,  // (B,192,H,W)
    const float* __restrict__ rpb,  // (8,361)
    float* __restrict__ out)        // (B,64,H,W)
{
    __shared__ __align__(16) float s_k[100][8];
    __shared__ __align__(16) float s_v[100][8];
    __shared__ float s_b[361];

    int head = blockIdx.y, bb = blockIdx.z;
    int wy = blockIdx.x / 20, wx = blockIdx.x - wy * 20;
    int tid = threadIdx.x;

    for (int i = tid; i < 361; i += 128) s_b[i] = rpb[head * 361 + i];

    int ty = tid / 10, tx = tid - ty * 10;
    float q[8];
    if (tid < 100) {
        int y = wy * 10 + ty, x = wx * 10 + tx;
        int gp = y * WW + x;
        const float* qb = qkv + ((size_t)bb * 192 + head * 8) * HWP + gp;
        const float* kb = qb + (size_t)64 * HWP;
        const float* vb = qb + (size_t)128 * HWP;
        const float scale = 0.3535533905932738f; // 1/sqrt(8)
#pragma unroll
        for (int cc = 0; cc < 8; ++cc) q[cc] = qb[(size_t)cc * HWP] * scale;
        float4 t0, t1;
        t0.x = kb[0];               t0.y = kb[(size_t)1 * HWP];
        t0.z = kb[(size_t)2 * HWP]; t0.w = kb[(size_t)3 * HWP];
        t1.x = kb[(size_t)4 * HWP]; t1.y = kb[(size_t)5 * HWP];
        t1.z = kb[(size_t)6 * HWP]; t1.w = kb[(size_t)7 * HWP];
        *(float4*)(&s_k[tid][0]) = t0;
        *(float4*)(&s_k[tid][4]) = t1;
        t0.x = vb[0];               t0.y = vb[(size_t)1 * HWP];
        t0.z = vb[(size_t)2 * HWP]; t0.w = vb[(size_t)3 * HWP];
        t1.x = vb[(size_t)4 * HWP]; t1.y = vb[(size_t)5 * HWP];
        t1.z = vb[(size_t)6 * HWP]; t1.w = vb[(size_t)7 * HWP];
        *(float4*)(&s_v[tid][0]) = t0;
        *(float4*)(&s_v[tid][4]) = t1;
    }
    __syncthreads();

    if (tid < 100) {
        const float4* k4 = (const float4*)s_k;
        const float4* v4 = (const float4*)s_v;
        const float* brow = s_b + (180 - ty * 19 - tx);

        f16x2 s16[50];
        float m = -1e30f;
#pragma unroll
        for (int i = 0; i < 50; ++i) {
            const int k0 = 2 * i, k1 = 2 * i + 1;
            const int c0 = (k0 / 10) * 19 + (k0 % 10);
            const int c1 = (k1 / 10) * 19 + (k1 % 10);
            float4 ka = k4[k0 * 2], kb2 = k4[k0 * 2 + 1];
            float s0 = brow[c0]
                     + q[0] * ka.x + q[1] * ka.y + q[2] * ka.z + q[3] * ka.w
                     + q[4] * kb2.x + q[5] * kb2.y + q[6] * kb2.z + q[7] * kb2.w;
            ka = k4[k1 * 2]; kb2 = k4[k1 * 2 + 1];
            float s1 = brow[c1]
                     + q[0] * ka.x + q[1] * ka.y + q[2] * ka.z + q[3] * ka.w
                     + q[4] * kb2.x + q[5] * kb2.y + q[6] * kb2.z + q[7] * kb2.w;
            m = fmaxf(m, fmaxf(s0, s1));
            s16[i] = __builtin_amdgcn_cvt_pkrtz(s0, s1);
        }
        float l = 0.f;
        float o[8];
#pragma unroll
        for (int cc = 0; cc < 8; ++cc) o[cc] = 0.f;
#pragma unroll
        for (int i = 0; i < 50; ++i) {
            float e0 = __expf((float)s16[i][0] - m);
            float e1 = __expf((float)s16[i][1] - m);
            l += e0 + e1;
            float4 va = v4[4 * i], vb2 = v4[4 * i + 1];
            o[0] += e0 * va.x; o[1] += e0 * va.y; o[2] += e0 * va.z; o[3] += e0 * va.w;
            o[4] += e0 * vb2.x; o[5] += e0 * vb2.y; o[6] += e0 * vb2.z; o[7] += e0 * vb2.w;
            va = v4[4 * i + 2]; vb2 = v4[4 * i + 3];
            o[0] += e1 * va.x; o[1] += e1 * va.y; o[2] += e1 * va.z; o[3] += e1 * va.w;
            o[4] += e1 * vb2.x; o[5] += e1 * vb2.y; o[6] += e1 * vb2.z; o[7] += e1 * vb2.w;
        }
        float rl = 1.f / l;
        int y = wy * 10 + ty, x = wx * 10 + tx;
        float* ob = out + ((size_t)bb * 64 + head * 8) * HWP + y * WW + x;
#pragma unroll
        for (int cc = 0; cc < 8; ++cc) ob[(size_t)cc * HWP] = o[cc] * rl;
    }
}

// ------- geometric ensemble -> D4-orbit weight table packed f16x2 (ci, rep2, co) -------
__global__ __launch_bounds__(256) void geo_kernel(
    const float* __restrict__ k, f16x2* __restrict__ out)
{
    int i = blockIdx.x * 256 + threadIdx.x;
    if (i >= 256 * 14) return;
    int oc = i / 14, r2 = i - oc * 14;   // oc = co*16 + ci
    int co = oc >> 4, ci = oc & 15;
    const float* kb = k + oc * 169;
    float sv[2];
#pragma unroll
    for (int t = 0; t < 2; ++t) {
        int rep = 2 * r2 + t;
        int a = 0, r = rep;
        while (r >= 7 - a) { r -= 7 - a; ++a; }
        int b2 = a + r;
        int y = 6 + a, x = 6 + b2;
        float s = kb[y * 13 + x] + kb[y * 13 + (12 - x)] + kb[(12 - y) * 13 + x] + kb[(12 - y) * 13 + (12 - x)]
                + kb[(12 - x) * 13 + y] + kb[x * 13 + y] + kb[(12 - x) * 13 + (12 - y)] + kb[x * 13 + (12 - y)];
        sv[t] = s * 0.125f;
    }
    f16x2 v;
    v[0] = (__fp16)sv[0];
    v[1] = (__fp16)sv[1];
    out[(ci * 14 + r2) * 16 + co] = v;
}

// ---------------- global mean over H,W of first-16 channels (sum of 2 partials) --------
__global__ __launch_bounds__(256) void gmean2_kernel(
    const float* __restrict__ in0, const float* __restrict__ in1, float* __restrict__ g)
{
    int bc = blockIdx.x;            // b*16 + c
    int bb = bc >> 4, c = bc & 15;
    const float* p0 = in0 + ((size_t)bb * 64 + c) * HWP;
    const float* p1 = in1 + ((size_t)bb * 64 + c) * HWP;
    float s = 0.f;
    for (int i = threadIdx.x; i < HWP; i += 256) s += p0[i] + p1[i];
#pragma unroll
    for (int off = 32; off > 0; off >>= 1) s += __shfl_down(s, off);
    __shared__ float red[4];
    int wave = threadIdx.x >> 6;
    if ((threadIdx.x & 63) == 0) red[wave] = s;
    __syncthreads();
    if (threadIdx.x == 0)
        g[bc] = (red[0] + red[1] + red[2] + red[3]) * (1.f / 40000.f);
}

// ---------------- tiny MLP -> dynamic 3x3 kernels ----------------
__global__ __launch_bounds__(192) void dynk_kernel(
    const float* __restrict__ g, const float* __restrict__ w1, const float* __restrict__ b1,
    const float* __restrict__ w2, const float* __restrict__ b2, float* __restrict__ dk)
{
    int bb = blockIdx.x;
    __shared__ float s_g2[8];
    int tid = threadIdx.x;
    if (tid < 8) {
        float a = b1[tid];
        for (int c = 0; c < 16; ++c) a += w1[tid * 16 + c] * g[bb * 16 + c];
        s_g2[tid] = gelu_f(a);
    }
    __syncthreads();
    if (tid < 144) {
        float a = b2[tid];
#pragma unroll
        for (int i = 0; i < 8; ++i) a += w2[tid * 8 + i] * s_g2[i];
        dk[bb * 144 + tid] = a;
    }
}

// ------- 13x13 D4-symmetric conv via 28 orbit sums (dot2) + dynamic depthwise 3x3 -------
__global__ __launch_bounds__(256, 4) void lkconv_kernel(
    const float* __restrict__ in0, const float* __restrict__ in1,
    const f16x2* __restrict__ lkO,  // (16,14,16)  [ci][rep2][co] packed
    const float* __restrict__ dk,   // (B,144)
    float* __restrict__ out)        // 4 partial buffers, stride PARTSZ
{
    __shared__ float s_p[4][28 * LKS];  // 17.9 KB
    int z = blockIdx.z;
    int bb = z >> 2, q = z & 3;
    int tid = threadIdx.x;
    int tx = tid & 15, ty = tid >> 4;
    int x0 = blockIdx.x * 16, y0 = blockIdx.y * 16;
    int x = x0 + tx, y = y0 + ty;

    const float* ib0 = in0 + ((size_t)bb * 64 + q * 4) * HWP;
    const float* ib1 = in1 + ((size_t)bb * 64 + q * 4) * HWP;
    for (int i = tid; i < 4 * 784; i += 256) {
        int ci = i / 784; int r = i - ci * 784;
        int py = r / 28, px = r - py * 28;
        int yy = y0 + py - 6, xx = x0 + px - 6;
        float v = 0.f;
        if ((unsigned)yy < HH && (unsigned)xx < WW) {
            int gp = (size_t)ci * HWP + yy * WW + xx;
            v = ib0[gp] + ib1[gp];
        }
        s_p[ci][py * LKS + px] = v;
    }
    __syncthreads();

    float acc[16];
#pragma unroll
    for (int co = 0; co < 16; ++co) acc[co] = 0.f;

#pragma unroll
    for (int ci4 = 0; ci4 < 4; ++ci4) {
        int ci = q * 4 + ci4;
        float orb[28];
#pragma unroll
        for (int o = 0; o < 28; ++o) orb[o] = 0.f;
#pragma unroll
        for (int ky = 0; ky < 13; ++ky) {
#pragma unroll
            for (int kx = 0; kx < 13; ++kx) {
                const int a = (ky < 6) ? (6 - ky) : (ky - 6);
                const int b = (kx < 6) ? (6 - kx) : (kx - 6);
                const int lo = (a < b) ? a : b;
                const int hi = (a < b) ? b : a;
                const int idx = lo * 7 - (lo * (lo - 1)) / 2 + (hi - lo);
                orb[idx] += s_p[ci4][(ty + ky) * LKS + tx + kx];
            }
        }
        const f16x2* wci = lkO + ci * 14 * 16;
#pragma unroll
        for (int o2 = 0; o2 < 14; ++o2) {
            f16x2 ov = pk2(orb[2 * o2], orb[2 * o2 + 1]);
            const f16x2* wr = wci + o2 * 16;
#pragma unroll
            for (int co = 0; co < 16; ++co) acc[co] = fdot2f(ov, wr[co], acc[co]);
        }
        float d = 0.f;
        const float* dkr = dk + bb * 144 + ci * 9;
#pragma unroll
        for (int dy = 0; dy < 3; ++dy)
#pragma unroll
            for (int dx = 0; dx < 3; ++dx)
                d += s_p[ci4][(ty + 5 + dy) * LKS + tx + 5 + dx] * dkr[dy * 3 + dx];
#pragma unroll
        for (int co = 0; co < 16; ++co) acc[co] += (co == ci) ? d : 0.f;
    }

    if (x < WW && y < HH) {
        int p = y * WW + x;
        float* ob = out + (size_t)q * PARTSZ + (size_t)bb * 16 * HWP + p;
#pragma unroll
        for (int co = 0; co < 16; ++co) ob[(size_t)co * HWP] = acc[co];
    }
}

// ------- 1x1 conv over concat(sum of 4 x1 partials, (y0+y1)[16..63]), dot2; += xout -----
__global__ __launch_bounds__(256, 2) void pconv_add_kernel(
    const float* __restrict__ x1q,  // 4 partial buffers, stride PARTSZ
    const float* __restrict__ y0, const float* __restrict__ y1,
    const f16x2* __restrict__ wt,   // (32, 64) packed over concat axis
    const float* __restrict__ bias,
    float* __restrict__ xout)
{
    int p4 = blockIdx.x * 256 + threadIdx.x;
    int o0 = blockIdx.y * 16;
    int bb = blockIdx.z;
    if (p4 >= NP4) return;
    float4 acc[16];
#pragma unroll
    for (int j = 0; j < 16; ++j) {
        float bv = bias[o0 + j];
        acc[j] = make_float4(bv, bv, bv, bv);
    }
    const float4* xb0 = (const float4*)(x1q + (size_t)bb * 16 * HWP) + p4;
    const float4* xb1 = (const float4*)(x1q + PARTSZ + (size_t)bb * 16 * HWP) + p4;
    const float4* xb2 = (const float4*)(x1q + 2 * PARTSZ + (size_t)bb * 16 * HWP) + p4;
    const float4* xb3 = (const float4*)(x1q + 3 * PARTSZ + (size_t)bb * 16 * HWP) + p4;
    for (int c2 = 0; c2 < 8; ++c2) {
        int ca = 2 * c2, cb = 2 * c2 + 1;
        float4 a0 = xb0[(size_t)ca * NP4], a1 = xb1[(size_t)ca * NP4];
        float4 a2 = xb2[(size_t)ca * NP4], a3 = xb3[(size_t)ca * NP4];
        float4 s0;
        s0.x = (a0.x + a1.x) + (a2.x + a3.x);
        s0.y = (a0.y + a1.y) + (a2.y + a3.y);
        s0.z = (a0.z + a1.z) + (a2.z + a3.z);
        s0.w = (a0.w + a1.w) + (a2.w + a3.w);
        a0 = xb0[(size_t)cb * NP4]; a1 = xb1[(size_t)cb * NP4];
        a2 = xb2[(size_t)cb * NP4]; a3 = xb3[(size_t)cb * NP4];
        float4 s1;
        s1.x = (a0.x + a1.x) + (a2.x + a3.x);
        s1.y = (a0.y + a1.y) + (a2.y + a3.y);
        s1.z = (a0.z + a1.z) + (a2.z + a3.z);
        s1.w = (a0.w + a1.w) + (a2.w + a3.w);
        f16x2 px = pk2(s0.x, s1.x), py = pk2(s0.y, s1.y);
        f16x2 pz = pk2(s0.z, s1.z), pw = pk2(s0.w, s1.w);
        const f16x2* wr = wt + c2 * 64 + o0;
#pragma unroll
        for (int j = 0; j < 16; ++j) {
            f16x2 w = wr[j];
            acc[j].x = fdot2f(px, w, acc[j].x);
            acc[j].y = fdot2f(py, w, acc[j].y);
            acc[j].z = fdot2f(pz, w, acc[j].z);
            acc[j].w = fdot2f(pw, w, acc[j].w);
        }
    }
    const float4* yb0 = (const float4*)(y0 + ((size_t)bb * 64 + 16) * HWP) + p4;
    const float4* yb1 = (const float4*)(y1 + ((size_t)bb * 64 + 16) * HWP) + p4;
    for (int c2 = 8; c2 < 32; ++c2) {
        int cy = 2 * (c2 - 8);
        float4 v00 = yb0[(size_t)cy * NP4], v10 = yb1[(size_t)cy * NP4];
        float4 v01 = yb0[(size_t)(cy + 1) * NP4], v11 = yb1[(size_t)(cy + 1) * NP4];
        float4 s0, s1;
        s0.x = v00.x + v10.x; s0.y = v00.y + v10.y; s0.z = v00.z + v10.z; s0.w = v00.w + v10.w;
        s1.x = v01.x + v11.x; s1.y = v01.y + v11.y; s1.z = v01.z + v11.z; s1.w = v01.w + v11.w;
        f16x2 px = pk2(s0.x, s1.x), py = pk2(s0.y, s1.y);
        f16x2 pz = pk2(s0.z, s1.z), pw = pk2(s0.w, s1.w);
        const f16x2* wr = wt + c2 * 64 + o0;
#pragma unroll
        for (int j = 0; j < 16; ++j) {
            f16x2 w = wr[j];
            acc[j].x = fdot2f(px, w, acc[j].x);
            acc[j].y = fdot2f(py, w, acc[j].y);
            acc[j].z = fdot2f(pz, w, acc[j].z);
            acc[j].w = fdot2f(pw, w, acc[j].w);
        }
    }
    float4* ob = (float4*)(xout + ((size_t)bb * 64 + o0) * HWP) + p4;
#pragma unroll
    for (int j = 0; j < 16; ++j) {
        float4 old = ob[(size_t)j * NP4];
        old.x += acc[j].x; old.y += acc[j].y; old.z += acc[j].z; old.w += acc[j].w;
        ob[(size_t)j * NP4] = old;
    }
}

// ---------------- final 3x3 conv, 4-way ci-split, dot2 ----------------
__global__ __launch_bounds__(256, 4) void conv3_part_kernel(
    const float* __restrict__ in, const f16x2* __restrict__ wt3h,  // (ci2,tap,64)
    const float* __restrict__ bias, const float* __restrict__ skip,
    float* __restrict__ pbase, float* __restrict__ xout)
{
    __shared__ float s_p[16][18 * DPS];
    int tid = threadIdx.x;
    int tx = tid & 15, ty = tid >> 4;
    int x0 = blockIdx.x * 16, y0 = blockIdx.y * 16;
    int bb = blockIdx.z >> 2, q = blockIdx.z & 3;
    int cbase = q * 16;
    int x = x0 + tx, y = y0 + ty;

    float acc[64];
#pragma unroll
    for (int o = 0; o < 64; ++o) acc[o] = 0.f;

    const float* ibase = in + ((size_t)bb * 64 + cbase) * HWP;
    for (int i = tid; i < 16 * 324; i += 256) {
        int ci = i / 324; int r = i - ci * 324;
        int py = r / 18, px = r - py * 18;
        int yy = y0 + py - 1, xx = x0 + px - 1;
        float v = 0.f;
        if ((unsigned)yy < HH && (unsigned)xx < WW)
            v = ibase[(size_t)ci * HWP + yy * WW + xx];
        s_p[ci][py * DPS + px] = v;
    }
    __syncthreads();

    int cb2 = q * 8;
#pragma unroll 2
    for (int c2 = 0; c2 < 8; ++c2) {
        const f16x2* wr0 = wt3h + (size_t)(cb2 + c2) * 9 * 64;
#pragma unroll
        for (int ky = 0; ky < 3; ++ky) {
#pragma unroll
            for (int kx = 0; kx < 3; ++kx) {
                float xv0 = s_p[2 * c2][(ty + ky) * DPS + tx + kx];
                float xv1 = s_p[2 * c2 + 1][(ty + ky) * DPS + tx + kx];
                f16x2 xp = pk2(xv0, xv1);
                const f16x2* wr = wr0 + (ky * 3 + kx) * 64;
#pragma unroll
                for (int o = 0; o < 64; ++o) acc[o] = fdot2f(xp, wr[o], acc[o]);
            }
        }
    }

    if (x < WW && y < HH) {
        int p = y * WW + x;
        if (q < 3) {
            float* ob = pbase + (size_t)q * PART64 + (size_t)bb * 64 * HWP + p;
#pragma unroll
            for (int o = 0; o < 64; ++o) ob[(size_t)o * HWP] = acc[o];
        } else {
            const float* sb = skip + (size_t)bb * 64 * HWP + p;
            float* ob = xout + (size_t)bb * 64 * HWP + p;
#pragma unroll
            for (int o = 0; o < 64; ++o)
                ob[(size_t)o * HWP] = acc[o] + bias[o] + sb[(size_t)o * HWP];
        }
    }
}

// ---------------- combine conv3 partials: x += p0 + p1 + p2 ----------------
__global__ __launch_bounds__(256) void combine4_kernel(
    const float* __restrict__ p, float* __restrict__ x)
{
    int idx = blockIdx.x * 256 + threadIdx.x;   // float4 index over B*64*NP4
    if (idx >= BB * 64 * NP4) return;
    const float4* pf = (const float4*)p;
    float4 a = pf[idx];
    float4 b = pf[idx + 2560000];
    float4 c = pf[idx + 5120000];
    float4 r = ((float4*)x)[idx];
    r.x += a.x + b.x + c.x;
    r.y += a.y + b.y + c.y;
    r.z += a.z + b.z + c.z;
    r.w += a.w + b.w + c.w;
    ((float4*)x)[idx] = r;
}

extern "C" void kernel_launch(void* const* d_in, const int* in_sizes, int n_in,
                              void* d_out, int out_size, void* d_ws, size_t ws_size,
                              hipStream_t stream)
{
    const float* x_in      = (const float*)d_in[0];
    const float* ln_proj_w = (const float*)d_in[1];
    const float* ln_proj_b = (const float*)d_in[2];
    const float* proj_p_w  = (const float*)d_in[3];
    const float* proj_p_b  = (const float*)d_in[4];
    const float* proj_d_w  = (const float*)d_in[5];
    const float* proj_d_b  = (const float*)d_in[6];
    const float* proj_a_w  = (const float*)d_in[7];
    const float* proj_a_b  = (const float*)d_in[8];
    const float* ln_attn_w = (const float*)d_in[9];
    const float* ln_attn_b = (const float*)d_in[10];
    const float* qkv_w     = (const float*)d_in[11];
    const float* qkv_b     = (const float*)d_in[12];
    const float* attn_o_w  = (const float*)d_in[13];
    const float* attn_o_b  = (const float*)d_in[14];
    const float* rpb       = (const float*)d_in[15];
    const float* dwcp1_w   = (const float*)d_in[16];
    const float* dwcp1_b   = (const float*)d_in[17];
    const float* dwcp2_w   = (const float*)d_in[18];
    const float* dwcp2_b   = (const float*)d_in[19];
    const float* pconv_w   = (const float*)d_in[20];
    const float* pconv_b   = (const float*)d_in[21];
    const float* ffn_p_w   = (const float*)d_in[22];
    const float* ffn_p_b   = (const float*)d_in[23];
    const float* ffn_d_w   = (const float*)d_in[24];
    const float* ffn_d_b   = (const float*)d_in[25];
    const float* ffn_a_w   = (const float*)d_in[26];
    const float* ffn_a_b   = (const float*)d_in[27];
    const float* ln_out_w  = (const float*)d_in[28];
    const float* ln_out_b  = (const float*)d_in[29];
    const float* conv_o_w  = (const float*)d_in[30];
    const float* conv_o_b  = (const float*)d_in[31];
    const float* plk       = (const float*)d_in[32];

    float* X  = (float*)d_out;
    float* ws = (float*)d_ws;

    // workspace map (floats):
    //  0        .. 10.24M : A / AP0 (dwproj partial 0) / winattn out
    //  10.24M   .. 40.96M : QKV | R1 | conv3 partials P0/P1/P2
    //  23.04M   .. 33.28M : AP1 (ffn dwproj partial 1)
    //  33.28M   .. 43.52M : R2Q (lkconv partials) / AP1p (proj dwproj partial 1)
    //  43.52M   ..        : LKTH, GM, DK, WTH, WAH  (always live)
    float* A    = ws;
    float* AP0  = ws;
    float* QKV  = ws + 10240000;
    float* R1   = ws + 10240000;
    float* P3B  = ws + 10240000;           // conv3 partials P0,P1,P2 (stride PART64)
    float* AP1  = ws + 23040000;
    float* R2Q  = ws + 33280000;
    float* AP1p = ws + 33280000;           // proj dwproj partial 1 (R2Q region, dead here)
    f16x2* LKTH = (f16x2*)(ws + 43520000); // 3584 slots
    float* GM   = ws + 43520000 + 4096;
    float* DK   = GM + 64;
    f16x2* WTH  = (f16x2*)(DK + 576);      // 49152 slots (float-sized)
    f16x8* WAH  = (f16x8*)(DK + 576 + 49152);  // 4352 slots x 16B

    dim3 b256(256);
    dim3 gLN(157, 4);
    dim3 gT8(13, 13, 8);
    dim3 gT16(13, 13, 16);

    prep_kernel<<<dim3(192), b256, 0, stream>>>(proj_p_w, attn_o_w, ffn_p_w, proj_a_w,
                                                ffn_a_w, pconv_w, conv_o_w, qkv_w, WTH);
    prepA_kernel<<<dim3(17), b256, 0, stream>>>(qkv_w, proj_p_w, attn_o_w, ffn_p_w, WAH);
    geo_kernel<<<dim3(14), b256, 0, stream>>>(plk, LKTH);

    // x = LN(x); x = conv_ffn(x) [proj] — dwproj 2-way split, combine fused into attn LN
    ln_kernel<<<gLN, b256, 0, stream>>>(x_in, ln_proj_w, ln_proj_b, A);
    conv1x1_mfma_kernel<<<dim3(157, 2, 4), b256, 0, stream>>>(A, WAH + 1536, proj_p_b, R1, 128, 1, 0);
    dwproj_kernel<<<gT8, b256, 0, stream>>>(R1, proj_d_w, proj_d_b, WTH + 11264, proj_a_b,
                                            AP0, AP1p, 128, 1);

    // X = AP0+AP1p ; AP0 = LN(X) in place; then attention
    ln2_kernel<<<gLN, b256, 0, stream>>>(AP0, AP1p, ln_attn_w, ln_attn_b, X, AP0);
    conv1x1_mfma_kernel<<<dim3(157, 3, 4), b256, 0, stream>>>(AP0, WAH + 0, qkv_b, QKV, 192, 0, 0);
    winattn2_kernel<<<dim3(400, 8, 4), dim3(128), 0, stream>>>(QKV, rpb, A);
    conv1x1_mfma_kernel<<<dim3(157, 1, 4), b256, 0, stream>>>(A, WAH + 2560, attn_o_b, X, 64, 0, 1);

    for (int i = 0; i < 2; ++i) {
        conv1x1_mfma_kernel<<<dim3(157, 2, 4), b256, 0, stream>>>(X, WAH + 3072 + i * 640, ffn_p_b + i * 80, R1, 80, 1, 0);
        dwproj_kernel<<<gT8, b256, 0, stream>>>(R1, ffn_d_w + i * 720, ffn_d_b + i * 80,
                                                WTH + 15360 + i * 2560, ffn_a_b + i * 64,
                                                AP0, AP1, 80, 1);
        gmean2_kernel<<<dim3(64), b256, 0, stream>>>(AP0, AP1, GM);
        dynk_kernel<<<dim3(4), dim3(192), 0, stream>>>(GM, dwcp1_w + i * 128, dwcp1_b + i * 8,
                                                       dwcp2_w + i * 1152, dwcp2_b + i * 144, DK);
        lkconv_kernel<<<gT16, b256, 0, stream>>>(AP0, AP1, LKTH, DK, R2Q);
        pconv_add_kernel<<<dim3(40, 4, 4), b256, 0, stream>>>(R2Q, AP0, AP1,
                                                              WTH + 20480 + i * 2048, pconv_b + i * 64, X);
    }

    // x = conv3x3(LN(x)) + skip  — 4-way ci-split; q==3 folds bias+skip into X
    ln_kernel<<<gLN, b256, 0, stream>>>(X, ln_out_w, ln_out_b, A);
    conv3_part_kernel<<<gT16, b256, 0, stream>>>(A, WTH + 24576, conv_o_b, x_in, P3B, X);
    combine4_kernel<<<dim3(10000), b256, 0, stream>>>(P3B, X);
}

// Round 14
// 1148.540 us; speedup vs baseline: 1.4927x; 1.0817x over previous
//
#include <hip/hip_runtime.h>
#include <math.h>

#define HH 200
#define WW 200
#define HWP 40000
#define NP4 10000
#define BB 4

#define LKS 40   // lkconv LDS row stride
#define DPS 24   // dwproj LDS row stride
#define PARTSZ 2560000    // one (B,16,H,W) partial buffer (lkconv)

typedef __fp16 f16x2 __attribute__((ext_vector_type(2)));
typedef __fp16 f16x8 __attribute__((ext_vector_type(8)));
typedef float fx4 __attribute__((ext_vector_type(4)));

#if __has_builtin(__builtin_amdgcn_fdot2)
__device__ __forceinline__ float fdot2f(f16x2 a, f16x2 b, float c) {
    return __builtin_amdgcn_fdot2(a, b, c, false);
}
#else
__device__ __forceinline__ float fdot2f(f16x2 a, f16x2 b, float c) {
    return c + (float)a[0] * (float)b[0] + (float)a[1] * (float)b[1];
}
#endif

__device__ __forceinline__ f16x2 pk2(float a, float b) {
    return __builtin_amdgcn_cvt_pkrtz(a, b);
}

__device__ __forceinline__ float gelu_f(float x) {
    return 0.5f * x * (1.0f + erff(x * 0.7071067811865475f));
}

// ---------------- weight prep: transpose + pack to f16x2 along reduction (ci) axis ------
// wth layout offsets (f16x2 slots):
//  11264  wtPA  (64,64)   proj_a
//  15360  wtFA0 (40,64)   ffn_a[0]
//  17920  wtFA1 (40,64)   ffn_a[1]
//  20480  wtPC0 (32,64)   pconv[0]
//  22528  wtPC1 (32,64)   pconv[1]
__device__ __forceinline__ void pk_w(const float* __restrict__ w, f16x2* __restrict__ dst,
                                     int Co, int Ci, int idx) {
    int c2 = idx / Co, o = idx - c2 * Co;
    f16x2 r;
    r[0] = (__fp16)w[o * Ci + 2 * c2];
    r[1] = (__fp16)w[o * Ci + 2 * c2 + 1];
    dst[idx] = r;
}

__global__ __launch_bounds__(256) void prep_kernel(
    const float* __restrict__ pa, const float* __restrict__ fa,
    const float* __restrict__ pc, f16x2* __restrict__ wth)
{
    int i = blockIdx.x * 256 + threadIdx.x;
    if (i < 4096) { pk_w(pa, wth + 11264, 64, 128, i); return; } i -= 4096;
    if (i < 2560) { pk_w(fa, wth + 15360, 64, 80, i); return; } i -= 2560;
    if (i < 2560) { pk_w(fa + 5120, wth + 17920, 64, 80, i); return; } i -= 2560;
    if (i < 2048) { pk_w(pc, wth + 20480, 64, 64, i); return; } i -= 2048;
    if (i < 2048) { pk_w(pc + 4096, wth + 22528, 64, 64, i); return; }
}

// ------- MFMA A-fragment prep for 1x1 convs (all Ci=64, ksteps=2) -------
// slots: qkv 0..1536, proj_p 1536..2560, attn_o 2560..3072, ffn_p0 3072..3712,
// ffn_p1 3712..4352.
__global__ __launch_bounds__(256) void prepA_kernel(
    const float* __restrict__ qkvw, const float* __restrict__ pp,
    const float* __restrict__ ao, const float* __restrict__ fp,
    f16x8* __restrict__ wA)
{
    int s = blockIdx.x * 256 + threadIdx.x;
    if (s >= 4352) return;
    const float* src;
    int base;
    if (s < 1536)      { src = qkvw;      base = 0; }
    else if (s < 2560) { src = pp;        base = 1536; }
    else if (s < 3072) { src = ao;        base = 2560; }
    else if (s < 3712) { src = fp;        base = 3072; }
    else               { src = fp + 5120; base = 3712; }
    int r = s - base;
    int lane = r & 63;
    int t = r >> 6;
    int ks = t & 1;
    int cot = t >> 1;
    int co = cot * 16 + (lane & 15);
    int k0 = ks * 32 + ((lane >> 4) << 3);
    f16x8 v;
#pragma unroll
    for (int j = 0; j < 8; ++j) v[j] = (__fp16)src[co * 64 + k0 + j];
    wA[s] = v;
}

// ------- MFMA A-fragment prep for conv3 (K = 576, k = tap*64 + ci) -------
// slot s: lane = s&63; u = s>>6; cot = u&3; t = u>>2 (0..17).
// co = cot*16 + (lane&15); k = t*32 + (lane>>4)*8 + j; tap = k>>6; ci = k&63.
__global__ __launch_bounds__(256) void prepA3_kernel(
    const float* __restrict__ co3, f16x8* __restrict__ wA3)
{
    int s = blockIdx.x * 256 + threadIdx.x;
    if (s >= 4608) return;
    int lane = s & 63;
    int u = s >> 6;
    int cot = u & 3;
    int t = u >> 2;
    int co = cot * 16 + (lane & 15);
    int k0 = t * 32 + ((lane >> 4) << 3);
    f16x8 v;
#pragma unroll
    for (int j = 0; j < 8; ++j) {
        int k = k0 + j;
        int tap = k >> 6, ci = k & 63;
        v[j] = (__fp16)co3[(co * 64 + ci) * 9 + tap];
    }
    wA3[s] = v;
}

// ---------------- LayerNorm over 64 channels ----------------
__global__ __launch_bounds__(256, 2) void ln_kernel(
    const float* __restrict__ in, const float* __restrict__ w,
    const float* __restrict__ b, float* __restrict__ out)
{
    int p = blockIdx.x * 256 + threadIdx.x;
    int bb = blockIdx.y;
    if (p >= HWP) return;
    const float* ib = in + (size_t)bb * 64 * HWP + p;
    float v[64];
    float mu = 0.f;
#pragma unroll
    for (int c = 0; c < 64; ++c) { v[c] = ib[(size_t)c * HWP]; mu += v[c]; }
    mu *= (1.f / 64.f);
    float var = 0.f;
#pragma unroll
    for (int c = 0; c < 64; ++c) { float d = v[c] - mu; var += d * d; }
    var *= (1.f / 64.f);
    float r = rsqrtf(var + 1e-6f);
    float* ob = out + (size_t)bb * 64 * HWP + p;
#pragma unroll
    for (int c = 0; c < 64; ++c) ob[(size_t)c * HWP] = (v[c] - mu) * r * w[c] + b[c];
}

// ------- LayerNorm over sum of two partials; writes xsum = in0+in1 AND lnout = LN ------
__global__ __launch_bounds__(256, 2) void ln2_kernel(
    const float* in0, const float* in1,
    const float* __restrict__ w, const float* __restrict__ b,
    float* __restrict__ xsum, float* lnout)
{
    int p = blockIdx.x * 256 + threadIdx.x;
    int bb = blockIdx.y;
    if (p >= HWP) return;
    const float* i0 = in0 + (size_t)bb * 64 * HWP + p;
    const float* i1 = in1 + (size_t)bb * 64 * HWP + p;
    float v[64];
    float mu = 0.f;
#pragma unroll
    for (int c = 0; c < 64; ++c) { v[c] = i0[(size_t)c * HWP] + i1[(size_t)c * HWP]; mu += v[c]; }
    mu *= (1.f / 64.f);
    float var = 0.f;
#pragma unroll
    for (int c = 0; c < 64; ++c) { float d = v[c] - mu; var += d * d; }
    var *= (1.f / 64.f);
    float r = rsqrtf(var + 1e-6f);
    float* xb = xsum + (size_t)bb * 64 * HWP + p;
    float* ob = lnout + (size_t)bb * 64 * HWP + p;
#pragma unroll
    for (int c = 0; c < 64; ++c) {
        xb[(size_t)c * HWP] = v[c];
        ob[(size_t)c * HWP] = (v[c] - mu) * r * w[c] + b[c];
    }
}

// ---------------- 1x1 conv via MFMA f16 (Ci=64): wave = 64 px x up-to-4 co-tiles -------
__global__ __launch_bounds__(256, 2) void conv1x1_mfma_kernel(
    const float* __restrict__ in, const f16x8* __restrict__ wA,
    const float* __restrict__ bias, float* __restrict__ out,
    int Co, int do_gelu, int do_add)
{
    int lane = threadIdx.x & 63;
    int wv = threadIdx.x >> 6;
    int px0 = blockIdx.x * 256 + wv * 64;
    if (px0 >= HWP) return;
    int bb = blockIdx.z;
    int cot0 = blockIdx.y * 4;
    int nCot = (Co >> 4) - cot0; if (nCot > 4) nCot = 4;
    int row = lane >> 4;
    int colp = lane & 15;

    fx4 acc[4][4];
#pragma unroll
    for (int c = 0; c < 4; ++c)
#pragma unroll
        for (int nt = 0; nt < 4; ++nt)
#pragma unroll
            for (int r = 0; r < 4; ++r) acc[c][nt][r] = 0.f;

    const float* ib = in + (size_t)bb * 64 * HWP;
#pragma unroll
    for (int ks = 0; ks < 2; ++ks) {
        f16x8 afr[4];
#pragma unroll
        for (int c = 0; c < 4; ++c)
            if (c < nCot) afr[c] = wA[(((cot0 + c) * 2 + ks) << 6) + lane];
#pragma unroll
        for (int nt = 0; nt < 4; ++nt) {
            int px = px0 + nt * 16 + colp;
            const float* bp = ib + (size_t)(ks * 32 + row * 8) * HWP + px;
            union { f16x8 v; f16x2 h[4]; } bu;
            bu.h[0] = pk2(bp[0],              bp[(size_t)1 * HWP]);
            bu.h[1] = pk2(bp[(size_t)2 * HWP], bp[(size_t)3 * HWP]);
            bu.h[2] = pk2(bp[(size_t)4 * HWP], bp[(size_t)5 * HWP]);
            bu.h[3] = pk2(bp[(size_t)6 * HWP], bp[(size_t)7 * HWP]);
#pragma unroll
            for (int c = 0; c < 4; ++c)
                if (c < nCot)
                    acc[c][nt] = __builtin_amdgcn_mfma_f32_16x16x32_f16(afr[c], bu.v, acc[c][nt], 0, 0, 0);
        }
    }

#pragma unroll
    for (int c = 0; c < 4; ++c) {
        if (c < nCot) {
#pragma unroll
            for (int r = 0; r < 4; ++r) {
                int co = (cot0 + c) * 16 + row * 4 + r;
                float bv = bias[co];
                float* op = out + ((size_t)bb * Co + co) * HWP;
#pragma unroll
                for (int nt = 0; nt < 4; ++nt) {
                    int px = px0 + nt * 16 + colp;
                    float v = acc[c][nt][r] + bv;
                    if (do_gelu) v = gelu_f(v);
                    if (do_add) v += op[px];
                    op[px] = v;
                }
            }
        }
    }
}

// ---------------- conv3 via MFMA: 9 shifted 1x1 GEMMs, K=576, bias+skip fused ----------
__global__ __launch_bounds__(256, 2) void conv3_mfma_kernel(
    const float* __restrict__ in,   // LN'd (B,64,H,W)
    const f16x8* __restrict__ wA3,  // 4608 slots: (t*4+cot)*64+lane
    const float* __restrict__ bias, const float* __restrict__ skip,
    float* __restrict__ out)
{
    int lane = threadIdx.x & 63;
    int wv = threadIdx.x >> 6;
    int px0 = blockIdx.x * 256 + wv * 64;
    if (px0 >= HWP) return;
    int bb = blockIdx.z;
    int row = lane >> 4;
    int colp = lane & 15;

    fx4 acc[4][4];
#pragma unroll
    for (int c = 0; c < 4; ++c)
#pragma unroll
        for (int nt = 0; nt < 4; ++nt)
#pragma unroll
            for (int r = 0; r < 4; ++r) acc[c][nt][r] = 0.f;

    int py[4], pxx[4];
#pragma unroll
    for (int nt = 0; nt < 4; ++nt) {
        int p = px0 + nt * 16 + colp;
        py[nt] = p / WW;
        pxx[nt] = p - py[nt] * WW;
    }

    const float* ib = in + (size_t)bb * 64 * HWP;
    for (int t = 0; t < 18; ++t) {
        int tap = t >> 1, ks = t & 1;
        int dy = tap / 3 - 1, dx = tap % 3 - 1;
        f16x8 afr[4];
#pragma unroll
        for (int c = 0; c < 4; ++c) afr[c] = wA3[((t * 4 + c) << 6) + lane];
        const float* kb = ib + (size_t)(ks * 32 + row * 8) * HWP;
#pragma unroll
        for (int nt = 0; nt < 4; ++nt) {
            int yy = py[nt] + dy, xx = pxx[nt] + dx;
            union { f16x8 v; f16x2 h[4]; } bu;
            if ((unsigned)yy < HH && (unsigned)xx < WW) {
                const float* bp = kb + yy * WW + xx;
                bu.h[0] = pk2(bp[0],              bp[(size_t)1 * HWP]);
                bu.h[1] = pk2(bp[(size_t)2 * HWP], bp[(size_t)3 * HWP]);
                bu.h[2] = pk2(bp[(size_t)4 * HWP], bp[(size_t)5 * HWP]);
                bu.h[3] = pk2(bp[(size_t)6 * HWP], bp[(size_t)7 * HWP]);
            } else {
                bu.h[0] = pk2(0.f, 0.f); bu.h[1] = bu.h[0];
                bu.h[2] = bu.h[0];       bu.h[3] = bu.h[0];
            }
#pragma unroll
            for (int c = 0; c < 4; ++c)
                acc[c][nt] = __builtin_amdgcn_mfma_f32_16x16x32_f16(afr[c], bu.v, acc[c][nt], 0, 0, 0);
        }
    }

#pragma unroll
    for (int c = 0; c < 4; ++c) {
#pragma unroll
        for (int r = 0; r < 4; ++r) {
            int co = c * 16 + row * 4 + r;
            float bv = bias[co];
            const float* sb = skip + ((size_t)bb * 64 + co) * HWP;
            float* op = out + ((size_t)bb * 64 + co) * HWP;
#pragma unroll
            for (int nt = 0; nt < 4; ++nt) {
                int px = px0 + nt * 16 + colp;
                op[px] = acc[c][nt][r] + bv + sb[px];
            }
        }
    }
}

// ------- fused: gelu(dwconv3x3(in)) + in, then 1x1 proj partial (ci-split), dot2 -------
__global__ __launch_bounds__(256, 4) void dwproj_kernel(
    const float* __restrict__ in,   // (B,Ci,H,W)
    const float* __restrict__ dw,   // (Ci,9)
    const float* __restrict__ db,   // (Ci)
    const f16x2* __restrict__ awt,  // (Ci/2, 64) packed
    const float* __restrict__ ab,   // (64)
    float* __restrict__ out0, float* __restrict__ out1,
    int Ci, int splitlog)
{
    __shared__ float s_p[16][18 * DPS];
    int tid = threadIdx.x;
    int tx = tid & 15, ty = tid >> 4;
    int x0 = blockIdx.x * 16, y0 = blockIdx.y * 16;
    int part = blockIdx.z & ((1 << splitlog) - 1);
    int bb = blockIdx.z >> splitlog;
    int cic = Ci >> splitlog;
    int cbase = part * cic;
    float* dst = (part == 0) ? out0 : out1;
    int x = x0 + tx, y = y0 + ty;

    float acc[64];
    if (part == 0) {
#pragma unroll
        for (int o = 0; o < 64; ++o) acc[o] = ab[o];
    } else {
#pragma unroll
        for (int o = 0; o < 64; ++o) acc[o] = 0.f;
    }

    const float* ibase = in + (size_t)bb * Ci * HWP;
    for (int c0 = cbase; c0 < cbase + cic; c0 += 16) {
        int chunk = cbase + cic - c0; if (chunk > 16) chunk = 16;
        __syncthreads();
        for (int i = tid; i < chunk * 324; i += 256) {
            int ci = i / 324; int r = i - ci * 324;
            int py = r / 18, px = r - py * 18;
            int yy = y0 + py - 1, xx = x0 + px - 1;
            float v = 0.f;
            if ((unsigned)yy < HH && (unsigned)xx < WW)
                v = ibase[(size_t)(c0 + ci) * HWP + yy * WW + xx];
            s_p[ci][py * DPS + px] = v;
        }
        __syncthreads();
        for (int ci = 0; ci < chunk; ci += 2) {
            int c = c0 + ci;
            float s0v = db[c], s1v = db[c + 1];
            const float* dwr0 = dw + c * 9;
            const float* dwr1 = dwr0 + 9;
#pragma unroll
            for (int ky = 0; ky < 3; ++ky)
#pragma unroll
                for (int kx = 0; kx < 3; ++kx) {
                    s0v += s_p[ci][(ty + ky) * DPS + tx + kx] * dwr0[ky * 3 + kx];
                    s1v += s_p[ci + 1][(ty + ky) * DPS + tx + kx] * dwr1[ky * 3 + kx];
                }
            float v0 = gelu_f(s0v) + s_p[ci][(ty + 1) * DPS + tx + 1];
            float v1 = gelu_f(s1v) + s_p[ci + 1][(ty + 1) * DPS + tx + 1];
            f16x2 vp = pk2(v0, v1);
            const f16x2* wr = awt + (size_t)((c >> 1)) * 64;
#pragma unroll
            for (int o = 0; o < 64; ++o) acc[o] = fdot2f(vp, wr[o], acc[o]);
        }
    }

    if (x < WW && y < HH) {
        int p = y * WW + x;
        float* ob = dst + (size_t)bb * 64 * HWP + p;
#pragma unroll
        for (int o = 0; o < 64; ++o) ob[(size_t)o * HWP] = acc[o];
    }
}

// ---------------- attention v3: qkv precomputed; scores cached in f16-packed regs -------
__global__ __launch_bounds__(128, 4) void winattn2_kernel(
    const float* __restrict__ qkv,  // (B,192,H,W)
    const float* __restrict__ rpb,  // (8,361)
    float* __restrict__ out)        // (B,64,H,W)
{
    __shared__ __align__(16) float s_k[100][8];
    __shared__ __align__(16) float s_v[100][8];
    __shared__ float s_b[361];

    int head = blockIdx.y, bb = blockIdx.z;
    int wy = blockIdx.x / 20, wx = blockIdx.x - wy * 20;
    int tid = threadIdx.x;

    for (int i = tid; i < 361; i += 128) s_b[i] = rpb[head * 361 + i];

    int ty = tid / 10, tx = tid - ty * 10;
    float q[8];
    if (tid < 100) {
        int y = wy * 10 + ty, x = wx * 10 + tx;
        int gp = y * WW + x;
        const float* qb = qkv + ((size_t)bb * 192 + head * 8) * HWP + gp;
        const float* kb = qb + (size_t)64 * HWP;
        const float* vb = qb + (size_t)128 * HWP;
        const float scale = 0.3535533905932738f; // 1/sqrt(8)
#pragma unroll
        for (int cc = 0; cc < 8; ++cc) q[cc] = qb[(size_t)cc * HWP] * scale;
        float4 t0, t1;
        t0.x = kb[0];               t0.y = kb[(size_t)1 * HWP];
        t0.z = kb[(size_t)2 * HWP]; t0.w = kb[(size_t)3 * HWP];
        t1.x = kb[(size_t)4 * HWP]; t1.y = kb[(size_t)5 * HWP];
        t1.z = kb[(size_t)6 * HWP]; t1.w = kb[(size_t)7 * HWP];
        *(float4*)(&s_k[tid][0]) = t0;
        *(float4*)(&s_k[tid][4]) = t1;
        t0.x = vb[0];               t0.y = vb[(size_t)1 * HWP];
        t0.z = vb[(size_t)2 * HWP]; t0.w = vb[(size_t)3 * HWP];
        t1.x = vb[(size_t)4 * HWP]; t1.y = vb[(size_t)5 * HWP];
        t1.z = vb[(size_t)6 * HWP]; t1.w = vb[(size_t)7 * HWP];
        *(float4*)(&s_v[tid][0]) = t0;
        *(float4*)(&s_v[tid][4]) = t1;
    }
    __syncthreads();

    if (tid < 100) {
        const float4* k4 = (const float4*)s_k;
        const float4* v4 = (const float4*)s_v;
        const float* brow = s_b + (180 - ty * 19 - tx);

        f16x2 s16[50];
        float m = -1e30f;
#pragma unroll
        for (int i = 0; i < 50; ++i) {
            const int k0 = 2 * i, k1 = 2 * i + 1;
            const int c0 = (k0 / 10) * 19 + (k0 % 10);
            const int c1 = (k1 / 10) * 19 + (k1 % 10);
            float4 ka = k4[k0 * 2], kb2 = k4[k0 * 2 + 1];
            float s0 = brow[c0]
                     + q[0] * ka.x + q[1] * ka.y + q[2] * ka.z + q[3] * ka.w
                     + q[4] * kb2.x + q[5] * kb2.y + q[6] * kb2.z + q[7] * kb2.w;
            ka = k4[k1 * 2]; kb2 = k4[k1 * 2 + 1];
            float s1 = brow[c1]
                     + q[0] * ka.x + q[1] * ka.y + q[2] * ka.z + q[3] * ka.w
                     + q[4] * kb2.x + q[5] * kb2.y + q[6] * kb2.z + q[7] * kb2.w;
            m = fmaxf(m, fmaxf(s0, s1));
            s16[i] = __builtin_amdgcn_cvt_pkrtz(s0, s1);
        }
        float l = 0.f;
        float o[8];
#pragma unroll
        for (int cc = 0; cc < 8; ++cc) o[cc] = 0.f;
#pragma unroll
        for (int i = 0; i < 50; ++i) {
            float e0 = __expf((float)s16[i][0] - m);
            float e1 = __expf((float)s16[i][1] - m);
            l += e0 + e1;
            float4 va = v4[4 * i], vb2 = v4[4 * i + 1];
            o[0] += e0 * va.x; o[1] += e0 * va.y; o[2] += e0 * va.z; o[3] += e0 * va.w;
            o[4] += e0 * vb2.x; o[5] += e0 * vb2.y; o[6] += e0 * vb2.z; o[7] += e0 * vb2.w;
            va = v4[4 * i + 2]; vb2 = v4[4 * i + 3];
            o[0] += e1 * va.x; o[1] += e1 * va.y; o[2] += e1 * va.z; o[3] += e1 * va.w;
            o[4] += e1 * vb2.x; o[5] += e1 * vb2.y; o[6] += e1 * vb2.z; o[7] += e1 * vb2.w;
        }
        float rl = 1.f / l;
        int y = wy * 10 + ty, x = wx * 10 + tx;
        float* ob = out + ((size_t)bb * 64 + head * 8) * HWP + y * WW + x;
#pragma unroll
        for (int cc = 0; cc < 8; ++cc) ob[(size_t)cc * HWP] = o[cc] * rl;
    }
}

// ------- geometric ensemble -> D4-orbit weight table packed f16x2 (ci, rep2, co) -------
__global__ __launch_bounds__(256) void geo_kernel(
    const float* __restrict__ k, f16x2* __restrict__ out)
{
    int i = blockIdx.x * 256 + threadIdx.x;
    if (i >= 256 * 14) return;
    int oc = i / 14, r2 = i - oc * 14;   // oc = co*16 + ci
    int co = oc >> 4, ci = oc & 15;
    const float* kb = k + oc * 169;
    float sv[2];
#pragma unroll
    for (int t = 0; t < 2; ++t) {
        int rep = 2 * r2 + t;
        int a = 0, r = rep;
        while (r >= 7 - a) { r -= 7 - a; ++a; }
        int b2 = a + r;
        int y = 6 + a, x = 6 + b2;
        float s = kb[y * 13 + x] + kb[y * 13 + (12 - x)] + kb[(12 - y) * 13 + x] + kb[(12 - y) * 13 + (12 - x)]
                + kb[(12 - x) * 13 + y] + kb[x * 13 + y] + kb[(12 - x) * 13 + (12 - y)] + kb[x * 13 + (12 - y)];
        sv[t] = s * 0.125f;
    }
    f16x2 v;
    v[0] = (__fp16)sv[0];
    v[1] = (__fp16)sv[1];
    out[(ci * 14 + r2) * 16 + co] = v;
}

// ---------------- global mean over H,W of first-16 channels (sum of 2 partials) --------
__global__ __launch_bounds__(256) void gmean2_kernel(
    const float* __restrict__ in0, const float* __restrict__ in1, float* __restrict__ g)
{
    int bc = blockIdx.x;            // b*16 + c
    int bb = bc >> 4, c = bc & 15;
    const float* p0 = in0 + ((size_t)bb * 64 + c) * HWP;
    const float* p1 = in1 + ((size_t)bb * 64 + c) * HWP;
    float s = 0.f;
    for (int i = threadIdx.x; i < HWP; i += 256) s += p0[i] + p1[i];
#pragma unroll
    for (int off = 32; off > 0; off >>= 1) s += __shfl_down(s, off);
    __shared__ float red[4];
    int wave = threadIdx.x >> 6;
    if ((threadIdx.x & 63) == 0) red[wave] = s;
    __syncthreads();
    if (threadIdx.x == 0)
        g[bc] = (red[0] + red[1] + red[2] + red[3]) * (1.f / 40000.f);
}

// ---------------- tiny MLP -> dynamic 3x3 kernels ----------------
__global__ __launch_bounds__(192) void dynk_kernel(
    const float* __restrict__ g, const float* __restrict__ w1, const float* __restrict__ b1,
    const float* __restrict__ w2, const float* __restrict__ b2, float* __restrict__ dk)
{
    int bb = blockIdx.x;
    __shared__ float s_g2[8];
    int tid = threadIdx.x;
    if (tid < 8) {
        float a = b1[tid];
        for (int c = 0; c < 16; ++c) a += w1[tid * 16 + c] * g[bb * 16 + c];
        s_g2[tid] = gelu_f(a);
    }
    __syncthreads();
    if (tid < 144) {
        float a = b2[tid];
#pragma unroll
        for (int i = 0; i < 8; ++i) a += w2[tid * 8 + i] * s_g2[i];
        dk[bb * 144 + tid] = a;
    }
}

// ------- 13x13 D4-symmetric conv via 28 orbit sums (dot2) + dynamic depthwise 3x3 -------
__global__ __launch_bounds__(256, 4) void lkconv_kernel(
    const float* __restrict__ in0, const float* __restrict__ in1,
    const f16x2* __restrict__ lkO,  // (16,14,16)  [ci][rep2][co] packed
    const float* __restrict__ dk,   // (B,144)
    float* __restrict__ out)        // 4 partial buffers, stride PARTSZ
{
    __shared__ float s_p[4][28 * LKS];  // 17.9 KB
    int z = blockIdx.z;
    int bb = z >> 2, q = z & 3;
    int tid = threadIdx.x;
    int tx = tid & 15, ty = tid >> 4;
    int x0 = blockIdx.x * 16, y0 = blockIdx.y * 16;
    int x = x0 + tx, y = y0 + ty;

    const float* ib0 = in0 + ((size_t)bb * 64 + q * 4) * HWP;
    const float* ib1 = in1 + ((size_t)bb * 64 + q * 4) * HWP;
    for (int i = tid; i < 4 * 784; i += 256) {
        int ci = i / 784; int r = i - ci * 784;
        int py = r / 28, px = r - py * 28;
        int yy = y0 + py - 6, xx = x0 + px - 6;
        float v = 0.f;
        if ((unsigned)yy < HH && (unsigned)xx < WW) {
            int gp = (size_t)ci * HWP + yy * WW + xx;
            v = ib0[gp] + ib1[gp];
        }
        s_p[ci][py * LKS + px] = v;
    }
    __syncthreads();

    float acc[16];
#pragma unroll
    for (int co = 0; co < 16; ++co) acc[co] = 0.f;

#pragma unroll
    for (int ci4 = 0; ci4 < 4; ++ci4) {
        int ci = q * 4 + ci4;
        float orb[28];
#pragma unroll
        for (int o = 0; o < 28; ++o) orb[o] = 0.f;
#pragma unroll
        for (int ky = 0; ky < 13; ++ky) {
#pragma unroll
            for (int kx = 0; kx < 13; ++kx) {
                const int a = (ky < 6) ? (6 - ky) : (ky - 6);
                const int b = (kx < 6) ? (6 - kx) : (kx - 6);
                const int lo = (a < b) ? a : b;
                const int hi = (a < b) ? b : a;
                const int idx = lo * 7 - (lo * (lo - 1)) / 2 + (hi - lo);
                orb[idx] += s_p[ci4][(ty + ky) * LKS + tx + kx];
            }
        }
        const f16x2* wci = lkO + ci * 14 * 16;
#pragma unroll
        for (int o2 = 0; o2 < 14; ++o2) {
            f16x2 ov = pk2(orb[2 * o2], orb[2 * o2 + 1]);
            const f16x2* wr = wci + o2 * 16;
#pragma unroll
            for (int co = 0; co < 16; ++co) acc[co] = fdot2f(ov, wr[co], acc[co]);
        }
        float d = 0.f;
        const float* dkr = dk + bb * 144 + ci * 9;
#pragma unroll
        for (int dy = 0; dy < 3; ++dy)
#pragma unroll
            for (int dx = 0; dx < 3; ++dx)
                d += s_p[ci4][(ty + 5 + dy) * LKS + tx + 5 + dx] * dkr[dy * 3 + dx];
#pragma unroll
        for (int co = 0; co < 16; ++co) acc[co] += (co == ci) ? d : 0.f;
    }

    if (x < WW && y < HH) {
        int p = y * WW + x;
        float* ob = out + (size_t)q * PARTSZ + (size_t)bb * 16 * HWP + p;
#pragma unroll
        for (int co = 0; co < 16; ++co) ob[(size_t)co * HWP] = acc[co];
    }
}

// ------- 1x1 conv over concat(sum of 4 x1 partials, (y0+y1)[16..63]), dot2; += xout -----
__global__ __launch_bounds__(256, 2) void pconv_add_kernel(
    const float* __restrict__ x1q,  // 4 partial buffers, stride PARTSZ
    const float* __restrict__ y0, const float* __restrict__ y1,
    const f16x2* __restrict__ wt,   // (32, 64) packed over concat axis
    const float* __restrict__ bias,
    float* __restrict__ xout)
{
    int p4 = blockIdx.x * 256 + threadIdx.x;
    int o0 = blockIdx.y * 16;
    int bb = blockIdx.z;
    if (p4 >= NP4) return;
    float4 acc[16];
#pragma unroll
    for (int j = 0; j < 16; ++j) {
        float bv = bias[o0 + j];
        acc[j] = make_float4(bv, bv, bv, bv);
    }
    const float4* xb0 = (const float4*)(x1q + (size_t)bb * 16 * HWP) + p4;
    const float4* xb1 = (const float4*)(x1q + PARTSZ + (size_t)bb * 16 * HWP) + p4;
    const float4* xb2 = (const float4*)(x1q + 2 * PARTSZ + (size_t)bb * 16 * HWP) + p4;
    const float4* xb3 = (const float4*)(x1q + 3 * PARTSZ + (size_t)bb * 16 * HWP) + p4;
    for (int c2 = 0; c2 < 8; ++c2) {
        int ca = 2 * c2, cb = 2 * c2 + 1;
        float4 a0 = xb0[(size_t)ca * NP4], a1 = xb1[(size_t)ca * NP4];
        float4 a2 = xb2[(size_t)ca * NP4], a3 = xb3[(size_t)ca * NP4];
        float4 s0;
        s0.x = (a0.x + a1.x) + (a2.x + a3.x);
        s0.y = (a0.y + a1.y) + (a2.y + a3.y);
        s0.z = (a0.z + a1.z) + (a2.z + a3.z);
        s0.w = (a0.w + a1.w) + (a2.w + a3.w);
        a0 = xb0[(size_t)cb * NP4]; a1 = xb1[(size_t)cb * NP4];
        a2 = xb2[(size_t)cb * NP4]; a3 = xb3[(size_t)cb * NP4];
        float4 s1;
        s1.x = (a0.x + a1.x) + (a2.x + a3.x);
        s1.y = (a0.y + a1.y) + (a2.y + a3.y);
        s1.z = (a0.z + a1.z) + (a2.z + a3.z);
        s1.w = (a0.w + a1.w) + (a2.w + a3.w);
        f16x2 px = pk2(s0.x, s1.x), py = pk2(s0.y, s1.y);
        f16x2 pz = pk2(s0.z, s1.z), pw = pk2(s0.w, s1.w);
        const f16x2* wr = wt + c2 * 64 + o0;
#pragma unroll
        for (int j = 0; j < 16; ++j) {
            f16x2 w = wr[j];
            acc[j].x = fdot2f(px, w, acc[j].x);
            acc[j].y = fdot2f(py, w, acc[j].y);
            acc[j].z = fdot2f(pz, w, acc[j].z);
            acc[j].w = fdot2f(pw, w, acc[j].w);
        }
    }
    const float4* yb0 = (const float4*)(y0 + ((size_t)bb * 64 + 16) * HWP) + p4;
    const float4* yb1 = (const float4*)(y1 + ((size_t)bb * 64 + 16) * HWP) + p4;
    for (int c2 = 8; c2 < 32; ++c2) {
        int cy = 2 * (c2 - 8);
        float4 v00 = yb0[(size_t)cy * NP4], v10 = yb1[(size_t)cy * NP4];
        float4 v01 = yb0[(size_t)(cy + 1) * NP4], v11 = yb1[(size_t)(cy + 1) * NP4];
        float4 s0, s1;
        s0.x = v00.x + v10.x; s0.y = v00.y + v10.y; s0.z = v00.z + v10.z; s0.w = v00.w + v10.w;
        s1.x = v01.x + v11.x; s1.y = v01.y + v11.y; s1.z = v01.z + v11.z; s1.w = v01.w + v11.w;
        f16x2 px = pk2(s0.x, s1.x), py = pk2(s0.y, s1.y);
        f16x2 pz = pk2(s0.z, s1.z), pw = pk2(s0.w, s1.w);
        const f16x2* wr = wt + c2 * 64 + o0;
#pragma unroll
        for (int j = 0; j < 16; ++j) {
            f16x2 w = wr[j];
            acc[j].x = fdot2f(px, w, acc[j].x);
            acc[j].y = fdot2f(py, w, acc[j].y);
            acc[j].z = fdot2f(pz, w, acc[j].z);
            acc[j].w = fdot2f(pw, w, acc[j].w);
        }
    }
    float4* ob = (float4*)(xout + ((size_t)bb * 64 + o0) * HWP) + p4;
#pragma unroll
    for (int j = 0; j < 16; ++j) {
        float4 old = ob[(size_t)j * NP4];
        old.x += acc[j].x; old.y += acc[j].y; old.z += acc[j].z; old.w += acc[j].w;
        ob[(size_t)j * NP4] = old;
    }
}

extern "C" void kernel_launch(void* const* d_in, const int* in_sizes, int n_in,
                              void* d_out, int out_size, void* d_ws, size_t ws_size,
                              hipStream_t stream)
{
    const float* x_in      = (const float*)d_in[0];
    const float* ln_proj_w = (const float*)d_in[1];
    const float* ln_proj_b = (const float*)d_in[2];
    const float* proj_p_w  = (const float*)d_in[3];
    const float* proj_p_b  = (const float*)d_in[4];
    const float* proj_d_w  = (const float*)d_in[5];
    const float* proj_d_b  = (const float*)d_in[6];
    const float* proj_a_w  = (const float*)d_in[7];
    const float* proj_a_b  = (const float*)d_in[8];
    const float* ln_attn_w = (const float*)d_in[9];
    const float* ln_attn_b = (const float*)d_in[10];
    const float* qkv_w     = (const float*)d_in[11];
    const float* qkv_b     = (const float*)d_in[12];
    const float* attn_o_w  = (const float*)d_in[13];
    const float* attn_o_b  = (const float*)d_in[14];
    const float* rpb       = (const float*)d_in[15];
    const float* dwcp1_w   = (const float*)d_in[16];
    const float* dwcp1_b   = (const float*)d_in[17];
    const float* dwcp2_w   = (const float*)d_in[18];
    const float* dwcp2_b   = (const float*)d_in[19];
    const float* pconv_w   = (const float*)d_in[20];
    const float* pconv_b   = (const float*)d_in[21];
    const float* ffn_p_w   = (const float*)d_in[22];
    const float* ffn_p_b   = (const float*)d_in[23];
    const float* ffn_d_w   = (const float*)d_in[24];
    const float* ffn_d_b   = (const float*)d_in[25];
    const float* ffn_a_w   = (const float*)d_in[26];
    const float* ffn_a_b   = (const float*)d_in[27];
    const float* ln_out_w  = (const float*)d_in[28];
    const float* ln_out_b  = (const float*)d_in[29];
    const float* conv_o_w  = (const float*)d_in[30];
    const float* conv_o_b  = (const float*)d_in[31];
    const float* plk       = (const float*)d_in[32];

    float* X  = (float*)d_out;
    float* ws = (float*)d_ws;

    // workspace map (floats):
    //  0        .. 10.24M : A / AP0 (dwproj partial 0) / winattn out
    //  10.24M   .. 40.96M : QKV | R1
    //  23.04M   .. 33.28M : AP1 (ffn dwproj partial 1)
    //  33.28M   .. 43.52M : R2Q (lkconv partials) / AP1p (proj dwproj partial 1)
    //  43.52M   ..        : LKTH, GM, DK, WTH, WAH, WA3  (always live)
    float* A    = ws;
    float* AP0  = ws;
    float* QKV  = ws + 10240000;
    float* R1   = ws + 10240000;
    float* AP1  = ws + 23040000;
    float* R2Q  = ws + 33280000;
    float* AP1p = ws + 33280000;
    f16x2* LKTH = (f16x2*)(ws + 43520000); // 3584 slots
    float* GM   = ws + 43520000 + 4096;
    float* DK   = GM + 64;
    f16x2* WTH  = (f16x2*)(DK + 576);          // 49152 float-sized slots
    f16x8* WAH  = (f16x8*)(DK + 576 + 49152);  // 4352 slots x 16B
    f16x8* WA3  = WAH + 4352;                  // 4608 slots x 16B

    dim3 b256(256);
    dim3 gLN(157, 4);
    dim3 gT8(13, 13, 8);
    dim3 gT16(13, 13, 16);

    prep_kernel<<<dim3(52), b256, 0, stream>>>(proj_a_w, ffn_a_w, pconv_w, WTH);
    prepA_kernel<<<dim3(17), b256, 0, stream>>>(qkv_w, proj_p_w, attn_o_w, ffn_p_w, WAH);
    prepA3_kernel<<<dim3(18), b256, 0, stream>>>(conv_o_w, WA3);
    geo_kernel<<<dim3(14), b256, 0, stream>>>(plk, LKTH);

    // x = LN(x); x = conv_ffn(x) [proj] — dwproj 2-way split, combine fused into attn LN
    ln_kernel<<<gLN, b256, 0, stream>>>(x_in, ln_proj_w, ln_proj_b, A);
    conv1x1_mfma_kernel<<<dim3(157, 2, 4), b256, 0, stream>>>(A, WAH + 1536, proj_p_b, R1, 128, 1, 0);
    dwproj_kernel<<<gT8, b256, 0, stream>>>(R1, proj_d_w, proj_d_b, WTH + 11264, proj_a_b,
                                            AP0, AP1p, 128, 1);

    // X = AP0+AP1p ; AP0 = LN(X) in place; then attention
    ln2_kernel<<<gLN, b256, 0, stream>>>(AP0, AP1p, ln_attn_w, ln_attn_b, X, AP0);
    conv1x1_mfma_kernel<<<dim3(157, 3, 4), b256, 0, stream>>>(AP0, WAH + 0, qkv_b, QKV, 192, 0, 0);
    winattn2_kernel<<<dim3(400, 8, 4), dim3(128), 0, stream>>>(QKV, rpb, A);
    conv1x1_mfma_kernel<<<dim3(157, 1, 4), b256, 0, stream>>>(A, WAH + 2560, attn_o_b, X, 64, 0, 1);

    for (int i = 0; i < 2; ++i) {
        conv1x1_mfma_kernel<<<dim3(157, 2, 4), b256, 0, stream>>>(X, WAH + 3072 + i * 640, ffn_p_b + i * 80, R1, 80, 1, 0);
        dwproj_kernel<<<gT8, b256, 0, stream>>>(R1, ffn_d_w + i * 720, ffn_d_b + i * 80,
                                                WTH + 15360 + i * 2560, ffn_a_b + i * 64,
                                                AP0, AP1, 80, 1);
        gmean2_kernel<<<dim3(64), b256, 0, stream>>>(AP0, AP1, GM);
        dynk_kernel<<<dim3(4), dim3(192), 0, stream>>>(GM, dwcp1_w + i * 128, dwcp1_b + i * 8,
                                                       dwcp2_w + i * 1152, dwcp2_b + i * 144, DK);
        lkconv_kernel<<<gT16, b256, 0, stream>>>(AP0, AP1, LKTH, DK, R2Q);
        pconv_add_kernel<<<dim3(40, 4, 4), b256, 0, stream>>>(R2Q, AP0, AP1,
                                                              WTH + 20480 + i * 2048, pconv_b + i * 64, X);
    }

    // x = conv3x3(LN(x)) + skip — MFMA implicit GEMM (9 shifted taps), bias+skip fused
    ln_kernel<<<gLN, b256, 0, stream>>>(X, ln_out_w, ln_out_b, A);
    conv3_mfma_kernel<<<dim3(157, 1, 4), b256, 0, stream>>>(A, WA3, conv_o_b, x_in, X);
}

// Round 15
// 1056.560 us; speedup vs baseline: 1.6226x; 1.0871x over previous
//
#include <hip/hip_runtime.h>
#include <math.h>

#define HH 200
#define WW 200
#define HWP 40000
#define NP4 10000
#define BB 4

#define LKS 40   // lkconv LDS row stride
#define DPS 24   // dwgelu LDS row stride
#define PARTSZ 2560000    // one (B,16,H,W) partial buffer (lkconv)

typedef __fp16 f16x2 __attribute__((ext_vector_type(2)));
typedef __fp16 f16x8 __attribute__((ext_vector_type(8)));
typedef float fx4 __attribute__((ext_vector_type(4)));

#if __has_builtin(__builtin_amdgcn_fdot2)
__device__ __forceinline__ float fdot2f(f16x2 a, f16x2 b, float c) {
    return __builtin_amdgcn_fdot2(a, b, c, false);
}
#else
__device__ __forceinline__ float fdot2f(f16x2 a, f16x2 b, float c) {
    return c + (float)a[0] * (float)b[0] + (float)a[1] * (float)b[1];
}
#endif

__device__ __forceinline__ f16x2 pk2(float a, float b) {
    return __builtin_amdgcn_cvt_pkrtz(a, b);
}

__device__ __forceinline__ float gelu_f(float x) {
    return 0.5f * x * (1.0f + erff(x * 0.7071067811865475f));
}

// ---------------- pconv weight pack (ci,co) f16x2 ----------------
// wth slots: pconv[0] at 0 (32x64), pconv[1] at 2048
__global__ __launch_bounds__(256) void prep_kernel(
    const float* __restrict__ pc, f16x2* __restrict__ wth)
{
    int i = blockIdx.x * 256 + threadIdx.x;
    if (i >= 4096) return;
    int w = i >> 11;             // which pconv
    int r = i & 2047;
    int c2 = r / 64, o = r - c2 * 64;
    const float* src = pc + w * 4096;
    f16x2 v;
    v[0] = (__fp16)src[o * 64 + 2 * c2];
    v[1] = (__fp16)src[o * 64 + 2 * c2 + 1];
    wth[w * 2048 + r] = v;
}

// ------- MFMA A-fragment prep for Ci=64 1x1 convs (ksteps=2) -------
// slots: qkv 0..1536, proj_p 1536..2560, attn_o 2560..3072, ffn_p0 3072..3712,
// ffn_p1 3712..4352.
__global__ __launch_bounds__(256) void prepA_kernel(
    const float* __restrict__ qkvw, const float* __restrict__ pp,
    const float* __restrict__ ao, const float* __restrict__ fp,
    f16x8* __restrict__ wA)
{
    int s = blockIdx.x * 256 + threadIdx.x;
    if (s >= 4352) return;
    const float* src;
    int base;
    if (s < 1536)      { src = qkvw;      base = 0; }
    else if (s < 2560) { src = pp;        base = 1536; }
    else if (s < 3072) { src = ao;        base = 2560; }
    else if (s < 3712) { src = fp;        base = 3072; }
    else               { src = fp + 5120; base = 3712; }
    int r = s - base;
    int lane = r & 63;
    int t = r >> 6;
    int ks = t & 1;
    int cot = t >> 1;
    int co = cot * 16 + (lane & 15);
    int k0 = ks * 32 + ((lane >> 4) << 3);
    f16x8 v;
#pragma unroll
    for (int j = 0; j < 8; ++j) v[j] = (__fp16)src[co * 64 + k0 + j];
    wA[s] = v;
}

// ------- MFMA A-fragment prep, generalized K (proj_a Ci=128 ks4; ffn_a Ci=80 ks3) -----
// slots: pa 0..1024, fa0 1024..1792, fa1 1792..2560. Co=64 for all.
__global__ __launch_bounds__(256) void prepA2_kernel(
    const float* __restrict__ pa, const float* __restrict__ fa,
    f16x8* __restrict__ wA2)
{
    int s = blockIdx.x * 256 + threadIdx.x;
    if (s >= 2560) return;
    const float* src; int base, Ci, ksteps;
    if (s < 1024)      { src = pa;        base = 0;    Ci = 128; ksteps = 4; }
    else if (s < 1792) { src = fa;        base = 1024; Ci = 80;  ksteps = 3; }
    else               { src = fa + 5120; base = 1792; Ci = 80;  ksteps = 3; }
    int r = s - base;
    int lane = r & 63;
    int u = r >> 6;
    int ks = u % ksteps;
    int cot = u / ksteps;
    int co = cot * 16 + (lane & 15);
    int k0 = ks * 32 + ((lane >> 4) << 3);
    f16x8 v;
#pragma unroll
    for (int j = 0; j < 8; ++j) {
        int k = k0 + j;
        v[j] = (k < Ci) ? (__fp16)src[co * Ci + k] : (__fp16)0.f;
    }
    wA2[s] = v;
}

// ------- MFMA A-fragment prep for conv3 (K = 576, k = tap*64 + ci) -------
__global__ __launch_bounds__(256) void prepA3_kernel(
    const float* __restrict__ co3, f16x8* __restrict__ wA3)
{
    int s = blockIdx.x * 256 + threadIdx.x;
    if (s >= 4608) return;
    int lane = s & 63;
    int u = s >> 6;
    int cot = u & 3;
    int t = u >> 2;
    int co = cot * 16 + (lane & 15);
    int k0 = t * 32 + ((lane >> 4) << 3);
    f16x8 v;
#pragma unroll
    for (int j = 0; j < 8; ++j) {
        int k = k0 + j;
        int tap = k >> 6, ci = k & 63;
        v[j] = (__fp16)co3[(co * 64 + ci) * 9 + tap];
    }
    wA3[s] = v;
}

// ---------------- LayerNorm over 64 channels ----------------
__global__ __launch_bounds__(256, 2) void ln_kernel(
    const float* __restrict__ in, const float* __restrict__ w,
    const float* __restrict__ b, float* __restrict__ out)
{
    int p = blockIdx.x * 256 + threadIdx.x;
    int bb = blockIdx.y;
    if (p >= HWP) return;
    const float* ib = in + (size_t)bb * 64 * HWP + p;
    float v[64];
    float mu = 0.f;
#pragma unroll
    for (int c = 0; c < 64; ++c) { v[c] = ib[(size_t)c * HWP]; mu += v[c]; }
    mu *= (1.f / 64.f);
    float var = 0.f;
#pragma unroll
    for (int c = 0; c < 64; ++c) { float d = v[c] - mu; var += d * d; }
    var *= (1.f / 64.f);
    float r = rsqrtf(var + 1e-6f);
    float* ob = out + (size_t)bb * 64 * HWP + p;
#pragma unroll
    for (int c = 0; c < 64; ++c) ob[(size_t)c * HWP] = (v[c] - mu) * r * w[c] + b[c];
}

// ---------------- 1x1 conv via MFMA f16 (Ci=64 f32 input) ----------------
__global__ __launch_bounds__(256, 2) void conv1x1_mfma_kernel(
    const float* __restrict__ in, const f16x8* __restrict__ wA,
    const float* __restrict__ bias, float* __restrict__ out,
    int Co, int do_gelu, int do_add)
{
    int lane = threadIdx.x & 63;
    int wv = threadIdx.x >> 6;
    int px0 = blockIdx.x * 256 + wv * 64;
    if (px0 >= HWP) return;
    int bb = blockIdx.z;
    int cot0 = blockIdx.y * 4;
    int nCot = (Co >> 4) - cot0; if (nCot > 4) nCot = 4;
    int row = lane >> 4;
    int colp = lane & 15;

    fx4 acc[4][4];
#pragma unroll
    for (int c = 0; c < 4; ++c)
#pragma unroll
        for (int nt = 0; nt < 4; ++nt)
#pragma unroll
            for (int r = 0; r < 4; ++r) acc[c][nt][r] = 0.f;

    const float* ib = in + (size_t)bb * 64 * HWP;
#pragma unroll
    for (int ks = 0; ks < 2; ++ks) {
        f16x8 afr[4];
#pragma unroll
        for (int c = 0; c < 4; ++c)
            if (c < nCot) afr[c] = wA[(((cot0 + c) * 2 + ks) << 6) + lane];
#pragma unroll
        for (int nt = 0; nt < 4; ++nt) {
            int px = px0 + nt * 16 + colp;
            const float* bp = ib + (size_t)(ks * 32 + row * 8) * HWP + px;
            union { f16x8 v; f16x2 h[4]; } bu;
            bu.h[0] = pk2(bp[0],              bp[(size_t)1 * HWP]);
            bu.h[1] = pk2(bp[(size_t)2 * HWP], bp[(size_t)3 * HWP]);
            bu.h[2] = pk2(bp[(size_t)4 * HWP], bp[(size_t)5 * HWP]);
            bu.h[3] = pk2(bp[(size_t)6 * HWP], bp[(size_t)7 * HWP]);
#pragma unroll
            for (int c = 0; c < 4; ++c)
                if (c < nCot)
                    acc[c][nt] = __builtin_amdgcn_mfma_f32_16x16x32_f16(afr[c], bu.v, acc[c][nt], 0, 0, 0);
        }
    }

#pragma unroll
    for (int c = 0; c < 4; ++c) {
        if (c < nCot) {
#pragma unroll
            for (int r = 0; r < 4; ++r) {
                int co = (cot0 + c) * 16 + row * 4 + r;
                float bv = bias[co];
                float* op = out + ((size_t)bb * Co + co) * HWP;
#pragma unroll
                for (int nt = 0; nt < 4; ++nt) {
                    int px = px0 + nt * 16 + colp;
                    float v = acc[c][nt][r] + bv;
                    if (do_gelu) v = gelu_f(v);
                    if (do_add) v += op[px];
                    op[px] = v;
                }
            }
        }
    }
}

// ---------------- 1x1 conv via MFMA, f16 input, generalized K, Co=64 ----------------
__global__ __launch_bounds__(256, 2) void conv1x1h_mfma_kernel(
    const __fp16* __restrict__ in,   // (B,Ci,H,W) f16
    const f16x8* __restrict__ wA,    // (4 cot x ksteps x 64) slots
    const float* __restrict__ bias, float* __restrict__ out,
    int Ci, int ksteps)
{
    int lane = threadIdx.x & 63;
    int wv = threadIdx.x >> 6;
    int px0 = blockIdx.x * 256 + wv * 64;
    if (px0 >= HWP) return;
    int bb = blockIdx.z;
    int row = lane >> 4;
    int colp = lane & 15;

    fx4 acc[4][4];
#pragma unroll
    for (int c = 0; c < 4; ++c)
#pragma unroll
        for (int nt = 0; nt < 4; ++nt)
#pragma unroll
            for (int r = 0; r < 4; ++r) acc[c][nt][r] = 0.f;

    const __fp16* ib = in + (size_t)bb * Ci * HWP;
    for (int ks = 0; ks < ksteps; ++ks) {
        f16x8 afr[4];
#pragma unroll
        for (int c = 0; c < 4; ++c)
            afr[c] = wA[((c * ksteps + ks) << 6) + lane];
        int k0 = ks * 32 + row * 8;
        bool ok = (k0 < Ci);
#pragma unroll
        for (int nt = 0; nt < 4; ++nt) {
            int px = px0 + nt * 16 + colp;
            f16x8 bv;
            if (ok) {
                const __fp16* bp = ib + (size_t)k0 * HWP + px;
#pragma unroll
                for (int j = 0; j < 8; ++j) bv[j] = bp[(size_t)j * HWP];
            } else {
#pragma unroll
                for (int j = 0; j < 8; ++j) bv[j] = (__fp16)0.f;
            }
#pragma unroll
            for (int c = 0; c < 4; ++c)
                acc[c][nt] = __builtin_amdgcn_mfma_f32_16x16x32_f16(afr[c], bv, acc[c][nt], 0, 0, 0);
        }
    }

#pragma unroll
    for (int c = 0; c < 4; ++c) {
#pragma unroll
        for (int r = 0; r < 4; ++r) {
            int co = c * 16 + row * 4 + r;
            float bv = bias[co];
            float* op = out + ((size_t)bb * 64 + co) * HWP;
#pragma unroll
            for (int nt = 0; nt < 4; ++nt) {
                int px = px0 + nt * 16 + colp;
                op[px] = acc[c][nt][r] + bv;
            }
        }
    }
}

// ---------------- conv3 via MFMA: 9 shifted 1x1 GEMMs, K=576, bias+skip fused ----------
__global__ __launch_bounds__(256, 2) void conv3_mfma_kernel(
    const float* __restrict__ in,   // LN'd (B,64,H,W)
    const f16x8* __restrict__ wA3,  // 4608 slots
    const float* __restrict__ bias, const float* __restrict__ skip,
    float* __restrict__ out)
{
    int lane = threadIdx.x & 63;
    int wv = threadIdx.x >> 6;
    int px0 = blockIdx.x * 256 + wv * 64;
    if (px0 >= HWP) return;
    int bb = blockIdx.z;
    int row = lane >> 4;
    int colp = lane & 15;

    fx4 acc[4][4];
#pragma unroll
    for (int c = 0; c < 4; ++c)
#pragma unroll
        for (int nt = 0; nt < 4; ++nt)
#pragma unroll
            for (int r = 0; r < 4; ++r) acc[c][nt][r] = 0.f;

    int py[4], pxx[4];
#pragma unroll
    for (int nt = 0; nt < 4; ++nt) {
        int p = px0 + nt * 16 + colp;
        py[nt] = p / WW;
        pxx[nt] = p - py[nt] * WW;
    }

    const float* ib = in + (size_t)bb * 64 * HWP;
    for (int t = 0; t < 18; ++t) {
        int tap = t >> 1, ks = t & 1;
        int dy = tap / 3 - 1, dx = tap % 3 - 1;
        f16x8 afr[4];
#pragma unroll
        for (int c = 0; c < 4; ++c) afr[c] = wA3[((t * 4 + c) << 6) + lane];
        const float* kb = ib + (size_t)(ks * 32 + row * 8) * HWP;
#pragma unroll
        for (int nt = 0; nt < 4; ++nt) {
            int yy = py[nt] + dy, xx = pxx[nt] + dx;
            union { f16x8 v; f16x2 h[4]; } bu;
            if ((unsigned)yy < HH && (unsigned)xx < WW) {
                const float* bp = kb + yy * WW + xx;
                bu.h[0] = pk2(bp[0],              bp[(size_t)1 * HWP]);
                bu.h[1] = pk2(bp[(size_t)2 * HWP], bp[(size_t)3 * HWP]);
                bu.h[2] = pk2(bp[(size_t)4 * HWP], bp[(size_t)5 * HWP]);
                bu.h[3] = pk2(bp[(size_t)6 * HWP], bp[(size_t)7 * HWP]);
            } else {
                bu.h[0] = pk2(0.f, 0.f); bu.h[1] = bu.h[0];
                bu.h[2] = bu.h[0];       bu.h[3] = bu.h[0];
            }
#pragma unroll
            for (int c = 0; c < 4; ++c)
                acc[c][nt] = __builtin_amdgcn_mfma_f32_16x16x32_f16(afr[c], bu.v, acc[c][nt], 0, 0, 0);
        }
    }

#pragma unroll
    for (int c = 0; c < 4; ++c) {
#pragma unroll
        for (int r = 0; r < 4; ++r) {
            int co = c * 16 + row * 4 + r;
            float bv = bias[co];
            const float* sb = skip + ((size_t)bb * 64 + co) * HWP;
            float* op = out + ((size_t)bb * 64 + co) * HWP;
#pragma unroll
            for (int nt = 0; nt < 4; ++nt) {
                int px = px0 + nt * 16 + colp;
                op[px] = acc[c][nt][r] + bv + sb[px];
            }
        }
    }
}

// ------- dwgelu: v = gelu(dwconv3x3(in)) + in, written f16 NCHW; 4-way channel split ----
// grid (13,13,B*4): z -> bb = z>>2, part = z&3; channels [part*Ci/4, ...)
__global__ __launch_bounds__(256, 4) void dwgelu_kernel(
    const float* __restrict__ in,   // (B,Ci,H,W) f32
    const float* __restrict__ dw,   // (Ci,9)
    const float* __restrict__ db,   // (Ci)
    __fp16* __restrict__ vout,      // (B,Ci,H,W) f16
    int Ci)
{
    __shared__ float s_p[16][18 * DPS];
    int tid = threadIdx.x;
    int tx = tid & 15, ty = tid >> 4;
    int x0 = blockIdx.x * 16, y0 = blockIdx.y * 16;
    int part = blockIdx.z & 3;
    int bb = blockIdx.z >> 2;
    int cic = Ci >> 2;
    int cbase = part * cic;
    int x = x0 + tx, y = y0 + ty;
    bool inb = (x < WW && y < HH);
    int p = y * WW + x;

    const float* ibase = in + (size_t)bb * Ci * HWP;
    __fp16* obase = vout + (size_t)bb * Ci * HWP;
    for (int c0 = cbase; c0 < cbase + cic; c0 += 16) {
        int chunk = cbase + cic - c0; if (chunk > 16) chunk = 16;
        __syncthreads();
        for (int i = tid; i < chunk * 324; i += 256) {
            int ci = i / 324; int r = i - ci * 324;
            int py = r / 18, px = r - py * 18;
            int yy = y0 + py - 1, xx = x0 + px - 1;
            float v = 0.f;
            if ((unsigned)yy < HH && (unsigned)xx < WW)
                v = ibase[(size_t)(c0 + ci) * HWP + yy * WW + xx];
            s_p[ci][py * DPS + px] = v;
        }
        __syncthreads();
        if (inb) {
            for (int ci = 0; ci < chunk; ++ci) {
                int c = c0 + ci;
                float s = db[c];
                const float* dwr = dw + c * 9;
#pragma unroll
                for (int ky = 0; ky < 3; ++ky)
#pragma unroll
                    for (int kx = 0; kx < 3; ++kx)
                        s += s_p[ci][(ty + ky) * DPS + tx + kx] * dwr[ky * 3 + kx];
                float v = gelu_f(s) + s_p[ci][(ty + 1) * DPS + tx + 1];
                obase[(size_t)c * HWP + p] = (__fp16)v;
            }
        }
    }
}

// ---------------- attention v3: qkv precomputed; scores cached in f16-packed regs -------
__global__ __launch_bounds__(128, 4) void winattn2_kernel(
    const float* __restrict__ qkv,  // (B,192,H,W)
    const float* __restrict__ rpb,  // (8,361)
    float* __restrict__ out)        // (B,64,H,W)
{
    __shared__ __align__(16) float s_k[100][8];
    __shared__ __align__(16) float s_v[100][8];
    __shared__ float s_b[361];

    int head = blockIdx.y, bb = blockIdx.z;
    int wy = blockIdx.x / 20, wx = blockIdx.x - wy * 20;
    int tid = threadIdx.x;

    for (int i = tid; i < 361; i += 128) s_b[i] = rpb[head * 361 + i];

    int ty = tid / 10, tx = tid - ty * 10;
    float q[8];
    if (tid < 100) {
        int y = wy * 10 + ty, x = wx * 10 + tx;
        int gp = y * WW + x;
        const float* qb = qkv + ((size_t)bb * 192 + head * 8) * HWP + gp;
        const float* kb = qb + (size_t)64 * HWP;
        const float* vb = qb + (size_t)128 * HWP;
        const float scale = 0.3535533905932738f; // 1/sqrt(8)
#pragma unroll
        for (int cc = 0; cc < 8; ++cc) q[cc] = qb[(size_t)cc * HWP] * scale;
        float4 t0, t1;
        t0.x = kb[0];               t0.y = kb[(size_t)1 * HWP];
        t0.z = kb[(size_t)2 * HWP]; t0.w = kb[(size_t)3 * HWP];
        t1.x = kb[(size_t)4 * HWP]; t1.y = kb[(size_t)5 * HWP];
        t1.z = kb[(size_t)6 * HWP]; t1.w = kb[(size_t)7 * HWP];
        *(float4*)(&s_k[tid][0]) = t0;
        *(float4*)(&s_k[tid][4]) = t1;
        t0.x = vb[0];               t0.y = vb[(size_t)1 * HWP];
        t0.z = vb[(size_t)2 * HWP]; t0.w = vb[(size_t)3 * HWP];
        t1.x = vb[(size_t)4 * HWP]; t1.y = vb[(size_t)5 * HWP];
        t1.z = vb[(size_t)6 * HWP]; t1.w = vb[(size_t)7 * HWP];
        *(float4*)(&s_v[tid][0]) = t0;
        *(float4*)(&s_v[tid][4]) = t1;
    }
    __syncthreads();

    if (tid < 100) {
        const float4* k4 = (const float4*)s_k;
        const float4* v4 = (const float4*)s_v;
        const float* brow = s_b + (180 - ty * 19 - tx);

        f16x2 s16[50];
        float m = -1e30f;
#pragma unroll
        for (int i = 0; i < 50; ++i) {
            const int k0 = 2 * i, k1 = 2 * i + 1;
            const int c0 = (k0 / 10) * 19 + (k0 % 10);
            const int c1 = (k1 / 10) * 19 + (k1 % 10);
            float4 ka = k4[k0 * 2], kb2 = k4[k0 * 2 + 1];
            float s0 = brow[c0]
                     + q[0] * ka.x + q[1] * ka.y + q[2] * ka.z + q[3] * ka.w
                     + q[4] * kb2.x + q[5] * kb2.y + q[6] * kb2.z + q[7] * kb2.w;
            ka = k4[k1 * 2]; kb2 = k4[k1 * 2 + 1];
            float s1 = brow[c1]
                     + q[0] * ka.x + q[1] * ka.y + q[2] * ka.z + q[3] * ka.w
                     + q[4] * kb2.x + q[5] * kb2.y + q[6] * kb2.z + q[7] * kb2.w;
            m = fmaxf(m, fmaxf(s0, s1));
            s16[i] = __builtin_amdgcn_cvt_pkrtz(s0, s1);
        }
        float l = 0.f;
        float o[8];
#pragma unroll
        for (int cc = 0; cc < 8; ++cc) o[cc] = 0.f;
#pragma unroll
        for (int i = 0; i < 50; ++i) {
            float e0 = __expf((float)s16[i][0] - m);
            float e1 = __expf((float)s16[i][1] - m);
            l += e0 + e1;
            float4 va = v4[4 * i], vb2 = v4[4 * i + 1];
            o[0] += e0 * va.x; o[1] += e0 * va.y; o[2] += e0 * va.z; o[3] += e0 * va.w;
            o[4] += e0 * vb2.x; o[5] += e0 * vb2.y; o[6] += e0 * vb2.z; o[7] += e0 * vb2.w;
            va = v4[4 * i + 2]; vb2 = v4[4 * i + 3];
            o[0] += e1 * va.x; o[1] += e1 * va.y; o[2] += e1 * va.z; o[3] += e1 * va.w;
            o[4] += e1 * vb2.x; o[5] += e1 * vb2.y; o[6] += e1 * vb2.z; o[7] += e1 * vb2.w;
        }
        float rl = 1.f / l;
        int y = wy * 10 + ty, x = wx * 10 + tx;
        float* ob = out + ((size_t)bb * 64 + head * 8) * HWP + y * WW + x;
#pragma unroll
        for (int cc = 0; cc < 8; ++cc) ob[(size_t)cc * HWP] = o[cc] * rl;
    }
}

// ------- geometric ensemble -> D4-orbit weight table packed f16x2 (ci, rep2, co) -------
__global__ __launch_bounds__(256) void geo_kernel(
    const float* __restrict__ k, f16x2* __restrict__ out)
{
    int i = blockIdx.x * 256 + threadIdx.x;
    if (i >= 256 * 14) return;
    int oc = i / 14, r2 = i - oc * 14;   // oc = co*16 + ci
    int co = oc >> 4, ci = oc & 15;
    const float* kb = k + oc * 169;
    float sv[2];
#pragma unroll
    for (int t = 0; t < 2; ++t) {
        int rep = 2 * r2 + t;
        int a = 0, r = rep;
        while (r >= 7 - a) { r -= 7 - a; ++a; }
        int b2 = a + r;
        int y = 6 + a, x = 6 + b2;
        float s = kb[y * 13 + x] + kb[y * 13 + (12 - x)] + kb[(12 - y) * 13 + x] + kb[(12 - y) * 13 + (12 - x)]
                + kb[(12 - x) * 13 + y] + kb[x * 13 + y] + kb[(12 - x) * 13 + (12 - y)] + kb[x * 13 + (12 - y)];
        sv[t] = s * 0.125f;
    }
    f16x2 v;
    v[0] = (__fp16)sv[0];
    v[1] = (__fp16)sv[1];
    out[(ci * 14 + r2) * 16 + co] = v;
}

// ---------------- global mean over H,W of first-16 channels ----------------
__global__ __launch_bounds__(256) void gmean_kernel(
    const float* __restrict__ in, float* __restrict__ g)
{
    int bc = blockIdx.x;            // b*16 + c
    int bb = bc >> 4, c = bc & 15;
    const float* p = in + ((size_t)bb * 64 + c) * HWP;
    float s = 0.f;
    for (int i = threadIdx.x; i < HWP; i += 256) s += p[i];
#pragma unroll
    for (int off = 32; off > 0; off >>= 1) s += __shfl_down(s, off);
    __shared__ float red[4];
    int wave = threadIdx.x >> 6;
    if ((threadIdx.x & 63) == 0) red[wave] = s;
    __syncthreads();
    if (threadIdx.x == 0)
        g[bc] = (red[0] + red[1] + red[2] + red[3]) * (1.f / 40000.f);
}

// ---------------- tiny MLP -> dynamic 3x3 kernels ----------------
__global__ __launch_bounds__(192) void dynk_kernel(
    const float* __restrict__ g, const float* __restrict__ w1, const float* __restrict__ b1,
    const float* __restrict__ w2, const float* __restrict__ b2, float* __restrict__ dk)
{
    int bb = blockIdx.x;
    __shared__ float s_g2[8];
    int tid = threadIdx.x;
    if (tid < 8) {
        float a = b1[tid];
        for (int c = 0; c < 16; ++c) a += w1[tid * 16 + c] * g[bb * 16 + c];
        s_g2[tid] = gelu_f(a);
    }
    __syncthreads();
    if (tid < 144) {
        float a = b2[tid];
#pragma unroll
        for (int i = 0; i < 8; ++i) a += w2[tid * 8 + i] * s_g2[i];
        dk[bb * 144 + tid] = a;
    }
}

// ------- 13x13 D4-symmetric conv via 28 orbit sums (dot2) + dynamic depthwise 3x3 -------
__global__ __launch_bounds__(256, 4) void lkconv_kernel(
    const float* __restrict__ in,   // (B,64,H,W) — channels 0..15 used
    const f16x2* __restrict__ lkO,  // (16,14,16)
    const float* __restrict__ dk,   // (B,144)
    float* __restrict__ out)        // 4 partial buffers, stride PARTSZ
{
    __shared__ float s_p[4][28 * LKS];
    int z = blockIdx.z;
    int bb = z >> 2, q = z & 3;
    int tid = threadIdx.x;
    int tx = tid & 15, ty = tid >> 4;
    int x0 = blockIdx.x * 16, y0 = blockIdx.y * 16;
    int x = x0 + tx, y = y0 + ty;

    const float* ib = in + ((size_t)bb * 64 + q * 4) * HWP;
    for (int i = tid; i < 4 * 784; i += 256) {
        int ci = i / 784; int r = i - ci * 784;
        int py = r / 28, px = r - py * 28;
        int yy = y0 + py - 6, xx = x0 + px - 6;
        float v = 0.f;
        if ((unsigned)yy < HH && (unsigned)xx < WW)
            v = ib[(size_t)ci * HWP + yy * WW + xx];
        s_p[ci][py * LKS + px] = v;
    }
    __syncthreads();

    float acc[16];
#pragma unroll
    for (int co = 0; co < 16; ++co) acc[co] = 0.f;

#pragma unroll
    for (int ci4 = 0; ci4 < 4; ++ci4) {
        int ci = q * 4 + ci4;
        float orb[28];
#pragma unroll
        for (int o = 0; o < 28; ++o) orb[o] = 0.f;
#pragma unroll
        for (int ky = 0; ky < 13; ++ky) {
#pragma unroll
            for (int kx = 0; kx < 13; ++kx) {
                const int a = (ky < 6) ? (6 - ky) : (ky - 6);
                const int b = (kx < 6) ? (6 - kx) : (kx - 6);
                const int lo = (a < b) ? a : b;
                const int hi = (a < b) ? b : a;
                const int idx = lo * 7 - (lo * (lo - 1)) / 2 + (hi - lo);
                orb[idx] += s_p[ci4][(ty + ky) * LKS + tx + kx];
            }
        }
        const f16x2* wci = lkO + ci * 14 * 16;
#pragma unroll
        for (int o2 = 0; o2 < 14; ++o2) {
            f16x2 ov = pk2(orb[2 * o2], orb[2 * o2 + 1]);
            const f16x2* wr = wci + o2 * 16;
#pragma unroll
            for (int co = 0; co < 16; ++co) acc[co] = fdot2f(ov, wr[co], acc[co]);
        }
        float d = 0.f;
        const float* dkr = dk + bb * 144 + ci * 9;
#pragma unroll
        for (int dy = 0; dy < 3; ++dy)
#pragma unroll
            for (int dx = 0; dx < 3; ++dx)
                d += s_p[ci4][(ty + 5 + dy) * LKS + tx + 5 + dx] * dkr[dy * 3 + dx];
#pragma unroll
        for (int co = 0; co < 16; ++co) acc[co] += (co == ci) ? d : 0.f;
    }

    if (x < WW && y < HH) {
        int p = y * WW + x;
        float* ob = out + (size_t)q * PARTSZ + (size_t)bb * 16 * HWP + p;
#pragma unroll
        for (int co = 0; co < 16; ++co) ob[(size_t)co * HWP] = acc[co];
    }
}

// ------- 1x1 conv over concat(sum of 4 x1 partials, y[16..63]), dot2; += xout -----
__global__ __launch_bounds__(256, 2) void pconv_add_kernel(
    const float* __restrict__ x1q,  // 4 partial buffers, stride PARTSZ
    const float* __restrict__ yy,   // (B,64,H,W), channels 16..63 used
    const f16x2* __restrict__ wt,   // (32, 64)
    const float* __restrict__ bias,
    float* __restrict__ xout)
{
    int p4 = blockIdx.x * 256 + threadIdx.x;
    int o0 = blockIdx.y * 16;
    int bb = blockIdx.z;
    if (p4 >= NP4) return;
    float4 acc[16];
#pragma unroll
    for (int j = 0; j < 16; ++j) {
        float bv = bias[o0 + j];
        acc[j] = make_float4(bv, bv, bv, bv);
    }
    const float4* xb0 = (const float4*)(x1q + (size_t)bb * 16 * HWP) + p4;
    const float4* xb1 = (const float4*)(x1q + PARTSZ + (size_t)bb * 16 * HWP) + p4;
    const float4* xb2 = (const float4*)(x1q + 2 * PARTSZ + (size_t)bb * 16 * HWP) + p4;
    const float4* xb3 = (const float4*)(x1q + 3 * PARTSZ + (size_t)bb * 16 * HWP) + p4;
    for (int c2 = 0; c2 < 8; ++c2) {
        int ca = 2 * c2, cb = 2 * c2 + 1;
        float4 a0 = xb0[(size_t)ca * NP4], a1 = xb1[(size_t)ca * NP4];
        float4 a2 = xb2[(size_t)ca * NP4], a3 = xb3[(size_t)ca * NP4];
        float4 s0;
        s0.x = (a0.x + a1.x) + (a2.x + a3.x);
        s0.y = (a0.y + a1.y) + (a2.y + a3.y);
        s0.z = (a0.z + a1.z) + (a2.z + a3.z);
        s0.w = (a0.w + a1.w) + (a2.w + a3.w);
        a0 = xb0[(size_t)cb * NP4]; a1 = xb1[(size_t)cb * NP4];
        a2 = xb2[(size_t)cb * NP4]; a3 = xb3[(size_t)cb * NP4];
        float4 s1;
        s1.x = (a0.x + a1.x) + (a2.x + a3.x);
        s1.y = (a0.y + a1.y) + (a2.y + a3.y);
        s1.z = (a0.z + a1.z) + (a2.z + a3.z);
        s1.w = (a0.w + a1.w) + (a2.w + a3.w);
        f16x2 px = pk2(s0.x, s1.x), py = pk2(s0.y, s1.y);
        f16x2 pz = pk2(s0.z, s1.z), pw = pk2(s0.w, s1.w);
        const f16x2* wr = wt + c2 * 64 + o0;
#pragma unroll
        for (int j = 0; j < 16; ++j) {
            f16x2 w = wr[j];
            acc[j].x = fdot2f(px, w, acc[j].x);
            acc[j].y = fdot2f(py, w, acc[j].y);
            acc[j].z = fdot2f(pz, w, acc[j].z);
            acc[j].w = fdot2f(pw, w, acc[j].w);
        }
    }
    const float4* yb = (const float4*)(yy + ((size_t)bb * 64 + 16) * HWP) + p4;
    for (int c2 = 8; c2 < 32; ++c2) {
        int cy = 2 * (c2 - 8);
        float4 s0 = yb[(size_t)cy * NP4];
        float4 s1 = yb[(size_t)(cy + 1) * NP4];
        f16x2 px = pk2(s0.x, s1.x), py = pk2(s0.y, s1.y);
        f16x2 pz = pk2(s0.z, s1.z), pw = pk2(s0.w, s1.w);
        const f16x2* wr = wt + c2 * 64 + o0;
#pragma unroll
        for (int j = 0; j < 16; ++j) {
            f16x2 w = wr[j];
            acc[j].x = fdot2f(px, w, acc[j].x);
            acc[j].y = fdot2f(py, w, acc[j].y);
            acc[j].z = fdot2f(pz, w, acc[j].z);
            acc[j].w = fdot2f(pw, w, acc[j].w);
        }
    }
    float4* ob = (float4*)(xout + ((size_t)bb * 64 + o0) * HWP) + p4;
#pragma unroll
    for (int j = 0; j < 16; ++j) {
        float4 old = ob[(size_t)j * NP4];
        old.x += acc[j].x; old.y += acc[j].y; old.z += acc[j].z; old.w += acc[j].w;
        ob[(size_t)j * NP4] = old;
    }
}

extern "C" void kernel_launch(void* const* d_in, const int* in_sizes, int n_in,
                              void* d_out, int out_size, void* d_ws, size_t ws_size,
                              hipStream_t stream)
{
    const float* x_in      = (const float*)d_in[0];
    const float* ln_proj_w = (const float*)d_in[1];
    const float* ln_proj_b = (const float*)d_in[2];
    const float* proj_p_w  = (const float*)d_in[3];
    const float* proj_p_b  = (const float*)d_in[4];
    const float* proj_d_w  = (const float*)d_in[5];
    const float* proj_d_b  = (const float*)d_in[6];
    const float* proj_a_w  = (const float*)d_in[7];
    const float* proj_a_b  = (const float*)d_in[8];
    const float* ln_attn_w = (const float*)d_in[9];
    const float* ln_attn_b = (const float*)d_in[10];
    const float* qkv_w     = (const float*)d_in[11];
    const float* qkv_b     = (const float*)d_in[12];
    const float* attn_o_w  = (const float*)d_in[13];
    const float* attn_o_b  = (const float*)d_in[14];
    const float* rpb       = (const float*)d_in[15];
    const float* dwcp1_w   = (const float*)d_in[16];
    const float* dwcp1_b   = (const float*)d_in[17];
    const float* dwcp2_w   = (const float*)d_in[18];
    const float* dwcp2_b   = (const float*)d_in[19];
    const float* pconv_w   = (const float*)d_in[20];
    const float* pconv_b   = (const float*)d_in[21];
    const float* ffn_p_w   = (const float*)d_in[22];
    const float* ffn_p_b   = (const float*)d_in[23];
    const float* ffn_d_w   = (const float*)d_in[24];
    const float* ffn_d_b   = (const float*)d_in[25];
    const float* ffn_a_w   = (const float*)d_in[26];
    const float* ffn_a_b   = (const float*)d_in[27];
    const float* ln_out_w  = (const float*)d_in[28];
    const float* ln_out_b  = (const float*)d_in[29];
    const float* conv_o_w  = (const float*)d_in[30];
    const float* conv_o_b  = (const float*)d_in[31];
    const float* plk       = (const float*)d_in[32];

    float* X  = (float*)d_out;
    float* ws = (float*)d_ws;

    // workspace map (floats):
    //  0        .. 10.24M : A (LN out / winattn out / ffn Y)
    //  10.24M   .. 30.72M : R1 (proj 128ch) | QKV (10.24..40.96)
    //  23.04M   .. 29.44M : Vf (ffn dwgelu f16, 80ch)
    //  30.72M   .. 40.96M : Vp (proj dwgelu f16, 128ch)
    //  33.28M   .. 43.52M : R2Q (lkconv partials)   [disjoint in time from Vp]
    //  43.52M   ..        : LKTH, GM, DK, WTH, WAH, WA2, WA3
    float* A    = ws;
    float* Y    = ws;
    float* R1   = ws + 10240000;
    float* QKV  = ws + 10240000;
    __fp16* Vf  = (__fp16*)(ws + 23040000);
    __fp16* Vp  = (__fp16*)(ws + 30720000);
    float* R2Q  = ws + 33280000;
    f16x2* LKTH = (f16x2*)(ws + 43520000);       // 3584 slots
    float* GM   = ws + 43524096;
    float* DK   = GM + 64;
    f16x2* WTH  = (f16x2*)(DK + 576);            // 4096 slots
    f16x8* WAH  = (f16x8*)(DK + 576 + 4096);     // 4352 slots x 16B
    f16x8* WA2  = WAH + 4352;                    // 2560 slots
    f16x8* WA3  = WA2 + 2560;                    // 4608 slots

    dim3 b256(256);
    dim3 gLN(157, 4);
    dim3 gT16(13, 13, 16);
    dim3 gM1(157, 1, 4);

    prep_kernel<<<dim3(16), b256, 0, stream>>>(pconv_w, WTH);
    prepA_kernel<<<dim3(17), b256, 0, stream>>>(qkv_w, proj_p_w, attn_o_w, ffn_p_w, WAH);
    prepA2_kernel<<<dim3(10), b256, 0, stream>>>(proj_a_w, ffn_a_w, WA2);
    prepA3_kernel<<<dim3(18), b256, 0, stream>>>(conv_o_w, WA3);
    geo_kernel<<<dim3(14), b256, 0, stream>>>(plk, LKTH);

    // x = conv_ffn(LN(x)) [proj]
    ln_kernel<<<gLN, b256, 0, stream>>>(x_in, ln_proj_w, ln_proj_b, A);
    conv1x1_mfma_kernel<<<dim3(157, 2, 4), b256, 0, stream>>>(A, WAH + 1536, proj_p_b, R1, 128, 1, 0);
    dwgelu_kernel<<<gT16, b256, 0, stream>>>(R1, proj_d_w, proj_d_b, Vp, 128);
    conv1x1h_mfma_kernel<<<gM1, b256, 0, stream>>>(Vp, WA2 + 0, proj_a_b, X, 128, 4);

    // x = x + window_attention(LN(x))
    ln_kernel<<<gLN, b256, 0, stream>>>(X, ln_attn_w, ln_attn_b, A);
    conv1x1_mfma_kernel<<<dim3(157, 3, 4), b256, 0, stream>>>(A, WAH + 0, qkv_b, QKV, 192, 0, 0);
    winattn2_kernel<<<dim3(400, 8, 4), dim3(128), 0, stream>>>(QKV, rpb, A);
    conv1x1_mfma_kernel<<<gM1, b256, 0, stream>>>(A, WAH + 2560, attn_o_b, X, 64, 0, 1);

    for (int i = 0; i < 2; ++i) {
        conv1x1_mfma_kernel<<<dim3(157, 2, 4), b256, 0, stream>>>(X, WAH + 3072 + i * 640, ffn_p_b + i * 80, R1, 80, 1, 0);
        dwgelu_kernel<<<gT16, b256, 0, stream>>>(R1, ffn_d_w + i * 720, ffn_d_b + i * 80, Vf, 80);
        conv1x1h_mfma_kernel<<<gM1, b256, 0, stream>>>(Vf, WA2 + 1024 + i * 768, ffn_a_b + i * 64, Y, 80, 3);
        gmean_kernel<<<dim3(64), b256, 0, stream>>>(Y, GM);
        dynk_kernel<<<dim3(4), dim3(192), 0, stream>>>(GM, dwcp1_w + i * 128, dwcp1_b + i * 8,
                                                       dwcp2_w + i * 1152, dwcp2_b + i * 144, DK);
        lkconv_kernel<<<gT16, b256, 0, stream>>>(Y, LKTH, DK, R2Q);
        pconv_add_kernel<<<dim3(40, 4, 4), b256, 0, stream>>>(R2Q, Y, WTH + i * 2048, pconv_b + i * 64, X);
    }

    // x = conv3x3(LN(x)) + skip — MFMA implicit GEMM, bias+skip fused
    ln_kernel<<<gLN, b256, 0, stream>>>(X, ln_out_w, ln_out_b, A);
    conv3_mfma_kernel<<<gM1, b256, 0, stream>>>(A, WA3, conv_o_b, x_in, X);
}

// Round 16
// 965.125 us; speedup vs baseline: 1.7764x; 1.0947x over previous
//
#include <hip/hip_runtime.h>
#include <math.h>

#define HH 200
#define WW 200
#define HWP 40000
#define NP4 10000
#define BB 4

#define LKS 40   // lkconv LDS row stride (u32 entries)
#define DPS 24   // dwgelu LDS row stride
#define PARTSZ 2560000    // one (B,16,H,W) partial buffer (lkconv)

typedef __fp16 f16x2 __attribute__((ext_vector_type(2)));
typedef __fp16 f16x8 __attribute__((ext_vector_type(8)));
typedef float fx4 __attribute__((ext_vector_type(4)));

#if __has_builtin(__builtin_amdgcn_fdot2)
__device__ __forceinline__ float fdot2f(f16x2 a, f16x2 b, float c) {
    return __builtin_amdgcn_fdot2(a, b, c, false);
}
#else
__device__ __forceinline__ float fdot2f(f16x2 a, f16x2 b, float c) {
    return c + (float)a[0] * (float)b[0] + (float)a[1] * (float)b[1];
}
#endif

__device__ __forceinline__ f16x2 pk2(float a, float b) {
    return __builtin_amdgcn_cvt_pkrtz(a, b);
}

__device__ __forceinline__ float gelu_f(float x) {
    return 0.5f * x * (1.0f + erff(x * 0.7071067811865475f));
}

// ---------------- pconv weight pack (ci,co) f16x2 ----------------
__global__ __launch_bounds__(256) void prep_kernel(
    const float* __restrict__ pc, f16x2* __restrict__ wth)
{
    int i = blockIdx.x * 256 + threadIdx.x;
    if (i >= 4096) return;
    int w = i >> 11;
    int r = i & 2047;
    int c2 = r / 64, o = r - c2 * 64;
    const float* src = pc + w * 4096;
    f16x2 v;
    v[0] = (__fp16)src[o * 64 + 2 * c2];
    v[1] = (__fp16)src[o * 64 + 2 * c2 + 1];
    wth[w * 2048 + r] = v;
}

// ------- MFMA A-fragment prep for Ci=64 1x1 convs (ksteps=2) -------
__global__ __launch_bounds__(256) void prepA_kernel(
    const float* __restrict__ qkvw, const float* __restrict__ pp,
    const float* __restrict__ ao, const float* __restrict__ fp,
    f16x8* __restrict__ wA)
{
    int s = blockIdx.x * 256 + threadIdx.x;
    if (s >= 4352) return;
    const float* src;
    int base;
    if (s < 1536)      { src = qkvw;      base = 0; }
    else if (s < 2560) { src = pp;        base = 1536; }
    else if (s < 3072) { src = ao;        base = 2560; }
    else if (s < 3712) { src = fp;        base = 3072; }
    else               { src = fp + 5120; base = 3712; }
    int r = s - base;
    int lane = r & 63;
    int t = r >> 6;
    int ks = t & 1;
    int cot = t >> 1;
    int co = cot * 16 + (lane & 15);
    int k0 = ks * 32 + ((lane >> 4) << 3);
    f16x8 v;
#pragma unroll
    for (int j = 0; j < 8; ++j) v[j] = (__fp16)src[co * 64 + k0 + j];
    wA[s] = v;
}

// ------- MFMA A-fragment prep, generalized K (proj_a Ci=128 ks4; ffn_a Ci=80 ks3) -----
__global__ __launch_bounds__(256) void prepA2_kernel(
    const float* __restrict__ pa, const float* __restrict__ fa,
    f16x8* __restrict__ wA2)
{
    int s = blockIdx.x * 256 + threadIdx.x;
    if (s >= 2560) return;
    const float* src; int base, Ci, ksteps;
    if (s < 1024)      { src = pa;        base = 0;    Ci = 128; ksteps = 4; }
    else if (s < 1792) { src = fa;        base = 1024; Ci = 80;  ksteps = 3; }
    else               { src = fa + 5120; base = 1792; Ci = 80;  ksteps = 3; }
    int r = s - base;
    int lane = r & 63;
    int u = r >> 6;
    int ks = u % ksteps;
    int cot = u / ksteps;
    int co = cot * 16 + (lane & 15);
    int k0 = ks * 32 + ((lane >> 4) << 3);
    f16x8 v;
#pragma unroll
    for (int j = 0; j < 8; ++j) {
        int k = k0 + j;
        v[j] = (k < Ci) ? (__fp16)src[co * Ci + k] : (__fp16)0.f;
    }
    wA2[s] = v;
}

// ------- MFMA A-fragment prep for conv3 (K = 576, k = tap*64 + ci) -------
__global__ __launch_bounds__(256) void prepA3_kernel(
    const float* __restrict__ co3, f16x8* __restrict__ wA3)
{
    int s = blockIdx.x * 256 + threadIdx.x;
    if (s >= 4608) return;
    int lane = s & 63;
    int u = s >> 6;
    int cot = u & 3;
    int t = u >> 2;
    int co = cot * 16 + (lane & 15);
    int k0 = t * 32 + ((lane >> 4) << 3);
    f16x8 v;
#pragma unroll
    for (int j = 0; j < 8; ++j) {
        int k = k0 + j;
        int tap = k >> 6, ci = k & 63;
        v[j] = (__fp16)co3[(co * 64 + ci) * 9 + tap];
    }
    wA3[s] = v;
}

// ---------------- LayerNorm over 64 channels ----------------
__global__ __launch_bounds__(256, 2) void ln_kernel(
    const float* __restrict__ in, const float* __restrict__ w,
    const float* __restrict__ b, float* __restrict__ out)
{
    int p = blockIdx.x * 256 + threadIdx.x;
    int bb = blockIdx.y;
    if (p >= HWP) return;
    const float* ib = in + (size_t)bb * 64 * HWP + p;
    float v[64];
    float mu = 0.f;
#pragma unroll
    for (int c = 0; c < 64; ++c) { v[c] = ib[(size_t)c * HWP]; mu += v[c]; }
    mu *= (1.f / 64.f);
    float var = 0.f;
#pragma unroll
    for (int c = 0; c < 64; ++c) { float d = v[c] - mu; var += d * d; }
    var *= (1.f / 64.f);
    float r = rsqrtf(var + 1e-6f);
    float* ob = out + (size_t)bb * 64 * HWP + p;
#pragma unroll
    for (int c = 0; c < 64; ++c) ob[(size_t)c * HWP] = (v[c] - mu) * r * w[c] + b[c];
}

// ---------------- 1x1 conv via MFMA f16 (Ci=64 f32 input) ----------------
__global__ __launch_bounds__(256, 2) void conv1x1_mfma_kernel(
    const float* __restrict__ in, const f16x8* __restrict__ wA,
    const float* __restrict__ bias, float* __restrict__ out,
    int Co, int do_gelu, int do_add)
{
    int lane = threadIdx.x & 63;
    int wv = threadIdx.x >> 6;
    int px0 = blockIdx.x * 256 + wv * 64;
    if (px0 >= HWP) return;
    int bb = blockIdx.z;
    int cot0 = blockIdx.y * 4;
    int nCot = (Co >> 4) - cot0; if (nCot > 4) nCot = 4;
    int row = lane >> 4;
    int colp = lane & 15;

    fx4 acc[4][4];
#pragma unroll
    for (int c = 0; c < 4; ++c)
#pragma unroll
        for (int nt = 0; nt < 4; ++nt)
#pragma unroll
            for (int r = 0; r < 4; ++r) acc[c][nt][r] = 0.f;

    const float* ib = in + (size_t)bb * 64 * HWP;
#pragma unroll
    for (int ks = 0; ks < 2; ++ks) {
        f16x8 afr[4];
#pragma unroll
        for (int c = 0; c < 4; ++c)
            if (c < nCot) afr[c] = wA[(((cot0 + c) * 2 + ks) << 6) + lane];
#pragma unroll
        for (int nt = 0; nt < 4; ++nt) {
            int px = px0 + nt * 16 + colp;
            const float* bp = ib + (size_t)(ks * 32 + row * 8) * HWP + px;
            union { f16x8 v; f16x2 h[4]; } bu;
            bu.h[0] = pk2(bp[0],              bp[(size_t)1 * HWP]);
            bu.h[1] = pk2(bp[(size_t)2 * HWP], bp[(size_t)3 * HWP]);
            bu.h[2] = pk2(bp[(size_t)4 * HWP], bp[(size_t)5 * HWP]);
            bu.h[3] = pk2(bp[(size_t)6 * HWP], bp[(size_t)7 * HWP]);
#pragma unroll
            for (int c = 0; c < 4; ++c)
                if (c < nCot)
                    acc[c][nt] = __builtin_amdgcn_mfma_f32_16x16x32_f16(afr[c], bu.v, acc[c][nt], 0, 0, 0);
        }
    }

#pragma unroll
    for (int c = 0; c < 4; ++c) {
        if (c < nCot) {
#pragma unroll
            for (int r = 0; r < 4; ++r) {
                int co = (cot0 + c) * 16 + row * 4 + r;
                float bv = bias[co];
                float* op = out + ((size_t)bb * Co + co) * HWP;
#pragma unroll
                for (int nt = 0; nt < 4; ++nt) {
                    int px = px0 + nt * 16 + colp;
                    float v = acc[c][nt][r] + bv;
                    if (do_gelu) v = gelu_f(v);
                    if (do_add) v += op[px];
                    op[px] = v;
                }
            }
        }
    }
}

// ---------------- 1x1 conv via MFMA, f16 input, generalized K, Co=64 ----------------
__global__ __launch_bounds__(256, 2) void conv1x1h_mfma_kernel(
    const __fp16* __restrict__ in,   // (B,Ci,H,W) f16
    const f16x8* __restrict__ wA,    // (4 cot x ksteps x 64) slots
    const float* __restrict__ bias, float* __restrict__ out,
    int Ci, int ksteps)
{
    int lane = threadIdx.x & 63;
    int wv = threadIdx.x >> 6;
    int px0 = blockIdx.x * 256 + wv * 64;
    if (px0 >= HWP) return;
    int bb = blockIdx.z;
    int row = lane >> 4;
    int colp = lane & 15;

    fx4 acc[4][4];
#pragma unroll
    for (int c = 0; c < 4; ++c)
#pragma unroll
        for (int nt = 0; nt < 4; ++nt)
#pragma unroll
            for (int r = 0; r < 4; ++r) acc[c][nt][r] = 0.f;

    const __fp16* ib = in + (size_t)bb * Ci * HWP;
    for (int ks = 0; ks < ksteps; ++ks) {
        f16x8 afr[4];
#pragma unroll
        for (int c = 0; c < 4; ++c)
            afr[c] = wA[((c * ksteps + ks) << 6) + lane];
        int k0 = ks * 32 + row * 8;
        bool ok = (k0 < Ci);
#pragma unroll
        for (int nt = 0; nt < 4; ++nt) {
            int px = px0 + nt * 16 + colp;
            f16x8 bv;
            if (ok) {
                const __fp16* bp = ib + (size_t)k0 * HWP + px;
#pragma unroll
                for (int j = 0; j < 8; ++j) bv[j] = bp[(size_t)j * HWP];
            } else {
#pragma unroll
                for (int j = 0; j < 8; ++j) bv[j] = (__fp16)0.f;
            }
#pragma unroll
            for (int c = 0; c < 4; ++c)
                acc[c][nt] = __builtin_amdgcn_mfma_f32_16x16x32_f16(afr[c], bv, acc[c][nt], 0, 0, 0);
        }
    }

#pragma unroll
    for (int c = 0; c < 4; ++c) {
#pragma unroll
        for (int r = 0; r < 4; ++r) {
            int co = c * 16 + row * 4 + r;
            float bv = bias[co];
            float* op = out + ((size_t)bb * 64 + co) * HWP;
#pragma unroll
            for (int nt = 0; nt < 4; ++nt) {
                int px = px0 + nt * 16 + colp;
                op[px] = acc[c][nt][r] + bv;
            }
        }
    }
}

// ---------------- conv3 via MFMA: 9 shifted 1x1 GEMMs, K=576, bias+skip fused ----------
__global__ __launch_bounds__(256, 2) void conv3_mfma_kernel(
    const float* __restrict__ in,   // LN'd (B,64,H,W)
    const f16x8* __restrict__ wA3,  // 4608 slots
    const float* __restrict__ bias, const float* __restrict__ skip,
    float* __restrict__ out)
{
    int lane = threadIdx.x & 63;
    int wv = threadIdx.x >> 6;
    int px0 = blockIdx.x * 256 + wv * 64;
    if (px0 >= HWP) return;
    int bb = blockIdx.z;
    int row = lane >> 4;
    int colp = lane & 15;

    fx4 acc[4][4];
#pragma unroll
    for (int c = 0; c < 4; ++c)
#pragma unroll
        for (int nt = 0; nt < 4; ++nt)
#pragma unroll
            for (int r = 0; r < 4; ++r) acc[c][nt][r] = 0.f;

    int py[4], pxx[4];
#pragma unroll
    for (int nt = 0; nt < 4; ++nt) {
        int p = px0 + nt * 16 + colp;
        py[nt] = p / WW;
        pxx[nt] = p - py[nt] * WW;
    }

    const float* ib = in + (size_t)bb * 64 * HWP;
    for (int t = 0; t < 18; ++t) {
        int tap = t >> 1, ks = t & 1;
        int dy = tap / 3 - 1, dx = tap % 3 - 1;
        f16x8 afr[4];
#pragma unroll
        for (int c = 0; c < 4; ++c) afr[c] = wA3[((t * 4 + c) << 6) + lane];
        const float* kb = ib + (size_t)(ks * 32 + row * 8) * HWP;
#pragma unroll
        for (int nt = 0; nt < 4; ++nt) {
            int yy = py[nt] + dy, xx = pxx[nt] + dx;
            union { f16x8 v; f16x2 h[4]; } bu;
            if ((unsigned)yy < HH && (unsigned)xx < WW) {
                const float* bp = kb + yy * WW + xx;
                bu.h[0] = pk2(bp[0],              bp[(size_t)1 * HWP]);
                bu.h[1] = pk2(bp[(size_t)2 * HWP], bp[(size_t)3 * HWP]);
                bu.h[2] = pk2(bp[(size_t)4 * HWP], bp[(size_t)5 * HWP]);
                bu.h[3] = pk2(bp[(size_t)6 * HWP], bp[(size_t)7 * HWP]);
            } else {
                bu.h[0] = pk2(0.f, 0.f); bu.h[1] = bu.h[0];
                bu.h[2] = bu.h[0];       bu.h[3] = bu.h[0];
            }
#pragma unroll
            for (int c = 0; c < 4; ++c)
                acc[c][nt] = __builtin_amdgcn_mfma_f32_16x16x32_f16(afr[c], bu.v, acc[c][nt], 0, 0, 0);
        }
    }

#pragma unroll
    for (int c = 0; c < 4; ++c) {
#pragma unroll
        for (int r = 0; r < 4; ++r) {
            int co = c * 16 + row * 4 + r;
            float bv = bias[co];
            const float* sb = skip + ((size_t)bb * 64 + co) * HWP;
            float* op = out + ((size_t)bb * 64 + co) * HWP;
#pragma unroll
            for (int nt = 0; nt < 4; ++nt) {
                int px = px0 + nt * 16 + colp;
                op[px] = acc[c][nt][r] + bv + sb[px];
            }
        }
    }
}

// ------- dwgelu: v = gelu(dwconv3x3(in)) + in, written f16 NCHW; 4-way channel split ----
__global__ __launch_bounds__(256, 4) void dwgelu_kernel(
    const float* __restrict__ in,   // (B,Ci,H,W) f32
    const float* __restrict__ dw,   // (Ci,9)
    const float* __restrict__ db,   // (Ci)
    __fp16* __restrict__ vout,      // (B,Ci,H,W) f16
    int Ci)
{
    __shared__ float s_p[16][18 * DPS];
    int tid = threadIdx.x;
    int tx = tid & 15, ty = tid >> 4;
    int x0 = blockIdx.x * 16, y0 = blockIdx.y * 16;
    int part = blockIdx.z & 3;
    int bb = blockIdx.z >> 2;
    int cic = Ci >> 2;
    int cbase = part * cic;
    int x = x0 + tx, y = y0 + ty;
    bool inb = (x < WW && y < HH);
    int p = y * WW + x;

    const float* ibase = in + (size_t)bb * Ci * HWP;
    __fp16* obase = vout + (size_t)bb * Ci * HWP;
    for (int c0 = cbase; c0 < cbase + cic; c0 += 16) {
        int chunk = cbase + cic - c0; if (chunk > 16) chunk = 16;
        __syncthreads();
        for (int i = tid; i < chunk * 324; i += 256) {
            int ci = i / 324; int r = i - ci * 324;
            int py = r / 18, px = r - py * 18;
            int yy = y0 + py - 1, xx = x0 + px - 1;
            float v = 0.f;
            if ((unsigned)yy < HH && (unsigned)xx < WW)
                v = ibase[(size_t)(c0 + ci) * HWP + yy * WW + xx];
            s_p[ci][py * DPS + px] = v;
        }
        __syncthreads();
        if (inb) {
            for (int ci = 0; ci < chunk; ++ci) {
                int c = c0 + ci;
                float s = db[c];
                const float* dwr = dw + c * 9;
#pragma unroll
                for (int ky = 0; ky < 3; ++ky)
#pragma unroll
                    for (int kx = 0; kx < 3; ++kx)
                        s += s_p[ci][(ty + ky) * DPS + tx + kx] * dwr[ky * 3 + kx];
                float v = gelu_f(s) + s_p[ci][(ty + 1) * DPS + tx + 1];
                obase[(size_t)c * HWP + p] = (__fp16)v;
            }
        }
    }
}

// ---------------- attention v3: qkv precomputed; scores cached in f16-packed regs -------
__global__ __launch_bounds__(128, 4) void winattn2_kernel(
    const float* __restrict__ qkv,  // (B,192,H,W)
    const float* __restrict__ rpb,  // (8,361)
    float* __restrict__ out)        // (B,64,H,W)
{
    __shared__ __align__(16) float s_k[100][8];
    __shared__ __align__(16) float s_v[100][8];
    __shared__ float s_b[361];

    int head = blockIdx.y, bb = blockIdx.z;
    int wy = blockIdx.x / 20, wx = blockIdx.x - wy * 20;
    int tid = threadIdx.x;

    for (int i = tid; i < 361; i += 128) s_b[i] = rpb[head * 361 + i];

    int ty = tid / 10, tx = tid - ty * 10;
    float q[8];
    if (tid < 100) {
        int y = wy * 10 + ty, x = wx * 10 + tx;
        int gp = y * WW + x;
        const float* qb = qkv + ((size_t)bb * 192 + head * 8) * HWP + gp;
        const float* kb = qb + (size_t)64 * HWP;
        const float* vb = qb + (size_t)128 * HWP;
        const float scale = 0.3535533905932738f; // 1/sqrt(8)
#pragma unroll
        for (int cc = 0; cc < 8; ++cc) q[cc] = qb[(size_t)cc * HWP] * scale;
        float4 t0, t1;
        t0.x = kb[0];               t0.y = kb[(size_t)1 * HWP];
        t0.z = kb[(size_t)2 * HWP]; t0.w = kb[(size_t)3 * HWP];
        t1.x = kb[(size_t)4 * HWP]; t1.y = kb[(size_t)5 * HWP];
        t1.z = kb[(size_t)6 * HWP]; t1.w = kb[(size_t)7 * HWP];
        *(float4*)(&s_k[tid][0]) = t0;
        *(float4*)(&s_k[tid][4]) = t1;
        t0.x = vb[0];               t0.y = vb[(size_t)1 * HWP];
        t0.z = vb[(size_t)2 * HWP]; t0.w = vb[(size_t)3 * HWP];
        t1.x = vb[(size_t)4 * HWP]; t1.y = vb[(size_t)5 * HWP];
        t1.z = vb[(size_t)6 * HWP]; t1.w = vb[(size_t)7 * HWP];
        *(float4*)(&s_v[tid][0]) = t0;
        *(float4*)(&s_v[tid][4]) = t1;
    }
    __syncthreads();

    if (tid < 100) {
        const float4* k4 = (const float4*)s_k;
        const float4* v4 = (const float4*)s_v;
        const float* brow = s_b + (180 - ty * 19 - tx);

        f16x2 s16[50];
        float m = -1e30f;
#pragma unroll
        for (int i = 0; i < 50; ++i) {
            const int k0 = 2 * i, k1 = 2 * i + 1;
            const int c0 = (k0 / 10) * 19 + (k0 % 10);
            const int c1 = (k1 / 10) * 19 + (k1 % 10);
            float4 ka = k4[k0 * 2], kb2 = k4[k0 * 2 + 1];
            float s0 = brow[c0]
                     + q[0] * ka.x + q[1] * ka.y + q[2] * ka.z + q[3] * ka.w
                     + q[4] * kb2.x + q[5] * kb2.y + q[6] * kb2.z + q[7] * kb2.w;
            ka = k4[k1 * 2]; kb2 = k4[k1 * 2 + 1];
            float s1 = brow[c1]
                     + q[0] * ka.x + q[1] * ka.y + q[2] * ka.z + q[3] * ka.w
                     + q[4] * kb2.x + q[5] * kb2.y + q[6] * kb2.z + q[7] * kb2.w;
            m = fmaxf(m, fmaxf(s0, s1));
            s16[i] = __builtin_amdgcn_cvt_pkrtz(s0, s1);
        }
        float l = 0.f;
        float o[8];
#pragma unroll
        for (int cc = 0; cc < 8; ++cc) o[cc] = 0.f;
#pragma unroll
        for (int i = 0; i < 50; ++i) {
            float e0 = __expf((float)s16[i][0] - m);
            float e1 = __expf((float)s16[i][1] - m);
            l += e0 + e1;
            float4 va = v4[4 * i], vb2 = v4[4 * i + 1];
            o[0] += e0 * va.x; o[1] += e0 * va.y; o[2] += e0 * va.z; o[3] += e0 * va.w;
            o[4] += e0 * vb2.x; o[5] += e0 * vb2.y; o[6] += e0 * vb2.z; o[7] += e0 * vb2.w;
            va = v4[4 * i + 2]; vb2 = v4[4 * i + 3];
            o[0] += e1 * va.x; o[1] += e1 * va.y; o[2] += e1 * va.z; o[3] += e1 * va.w;
            o[4] += e1 * vb2.x; o[5] += e1 * vb2.y; o[6] += e1 * vb2.z; o[7] += e1 * vb2.w;
        }
        float rl = 1.f / l;
        int y = wy * 10 + ty, x = wx * 10 + tx;
        float* ob = out + ((size_t)bb * 64 + head * 8) * HWP + y * WW + x;
#pragma unroll
        for (int cc = 0; cc < 8; ++cc) ob[(size_t)cc * HWP] = o[cc] * rl;
    }
}

// ------- geometric ensemble -> D4-orbit table, ci-PAIR packed: (pair, rep, co) f16x2 ----
// out[(p*28+rep)*16+co] = ( w[ci=2p][rep][co], w[ci=2p+1][rep][co] )
__global__ __launch_bounds__(256) void geo_kernel(
    const float* __restrict__ k, f16x2* __restrict__ out)
{
    int i = blockIdx.x * 256 + threadIdx.x;
    if (i >= 3584) return;
    int p = i / 448;
    int r = i - p * 448;
    int rep = r >> 4, co = r & 15;
    // decode triangular index rep -> (a, b)
    int a = 0, rr = rep;
    while (rr >= 7 - a) { rr -= 7 - a; ++a; }
    int b2 = a + rr;
    int y = 6 + a, x = 6 + b2;
    float sv[2];
#pragma unroll
    for (int t = 0; t < 2; ++t) {
        int ci = 2 * p + t;
        const float* kb = k + (co * 16 + ci) * 169;
        float s = kb[y * 13 + x] + kb[y * 13 + (12 - x)] + kb[(12 - y) * 13 + x] + kb[(12 - y) * 13 + (12 - x)]
                + kb[(12 - x) * 13 + y] + kb[x * 13 + y] + kb[(12 - x) * 13 + (12 - y)] + kb[x * 13 + (12 - y)];
        sv[t] = s * 0.125f;
    }
    f16x2 v;
    v[0] = (__fp16)sv[0];
    v[1] = (__fp16)sv[1];
    out[i] = v;
}

// ---------------- global mean over H,W of first-16 channels ----------------
__global__ __launch_bounds__(256) void gmean_kernel(
    const float* __restrict__ in, float* __restrict__ g)
{
    int bc = blockIdx.x;            // b*16 + c
    int bb = bc >> 4, c = bc & 15;
    const float* p = in + ((size_t)bb * 64 + c) * HWP;
    float s = 0.f;
    for (int i = threadIdx.x; i < HWP; i += 256) s += p[i];
#pragma unroll
    for (int off = 32; off > 0; off >>= 1) s += __shfl_down(s, off);
    __shared__ float red[4];
    int wave = threadIdx.x >> 6;
    if ((threadIdx.x & 63) == 0) red[wave] = s;
    __syncthreads();
    if (threadIdx.x == 0)
        g[bc] = (red[0] + red[1] + red[2] + red[3]) * (1.f / 40000.f);
}

// ---------------- tiny MLP -> dynamic 3x3 kernels ----------------
__global__ __launch_bounds__(192) void dynk_kernel(
    const float* __restrict__ g, const float* __restrict__ w1, const float* __restrict__ b1,
    const float* __restrict__ w2, const float* __restrict__ b2, float* __restrict__ dk)
{
    int bb = blockIdx.x;
    __shared__ float s_g2[8];
    int tid = threadIdx.x;
    if (tid < 8) {
        float a = b1[tid];
        for (int c = 0; c < 16; ++c) a += w1[tid * 16 + c] * g[bb * 16 + c];
        s_g2[tid] = gelu_f(a);
    }
    __syncthreads();
    if (tid < 144) {
        float a = b2[tid];
#pragma unroll
        for (int i = 0; i < 8; ++i) a += w2[tid * 8 + i] * s_g2[i];
        dk[bb * 144 + tid] = a;
    }
}

// ------- 13x13 D4-symmetric conv via packed-pair orbit sums + dynamic depthwise 3x3 ----
// LDS holds ci-pairs packed f16x2; orbit sums use v_pk_add_f16 (2 channels/op).
__global__ __launch_bounds__(256, 6) void lkconv_kernel(
    const float* __restrict__ in,   // (B,64,H,W) — channels 0..15 used
    const f16x2* __restrict__ lkP,  // (8 pairs, 28 reps, 16 co)
    const float* __restrict__ dk,   // (B,144)
    float* __restrict__ out)        // 4 partial buffers, stride PARTSZ
{
    __shared__ f16x2 s_p[2][28 * LKS];   // 2 ci-pairs x 28x40 = 8.96 KB
    int z = blockIdx.z;
    int bb = z >> 2, q = z & 3;
    int tid = threadIdx.x;
    int tx = tid & 15, ty = tid >> 4;
    int x0 = blockIdx.x * 16, y0 = blockIdx.y * 16;
    int x = x0 + tx, y = y0 + ty;

    const float* ib = in + ((size_t)bb * 64 + q * 4) * HWP;
    for (int i = tid; i < 2 * 784; i += 256) {
        int pi = i / 784; int r = i - pi * 784;
        int py = r / 28, px = r - py * 28;
        int yy = y0 + py - 6, xx = x0 + px - 6;
        f16x2 v = pk2(0.f, 0.f);
        if ((unsigned)yy < HH && (unsigned)xx < WW) {
            int gp = yy * WW + xx;
            v = pk2(ib[(size_t)(2 * pi) * HWP + gp], ib[(size_t)(2 * pi + 1) * HWP + gp]);
        }
        s_p[pi][py * LKS + px] = v;
    }
    __syncthreads();

    float acc[16];
#pragma unroll
    for (int co = 0; co < 16; ++co) acc[co] = 0.f;

#pragma unroll
    for (int pi = 0; pi < 2; ++pi) {
        // packed orbit sums: 169 u32 reads + 169 v_pk_add_f16 for TWO channels
        f16x2 orb[28];
#pragma unroll
        for (int o = 0; o < 28; ++o) orb[o] = pk2(0.f, 0.f);
#pragma unroll
        for (int ky = 0; ky < 13; ++ky) {
#pragma unroll
            for (int kx = 0; kx < 13; ++kx) {
                const int a = (ky < 6) ? (6 - ky) : (ky - 6);
                const int b = (kx < 6) ? (6 - kx) : (kx - 6);
                const int lo = (a < b) ? a : b;
                const int hi = (a < b) ? b : a;
                const int idx = lo * 7 - (lo * (lo - 1)) / 2 + (hi - lo);
                orb[idx] += s_p[pi][(ty + ky) * LKS + tx + kx];
            }
        }
        const f16x2* wci = lkP + (size_t)(q * 2 + pi) * 28 * 16;
#pragma unroll
        for (int o = 0; o < 28; ++o) {
            f16x2 ov = orb[o];
            const f16x2* wr = wci + o * 16;
#pragma unroll
            for (int co = 0; co < 16; ++co) acc[co] = fdot2f(ov, wr[co], acc[co]);
        }
        // dynamic depthwise 3x3: channels ci = q*4 + 2*pi + h
#pragma unroll
        for (int h = 0; h < 2; ++h) {
            int ci = q * 4 + 2 * pi + h;
            float d = 0.f;
            const float* dkr = dk + bb * 144 + ci * 9;
#pragma unroll
            for (int dy = 0; dy < 3; ++dy)
#pragma unroll
                for (int dx = 0; dx < 3; ++dx)
                    d += (float)s_p[pi][(ty + 5 + dy) * LKS + tx + 5 + dx][h] * dkr[dy * 3 + dx];
#pragma unroll
            for (int co = 0; co < 16; ++co) acc[co] += (co == ci) ? d : 0.f;
        }
    }

    if (x < WW && y < HH) {
        int p = y * WW + x;
        float* ob = out + (size_t)q * PARTSZ + (size_t)bb * 16 * HWP + p;
#pragma unroll
        for (int co = 0; co < 16; ++co) ob[(size_t)co * HWP] = acc[co];
    }
}

// ------- 1x1 conv over concat(sum of 4 x1 partials, y[16..63]), dot2; += xout -----
__global__ __launch_bounds__(256, 2) void pconv_add_kernel(
    const float* __restrict__ x1q,  // 4 partial buffers, stride PARTSZ
    const float* __restrict__ yy,   // (B,64,H,W), channels 16..63 used
    const f16x2* __restrict__ wt,   // (32, 64)
    const float* __restrict__ bias,
    float* __restrict__ xout)
{
    int p4 = blockIdx.x * 256 + threadIdx.x;
    int o0 = blockIdx.y * 16;
    int bb = blockIdx.z;
    if (p4 >= NP4) return;
    float4 acc[16];
#pragma unroll
    for (int j = 0; j < 16; ++j) {
        float bv = bias[o0 + j];
        acc[j] = make_float4(bv, bv, bv, bv);
    }
    const float4* xb0 = (const float4*)(x1q + (size_t)bb * 16 * HWP) + p4;
    const float4* xb1 = (const float4*)(x1q + PARTSZ + (size_t)bb * 16 * HWP) + p4;
    const float4* xb2 = (const float4*)(x1q + 2 * PARTSZ + (size_t)bb * 16 * HWP) + p4;
    const float4* xb3 = (const float4*)(x1q + 3 * PARTSZ + (size_t)bb * 16 * HWP) + p4;
    for (int c2 = 0; c2 < 8; ++c2) {
        int ca = 2 * c2, cb = 2 * c2 + 1;
        float4 a0 = xb0[(size_t)ca * NP4], a1 = xb1[(size_t)ca * NP4];
        float4 a2 = xb2[(size_t)ca * NP4], a3 = xb3[(size_t)ca * NP4];
        float4 s0;
        s0.x = (a0.x + a1.x) + (a2.x + a3.x);
        s0.y = (a0.y + a1.y) + (a2.y + a3.y);
        s0.z = (a0.z + a1.z) + (a2.z + a3.z);
        s0.w = (a0.w + a1.w) + (a2.w + a3.w);
        a0 = xb0[(size_t)cb * NP4]; a1 = xb1[(size_t)cb * NP4];
        a2 = xb2[(size_t)cb * NP4]; a3 = xb3[(size_t)cb * NP4];
        float4 s1;
        s1.x = (a0.x + a1.x) + (a2.x + a3.x);
        s1.y = (a0.y + a1.y) + (a2.y + a3.y);
        s1.z = (a0.z + a1.z) + (a2.z + a3.z);
        s1.w = (a0.w + a1.w) + (a2.w + a3.w);
        f16x2 px = pk2(s0.x, s1.x), py = pk2(s0.y, s1.y);
        f16x2 pz = pk2(s0.z, s1.z), pw = pk2(s0.w, s1.w);
        const f16x2* wr = wt + c2 * 64 + o0;
#pragma unroll
        for (int j = 0; j < 16; ++j) {
            f16x2 w = wr[j];
            acc[j].x = fdot2f(px, w, acc[j].x);
            acc[j].y = fdot2f(py, w, acc[j].y);
            acc[j].z = fdot2f(pz, w, acc[j].z);
            acc[j].w = fdot2f(pw, w, acc[j].w);
        }
    }
    const float4* yb = (const float4*)(yy + ((size_t)bb * 64 + 16) * HWP) + p4;
    for (int c2 = 8; c2 < 32; ++c2) {
        int cy = 2 * (c2 - 8);
        float4 s0 = yb[(size_t)cy * NP4];
        float4 s1 = yb[(size_t)(cy + 1) * NP4];
        f16x2 px = pk2(s0.x, s1.x), py = pk2(s0.y, s1.y);
        f16x2 pz = pk2(s0.z, s1.z), pw = pk2(s0.w, s1.w);
        const f16x2* wr = wt + c2 * 64 + o0;
#pragma unroll
        for (int j = 0; j < 16; ++j) {
            f16x2 w = wr[j];
            acc[j].x = fdot2f(px, w, acc[j].x);
            acc[j].y = fdot2f(py, w, acc[j].y);
            acc[j].z = fdot2f(pz, w, acc[j].z);
            acc[j].w = fdot2f(pw, w, acc[j].w);
        }
    }
    float4* ob = (float4*)(xout + ((size_t)bb * 64 + o0) * HWP) + p4;
#pragma unroll
    for (int j = 0; j < 16; ++j) {
        float4 old = ob[(size_t)j * NP4];
        old.x += acc[j].x; old.y += acc[j].y; old.z += acc[j].z; old.w += acc[j].w;
        ob[(size_t)j * NP4] = old;
    }
}

extern "C" void kernel_launch(void* const* d_in, const int* in_sizes, int n_in,
                              void* d_out, int out_size, void* d_ws, size_t ws_size,
                              hipStream_t stream)
{
    const float* x_in      = (const float*)d_in[0];
    const float* ln_proj_w = (const float*)d_in[1];
    const float* ln_proj_b = (const float*)d_in[2];
    const float* proj_p_w  = (const float*)d_in[3];
    const float* proj_p_b  = (const float*)d_in[4];
    const float* proj_d_w  = (const float*)d_in[5];
    const float* proj_d_b  = (const float*)d_in[6];
    const float* proj_a_w  = (const float*)d_in[7];
    const float* proj_a_b  = (const float*)d_in[8];
    const float* ln_attn_w = (const float*)d_in[9];
    const float* ln_attn_b = (const float*)d_in[10];
    const float* qkv_w     = (const float*)d_in[11];
    const float* qkv_b     = (const float*)d_in[12];
    const float* attn_o_w  = (const float*)d_in[13];
    const float* attn_o_b  = (const float*)d_in[14];
    const float* rpb       = (const float*)d_in[15];
    const float* dwcp1_w   = (const float*)d_in[16];
    const float* dwcp1_b   = (const float*)d_in[17];
    const float* dwcp2_w   = (const float*)d_in[18];
    const float* dwcp2_b   = (const float*)d_in[19];
    const float* pconv_w   = (const float*)d_in[20];
    const float* pconv_b   = (const float*)d_in[21];
    const float* ffn_p_w   = (const float*)d_in[22];
    const float* ffn_p_b   = (const float*)d_in[23];
    const float* ffn_d_w   = (const float*)d_in[24];
    const float* ffn_d_b   = (const float*)d_in[25];
    const float* ffn_a_w   = (const float*)d_in[26];
    const float* ffn_a_b   = (const float*)d_in[27];
    const float* ln_out_w  = (const float*)d_in[28];
    const float* ln_out_b  = (const float*)d_in[29];
    const float* conv_o_w  = (const float*)d_in[30];
    const float* conv_o_b  = (const float*)d_in[31];
    const float* plk       = (const float*)d_in[32];

    float* X  = (float*)d_out;
    float* ws = (float*)d_ws;

    // workspace map (floats):
    //  0        .. 10.24M : A (LN out / winattn out / ffn Y)
    //  10.24M   .. 30.72M : R1 (proj 128ch) | QKV (10.24..40.96)
    //  23.04M   .. 29.44M : Vf (ffn dwgelu f16, 80ch)
    //  30.72M   .. 40.96M : Vp (proj dwgelu f16, 128ch)
    //  33.28M   .. 43.52M : R2Q (lkconv partials)   [disjoint in time from Vp]
    //  43.52M   ..        : LKTH, GM, DK, WTH, WAH, WA2, WA3
    float* A    = ws;
    float* Y    = ws;
    float* R1   = ws + 10240000;
    float* QKV  = ws + 10240000;
    __fp16* Vf  = (__fp16*)(ws + 23040000);
    __fp16* Vp  = (__fp16*)(ws + 30720000);
    float* R2Q  = ws + 33280000;
    f16x2* LKTH = (f16x2*)(ws + 43520000);       // 3584 slots
    float* GM   = ws + 43524096;
    float* DK   = GM + 64;
    f16x2* WTH  = (f16x2*)(DK + 576);            // 4096 slots
    f16x8* WAH  = (f16x8*)(DK + 576 + 4096);     // 4352 slots x 16B
    f16x8* WA2  = WAH + 4352;                    // 2560 slots
    f16x8* WA3  = WA2 + 2560;                    // 4608 slots

    dim3 b256(256);
    dim3 gLN(157, 4);
    dim3 gT16(13, 13, 16);
    dim3 gM1(157, 1, 4);

    prep_kernel<<<dim3(16), b256, 0, stream>>>(pconv_w, WTH);
    prepA_kernel<<<dim3(17), b256, 0, stream>>>(qkv_w, proj_p_w, attn_o_w, ffn_p_w, WAH);
    prepA2_kernel<<<dim3(10), b256, 0, stream>>>(proj_a_w, ffn_a_w, WA2);
    prepA3_kernel<<<dim3(18), b256, 0, stream>>>(conv_o_w, WA3);
    geo_kernel<<<dim3(14), b256, 0, stream>>>(plk, LKTH);

    // x = conv_ffn(LN(x)) [proj]
    ln_kernel<<<gLN, b256, 0, stream>>>(x_in, ln_proj_w, ln_proj_b, A);
    conv1x1_mfma_kernel<<<dim3(157, 2, 4), b256, 0, stream>>>(A, WAH + 1536, proj_p_b, R1, 128, 1, 0);
    dwgelu_kernel<<<gT16, b256, 0, stream>>>(R1, proj_d_w, proj_d_b, Vp, 128);
    conv1x1h_mfma_kernel<<<gM1, b256, 0, stream>>>(Vp, WA2 + 0, proj_a_b, X, 128, 4);

    // x = x + window_attention(LN(x))
    ln_kernel<<<gLN, b256, 0, stream>>>(X, ln_attn_w, ln_attn_b, A);
    conv1x1_mfma_kernel<<<dim3(157, 3, 4), b256, 0, stream>>>(A, WAH + 0, qkv_b, QKV, 192, 0, 0);
    winattn2_kernel<<<dim3(400, 8, 4), dim3(128), 0, stream>>>(QKV, rpb, A);
    conv1x1_mfma_kernel<<<gM1, b256, 0, stream>>>(A, WAH + 2560, attn_o_b, X, 64, 0, 1);

    for (int i = 0; i < 2; ++i) {
        conv1x1_mfma_kernel<<<dim3(157, 2, 4), b256, 0, stream>>>(X, WAH + 3072 + i * 640, ffn_p_b + i * 80, R1, 80, 1, 0);
        dwgelu_kernel<<<gT16, b256, 0, stream>>>(R1, ffn_d_w + i * 720, ffn_d_b + i * 80, Vf, 80);
        conv1x1h_mfma_kernel<<<gM1, b256, 0, stream>>>(Vf, WA2 + 1024 + i * 768, ffn_a_b + i * 64, Y, 80, 3);
        gmean_kernel<<<dim3(64), b256, 0, stream>>>(Y, GM);
        dynk_kernel<<<dim3(4), dim3(192), 0, stream>>>(GM, dwcp1_w + i * 128, dwcp1_b + i * 8,
                                                       dwcp2_w + i * 1152, dwcp2_b + i * 144, DK);
        lkconv_kernel<<<gT16, b256, 0, stream>>>(Y, LKTH, DK, R2Q);
        pconv_add_kernel<<<dim3(40, 4, 4), b256, 0, stream>>>(R2Q, Y, WTH + i * 2048, pconv_b + i * 64, X);
    }

    // x = conv3x3(LN(x)) + skip — MFMA implicit GEMM, bias+skip fused
    ln_kernel<<<gLN, b256, 0, stream>>>(X, ln_out_w, ln_out_b, A);
    conv3_mfma_kernel<<<gM1, b256, 0, stream>>>(A, WA3, conv_o_b, x_in, X);
}

// Round 17
// 947.098 us; speedup vs baseline: 1.8102x; 1.0190x over previous
//
#include <hip/hip_runtime.h>
#include <math.h>

#define HH 200
#define WW 200
#define HWP 40000
#define NP4 10000
#define BB 4

#define LKS 40   // lkconv LDS row stride (u32 entries)
#define DPS 24   // dwgelu LDS row stride
#define PARTSZ 2560000    // one (B,16,H,W) partial buffer (lkconv)

typedef __fp16 f16x2 __attribute__((ext_vector_type(2)));
typedef __fp16 f16x8 __attribute__((ext_vector_type(8)));
typedef float fx4 __attribute__((ext_vector_type(4)));

#if __has_builtin(__builtin_amdgcn_fdot2)
__device__ __forceinline__ float fdot2f(f16x2 a, f16x2 b, float c) {
    return __builtin_amdgcn_fdot2(a, b, c, false);
}
#else
__device__ __forceinline__ float fdot2f(f16x2 a, f16x2 b, float c) {
    return c + (float)a[0] * (float)b[0] + (float)a[1] * (float)b[1];
}
#endif

__device__ __forceinline__ f16x2 pk2(float a, float b) {
    return __builtin_amdgcn_cvt_pkrtz(a, b);
}

__device__ __forceinline__ float gelu_f(float x) {
    return 0.5f * x * (1.0f + erff(x * 0.7071067811865475f));
}

// ---------------- pconv weight pack (ci,co) f16x2 ----------------
__global__ __launch_bounds__(256) void prep_kernel(
    const float* __restrict__ pc, f16x2* __restrict__ wth)
{
    int i = blockIdx.x * 256 + threadIdx.x;
    if (i >= 4096) return;
    int w = i >> 11;
    int r = i & 2047;
    int c2 = r / 64, o = r - c2 * 64;
    const float* src = pc + w * 4096;
    f16x2 v;
    v[0] = (__fp16)src[o * 64 + 2 * c2];
    v[1] = (__fp16)src[o * 64 + 2 * c2 + 1];
    wth[w * 2048 + r] = v;
}

// ------- MFMA A-fragment prep for Ci=64 1x1 convs (ksteps=2) -------
__global__ __launch_bounds__(256) void prepA_kernel(
    const float* __restrict__ qkvw, const float* __restrict__ pp,
    const float* __restrict__ ao, const float* __restrict__ fp,
    f16x8* __restrict__ wA)
{
    int s = blockIdx.x * 256 + threadIdx.x;
    if (s >= 4352) return;
    const float* src;
    int base;
    if (s < 1536)      { src = qkvw;      base = 0; }
    else if (s < 2560) { src = pp;        base = 1536; }
    else if (s < 3072) { src = ao;        base = 2560; }
    else if (s < 3712) { src = fp;        base = 3072; }
    else               { src = fp + 5120; base = 3712; }
    int r = s - base;
    int lane = r & 63;
    int t = r >> 6;
    int ks = t & 1;
    int cot = t >> 1;
    int co = cot * 16 + (lane & 15);
    int k0 = ks * 32 + ((lane >> 4) << 3);
    f16x8 v;
#pragma unroll
    for (int j = 0; j < 8; ++j) v[j] = (__fp16)src[co * 64 + k0 + j];
    wA[s] = v;
}

// ------- MFMA A-fragment prep, generalized K (proj_a Ci=128 ks4; ffn_a Ci=80 ks3) -----
__global__ __launch_bounds__(256) void prepA2_kernel(
    const float* __restrict__ pa, const float* __restrict__ fa,
    f16x8* __restrict__ wA2)
{
    int s = blockIdx.x * 256 + threadIdx.x;
    if (s >= 2560) return;
    const float* src; int base, Ci, ksteps;
    if (s < 1024)      { src = pa;        base = 0;    Ci = 128; ksteps = 4; }
    else if (s < 1792) { src = fa;        base = 1024; Ci = 80;  ksteps = 3; }
    else               { src = fa + 5120; base = 1792; Ci = 80;  ksteps = 3; }
    int r = s - base;
    int lane = r & 63;
    int u = r >> 6;
    int ks = u % ksteps;
    int cot = u / ksteps;
    int co = cot * 16 + (lane & 15);
    int k0 = ks * 32 + ((lane >> 4) << 3);
    f16x8 v;
#pragma unroll
    for (int j = 0; j < 8; ++j) {
        int k = k0 + j;
        v[j] = (k < Ci) ? (__fp16)src[co * Ci + k] : (__fp16)0.f;
    }
    wA2[s] = v;
}

// ------- MFMA A-fragment prep for conv3 (K = 576, k = tap*64 + ci) -------
__global__ __launch_bounds__(256) void prepA3_kernel(
    const float* __restrict__ co3, f16x8* __restrict__ wA3)
{
    int s = blockIdx.x * 256 + threadIdx.x;
    if (s >= 4608) return;
    int lane = s & 63;
    int u = s >> 6;
    int cot = u & 3;
    int t = u >> 2;
    int co = cot * 16 + (lane & 15);
    int k0 = t * 32 + ((lane >> 4) << 3);
    f16x8 v;
#pragma unroll
    for (int j = 0; j < 8; ++j) {
        int k = k0 + j;
        int tap = k >> 6, ci = k & 63;
        v[j] = (__fp16)co3[(co * 64 + ci) * 9 + tap];
    }
    wA3[s] = v;
}

// ---------------- LayerNorm over 64 channels ----------------
__global__ __launch_bounds__(256, 2) void ln_kernel(
    const float* __restrict__ in, const float* __restrict__ w,
    const float* __restrict__ b, float* __restrict__ out)
{
    int p = blockIdx.x * 256 + threadIdx.x;
    int bb = blockIdx.y;
    if (p >= HWP) return;
    const float* ib = in + (size_t)bb * 64 * HWP + p;
    float v[64];
    float mu = 0.f;
#pragma unroll
    for (int c = 0; c < 64; ++c) { v[c] = ib[(size_t)c * HWP]; mu += v[c]; }
    mu *= (1.f / 64.f);
    float var = 0.f;
#pragma unroll
    for (int c = 0; c < 64; ++c) { float d = v[c] - mu; var += d * d; }
    var *= (1.f / 64.f);
    float r = rsqrtf(var + 1e-6f);
    float* ob = out + (size_t)bb * 64 * HWP + p;
#pragma unroll
    for (int c = 0; c < 64; ++c) ob[(size_t)c * HWP] = (v[c] - mu) * r * w[c] + b[c];
}

// ---------------- 1x1 conv via MFMA f16 (Ci=64 f32 input) ----------------
__global__ __launch_bounds__(256, 2) void conv1x1_mfma_kernel(
    const float* __restrict__ in, const f16x8* __restrict__ wA,
    const float* __restrict__ bias, float* __restrict__ out,
    int Co, int do_gelu, int do_add)
{
    int lane = threadIdx.x & 63;
    int wv = threadIdx.x >> 6;
    int px0 = blockIdx.x * 256 + wv * 64;
    if (px0 >= HWP) return;
    int bb = blockIdx.z;
    int cot0 = blockIdx.y * 4;
    int nCot = (Co >> 4) - cot0; if (nCot > 4) nCot = 4;
    int row = lane >> 4;
    int colp = lane & 15;

    fx4 acc[4][4];
#pragma unroll
    for (int c = 0; c < 4; ++c)
#pragma unroll
        for (int nt = 0; nt < 4; ++nt)
#pragma unroll
            for (int r = 0; r < 4; ++r) acc[c][nt][r] = 0.f;

    const float* ib = in + (size_t)bb * 64 * HWP;
#pragma unroll
    for (int ks = 0; ks < 2; ++ks) {
        f16x8 afr[4];
#pragma unroll
        for (int c = 0; c < 4; ++c)
            if (c < nCot) afr[c] = wA[(((cot0 + c) * 2 + ks) << 6) + lane];
#pragma unroll
        for (int nt = 0; nt < 4; ++nt) {
            int px = px0 + nt * 16 + colp;
            const float* bp = ib + (size_t)(ks * 32 + row * 8) * HWP + px;
            union { f16x8 v; f16x2 h[4]; } bu;
            bu.h[0] = pk2(bp[0],              bp[(size_t)1 * HWP]);
            bu.h[1] = pk2(bp[(size_t)2 * HWP], bp[(size_t)3 * HWP]);
            bu.h[2] = pk2(bp[(size_t)4 * HWP], bp[(size_t)5 * HWP]);
            bu.h[3] = pk2(bp[(size_t)6 * HWP], bp[(size_t)7 * HWP]);
#pragma unroll
            for (int c = 0; c < 4; ++c)
                if (c < nCot)
                    acc[c][nt] = __builtin_amdgcn_mfma_f32_16x16x32_f16(afr[c], bu.v, acc[c][nt], 0, 0, 0);
        }
    }

#pragma unroll
    for (int c = 0; c < 4; ++c) {
        if (c < nCot) {
#pragma unroll
            for (int r = 0; r < 4; ++r) {
                int co = (cot0 + c) * 16 + row * 4 + r;
                float bv = bias[co];
                float* op = out + ((size_t)bb * Co + co) * HWP;
#pragma unroll
                for (int nt = 0; nt < 4; ++nt) {
                    int px = px0 + nt * 16 + colp;
                    float v = acc[c][nt][r] + bv;
                    if (do_gelu) v = gelu_f(v);
                    if (do_add) v += op[px];
                    op[px] = v;
                }
            }
        }
    }
}

// ---------------- 1x1 conv via MFMA, f16 input, generalized K, Co=64 ----------------
__global__ __launch_bounds__(256, 2) void conv1x1h_mfma_kernel(
    const __fp16* __restrict__ in,   // (B,Ci,H,W) f16
    const f16x8* __restrict__ wA,    // (4 cot x ksteps x 64) slots
    const float* __restrict__ bias, float* __restrict__ out,
    int Ci, int ksteps)
{
    int lane = threadIdx.x & 63;
    int wv = threadIdx.x >> 6;
    int px0 = blockIdx.x * 256 + wv * 64;
    if (px0 >= HWP) return;
    int bb = blockIdx.z;
    int row = lane >> 4;
    int colp = lane & 15;

    fx4 acc[4][4];
#pragma unroll
    for (int c = 0; c < 4; ++c)
#pragma unroll
        for (int nt = 0; nt < 4; ++nt)
#pragma unroll
            for (int r = 0; r < 4; ++r) acc[c][nt][r] = 0.f;

    const __fp16* ib = in + (size_t)bb * Ci * HWP;
    for (int ks = 0; ks < ksteps; ++ks) {
        f16x8 afr[4];
#pragma unroll
        for (int c = 0; c < 4; ++c)
            afr[c] = wA[((c * ksteps + ks) << 6) + lane];
        int k0 = ks * 32 + row * 8;
        bool ok = (k0 < Ci);
#pragma unroll
        for (int nt = 0; nt < 4; ++nt) {
            int px = px0 + nt * 16 + colp;
            f16x8 bv;
            if (ok) {
                const __fp16* bp = ib + (size_t)k0 * HWP + px;
#pragma unroll
                for (int j = 0; j < 8; ++j) bv[j] = bp[(size_t)j * HWP];
            } else {
#pragma unroll
                for (int j = 0; j < 8; ++j) bv[j] = (__fp16)0.f;
            }
#pragma unroll
            for (int c = 0; c < 4; ++c)
                acc[c][nt] = __builtin_amdgcn_mfma_f32_16x16x32_f16(afr[c], bv, acc[c][nt], 0, 0, 0);
        }
    }

#pragma unroll
    for (int c = 0; c < 4; ++c) {
#pragma unroll
        for (int r = 0; r < 4; ++r) {
            int co = c * 16 + row * 4 + r;
            float bv = bias[co];
            float* op = out + ((size_t)bb * 64 + co) * HWP;
#pragma unroll
            for (int nt = 0; nt < 4; ++nt) {
                int px = px0 + nt * 16 + colp;
                op[px] = acc[c][nt][r] + bv;
            }
        }
    }
}

// ---------------- conv3 via MFMA: 9 shifted 1x1 GEMMs, K=576, bias+skip fused ----------
__global__ __launch_bounds__(256, 2) void conv3_mfma_kernel(
    const float* __restrict__ in,   // LN'd (B,64,H,W)
    const f16x8* __restrict__ wA3,  // 4608 slots
    const float* __restrict__ bias, const float* __restrict__ skip,
    float* __restrict__ out)
{
    int lane = threadIdx.x & 63;
    int wv = threadIdx.x >> 6;
    int px0 = blockIdx.x * 256 + wv * 64;
    if (px0 >= HWP) return;
    int bb = blockIdx.z;
    int row = lane >> 4;
    int colp = lane & 15;

    fx4 acc[4][4];
#pragma unroll
    for (int c = 0; c < 4; ++c)
#pragma unroll
        for (int nt = 0; nt < 4; ++nt)
#pragma unroll
            for (int r = 0; r < 4; ++r) acc[c][nt][r] = 0.f;

    int py[4], pxx[4];
#pragma unroll
    for (int nt = 0; nt < 4; ++nt) {
        int p = px0 + nt * 16 + colp;
        py[nt] = p / WW;
        pxx[nt] = p - py[nt] * WW;
    }

    const float* ib = in + (size_t)bb * 64 * HWP;
    for (int t = 0; t < 18; ++t) {
        int tap = t >> 1, ks = t & 1;
        int dy = tap / 3 - 1, dx = tap % 3 - 1;
        f16x8 afr[4];
#pragma unroll
        for (int c = 0; c < 4; ++c) afr[c] = wA3[((t * 4 + c) << 6) + lane];
        const float* kb = ib + (size_t)(ks * 32 + row * 8) * HWP;
#pragma unroll
        for (int nt = 0; nt < 4; ++nt) {
            int yy = py[nt] + dy, xx = pxx[nt] + dx;
            union { f16x8 v; f16x2 h[4]; } bu;
            if ((unsigned)yy < HH && (unsigned)xx < WW) {
                const float* bp = kb + yy * WW + xx;
                bu.h[0] = pk2(bp[0],              bp[(size_t)1 * HWP]);
                bu.h[1] = pk2(bp[(size_t)2 * HWP], bp[(size_t)3 * HWP]);
                bu.h[2] = pk2(bp[(size_t)4 * HWP], bp[(size_t)5 * HWP]);
                bu.h[3] = pk2(bp[(size_t)6 * HWP], bp[(size_t)7 * HWP]);
            } else {
                bu.h[0] = pk2(0.f, 0.f); bu.h[1] = bu.h[0];
                bu.h[2] = bu.h[0];       bu.h[3] = bu.h[0];
            }
#pragma unroll
            for (int c = 0; c < 4; ++c)
                acc[c][nt] = __builtin_amdgcn_mfma_f32_16x16x32_f16(afr[c], bu.v, acc[c][nt], 0, 0, 0);
        }
    }

#pragma unroll
    for (int c = 0; c < 4; ++c) {
#pragma unroll
        for (int r = 0; r < 4; ++r) {
            int co = c * 16 + row * 4 + r;
            float bv = bias[co];
            const float* sb = skip + ((size_t)bb * 64 + co) * HWP;
            float* op = out + ((size_t)bb * 64 + co) * HWP;
#pragma unroll
            for (int nt = 0; nt < 4; ++nt) {
                int px = px0 + nt * 16 + colp;
                op[px] = acc[c][nt][r] + bv + sb[px];
            }
        }
    }
}

// ------- dwgelu: v = gelu(dwconv3x3(in)) + in, written f16 NCHW; 4-way channel split ----
__global__ __launch_bounds__(256, 4) void dwgelu_kernel(
    const float* __restrict__ in,   // (B,Ci,H,W) f32
    const float* __restrict__ dw,   // (Ci,9)
    const float* __restrict__ db,   // (Ci)
    __fp16* __restrict__ vout,      // (B,Ci,H,W) f16
    int Ci)
{
    __shared__ float s_p[16][18 * DPS];
    int tid = threadIdx.x;
    int tx = tid & 15, ty = tid >> 4;
    int x0 = blockIdx.x * 16, y0 = blockIdx.y * 16;
    int part = blockIdx.z & 3;
    int bb = blockIdx.z >> 2;
    int cic = Ci >> 2;
    int cbase = part * cic;
    int x = x0 + tx, y = y0 + ty;
    bool inb = (x < WW && y < HH);
    int p = y * WW + x;

    const float* ibase = in + (size_t)bb * Ci * HWP;
    __fp16* obase = vout + (size_t)bb * Ci * HWP;
    for (int c0 = cbase; c0 < cbase + cic; c0 += 16) {
        int chunk = cbase + cic - c0; if (chunk > 16) chunk = 16;
        __syncthreads();
        for (int i = tid; i < chunk * 324; i += 256) {
            int ci = i / 324; int r = i - ci * 324;
            int py = r / 18, px = r - py * 18;
            int yy = y0 + py - 1, xx = x0 + px - 1;
            float v = 0.f;
            if ((unsigned)yy < HH && (unsigned)xx < WW)
                v = ibase[(size_t)(c0 + ci) * HWP + yy * WW + xx];
            s_p[ci][py * DPS + px] = v;
        }
        __syncthreads();
        if (inb) {
            for (int ci = 0; ci < chunk; ++ci) {
                int c = c0 + ci;
                float s = db[c];
                const float* dwr = dw + c * 9;
#pragma unroll
                for (int ky = 0; ky < 3; ++ky)
#pragma unroll
                    for (int kx = 0; kx < 3; ++kx)
                        s += s_p[ci][(ty + ky) * DPS + tx + kx] * dwr[ky * 3 + kx];
                float v = gelu_f(s) + s_p[ci][(ty + 1) * DPS + tx + 1];
                obase[(size_t)c * HWP + p] = (__fp16)v;
            }
        }
    }
}

// ---------------- attention v4: packed-f16 dot2 for QK and PV ----------------
__global__ __launch_bounds__(128, 4) void winattn2_kernel(
    const float* __restrict__ qkv,  // (B,192,H,W)
    const float* __restrict__ rpb,  // (8,361)
    float* __restrict__ out)        // (B,64,H,W)
{
    __shared__ __align__(16) f16x2 s_k2[100][4];   // channel pairs
    __shared__ __align__(4) __fp16 s_vT[8][100];   // [cc][key] transposed
    __shared__ float s_b[361];

    int head = blockIdx.y, bb = blockIdx.z;
    int wy = blockIdx.x / 20, wx = blockIdx.x - wy * 20;
    int tid = threadIdx.x;

    for (int i = tid; i < 361; i += 128) s_b[i] = rpb[head * 361 + i];

    int ty = tid / 10, tx = tid - ty * 10;
    f16x2 q2[4];
    if (tid < 100) {
        int y = wy * 10 + ty, x = wx * 10 + tx;
        int gp = y * WW + x;
        const float* qb = qkv + ((size_t)bb * 192 + head * 8) * HWP + gp;
        const float* kb = qb + (size_t)64 * HWP;
        const float* vb = qb + (size_t)128 * HWP;
        const float scale = 0.3535533905932738f; // 1/sqrt(8)
#pragma unroll
        for (int c2 = 0; c2 < 4; ++c2) {
            q2[c2] = pk2(qb[(size_t)(2 * c2) * HWP] * scale,
                         qb[(size_t)(2 * c2 + 1) * HWP] * scale);
            s_k2[tid][c2] = pk2(kb[(size_t)(2 * c2) * HWP], kb[(size_t)(2 * c2 + 1) * HWP]);
        }
#pragma unroll
        for (int cc = 0; cc < 8; ++cc)
            s_vT[cc][tid] = (__fp16)vb[(size_t)cc * HWP];
    }
    __syncthreads();

    if (tid < 100) {
        const float* brow = s_b + (180 - ty * 19 - tx);

        f16x2 s16[50];
        float m = -1e30f;
#pragma unroll
        for (int i = 0; i < 50; ++i) {
            const int k0 = 2 * i, k1 = 2 * i + 1;
            const int c0 = (k0 / 10) * 19 + (k0 % 10);
            const int c1 = (k1 / 10) * 19 + (k1 % 10);
            float s0 = brow[c0];
            float s1 = brow[c1];
#pragma unroll
            for (int c2 = 0; c2 < 4; ++c2) {
                s0 = fdot2f(q2[c2], s_k2[k0][c2], s0);
                s1 = fdot2f(q2[c2], s_k2[k1][c2], s1);
            }
            m = fmaxf(m, fmaxf(s0, s1));
            s16[i] = pk2(s0, s1);
        }
        float l = 0.f;
        float o[8];
#pragma unroll
        for (int cc = 0; cc < 8; ++cc) o[cc] = 0.f;
#pragma unroll
        for (int i = 0; i < 50; ++i) {
            float e0 = __expf((float)s16[i][0] - m);
            float e1 = __expf((float)s16[i][1] - m);
            l += e0 + e1;
            f16x2 e2 = pk2(e0, e1);
#pragma unroll
            for (int cc = 0; cc < 8; ++cc)
                o[cc] = fdot2f(e2, *(const f16x2*)&s_vT[cc][2 * i], o[cc]);
        }
        float rl = 1.f / l;
        int y = wy * 10 + ty, x = wx * 10 + tx;
        float* ob = out + ((size_t)bb * 64 + head * 8) * HWP + y * WW + x;
#pragma unroll
        for (int cc = 0; cc < 8; ++cc) ob[(size_t)cc * HWP] = o[cc] * rl;
    }
}

// ------- geometric ensemble -> D4-orbit table, ci-PAIR packed: (pair, rep, co) f16x2 ----
__global__ __launch_bounds__(256) void geo_kernel(
    const float* __restrict__ k, f16x2* __restrict__ out)
{
    int i = blockIdx.x * 256 + threadIdx.x;
    if (i >= 3584) return;
    int p = i / 448;
    int r = i - p * 448;
    int rep = r >> 4, co = r & 15;
    int a = 0, rr = rep;
    while (rr >= 7 - a) { rr -= 7 - a; ++a; }
    int b2 = a + rr;
    int y = 6 + a, x = 6 + b2;
    float sv[2];
#pragma unroll
    for (int t = 0; t < 2; ++t) {
        int ci = 2 * p + t;
        const float* kb = k + (co * 16 + ci) * 169;
        float s = kb[y * 13 + x] + kb[y * 13 + (12 - x)] + kb[(12 - y) * 13 + x] + kb[(12 - y) * 13 + (12 - x)]
                + kb[(12 - x) * 13 + y] + kb[x * 13 + y] + kb[(12 - x) * 13 + (12 - y)] + kb[x * 13 + (12 - y)];
        sv[t] = s * 0.125f;
    }
    f16x2 v;
    v[0] = (__fp16)sv[0];
    v[1] = (__fp16)sv[1];
    out[i] = v;
}

// ---------------- global mean over H,W of first-16 channels ----------------
__global__ __launch_bounds__(256) void gmean_kernel(
    const float* __restrict__ in, float* __restrict__ g)
{
    int bc = blockIdx.x;            // b*16 + c
    int bb = bc >> 4, c = bc & 15;
    const float* p = in + ((size_t)bb * 64 + c) * HWP;
    float s = 0.f;
    for (int i = threadIdx.x; i < HWP; i += 256) s += p[i];
#pragma unroll
    for (int off = 32; off > 0; off >>= 1) s += __shfl_down(s, off);
    __shared__ float red[4];
    int wave = threadIdx.x >> 6;
    if ((threadIdx.x & 63) == 0) red[wave] = s;
    __syncthreads();
    if (threadIdx.x == 0)
        g[bc] = (red[0] + red[1] + red[2] + red[3]) * (1.f / 40000.f);
}

// ---------------- tiny MLP -> dynamic 3x3 kernels ----------------
__global__ __launch_bounds__(192) void dynk_kernel(
    const float* __restrict__ g, const float* __restrict__ w1, const float* __restrict__ b1,
    const float* __restrict__ w2, const float* __restrict__ b2, float* __restrict__ dk)
{
    int bb = blockIdx.x;
    __shared__ float s_g2[8];
    int tid = threadIdx.x;
    if (tid < 8) {
        float a = b1[tid];
        for (int c = 0; c < 16; ++c) a += w1[tid * 16 + c] * g[bb * 16 + c];
        s_g2[tid] = gelu_f(a);
    }
    __syncthreads();
    if (tid < 144) {
        float a = b2[tid];
#pragma unroll
        for (int i = 0; i < 8; ++i) a += w2[tid * 8 + i] * s_g2[i];
        dk[bb * 144 + tid] = a;
    }
}

// ------- 13x13 D4-symmetric conv via packed-pair orbit sums + dynamic depthwise 3x3 ----
__global__ __launch_bounds__(256, 6) void lkconv_kernel(
    const float* __restrict__ in,   // (B,64,H,W) — channels 0..15 used
    const f16x2* __restrict__ lkP,  // (8 pairs, 28 reps, 16 co)
    const float* __restrict__ dk,   // (B,144)
    float* __restrict__ out)        // 4 partial buffers, stride PARTSZ
{
    __shared__ f16x2 s_p[2][28 * LKS];   // 2 ci-pairs x 28x40 = 8.96 KB
    int z = blockIdx.z;
    int bb = z >> 2, q = z & 3;
    int tid = threadIdx.x;
    int tx = tid & 15, ty = tid >> 4;
    int x0 = blockIdx.x * 16, y0 = blockIdx.y * 16;
    int x = x0 + tx, y = y0 + ty;

    const float* ib = in + ((size_t)bb * 64 + q * 4) * HWP;
    for (int i = tid; i < 2 * 784; i += 256) {
        int pi = i / 784; int r = i - pi * 784;
        int py = r / 28, px = r - py * 28;
        int yy = y0 + py - 6, xx = x0 + px - 6;
        f16x2 v = pk2(0.f, 0.f);
        if ((unsigned)yy < HH && (unsigned)xx < WW) {
            int gp = yy * WW + xx;
            v = pk2(ib[(size_t)(2 * pi) * HWP + gp], ib[(size_t)(2 * pi + 1) * HWP + gp]);
        }
        s_p[pi][py * LKS + px] = v;
    }
    __syncthreads();

    float acc[16];
#pragma unroll
    for (int co = 0; co < 16; ++co) acc[co] = 0.f;

#pragma unroll
    for (int pi = 0; pi < 2; ++pi) {
        f16x2 orb[28];
#pragma unroll
        for (int o = 0; o < 28; ++o) orb[o] = pk2(0.f, 0.f);
#pragma unroll
        for (int ky = 0; ky < 13; ++ky) {
#pragma unroll
            for (int kx = 0; kx < 13; ++kx) {
                const int a = (ky < 6) ? (6 - ky) : (ky - 6);
                const int b = (kx < 6) ? (6 - kx) : (kx - 6);
                const int lo = (a < b) ? a : b;
                const int hi = (a < b) ? b : a;
                const int idx = lo * 7 - (lo * (lo - 1)) / 2 + (hi - lo);
                orb[idx] += s_p[pi][(ty + ky) * LKS + tx + kx];
            }
        }
        const f16x2* wci = lkP + (size_t)(q * 2 + pi) * 28 * 16;
#pragma unroll
        for (int o = 0; o < 28; ++o) {
            f16x2 ov = orb[o];
            const f16x2* wr = wci + o * 16;
#pragma unroll
            for (int co = 0; co < 16; ++co) acc[co] = fdot2f(ov, wr[co], acc[co]);
        }
#pragma unroll
        for (int h = 0; h < 2; ++h) {
            int ci = q * 4 + 2 * pi + h;
            float d = 0.f;
            const float* dkr = dk + bb * 144 + ci * 9;
#pragma unroll
            for (int dy = 0; dy < 3; ++dy)
#pragma unroll
                for (int dx = 0; dx < 3; ++dx)
                    d += (float)s_p[pi][(ty + 5 + dy) * LKS + tx + 5 + dx][h] * dkr[dy * 3 + dx];
#pragma unroll
            for (int co = 0; co < 16; ++co) acc[co] += (co == ci) ? d : 0.f;
        }
    }

    if (x < WW && y < HH) {
        int p = y * WW + x;
        float* ob = out + (size_t)q * PARTSZ + (size_t)bb * 16 * HWP + p;
#pragma unroll
        for (int co = 0; co < 16; ++co) ob[(size_t)co * HWP] = acc[co];
    }
}

// ------- 1x1 conv over concat(sum of 4 x1 partials, y[16..63]), dot2; += xout -----
__global__ __launch_bounds__(256, 2) void pconv_add_kernel(
    const float* __restrict__ x1q,  // 4 partial buffers, stride PARTSZ
    const float* __restrict__ yy,   // (B,64,H,W), channels 16..63 used
    const f16x2* __restrict__ wt,   // (32, 64)
    const float* __restrict__ bias,
    float* __restrict__ xout)
{
    int p4 = blockIdx.x * 256 + threadIdx.x;
    int o0 = blockIdx.y * 16;
    int bb = blockIdx.z;
    if (p4 >= NP4) return;
    float4 acc[16];
#pragma unroll
    for (int j = 0; j < 16; ++j) {
        float bv = bias[o0 + j];
        acc[j] = make_float4(bv, bv, bv, bv);
    }
    const float4* xb0 = (const float4*)(x1q + (size_t)bb * 16 * HWP) + p4;
    const float4* xb1 = (const float4*)(x1q + PARTSZ + (size_t)bb * 16 * HWP) + p4;
    const float4* xb2 = (const float4*)(x1q + 2 * PARTSZ + (size_t)bb * 16 * HWP) + p4;
    const float4* xb3 = (const float4*)(x1q + 3 * PARTSZ + (size_t)bb * 16 * HWP) + p4;
    for (int c2 = 0; c2 < 8; ++c2) {
        int ca = 2 * c2, cb = 2 * c2 + 1;
        float4 a0 = xb0[(size_t)ca * NP4], a1 = xb1[(size_t)ca * NP4];
        float4 a2 = xb2[(size_t)ca * NP4], a3 = xb3[(size_t)ca * NP4];
        float4 s0;
        s0.x = (a0.x + a1.x) + (a2.x + a3.x);
        s0.y = (a0.y + a1.y) + (a2.y + a3.y);
        s0.z = (a0.z + a1.z) + (a2.z + a3.z);
        s0.w = (a0.w + a1.w) + (a2.w + a3.w);
        a0 = xb0[(size_t)cb * NP4]; a1 = xb1[(size_t)cb * NP4];
        a2 = xb2[(size_t)cb * NP4]; a3 = xb3[(size_t)cb * NP4];
        float4 s1;
        s1.x = (a0.x + a1.x) + (a2.x + a3.x);
        s1.y = (a0.y + a1.y) + (a2.y + a3.y);
        s1.z = (a0.z + a1.z) + (a2.z + a3.z);
        s1.w = (a0.w + a1.w) + (a2.w + a3.w);
        f16x2 px = pk2(s0.x, s1.x), py = pk2(s0.y, s1.y);
        f16x2 pz = pk2(s0.z, s1.z), pw = pk2(s0.w, s1.w);
        const f16x2* wr = wt + c2 * 64 + o0;
#pragma unroll
        for (int j = 0; j < 16; ++j) {
            f16x2 w = wr[j];
            acc[j].x = fdot2f(px, w, acc[j].x);
            acc[j].y = fdot2f(py, w, acc[j].y);
            acc[j].z = fdot2f(pz, w, acc[j].z);
            acc[j].w = fdot2f(pw, w, acc[j].w);
        }
    }
    const float4* yb = (const float4*)(yy + ((size_t)bb * 64 + 16) * HWP) + p4;
    for (int c2 = 8; c2 < 32; ++c2) {
        int cy = 2 * (c2 - 8);
        float4 s0 = yb[(size_t)cy * NP4];
        float4 s1 = yb[(size_t)(cy + 1) * NP4];
        f16x2 px = pk2(s0.x, s1.x), py = pk2(s0.y, s1.y);
        f16x2 pz = pk2(s0.z, s1.z), pw = pk2(s0.w, s1.w);
        const f16x2* wr = wt + c2 * 64 + o0;
#pragma unroll
        for (int j = 0; j < 16; ++j) {
            f16x2 w = wr[j];
            acc[j].x = fdot2f(px, w, acc[j].x);
            acc[j].y = fdot2f(py, w, acc[j].y);
            acc[j].z = fdot2f(pz, w, acc[j].z);
            acc[j].w = fdot2f(pw, w, acc[j].w);
        }
    }
    float4* ob = (float4*)(xout + ((size_t)bb * 64 + o0) * HWP) + p4;
#pragma unroll
    for (int j = 0; j < 16; ++j) {
        float4 old = ob[(size_t)j * NP4];
        old.x += acc[j].x; old.y += acc[j].y; old.z += acc[j].z; old.w += acc[j].w;
        ob[(size_t)j * NP4] = old;
    }
}

extern "C" void kernel_launch(void* const* d_in, const int* in_sizes, int n_in,
                              void* d_out, int out_size, void* d_ws, size_t ws_size,
                              hipStream_t stream)
{
    const float* x_in      = (const float*)d_in[0];
    const float* ln_proj_w = (const float*)d_in[1];
    const float* ln_proj_b = (const float*)d_in[2];
    const float* proj_p_w  = (const float*)d_in[3];
    const float* proj_p_b  = (const float*)d_in[4];
    const float* proj_d_w  = (const float*)d_in[5];
    const float* proj_d_b  = (const float*)d_in[6];
    const float* proj_a_w  = (const float*)d_in[7];
    const float* proj_a_b  = (const float*)d_in[8];
    const float* ln_attn_w = (const float*)d_in[9];
    const float* ln_attn_b = (const float*)d_in[10];
    const float* qkv_w     = (const float*)d_in[11];
    const float* qkv_b     = (const float*)d_in[12];
    const float* attn_o_w  = (const float*)d_in[13];
    const float* attn_o_b  = (const float*)d_in[14];
    const float* rpb       = (const float*)d_in[15];
    const float* dwcp1_w   = (const float*)d_in[16];
    const float* dwcp1_b   = (const float*)d_in[17];
    const float* dwcp2_w   = (const float*)d_in[18];
    const float* dwcp2_b   = (const float*)d_in[19];
    const float* pconv_w   = (const float*)d_in[20];
    const float* pconv_b   = (const float*)d_in[21];
    const float* ffn_p_w   = (const float*)d_in[22];
    const float* ffn_p_b   = (const float*)d_in[23];
    const float* ffn_d_w   = (const float*)d_in[24];
    const float* ffn_d_b   = (const float*)d_in[25];
    const float* ffn_a_w   = (const float*)d_in[26];
    const float* ffn_a_b   = (const float*)d_in[27];
    const float* ln_out_w  = (const float*)d_in[28];
    const float* ln_out_b  = (const float*)d_in[29];
    const float* conv_o_w  = (const float*)d_in[30];
    const float* conv_o_b  = (const float*)d_in[31];
    const float* plk       = (const float*)d_in[32];

    float* X  = (float*)d_out;
    float* ws = (float*)d_ws;

    // workspace map (floats):
    //  0        .. 10.24M : A (LN out / winattn out / ffn Y)
    //  10.24M   .. 30.72M : R1 (proj 128ch) | QKV (10.24..40.96)
    //  23.04M   .. 29.44M : Vf (ffn dwgelu f16, 80ch)
    //  30.72M   .. 40.96M : Vp (proj dwgelu f16, 128ch)
    //  33.28M   .. 43.52M : R2Q (lkconv partials)   [disjoint in time from Vp]
    //  43.52M   ..        : LKTH, GM, DK, WTH, WAH, WA2, WA3
    float* A    = ws;
    float* Y    = ws;
    float* R1   = ws + 10240000;
    float* QKV  = ws + 10240000;
    __fp16* Vf  = (__fp16*)(ws + 23040000);
    __fp16* Vp  = (__fp16*)(ws + 30720000);
    float* R2Q  = ws + 33280000;
    f16x2* LKTH = (f16x2*)(ws + 43520000);       // 3584 slots
    float* GM   = ws + 43524096;
    float* DK   = GM + 64;
    f16x2* WTH  = (f16x2*)(DK + 576);            // 4096 slots
    f16x8* WAH  = (f16x8*)(DK + 576 + 4096);     // 4352 slots x 16B
    f16x8* WA2  = WAH + 4352;                    // 2560 slots
    f16x8* WA3  = WA2 + 2560;                    // 4608 slots

    dim3 b256(256);
    dim3 gLN(157, 4);
    dim3 gT16(13, 13, 16);
    dim3 gM1(157, 1, 4);

    prep_kernel<<<dim3(16), b256, 0, stream>>>(pconv_w, WTH);
    prepA_kernel<<<dim3(17), b256, 0, stream>>>(qkv_w, proj_p_w, attn_o_w, ffn_p_w, WAH);
    prepA2_kernel<<<dim3(10), b256, 0, stream>>>(proj_a_w, ffn_a_w, WA2);
    prepA3_kernel<<<dim3(18), b256, 0, stream>>>(conv_o_w, WA3);
    geo_kernel<<<dim3(14), b256, 0, stream>>>(plk, LKTH);

    // x = conv_ffn(LN(x)) [proj]
    ln_kernel<<<gLN, b256, 0, stream>>>(x_in, ln_proj_w, ln_proj_b, A);
    conv1x1_mfma_kernel<<<dim3(157, 2, 4), b256, 0, stream>>>(A, WAH + 1536, proj_p_b, R1, 128, 1, 0);
    dwgelu_kernel<<<gT16, b256, 0, stream>>>(R1, proj_d_w, proj_d_b, Vp, 128);
    conv1x1h_mfma_kernel<<<gM1, b256, 0, stream>>>(Vp, WA2 + 0, proj_a_b, X, 128, 4);

    // x = x + window_attention(LN(x))
    ln_kernel<<<gLN, b256, 0, stream>>>(X, ln_attn_w, ln_attn_b, A);
    conv1x1_mfma_kernel<<<dim3(157, 3, 4), b256, 0, stream>>>(A, WAH + 0, qkv_b, QKV, 192, 0, 0);
    winattn2_kernel<<<dim3(400, 8, 4), dim3(128), 0, stream>>>(QKV, rpb, A);
    conv1x1_mfma_kernel<<<gM1, b256, 0, stream>>>(A, WAH + 2560, attn_o_b, X, 64, 0, 1);

    for (int i = 0; i < 2; ++i) {
        conv1x1_mfma_kernel<<<dim3(157, 2, 4), b256, 0, stream>>>(X, WAH + 3072 + i * 640, ffn_p_b + i * 80, R1, 80, 1, 0);
        dwgelu_kernel<<<gT16, b256, 0, stream>>>(R1, ffn_d_w + i * 720, ffn_d_b + i * 80, Vf, 80);
        conv1x1h_mfma_kernel<<<gM1, b256, 0, stream>>>(Vf, WA2 + 1024 + i * 768, ffn_a_b + i * 64, Y, 80, 3);
        gmean_kernel<<<dim3(64), b256, 0, stream>>>(Y, GM);
        dynk_kernel<<<dim3(4), dim3(192), 0, stream>>>(GM, dwcp1_w + i * 128, dwcp1_b + i * 8,
                                                       dwcp2_w + i * 1152, dwcp2_b + i * 144, DK);
        lkconv_kernel<<<gT16, b256, 0, stream>>>(Y, LKTH, DK, R2Q);
        pconv_add_kernel<<<dim3(40, 4, 4), b256, 0, stream>>>(R2Q, Y, WTH + i * 2048, pconv_b + i * 64, X);
    }

    // x = conv3x3(LN(x)) + skip — MFMA implicit GEMM, bias+skip fused
    ln_kernel<<<gLN, b256, 0, stream>>>(X, ln_out_w, ln_out_b, A);
    conv3_mfma_kernel<<<gM1, b256, 0, stream>>>(A, WA3, conv_o_b, x_in, X);
}

// Round 18
// 939.220 us; speedup vs baseline: 1.8254x; 1.0084x over previous
//
#include <hip/hip_runtime.h>
#include <math.h>

#define HH 200
#define WW 200
#define HWP 40000
#define NP4 10000
#define BB 4

#define LKS 40   // lkconv LDS row stride (u32 entries)
#define DPS 24   // dwgelu LDS row stride
#define PARTSZ 2560000    // one (B,16,H,W) partial buffer (lkconv)

typedef __fp16 f16x2 __attribute__((ext_vector_type(2)));
typedef __fp16 f16x8 __attribute__((ext_vector_type(8)));
typedef float fx4 __attribute__((ext_vector_type(4)));

#if __has_builtin(__builtin_amdgcn_fdot2)
__device__ __forceinline__ float fdot2f(f16x2 a, f16x2 b, float c) {
    return __builtin_amdgcn_fdot2(a, b, c, false);
}
#else
__device__ __forceinline__ float fdot2f(f16x2 a, f16x2 b, float c) {
    return c + (float)a[0] * (float)b[0] + (float)a[1] * (float)b[1];
}
#endif

__device__ __forceinline__ f16x2 pk2(float a, float b) {
    return __builtin_amdgcn_cvt_pkrtz(a, b);
}

__device__ __forceinline__ float gelu_f(float x) {
    return 0.5f * x * (1.0f + erff(x * 0.7071067811865475f));
}

// ---------------- pconv weight pack (ci,co) f16x2 ----------------
__global__ __launch_bounds__(256) void prep_kernel(
    const float* __restrict__ pc, f16x2* __restrict__ wth)
{
    int i = blockIdx.x * 256 + threadIdx.x;
    if (i >= 4096) return;
    int w = i >> 11;
    int r = i & 2047;
    int c2 = r / 64, o = r - c2 * 64;
    const float* src = pc + w * 4096;
    f16x2 v;
    v[0] = (__fp16)src[o * 64 + 2 * c2];
    v[1] = (__fp16)src[o * 64 + 2 * c2 + 1];
    wth[w * 2048 + r] = v;
}

// ------- MFMA A-fragment prep for Ci=64 1x1 convs (ksteps=2) -------
__global__ __launch_bounds__(256) void prepA_kernel(
    const float* __restrict__ qkvw, const float* __restrict__ pp,
    const float* __restrict__ ao, const float* __restrict__ fp,
    f16x8* __restrict__ wA)
{
    int s = blockIdx.x * 256 + threadIdx.x;
    if (s >= 4352) return;
    const float* src;
    int base;
    if (s < 1536)      { src = qkvw;      base = 0; }
    else if (s < 2560) { src = pp;        base = 1536; }
    else if (s < 3072) { src = ao;        base = 2560; }
    else if (s < 3712) { src = fp;        base = 3072; }
    else               { src = fp + 5120; base = 3712; }
    int r = s - base;
    int lane = r & 63;
    int t = r >> 6;
    int ks = t & 1;
    int cot = t >> 1;
    int co = cot * 16 + (lane & 15);
    int k0 = ks * 32 + ((lane >> 4) << 3);
    f16x8 v;
#pragma unroll
    for (int j = 0; j < 8; ++j) v[j] = (__fp16)src[co * 64 + k0 + j];
    wA[s] = v;
}

// ------- MFMA A-fragment prep, generalized K (proj_a Ci=128 ks4; ffn_a Ci=80 ks3) -----
__global__ __launch_bounds__(256) void prepA2_kernel(
    const float* __restrict__ pa, const float* __restrict__ fa,
    f16x8* __restrict__ wA2)
{
    int s = blockIdx.x * 256 + threadIdx.x;
    if (s >= 2560) return;
    const float* src; int base, Ci, ksteps;
    if (s < 1024)      { src = pa;        base = 0;    Ci = 128; ksteps = 4; }
    else if (s < 1792) { src = fa;        base = 1024; Ci = 80;  ksteps = 3; }
    else               { src = fa + 5120; base = 1792; Ci = 80;  ksteps = 3; }
    int r = s - base;
    int lane = r & 63;
    int u = r >> 6;
    int ks = u % ksteps;
    int cot = u / ksteps;
    int co = cot * 16 + (lane & 15);
    int k0 = ks * 32 + ((lane >> 4) << 3);
    f16x8 v;
#pragma unroll
    for (int j = 0; j < 8; ++j) {
        int k = k0 + j;
        v[j] = (k < Ci) ? (__fp16)src[co * Ci + k] : (__fp16)0.f;
    }
    wA2[s] = v;
}

// ------- MFMA A-fragment prep for conv3 (K = 576, k = tap*64 + ci) -------
__global__ __launch_bounds__(256) void prepA3_kernel(
    const float* __restrict__ co3, f16x8* __restrict__ wA3)
{
    int s = blockIdx.x * 256 + threadIdx.x;
    if (s >= 4608) return;
    int lane = s & 63;
    int u = s >> 6;
    int cot = u & 3;
    int t = u >> 2;
    int co = cot * 16 + (lane & 15);
    int k0 = t * 32 + ((lane >> 4) << 3);
    f16x8 v;
#pragma unroll
    for (int j = 0; j < 8; ++j) {
        int k = k0 + j;
        int tap = k >> 6, ci = k & 63;
        v[j] = (__fp16)co3[(co * 64 + ci) * 9 + tap];
    }
    wA3[s] = v;
}

// ---------------- LayerNorm over 64 channels, f16 output ----------------
__global__ __launch_bounds__(256, 2) void ln_kernel(
    const float* __restrict__ in, const float* __restrict__ w,
    const float* __restrict__ b, __fp16* __restrict__ out)
{
    int p = blockIdx.x * 256 + threadIdx.x;
    int bb = blockIdx.y;
    if (p >= HWP) return;
    const float* ib = in + (size_t)bb * 64 * HWP + p;
    float v[64];
    float mu = 0.f;
#pragma unroll
    for (int c = 0; c < 64; ++c) { v[c] = ib[(size_t)c * HWP]; mu += v[c]; }
    mu *= (1.f / 64.f);
    float var = 0.f;
#pragma unroll
    for (int c = 0; c < 64; ++c) { float d = v[c] - mu; var += d * d; }
    var *= (1.f / 64.f);
    float r = rsqrtf(var + 1e-6f);
    __fp16* ob = out + (size_t)bb * 64 * HWP + p;
#pragma unroll
    for (int c = 0; c < 64; ++c) ob[(size_t)c * HWP] = (__fp16)((v[c] - mu) * r * w[c] + b[c]);
}

// ---------------- 1x1 conv via MFMA, f32 input, outh/outf flags ----------------
__global__ __launch_bounds__(256, 2) void conv1x1_mfma_kernel(
    const float* __restrict__ in, const f16x8* __restrict__ wA,
    const float* __restrict__ bias, float* outf, __fp16* outh,
    int Co, int do_gelu, int do_add)
{
    int lane = threadIdx.x & 63;
    int wv = threadIdx.x >> 6;
    int px0 = blockIdx.x * 256 + wv * 64;
    if (px0 >= HWP) return;
    int bb = blockIdx.z;
    int cot0 = blockIdx.y * 4;
    int nCot = (Co >> 4) - cot0; if (nCot > 4) nCot = 4;
    int row = lane >> 4;
    int colp = lane & 15;

    fx4 acc[4][4];
#pragma unroll
    for (int c = 0; c < 4; ++c)
#pragma unroll
        for (int nt = 0; nt < 4; ++nt)
#pragma unroll
            for (int r = 0; r < 4; ++r) acc[c][nt][r] = 0.f;

    const float* ib = in + (size_t)bb * 64 * HWP;
#pragma unroll
    for (int ks = 0; ks < 2; ++ks) {
        f16x8 afr[4];
#pragma unroll
        for (int c = 0; c < 4; ++c)
            if (c < nCot) afr[c] = wA[(((cot0 + c) * 2 + ks) << 6) + lane];
#pragma unroll
        for (int nt = 0; nt < 4; ++nt) {
            int px = px0 + nt * 16 + colp;
            const float* bp = ib + (size_t)(ks * 32 + row * 8) * HWP + px;
            union { f16x8 v; f16x2 h[4]; } bu;
            bu.h[0] = pk2(bp[0],              bp[(size_t)1 * HWP]);
            bu.h[1] = pk2(bp[(size_t)2 * HWP], bp[(size_t)3 * HWP]);
            bu.h[2] = pk2(bp[(size_t)4 * HWP], bp[(size_t)5 * HWP]);
            bu.h[3] = pk2(bp[(size_t)6 * HWP], bp[(size_t)7 * HWP]);
#pragma unroll
            for (int c = 0; c < 4; ++c)
                if (c < nCot)
                    acc[c][nt] = __builtin_amdgcn_mfma_f32_16x16x32_f16(afr[c], bu.v, acc[c][nt], 0, 0, 0);
        }
    }

#pragma unroll
    for (int c = 0; c < 4; ++c) {
        if (c < nCot) {
#pragma unroll
            for (int r = 0; r < 4; ++r) {
                int co = (cot0 + c) * 16 + row * 4 + r;
                float bv = bias[co];
#pragma unroll
                for (int nt = 0; nt < 4; ++nt) {
                    int px = px0 + nt * 16 + colp;
                    float v = acc[c][nt][r] + bv;
                    if (do_gelu) v = gelu_f(v);
                    if (outh) {
                        outh[((size_t)bb * Co + co) * HWP + px] = (__fp16)v;
                    } else {
                        float* op = outf + ((size_t)bb * Co + co) * HWP;
                        if (do_add) v += op[px];
                        op[px] = v;
                    }
                }
            }
        }
    }
}

// ---------------- 1x1 conv via MFMA, f16 input, generalized (Ci, ksteps, Co) -----------
__global__ __launch_bounds__(256, 2) void convh_kernel(
    const __fp16* __restrict__ in,   // (B,Ci,H,W) f16
    const f16x8* __restrict__ wA,    // ((cot*ksteps+ks)<<6)+lane slots
    const float* __restrict__ bias, float* outf, __fp16* outh,
    int Ci, int ksteps, int Co, int do_gelu, int do_add)
{
    int lane = threadIdx.x & 63;
    int wv = threadIdx.x >> 6;
    int px0 = blockIdx.x * 256 + wv * 64;
    if (px0 >= HWP) return;
    int bb = blockIdx.z;
    int cot0 = blockIdx.y * 4;
    int nCot = (Co >> 4) - cot0; if (nCot > 4) nCot = 4;
    int row = lane >> 4;
    int colp = lane & 15;

    fx4 acc[4][4];
#pragma unroll
    for (int c = 0; c < 4; ++c)
#pragma unroll
        for (int nt = 0; nt < 4; ++nt)
#pragma unroll
            for (int r = 0; r < 4; ++r) acc[c][nt][r] = 0.f;

    const __fp16* ib = in + (size_t)bb * Ci * HWP;
    for (int ks = 0; ks < ksteps; ++ks) {
        f16x8 afr[4];
#pragma unroll
        for (int c = 0; c < 4; ++c)
            if (c < nCot) afr[c] = wA[(((cot0 + c) * ksteps + ks) << 6) + lane];
        int k0 = ks * 32 + row * 8;
        bool ok = (k0 < Ci);
#pragma unroll
        for (int nt = 0; nt < 4; ++nt) {
            int px = px0 + nt * 16 + colp;
            f16x8 bv;
            if (ok) {
                const __fp16* bp = ib + (size_t)k0 * HWP + px;
#pragma unroll
                for (int j = 0; j < 8; ++j) bv[j] = bp[(size_t)j * HWP];
            } else {
#pragma unroll
                for (int j = 0; j < 8; ++j) bv[j] = (__fp16)0.f;
            }
#pragma unroll
            for (int c = 0; c < 4; ++c)
                if (c < nCot)
                    acc[c][nt] = __builtin_amdgcn_mfma_f32_16x16x32_f16(afr[c], bv, acc[c][nt], 0, 0, 0);
        }
    }

#pragma unroll
    for (int c = 0; c < 4; ++c) {
        if (c < nCot) {
#pragma unroll
            for (int r = 0; r < 4; ++r) {
                int co = (cot0 + c) * 16 + row * 4 + r;
                float bv = bias[co];
#pragma unroll
                for (int nt = 0; nt < 4; ++nt) {
                    int px = px0 + nt * 16 + colp;
                    float v = acc[c][nt][r] + bv;
                    if (do_gelu) v = gelu_f(v);
                    if (outh) {
                        outh[((size_t)bb * Co + co) * HWP + px] = (__fp16)v;
                    } else {
                        float* op = outf + ((size_t)bb * Co + co) * HWP;
                        if (do_add) v += op[px];
                        op[px] = v;
                    }
                }
            }
        }
    }
}

// ---------------- conv3 via MFMA: f16 input, 9 shifted taps, bias+skip fused ----------
__global__ __launch_bounds__(256, 2) void conv3_mfma_kernel(
    const __fp16* __restrict__ in,  // LN'd (B,64,H,W) f16
    const f16x8* __restrict__ wA3,  // 4608 slots
    const float* __restrict__ bias, const float* __restrict__ skip,
    float* __restrict__ out)
{
    int lane = threadIdx.x & 63;
    int wv = threadIdx.x >> 6;
    int px0 = blockIdx.x * 256 + wv * 64;
    if (px0 >= HWP) return;
    int bb = blockIdx.z;
    int row = lane >> 4;
    int colp = lane & 15;

    fx4 acc[4][4];
#pragma unroll
    for (int c = 0; c < 4; ++c)
#pragma unroll
        for (int nt = 0; nt < 4; ++nt)
#pragma unroll
            for (int r = 0; r < 4; ++r) acc[c][nt][r] = 0.f;

    int py[4], pxx[4];
#pragma unroll
    for (int nt = 0; nt < 4; ++nt) {
        int p = px0 + nt * 16 + colp;
        py[nt] = p / WW;
        pxx[nt] = p - py[nt] * WW;
    }

    const __fp16* ib = in + (size_t)bb * 64 * HWP;
    for (int t = 0; t < 18; ++t) {
        int tap = t >> 1, ks = t & 1;
        int dy = tap / 3 - 1, dx = tap % 3 - 1;
        f16x8 afr[4];
#pragma unroll
        for (int c = 0; c < 4; ++c) afr[c] = wA3[((t * 4 + c) << 6) + lane];
        const __fp16* kb = ib + (size_t)(ks * 32 + row * 8) * HWP;
#pragma unroll
        for (int nt = 0; nt < 4; ++nt) {
            int yy = py[nt] + dy, xx = pxx[nt] + dx;
            f16x8 bv;
            if ((unsigned)yy < HH && (unsigned)xx < WW) {
                const __fp16* bp = kb + yy * WW + xx;
#pragma unroll
                for (int j = 0; j < 8; ++j) bv[j] = bp[(size_t)j * HWP];
            } else {
#pragma unroll
                for (int j = 0; j < 8; ++j) bv[j] = (__fp16)0.f;
            }
#pragma unroll
            for (int c = 0; c < 4; ++c)
                acc[c][nt] = __builtin_amdgcn_mfma_f32_16x16x32_f16(afr[c], bv, acc[c][nt], 0, 0, 0);
        }
    }

#pragma unroll
    for (int c = 0; c < 4; ++c) {
#pragma unroll
        for (int r = 0; r < 4; ++r) {
            int co = c * 16 + row * 4 + r;
            float bv = bias[co];
            const float* sb = skip + ((size_t)bb * 64 + co) * HWP;
            float* op = out + ((size_t)bb * 64 + co) * HWP;
#pragma unroll
            for (int nt = 0; nt < 4; ++nt) {
                int px = px0 + nt * 16 + colp;
                op[px] = acc[c][nt][r] + bv + sb[px];
            }
        }
    }
}

// ------- dwgelu: v = gelu(dwconv3x3(in)) + in, f16 in/out; 4-way channel split ----
__global__ __launch_bounds__(256, 4) void dwgelu_kernel(
    const __fp16* __restrict__ in,  // (B,Ci,H,W) f16
    const float* __restrict__ dw,   // (Ci,9)
    const float* __restrict__ db,   // (Ci)
    __fp16* __restrict__ vout,      // (B,Ci,H,W) f16
    int Ci)
{
    __shared__ float s_p[16][18 * DPS];
    int tid = threadIdx.x;
    int tx = tid & 15, ty = tid >> 4;
    int x0 = blockIdx.x * 16, y0 = blockIdx.y * 16;
    int part = blockIdx.z & 3;
    int bb = blockIdx.z >> 2;
    int cic = Ci >> 2;
    int cbase = part * cic;
    int x = x0 + tx, y = y0 + ty;
    bool inb = (x < WW && y < HH);
    int p = y * WW + x;

    const __fp16* ibase = in + (size_t)bb * Ci * HWP;
    __fp16* obase = vout + (size_t)bb * Ci * HWP;
    for (int c0 = cbase; c0 < cbase + cic; c0 += 16) {
        int chunk = cbase + cic - c0; if (chunk > 16) chunk = 16;
        __syncthreads();
        for (int i = tid; i < chunk * 324; i += 256) {
            int ci = i / 324; int r = i - ci * 324;
            int py = r / 18, px = r - py * 18;
            int yy = y0 + py - 1, xx = x0 + px - 1;
            float v = 0.f;
            if ((unsigned)yy < HH && (unsigned)xx < WW)
                v = (float)ibase[(size_t)(c0 + ci) * HWP + yy * WW + xx];
            s_p[ci][py * DPS + px] = v;
        }
        __syncthreads();
        if (inb) {
            for (int ci = 0; ci < chunk; ++ci) {
                int c = c0 + ci;
                float s = db[c];
                const float* dwr = dw + c * 9;
#pragma unroll
                for (int ky = 0; ky < 3; ++ky)
#pragma unroll
                    for (int kx = 0; kx < 3; ++kx)
                        s += s_p[ci][(ty + ky) * DPS + tx + kx] * dwr[ky * 3 + kx];
                float v = gelu_f(s) + s_p[ci][(ty + 1) * DPS + tx + 1];
                obase[(size_t)c * HWP + p] = (__fp16)v;
            }
        }
    }
}

// ---------------- attention v5: f16 qkv, exp2 domain, f16 out ----------------
__global__ __launch_bounds__(128, 4) void winattn2_kernel(
    const __fp16* __restrict__ qkv, // (B,192,H,W) f16
    const float* __restrict__ rpb,  // (8,361)
    __fp16* __restrict__ out)       // (B,64,H,W) f16
{
    __shared__ __align__(16) f16x2 s_k2[100][4];   // channel pairs
    __shared__ __align__(4) __fp16 s_vT[8][100];   // [cc][key] transposed
    __shared__ float s_b[361];

    int head = blockIdx.y, bb = blockIdx.z;
    int wy = blockIdx.x / 20, wx = blockIdx.x - wy * 20;
    int tid = threadIdx.x;

    const float log2e = 1.4426950408889634f;
    for (int i = tid; i < 361; i += 128) s_b[i] = rpb[head * 361 + i] * log2e;

    int ty = tid / 10, tx = tid - ty * 10;
    f16x2 q2[4];
    if (tid < 100) {
        int y = wy * 10 + ty, x = wx * 10 + tx;
        int gp = y * WW + x;
        const __fp16* qb = qkv + ((size_t)bb * 192 + head * 8) * HWP + gp;
        const __fp16* kb = qb + (size_t)64 * HWP;
        const __fp16* vb = qb + (size_t)128 * HWP;
        const float qsc = 0.3535533905932738f * log2e;
#pragma unroll
        for (int c2 = 0; c2 < 4; ++c2) {
            q2[c2] = pk2((float)qb[(size_t)(2 * c2) * HWP] * qsc,
                         (float)qb[(size_t)(2 * c2 + 1) * HWP] * qsc);
            f16x2 kv;
            kv[0] = kb[(size_t)(2 * c2) * HWP];
            kv[1] = kb[(size_t)(2 * c2 + 1) * HWP];
            s_k2[tid][c2] = kv;
        }
#pragma unroll
        for (int cc = 0; cc < 8; ++cc)
            s_vT[cc][tid] = vb[(size_t)cc * HWP];
    }
    __syncthreads();

    if (tid < 100) {
        const float* brow = s_b + (180 - ty * 19 - tx);

        f16x2 s16[50];
        float m = -1e30f;
#pragma unroll
        for (int i = 0; i < 50; ++i) {
            const int k0 = 2 * i, k1 = 2 * i + 1;
            const int c0 = (k0 / 10) * 19 + (k0 % 10);
            const int c1 = (k1 / 10) * 19 + (k1 % 10);
            float s0 = brow[c0];
            float s1 = brow[c1];
#pragma unroll
            for (int c2 = 0; c2 < 4; ++c2) {
                s0 = fdot2f(q2[c2], s_k2[k0][c2], s0);
                s1 = fdot2f(q2[c2], s_k2[k1][c2], s1);
            }
            m = fmaxf(m, fmaxf(s0, s1));
            s16[i] = pk2(s0, s1);
        }
        float l = 0.f;
        float o[8];
#pragma unroll
        for (int cc = 0; cc < 8; ++cc) o[cc] = 0.f;
#pragma unroll
        for (int i = 0; i < 50; ++i) {
            float e0 = exp2f((float)s16[i][0] - m);
            float e1 = exp2f((float)s16[i][1] - m);
            l += e0 + e1;
            f16x2 e2 = pk2(e0, e1);
#pragma unroll
            for (int cc = 0; cc < 8; ++cc)
                o[cc] = fdot2f(e2, *(const f16x2*)&s_vT[cc][2 * i], o[cc]);
        }
        float rl = 1.f / l;
        int y = wy * 10 + ty, x = wx * 10 + tx;
        __fp16* ob = out + ((size_t)bb * 64 + head * 8) * HWP + y * WW + x;
#pragma unroll
        for (int cc = 0; cc < 8; ++cc) ob[(size_t)cc * HWP] = (__fp16)(o[cc] * rl);
    }
}

// ------- geometric ensemble -> D4-orbit table, ci-PAIR packed: (pair, rep, co) f16x2 ----
__global__ __launch_bounds__(256) void geo_kernel(
    const float* __restrict__ k, f16x2* __restrict__ out)
{
    int i = blockIdx.x * 256 + threadIdx.x;
    if (i >= 3584) return;
    int p = i / 448;
    int r = i - p * 448;
    int rep = r >> 4, co = r & 15;
    int a = 0, rr = rep;
    while (rr >= 7 - a) { rr -= 7 - a; ++a; }
    int b2 = a + rr;
    int y = 6 + a, x = 6 + b2;
    float sv[2];
#pragma unroll
    for (int t = 0; t < 2; ++t) {
        int ci = 2 * p + t;
        const float* kb = k + (co * 16 + ci) * 169;
        float s = kb[y * 13 + x] + kb[y * 13 + (12 - x)] + kb[(12 - y) * 13 + x] + kb[(12 - y) * 13 + (12 - x)]
                + kb[(12 - x) * 13 + y] + kb[x * 13 + y] + kb[(12 - x) * 13 + (12 - y)] + kb[x * 13 + (12 - y)];
        sv[t] = s * 0.125f;
    }
    f16x2 v;
    v[0] = (__fp16)sv[0];
    v[1] = (__fp16)sv[1];
    out[i] = v;
}

// ---------------- global mean over H,W of first-16 channels ----------------
__global__ __launch_bounds__(256) void gmean_kernel(
    const float* __restrict__ in, float* __restrict__ g)
{
    int bc = blockIdx.x;            // b*16 + c
    int bb = bc >> 4, c = bc & 15;
    const float* p = in + ((size_t)bb * 64 + c) * HWP;
    float s = 0.f;
    for (int i = threadIdx.x; i < HWP; i += 256) s += p[i];
#pragma unroll
    for (int off = 32; off > 0; off >>= 1) s += __shfl_down(s, off);
    __shared__ float red[4];
    int wave = threadIdx.x >> 6;
    if ((threadIdx.x & 63) == 0) red[wave] = s;
    __syncthreads();
    if (threadIdx.x == 0)
        g[bc] = (red[0] + red[1] + red[2] + red[3]) * (1.f / 40000.f);
}

// ---------------- tiny MLP -> dynamic 3x3 kernels ----------------
__global__ __launch_bounds__(192) void dynk_kernel(
    const float* __restrict__ g, const float* __restrict__ w1, const float* __restrict__ b1,
    const float* __restrict__ w2, const float* __restrict__ b2, float* __restrict__ dk)
{
    int bb = blockIdx.x;
    __shared__ float s_g2[8];
    int tid = threadIdx.x;
    if (tid < 8) {
        float a = b1[tid];
        for (int c = 0; c < 16; ++c) a += w1[tid * 16 + c] * g[bb * 16 + c];
        s_g2[tid] = gelu_f(a);
    }
    __syncthreads();
    if (tid < 144) {
        float a = b2[tid];
#pragma unroll
        for (int i = 0; i < 8; ++i) a += w2[tid * 8 + i] * s_g2[i];
        dk[bb * 144 + tid] = a;
    }
}

// ------- 13x13 D4-symmetric conv via packed-pair orbit sums + dynamic depthwise 3x3 ----
__global__ __launch_bounds__(256, 6) void lkconv_kernel(
    const float* __restrict__ in,   // (B,64,H,W) — channels 0..15 used
    const f16x2* __restrict__ lkP,  // (8 pairs, 28 reps, 16 co)
    const float* __restrict__ dk,   // (B,144)
    float* __restrict__ out)        // 4 partial buffers, stride PARTSZ
{
    __shared__ f16x2 s_p[2][28 * LKS];   // 2 ci-pairs x 28x40 = 8.96 KB
    int z = blockIdx.z;
    int bb = z >> 2, q = z & 3;
    int tid = threadIdx.x;
    int tx = tid & 15, ty = tid >> 4;
    int x0 = blockIdx.x * 16, y0 = blockIdx.y * 16;
    int x = x0 + tx, y = y0 + ty;

    const float* ib = in + ((size_t)bb * 64 + q * 4) * HWP;
    for (int i = tid; i < 2 * 784; i += 256) {
        int pi = i / 784; int r = i - pi * 784;
        int py = r / 28, px = r - py * 28;
        int yy = y0 + py - 6, xx = x0 + px - 6;
        f16x2 v = pk2(0.f, 0.f);
        if ((unsigned)yy < HH && (unsigned)xx < WW) {
            int gp = yy * WW + xx;
            v = pk2(ib[(size_t)(2 * pi) * HWP + gp], ib[(size_t)(2 * pi + 1) * HWP + gp]);
        }
        s_p[pi][py * LKS + px] = v;
    }
    __syncthreads();

    float acc[16];
#pragma unroll
    for (int co = 0; co < 16; ++co) acc[co] = 0.f;

#pragma unroll
    for (int pi = 0; pi < 2; ++pi) {
        f16x2 orb[28];
#pragma unroll
        for (int o = 0; o < 28; ++o) orb[o] = pk2(0.f, 0.f);
#pragma unroll
        for (int ky = 0; ky < 13; ++ky) {
#pragma unroll
            for (int kx = 0; kx < 13; ++kx) {
                const int a = (ky < 6) ? (6 - ky) : (ky - 6);
                const int b = (kx < 6) ? (6 - kx) : (kx - 6);
                const int lo = (a < b) ? a : b;
                const int hi = (a < b) ? b : a;
                const int idx = lo * 7 - (lo * (lo - 1)) / 2 + (hi - lo);
                orb[idx] += s_p[pi][(ty + ky) * LKS + tx + kx];
            }
        }
        const f16x2* wci = lkP + (size_t)(q * 2 + pi) * 28 * 16;
#pragma unroll
        for (int o = 0; o < 28; ++o) {
            f16x2 ov = orb[o];
            const f16x2* wr = wci + o * 16;
#pragma unroll
            for (int co = 0; co < 16; ++co) acc[co] = fdot2f(ov, wr[co], acc[co]);
        }
#pragma unroll
        for (int h = 0; h < 2; ++h) {
            int ci = q * 4 + 2 * pi + h;
            float d = 0.f;
            const float* dkr = dk + bb * 144 + ci * 9;
#pragma unroll
            for (int dy = 0; dy < 3; ++dy)
#pragma unroll
                for (int dx = 0; dx < 3; ++dx)
                    d += (float)s_p[pi][(ty + 5 + dy) * LKS + tx + 5 + dx][h] * dkr[dy * 3 + dx];
#pragma unroll
            for (int co = 0; co < 16; ++co) acc[co] += (co == ci) ? d : 0.f;
        }
    }

    if (x < WW && y < HH) {
        int p = y * WW + x;
        float* ob = out + (size_t)q * PARTSZ + (size_t)bb * 16 * HWP + p;
#pragma unroll
        for (int co = 0; co < 16; ++co) ob[(size_t)co * HWP] = acc[co];
    }
}

// ------- 1x1 conv over concat(sum of 4 x1 partials, y[16..63]), dot2; += xout -----
__global__ __launch_bounds__(256, 2) void pconv_add_kernel(
    const float* __restrict__ x1q,  // 4 partial buffers, stride PARTSZ
    const float* __restrict__ yy,   // (B,64,H,W), channels 16..63 used
    const f16x2* __restrict__ wt,   // (32, 64)
    const float* __restrict__ bias,
    float* __restrict__ xout)
{
    int p4 = blockIdx.x * 256 + threadIdx.x;
    int o0 = blockIdx.y * 16;
    int bb = blockIdx.z;
    if (p4 >= NP4) return;
    float4 acc[16];
#pragma unroll
    for (int j = 0; j < 16; ++j) {
        float bv = bias[o0 + j];
        acc[j] = make_float4(bv, bv, bv, bv);
    }
    const float4* xb0 = (const float4*)(x1q + (size_t)bb * 16 * HWP) + p4;
    const float4* xb1 = (const float4*)(x1q + PARTSZ + (size_t)bb * 16 * HWP) + p4;
    const float4* xb2 = (const float4*)(x1q + 2 * PARTSZ + (size_t)bb * 16 * HWP) + p4;
    const float4* xb3 = (const float4*)(x1q + 3 * PARTSZ + (size_t)bb * 16 * HWP) + p4;
    for (int c2 = 0; c2 < 8; ++c2) {
        int ca = 2 * c2, cb = 2 * c2 + 1;
        float4 a0 = xb0[(size_t)ca * NP4], a1 = xb1[(size_t)ca * NP4];
        float4 a2 = xb2[(size_t)ca * NP4], a3 = xb3[(size_t)ca * NP4];
        float4 s0;
        s0.x = (a0.x + a1.x) + (a2.x + a3.x);
        s0.y = (a0.y + a1.y) + (a2.y + a3.y);
        s0.z = (a0.z + a1.z) + (a2.z + a3.z);
        s0.w = (a0.w + a1.w) + (a2.w + a3.w);
        a0 = xb0[(size_t)cb * NP4]; a1 = xb1[(size_t)cb * NP4];
        a2 = xb2[(size_t)cb * NP4]; a3 = xb3[(size_t)cb * NP4];
        float4 s1;
        s1.x = (a0.x + a1.x) + (a2.x + a3.x);
        s1.y = (a0.y + a1.y) + (a2.y + a3.y);
        s1.z = (a0.z + a1.z) + (a2.z + a3.z);
        s1.w = (a0.w + a1.w) + (a2.w + a3.w);
        f16x2 px = pk2(s0.x, s1.x), py = pk2(s0.y, s1.y);
        f16x2 pz = pk2(s0.z, s1.z), pw = pk2(s0.w, s1.w);
        const f16x2* wr = wt + c2 * 64 + o0;
#pragma unroll
        for (int j = 0; j < 16; ++j) {
            f16x2 w = wr[j];
            acc[j].x = fdot2f(px, w, acc[j].x);
            acc[j].y = fdot2f(py, w, acc[j].y);
            acc[j].z = fdot2f(pz, w, acc[j].z);
            acc[j].w = fdot2f(pw, w, acc[j].w);
        }
    }
    const float4* yb = (const float4*)(yy + ((size_t)bb * 64 + 16) * HWP) + p4;
    for (int c2 = 8; c2 < 32; ++c2) {
        int cy = 2 * (c2 - 8);
        float4 s0 = yb[(size_t)cy * NP4];
        float4 s1 = yb[(size_t)(cy + 1) * NP4];
        f16x2 px = pk2(s0.x, s1.x), py = pk2(s0.y, s1.y);
        f16x2 pz = pk2(s0.z, s1.z), pw = pk2(s0.w, s1.w);
        const f16x2* wr = wt + c2 * 64 + o0;
#pragma unroll
        for (int j = 0; j < 16; ++j) {
            f16x2 w = wr[j];
            acc[j].x = fdot2f(px, w, acc[j].x);
            acc[j].y = fdot2f(py, w, acc[j].y);
            acc[j].z = fdot2f(pz, w, acc[j].z);
            acc[j].w = fdot2f(pw, w, acc[j].w);
        }
    }
    float4* ob = (float4*)(xout + ((size_t)bb * 64 + o0) * HWP) + p4;
#pragma unroll
    for (int j = 0; j < 16; ++j) {
        float4 old = ob[(size_t)j * NP4];
        old.x += acc[j].x; old.y += acc[j].y; old.z += acc[j].z; old.w += acc[j].w;
        ob[(size_t)j * NP4] = old;
    }
}

extern "C" void kernel_launch(void* const* d_in, const int* in_sizes, int n_in,
                              void* d_out, int out_size, void* d_ws, size_t ws_size,
                              hipStream_t stream)
{
    const float* x_in      = (const float*)d_in[0];
    const float* ln_proj_w = (const float*)d_in[1];
    const float* ln_proj_b = (const float*)d_in[2];
    const float* proj_p_w  = (const float*)d_in[3];
    const float* proj_p_b  = (const float*)d_in[4];
    const float* proj_d_w  = (const float*)d_in[5];
    const float* proj_d_b  = (const float*)d_in[6];
    const float* proj_a_w  = (const float*)d_in[7];
    const float* proj_a_b  = (const float*)d_in[8];
    const float* ln_attn_w = (const float*)d_in[9];
    const float* ln_attn_b = (const float*)d_in[10];
    const float* qkv_w     = (const float*)d_in[11];
    const float* qkv_b     = (const float*)d_in[12];
    const float* attn_o_w  = (const float*)d_in[13];
    const float* attn_o_b  = (const float*)d_in[14];
    const float* rpb       = (const float*)d_in[15];
    const float* dwcp1_w   = (const float*)d_in[16];
    const float* dwcp1_b   = (const float*)d_in[17];
    const float* dwcp2_w   = (const float*)d_in[18];
    const float* dwcp2_b   = (const float*)d_in[19];
    const float* pconv_w   = (const float*)d_in[20];
    const float* pconv_b   = (const float*)d_in[21];
    const float* ffn_p_w   = (const float*)d_in[22];
    const float* ffn_p_b   = (const float*)d_in[23];
    const float* ffn_d_w   = (const float*)d_in[24];
    const float* ffn_d_b   = (const float*)d_in[25];
    const float* ffn_a_w   = (const float*)d_in[26];
    const float* ffn_a_b   = (const float*)d_in[27];
    const float* ln_out_w  = (const float*)d_in[28];
    const float* ln_out_b  = (const float*)d_in[29];
    const float* conv_o_w  = (const float*)d_in[30];
    const float* conv_o_b  = (const float*)d_in[31];
    const float* plk       = (const float*)d_in[32];

    float* X  = (float*)d_out;
    float* ws = (float*)d_ws;

    // workspace map (float-units):
    //  0      .. 10.24M : Y (f32 ffn out) | A16 (f16 LN out / attn out, 5.12M span)
    //  10.24M .. 17.92M : R1h (f16 128ch, 5.12M span) | QKVh (f16 192ch, 7.68M span)
    //  23.04M .. 28.16M : Vp/Vf (f16 dwgelu out)
    //  33.28M .. 43.52M : R2Q (lkconv partials)
    //  43.52M ..        : LKTH, GM, DK, WTH, WAH, WA2, WA3
    float*  Y    = ws;
    __fp16* A16  = (__fp16*)ws;
    __fp16* R1h  = (__fp16*)(ws + 10240000);
    __fp16* QKVh = (__fp16*)(ws + 10240000);
    __fp16* Vh   = (__fp16*)(ws + 23040000);
    float*  R2Q  = ws + 33280000;
    f16x2* LKTH = (f16x2*)(ws + 43520000);       // 3584 slots
    float* GM   = ws + 43524096;
    float* DK   = GM + 64;
    f16x2* WTH  = (f16x2*)(DK + 576);            // 4096 slots
    f16x8* WAH  = (f16x8*)(DK + 576 + 4096);     // 4352 slots x 16B
    f16x8* WA2  = WAH + 4352;                    // 2560 slots
    f16x8* WA3  = WA2 + 2560;                    // 4608 slots

    dim3 b256(256);
    dim3 gLN(157, 4);
    dim3 gT16(13, 13, 16);

    prep_kernel<<<dim3(16), b256, 0, stream>>>(pconv_w, WTH);
    prepA_kernel<<<dim3(17), b256, 0, stream>>>(qkv_w, proj_p_w, attn_o_w, ffn_p_w, WAH);
    prepA2_kernel<<<dim3(10), b256, 0, stream>>>(proj_a_w, ffn_a_w, WA2);
    prepA3_kernel<<<dim3(18), b256, 0, stream>>>(conv_o_w, WA3);
    geo_kernel<<<dim3(14), b256, 0, stream>>>(plk, LKTH);

    // x = conv_ffn(LN(x)) [proj]
    ln_kernel<<<gLN, b256, 0, stream>>>(x_in, ln_proj_w, ln_proj_b, A16);
    convh_kernel<<<dim3(157, 2, 4), b256, 0, stream>>>(A16, WAH + 1536, proj_p_b,
                                                       nullptr, R1h, 64, 2, 128, 1, 0);
    dwgelu_kernel<<<gT16, b256, 0, stream>>>(R1h, proj_d_w, proj_d_b, Vh, 128);
    convh_kernel<<<dim3(157, 1, 4), b256, 0, stream>>>(Vh, WA2 + 0, proj_a_b,
                                                       X, nullptr, 128, 4, 64, 0, 0);

    // x = x + window_attention(LN(x))
    ln_kernel<<<gLN, b256, 0, stream>>>(X, ln_attn_w, ln_attn_b, A16);
    convh_kernel<<<dim3(157, 3, 4), b256, 0, stream>>>(A16, WAH + 0, qkv_b,
                                                       nullptr, QKVh, 64, 2, 192, 0, 0);
    winattn2_kernel<<<dim3(400, 8, 4), dim3(128), 0, stream>>>(QKVh, rpb, A16);
    convh_kernel<<<dim3(157, 1, 4), b256, 0, stream>>>(A16, WAH + 2560, attn_o_b,
                                                       X, nullptr, 64, 2, 64, 0, 1);

    for (int i = 0; i < 2; ++i) {
        conv1x1_mfma_kernel<<<dim3(157, 2, 4), b256, 0, stream>>>(X, WAH + 3072 + i * 640,
                                                                  ffn_p_b + i * 80, nullptr, R1h, 80, 1, 0);
        dwgelu_kernel<<<gT16, b256, 0, stream>>>(R1h, ffn_d_w + i * 720, ffn_d_b + i * 80, Vh, 80);
        convh_kernel<<<dim3(157, 1, 4), b256, 0, stream>>>(Vh, WA2 + 1024 + i * 768,
                                                           ffn_a_b + i * 64, Y, nullptr, 80, 3, 64, 0, 0);
        gmean_kernel<<<dim3(64), b256, 0, stream>>>(Y, GM);
        dynk_kernel<<<dim3(4), dim3(192), 0, stream>>>(GM, dwcp1_w + i * 128, dwcp1_b + i * 8,
                                                       dwcp2_w + i * 1152, dwcp2_b + i * 144, DK);
        lkconv_kernel<<<gT16, b256, 0, stream>>>(Y, LKTH, DK, R2Q);
        pconv_add_kernel<<<dim3(40, 4, 4), b256, 0, stream>>>(R2Q, Y, WTH + i * 2048, pconv_b + i * 64, X);
    }

    // x = conv3x3(LN(x)) + skip — MFMA implicit GEMM (f16 in), bias+skip fused
    ln_kernel<<<gLN, b256, 0, stream>>>(X, ln_out_w, ln_out_b, A16);
    conv3_mfma_kernel<<<dim3(157, 1, 4), b256, 0, stream>>>(A16, WA3, conv_o_b, x_in, X);
}